// Round 7
// baseline (739.119 us; speedup 1.0000x reference)
//
#include <hip/hip_runtime.h>
#include <hip/hip_bf16.h>

typedef __bf16 bf16x8 __attribute__((ext_vector_type(8)));
typedef float  f32x4  __attribute__((ext_vector_type(4)));

#define T_TOK 2048
#define DDIM  1024
#define EDIM  2048
#define NCHUNK 16
#define CKLEN  128

// ---------------------------------------------------------------- transpose
// dst[(c*dmul + doff)*R + r] = op(src[r*S + c]);  R,C multiples of 32.
// OP 0: plain cast. OP 1: softplus(v + bias[c]) clipped to [1e-3, 0.1].
// OP 2: silu(v).
template<int OP, typename TS, typename TD>
__global__ __launch_bounds__(256)
void transpose_kernel(const TS* __restrict__ src, TD* __restrict__ dst,
                      int R, int C, int S, const float* __restrict__ bias,
                      int dmul, int doff)
{
    __shared__ float tile[32][33];
    const int tc0 = blockIdx.x * 32, tr0 = blockIdx.y * 32;
    const int tx = threadIdx.x & 31, ty = threadIdx.x >> 5;
#pragma unroll
    for (int p = 0; p < 4; ++p) {
        int rl = ty + p * 8;
        tile[rl][tx] = (float)src[(size_t)(tr0 + rl) * S + tc0 + tx];
    }
    __syncthreads();
#pragma unroll
    for (int p = 0; p < 4; ++p) {
        int cl = ty + p * 8;
        float v = tile[tx][cl];
        int c = tc0 + cl, r = tr0 + tx;
        if (OP == 1) {
            v += bias[c];
            v = (v > 20.f) ? v : log1pf(__expf(v));
            v = fminf(fmaxf(v, 0.001f), 0.1f);
        } else if (OP == 2) {
            v = v / (1.f + __expf(-v));
        }
        dst[((size_t)c * dmul + doff) * R + r] = (TD)v;
    }
}

// ---------------------------------------------------------------- rmsnorm
__global__ __launch_bounds__(256)
void rmsnorm_kernel(const float* __restrict__ x, const float* __restrict__ w,
                    __bf16* __restrict__ out)
{
    const int row = blockIdx.x;
    const int t = threadIdx.x;
    float4 v = ((const float4*)(x + (size_t)row * DDIM))[t];
    float ss = v.x * v.x + v.y * v.y + v.z * v.z + v.w * v.w;
#pragma unroll
    for (int m = 32; m; m >>= 1) ss += __shfl_xor(ss, m);
    __shared__ float red[4];
    if ((t & 63) == 0) red[t >> 6] = ss;
    __syncthreads();
    float scale = rsqrtf((red[0] + red[1] + red[2] + red[3]) * (1.f / DDIM) + 1e-5f);
    float4 wv = ((const float4*)w)[t];
    __bf16* o = out + (size_t)row * DDIM + t * 4;
    o[0] = (__bf16)(v.x * scale * wv.x);
    o[1] = (__bf16)(v.y * scale * wv.y);
    o[2] = (__bf16)(v.z * scale * wv.z);
    o[3] = (__bf16)(v.w * scale * wv.w);
}

// ---------------------------------------------------------------- conv+silu
__global__ __launch_bounds__(256)
void conv_silu_kernel(const __bf16* __restrict__ xp, const float* __restrict__ W,
                      const float* __restrict__ b, __bf16* __restrict__ xc)
{
    int idx = blockIdx.x * 256 + threadIdx.x;     // over T*E
    int t = idx >> 11, e = idx & (EDIM - 1);
    float s = b[e];
#pragma unroll
    for (int k = 0; k < 4; ++k) {                 // SAME pad: taps t-1..t+2
        int tt = t - 1 + k;
        if (tt >= 0 && tt < T_TOK)
            s += (float)xp[(size_t)tt * (2 * EDIM) + e] * W[k * EDIM + e];
    }
    s = s / (1.f + __expf(-s));
    xc[idx] = (__bf16)s;
}

// ---------------------------------------------------------------- glu
__global__ __launch_bounds__(256)
void glu_kernel(const __bf16* __restrict__ gu, __bf16* __restrict__ outm)
{
    int idx = blockIdx.x * 256 + threadIdx.x;     // over T*I
    int t = idx >> 11, i = idx & 2047;
    float g = (float)gu[(size_t)t * 4096 + i];
    float u = (float)gu[(size_t)t * 4096 + 2048 + i];
    outm[idx] = (__bf16)(g / (1.f + __expf(-g)) * u);
}

// ---------------------------------------------------------------- scan
template<int CTRL, int ROWMASK>
__device__ __forceinline__ float dpp_add(float v)
{
    int y = __builtin_amdgcn_update_dpp(0, __builtin_bit_cast(int, v),
                                        CTRL, ROWMASK, 0xf, true);
    return v + __builtin_bit_cast(float, y);
}

// Wave layout for scan1/scan2: lane = (c,i), c = lane>>5 selects channel
// e+c of the wave's channel pair, lane holds states n = 2i, 2i+1.
// bc2 layout: bc2[t*128 + 4i] = {B[t,2i], C[t,2i], B[t,2i+1], C[t,2i+1]}.

struct Blk1 { float4 da, db; bf16x8 x8; float4 bcv[8]; };
struct Blk2 { float4 da, db; bf16x8 x8, z8; float4 bcv[8]; };

__device__ __forceinline__ void load1(Blk1& b, const float* dtrow,
                                      const __bf16* xrow, const float* bcp, int t0)
{
    b.da = *(const float4*)(dtrow + t0);
    b.db = *(const float4*)(dtrow + t0 + 4);
    b.x8 = *(const bf16x8*)(xrow + t0);
#pragma unroll
    for (int j = 0; j < 8; ++j)
        b.bcv[j] = *(const float4*)(bcp + (size_t)(t0 + j) * 128);
}

__device__ __forceinline__ void load2(Blk2& b, const float* dtrow, const __bf16* xrow,
                                      const __bf16* zrow, const float* bcp, int t0)
{
    b.da = *(const float4*)(dtrow + t0);
    b.db = *(const float4*)(dtrow + t0 + 4);
    b.x8 = *(const bf16x8*)(xrow + t0);
    b.z8 = *(const bf16x8*)(zrow + t0);
#pragma unroll
    for (int j = 0; j < 8; ++j)
        b.bcv[j] = *(const float4*)(bcp + (size_t)(t0 + j) * 128);
}

// Pass 1: per (e,chunk) compute local h_end (h0=0) and P = prod(dA)
//         (P computed as exp2(An' * sum(dt)) -- no per-step product).
__global__ __launch_bounds__(256, 3)
void scan1_kernel(const float* __restrict__ dtT, const __bf16* __restrict__ xcT,
                  const float* __restrict__ bc2, const float* __restrict__ A_log,
                  float* __restrict__ hend, float* __restrict__ dAp)
{
    const int lane = threadIdx.x & 63, wave = threadIdx.x >> 6;
    const int c = lane >> 5, i = lane & 31;
    const int ck = blockIdx.x & (NCHUNK - 1);
    const int e  = (blockIdx.x >> 4) * 8 + wave * 2 + c;
    float2 al = *(const float2*)(A_log + 2 * i);
    const float L2E = 1.44269504f;
    const float An0 = -__expf(al.x) * L2E;
    const float An1 = -__expf(al.y) * L2E;
    const float*  dtrow = dtT + (size_t)e * T_TOK + ck * CKLEN;
    const __bf16* xrow  = xcT + (size_t)e * T_TOK + ck * CKLEN;
    const float*  bcp   = bc2 + (size_t)(ck * CKLEN) * 128 + 4 * i;
    float h0 = 0.f, h1 = 0.f, D = 0.f;

    auto step = [&](const Blk1& b) {
        float dtv[8] = {b.da.x, b.da.y, b.da.z, b.da.w,
                        b.db.x, b.db.y, b.db.z, b.db.w};
#pragma unroll
        for (int j = 0; j < 8; ++j) {
            float u = dtv[j] * (float)b.x8[j];
            float dA0 = __builtin_amdgcn_exp2f(dtv[j] * An0);
            float dA1 = __builtin_amdgcn_exp2f(dtv[j] * An1);
            h0 = fmaf(dA0, h0, u * b.bcv[j].x);
            h1 = fmaf(dA1, h1, u * b.bcv[j].z);
            D += dtv[j];
        }
    };

    Blk1 bA, bB;
    load1(bA, dtrow, xrow, bcp, 0);
    load1(bB, dtrow, xrow, bcp, 8);
    __builtin_amdgcn_sched_barrier(0);
    for (int t0 = 0; t0 + 16 < CKLEN; t0 += 16) {
        step(bA);
        load1(bA, dtrow, xrow, bcp, t0 + 16);
        __builtin_amdgcn_sched_barrier(0);
        step(bB);
        load1(bB, dtrow, xrow, bcp, t0 + 24);
        __builtin_amdgcn_sched_barrier(0);
    }
    step(bA);
    step(bB);

    size_t idx = ((size_t)e * NCHUNK + ck) * 64 + 2 * i;
    *(float2*)(hend + idx) = make_float2(h0, h1);
    *(float2*)(dAp + idx)  = make_float2(__builtin_amdgcn_exp2f(An0 * D),
                                         __builtin_amdgcn_exp2f(An1 * D));
}

// Mid: serial scan over the chunk summaries -> true h_start per chunk.
__global__ __launch_bounds__(256)
void scan_mid_kernel(const float* __restrict__ hend, const float* __restrict__ dAp,
                     float* __restrict__ h0)
{
    int gid = blockIdx.x * 256 + threadIdx.x;     // over E*64
    int e = gid >> 6, n = gid & 63;
    float h = 0.f;
#pragma unroll
    for (int ck = 0; ck < NCHUNK; ++ck) {
        size_t idx = ((size_t)e * NCHUNK + ck) * 64 + n;
        h0[idx] = h;
        h = dAp[idx] * h + hend[idx];
    }
}

// Pass 2: re-run each chunk from its true h_start, emit y (gated by silu(z)).
__global__ __launch_bounds__(256, 3)
void scan2_kernel(const float* __restrict__ dtT, const __bf16* __restrict__ xcT,
                  const __bf16* __restrict__ szT, const float* __restrict__ bc2,
                  const float* __restrict__ A_log, const float* __restrict__ h0s,
                  __bf16* __restrict__ yT)
{
    const int lane = threadIdx.x & 63, wave = threadIdx.x >> 6;
    const int c = lane >> 5, i = lane & 31;
    const int ck = blockIdx.x & (NCHUNK - 1);
    const int e  = (blockIdx.x >> 4) * 8 + wave * 2 + c;
    float2 al = *(const float2*)(A_log + 2 * i);
    const float L2E = 1.44269504f;
    const float An0 = -__expf(al.x) * L2E;
    const float An1 = -__expf(al.y) * L2E;
    const size_t base = (size_t)e * T_TOK + ck * CKLEN;
    const float*  dtrow = dtT + base;
    const __bf16* xrow  = xcT + base;
    const __bf16* zrow  = szT + base;
    __bf16*       yrow  = yT + base;
    const float*  bcp   = bc2 + (size_t)(ck * CKLEN) * 128 + 4 * i;
    float2 hh = *(const float2*)(h0s + ((size_t)e * NCHUNK + ck) * 64 + 2 * i);
    float h0 = hh.x, h1 = hh.y;
    float ysave = 0.f;

    auto step = [&](const Blk2& b, int t0) {
        float dtv[8] = {b.da.x, b.da.y, b.da.z, b.da.w,
                        b.db.x, b.db.y, b.db.z, b.db.w};
#pragma unroll
        for (int j = 0; j < 8; ++j) {
            float u = dtv[j] * (float)b.x8[j];
            float dA0 = __builtin_amdgcn_exp2f(dtv[j] * An0);
            float dA1 = __builtin_amdgcn_exp2f(dtv[j] * An1);
            h0 = fmaf(dA0, h0, u * b.bcv[j].x);
            h1 = fmaf(dA1, h1, u * b.bcv[j].z);
            float p = fmaf(h1, b.bcv[j].w, h0 * b.bcv[j].y);  // h0*C0 + h1*C1
            p *= (float)b.z8[j];                               // gate with silu(z)
            // 32-lane tree per half (5 steps, both channels at once)
            p = dpp_add<0x111, 0xf>(p);   // row_shr:1
            p = dpp_add<0x112, 0xf>(p);   // row_shr:2
            p = dpp_add<0x114, 0xf>(p);   // row_shr:4
            p = dpp_add<0x118, 0xf>(p);   // row_shr:8
            p = dpp_add<0x142, 0xa>(p);   // row_bcast:15 -> rows 1,3
            int pi = __builtin_bit_cast(int, p);
            float totA = __builtin_bit_cast(float, __builtin_amdgcn_readlane(pi, 31));
            float totB = __builtin_bit_cast(float, __builtin_amdgcn_readlane(pi, 63));
            float tot = (c == 0) ? totA : totB;   // pick this lane-half's channel
            int t31 = (t0 + j) & 31;
            ysave = (t31 == i) ? tot : ysave;     // bank per-t result at lane i==t
            if (t31 == 31)
                yrow[(t0 + j) - 31 + i] = (__bf16)ysave;
        }
    };

    Blk2 bA, bB;
    load2(bA, dtrow, xrow, zrow, bcp, 0);
    load2(bB, dtrow, xrow, zrow, bcp, 8);
    __builtin_amdgcn_sched_barrier(0);
    for (int t0 = 0; t0 + 16 < CKLEN; t0 += 16) {
        step(bA, t0);
        load2(bA, dtrow, xrow, zrow, bcp, t0 + 16);
        __builtin_amdgcn_sched_barrier(0);
        step(bB, t0 + 8);
        load2(bB, dtrow, xrow, zrow, bcp, t0 + 24);
        __builtin_amdgcn_sched_barrier(0);
    }
    step(bA, CKLEN - 16);
    step(bB, CKLEN - 8);
}

// ---------------------------------------------------------------- GEMM
// C[M,N] = A[M,K] @ Bt[N,K]^T.  M,N mult of 128, K mult of 32.
// EPI 0: f32 store. EPI 1: bf16 store. EPI 2: f32 store of acc + res.
template<int EPI>
__global__ __launch_bounds__(256)
void gemm_kernel(const __bf16* __restrict__ A, const __bf16* __restrict__ Bt,
                 void* __restrict__ Cout, const float* __restrict__ res,
                 int M, int N, int K)
{
    __shared__ bf16x8 sA[8 * 64];   // fragment-shuffled: [fm][lane] 16B each
    __shared__ bf16x8 sB[8 * 64];
    const int t = threadIdx.x;
    const int wave = t >> 6, lane = t & 63;
    const int brow = blockIdx.y * 128, bcol = blockIdx.x * 128;
    const int wr = (wave >> 1) * 64, wc = (wave & 1) * 64;
    f32x4 acc[4][4] = {};

    for (int k0 = 0; k0 < K; k0 += 32) {
        __syncthreads();
#pragma unroll
        for (int p = 0; p < 2; ++p) {
            int idx = (p * 256 + t) * 8;
            int r = idx >> 5;          // tile row 0..127
            int kk = idx & 31;         // 0,8,16,24
            bf16x8 va = *(const bf16x8*)(A + (size_t)(brow + r) * K + k0 + kk);
            bf16x8 vb = *(const bf16x8*)(Bt + (size_t)(bcol + r) * K + k0 + kk);
            int l = (r & 15) + (kk >> 3) * 16;   // dest lane within fragment
            sA[(r >> 4) * 64 + l] = va;
            sB[(r >> 4) * 64 + l] = vb;
        }
        __syncthreads();
        bf16x8 af[4], bg[4];
#pragma unroll
        for (int m = 0; m < 4; ++m) af[m] = sA[((wr >> 4) + m) * 64 + lane];
#pragma unroll
        for (int n = 0; n < 4; ++n) bg[n] = sB[((wc >> 4) + n) * 64 + lane];
#pragma unroll
        for (int m = 0; m < 4; ++m)
#pragma unroll
            for (int n = 0; n < 4; ++n)
                acc[m][n] = __builtin_amdgcn_mfma_f32_16x16x32_bf16(
                    af[m], bg[n], acc[m][n], 0, 0, 0);
    }

    const int c_l = lane & 15, r_l = (lane >> 4) * 4;
#pragma unroll
    for (int m = 0; m < 4; ++m) {
#pragma unroll
        for (int n = 0; n < 4; ++n) {
            int row = brow + wr + m * 16 + r_l;
            int col = bcol + wc + n * 16 + c_l;
#pragma unroll
            for (int i = 0; i < 4; ++i) {
                float v = acc[m][n][i];
                size_t off = (size_t)(row + i) * N + col;
                if (EPI == 0)      ((float*)Cout)[off] = v;
                else if (EPI == 1) ((__bf16*)Cout)[off] = (__bf16)v;
                else               ((float*)Cout)[off] = v + res[off];
            }
        }
    }
}

// ---------------------------------------------------------------- launch
extern "C" void kernel_launch(void* const* d_in, const int* in_sizes, int n_in,
                              void* d_out, int out_size, void* d_ws, size_t ws_size,
                              hipStream_t stream)
{
    (void)in_sizes; (void)n_in; (void)out_size; (void)ws_size;
    const float* x     = (const float*)d_in[0];
    const float* inw   = (const float*)d_in[1];
    const float* ffnw  = (const float*)d_in[2];
    const float* inpW  = (const float*)d_in[3];
    const float* convW = (const float*)d_in[4];
    const float* convB = (const float*)d_in[5];
    const float* dtW   = (const float*)d_in[6];
    const float* dtB   = (const float*)d_in[7];
    const float* BW    = (const float*)d_in[8];
    const float* CW    = (const float*)d_in[9];
    const float* Alog  = (const float*)d_in[10];
    const float* outpW = (const float*)d_in[11];
    const float* gateW = (const float*)d_in[12];
    const float* upW   = (const float*)d_in[13];
    const float* downW = (const float*)d_in[14];
    float* out = (float*)d_out;

    char* p = (char*)d_ws;
    auto alloc = [&](size_t n) { char* q = p; p += (n + 255) & ~(size_t)255; return q; };
    __bf16* wt_inproj = (__bf16*)alloc(4096ull * 1024 * 2);
    __bf16* wt_dt     = (__bf16*)alloc(2048ull * 2048 * 2);
    __bf16* wt_bc     = (__bf16*)alloc(128ull * 2048 * 2);   // interleaved {B,C} rows
    __bf16* wt_outp   = (__bf16*)alloc(1024ull * 2048 * 2);
    __bf16* wt_gu     = (__bf16*)alloc(4096ull * 1024 * 2);
    __bf16* wt_down   = (__bf16*)alloc(1024ull * 2048 * 2);
    __bf16* normed    = (__bf16*)alloc(2048ull * 1024 * 2);  // reused as n2
    __bf16* xp        = (__bf16*)alloc(2048ull * 4096 * 2);  // reused: h0 plane + gu
    __bf16* xc        = (__bf16*)alloc(2048ull * 2048 * 2);  // reused as y
    float*  dt_pre    = (float*)alloc(2048ull * 2048 * 4);   // reused: hend/dAp + ffnmid
    float*  bc        = (float*)alloc(2048ull * 128 * 4);
    float*  dtT       = (float*)alloc(2048ull * 2048 * 4);
    __bf16* xcT       = (__bf16*)alloc(2048ull * 2048 * 2);
    __bf16* szT       = (__bf16*)alloc(2048ull * 2048 * 2);
    __bf16* yT        = (__bf16*)alloc(2048ull * 2048 * 2);
    float*  x2        = (float*)alloc(2048ull * 1024 * 4);

    dim3 B256(256);
    // weight prep (f32 -> bf16, transposed to [N][K])
    transpose_kernel<0, float, __bf16><<<dim3(128, 32), B256, 0, stream>>>(inpW, wt_inproj, 1024, 4096, 4096, nullptr, 1, 0);
    transpose_kernel<0, float, __bf16><<<dim3(64, 64), B256, 0, stream>>>(dtW, wt_dt, 2048, 2048, 2048, nullptr, 1, 0);
    transpose_kernel<0, float, __bf16><<<dim3(2, 64), B256, 0, stream>>>(BW, wt_bc, 2048, 64, 64, nullptr, 2, 0);
    transpose_kernel<0, float, __bf16><<<dim3(2, 64), B256, 0, stream>>>(CW, wt_bc, 2048, 64, 64, nullptr, 2, 1);
    transpose_kernel<0, float, __bf16><<<dim3(32, 64), B256, 0, stream>>>(outpW, wt_outp, 2048, 1024, 1024, nullptr, 1, 0);
    transpose_kernel<0, float, __bf16><<<dim3(64, 32), B256, 0, stream>>>(gateW, wt_gu, 1024, 2048, 2048, nullptr, 1, 0);
    transpose_kernel<0, float, __bf16><<<dim3(64, 32), B256, 0, stream>>>(upW, wt_gu + 2048ull * 1024, 1024, 2048, 2048, nullptr, 1, 0);
    transpose_kernel<0, float, __bf16><<<dim3(32, 64), B256, 0, stream>>>(downW, wt_down, 2048, 1024, 1024, nullptr, 1, 0);

    // normed = rmsnorm(x, inw)
    rmsnorm_kernel<<<dim3(2048), B256, 0, stream>>>(x, inw, normed);
    // xp = normed @ in_proj  (bf16)
    gemm_kernel<1><<<dim3(32, 16), B256, 0, stream>>>(normed, wt_inproj, xp, nullptr, 2048, 4096, 1024);
    // xc = silu(conv(xp[:, :E]) + b)
    conv_silu_kernel<<<dim3(T_TOK * EDIM / 256), B256, 0, stream>>>(xp, convW, convB, xc);
    // dt_pre = xc @ dt_W
    gemm_kernel<0><<<dim3(16, 16), B256, 0, stream>>>(xc, wt_dt, dt_pre, nullptr, 2048, 2048, 2048);
    // bc = xc @ [B|C interleaved]  (bc[t][2n]=B_n, bc[t][2n+1]=C_n)
    gemm_kernel<0><<<dim3(1, 16), B256, 0, stream>>>(xc, wt_bc, bc, nullptr, 2048, 128, 2048);
    // channel-major transposes for the scan
    transpose_kernel<1, float, float><<<dim3(64, 64), B256, 0, stream>>>(dt_pre, dtT, 2048, 2048, 2048, dtB, 1, 0);
    transpose_kernel<0, __bf16, __bf16><<<dim3(64, 64), B256, 0, stream>>>(xc, xcT, 2048, 2048, 2048, nullptr, 1, 0);
    transpose_kernel<2, __bf16, __bf16><<<dim3(64, 64), B256, 0, stream>>>(xp + 2048, szT, 2048, 2048, 4096, nullptr, 1, 0);

    // chunked SSM scan.  dt_pre region is free now (dtT holds softplus'd dt);
    // xp's contents are dead after the szT transpose, reuse its head for h0.
    float* hend = dt_pre;                         // 8 MB (E*16*64 f32)
    float* dAp  = dt_pre + 2048ull * NCHUNK * 64; // 8 MB
    float* h0   = (float*)xp;                     // 8 MB (xp reused as gu only later)
    scan1_kernel<<<dim3(4096), B256, 0, stream>>>(dtT, xcT, bc, Alog, hend, dAp);
    scan_mid_kernel<<<dim3(512), B256, 0, stream>>>(hend, dAp, h0);
    scan2_kernel<<<dim3(4096), B256, 0, stream>>>(dtT, xcT, szT, bc, Alog, h0, yT);

    // y = yT^T  (t-major, into xc buffer)
    __bf16* y = xc;
    transpose_kernel<0, __bf16, __bf16><<<dim3(64, 64), B256, 0, stream>>>(yT, y, 2048, 2048, 2048, nullptr, 1, 0);
    // x2 = x + y @ out_proj
    gemm_kernel<2><<<dim3(8, 16), B256, 0, stream>>>(y, wt_outp, x2, x, 2048, 1024, 2048);
    // n2 = rmsnorm(x2, ffnw)
    rmsnorm_kernel<<<dim3(2048), B256, 0, stream>>>(x2, ffnw, normed);
    // gu = n2 @ [gate|up]
    __bf16* gu = xp;
    gemm_kernel<1><<<dim3(32, 16), B256, 0, stream>>>(normed, wt_gu, gu, nullptr, 2048, 4096, 1024);
    // ffnmid = silu(gate)*up
    __bf16* ffnmid = (__bf16*)dt_pre;
    glu_kernel<<<dim3(T_TOK * 2048 / 256), B256, 0, stream>>>(gu, ffnmid);
    // out = x2 + ffnmid @ down
    gemm_kernel<2><<<dim3(8, 16), B256, 0, stream>>>(ffnmid, wt_down, out, x2, 2048, 1024, 2048);
}

// Round 8
// 543.245 us; speedup vs baseline: 1.3606x; 1.3606x over previous
//
#include <hip/hip_runtime.h>
#include <hip/hip_bf16.h>

typedef __bf16 bf16x8 __attribute__((ext_vector_type(8)));
typedef float  f32x4  __attribute__((ext_vector_type(4)));

#define T_TOK 2048
#define DDIM  1024
#define EDIM  2048
#define NCHUNK 32
#define CKLEN  64

// ---------------------------------------------------------------- transpose
// dst[(c*dmul + doff)*R + r] = op(src[r*S + c]);  R,C multiples of 32.
// OP 0: plain cast. OP 1: softplus(v + bias[c]) clipped to [1e-3, 0.1].
// OP 2: silu(v).
template<int OP, typename TS, typename TD>
__global__ __launch_bounds__(256)
void transpose_kernel(const TS* __restrict__ src, TD* __restrict__ dst,
                      int R, int C, int S, const float* __restrict__ bias,
                      int dmul, int doff)
{
    __shared__ float tile[32][33];
    const int tc0 = blockIdx.x * 32, tr0 = blockIdx.y * 32;
    const int tx = threadIdx.x & 31, ty = threadIdx.x >> 5;
#pragma unroll
    for (int p = 0; p < 4; ++p) {
        int rl = ty + p * 8;
        tile[rl][tx] = (float)src[(size_t)(tr0 + rl) * S + tc0 + tx];
    }
    __syncthreads();
#pragma unroll
    for (int p = 0; p < 4; ++p) {
        int cl = ty + p * 8;
        float v = tile[tx][cl];
        int c = tc0 + cl, r = tr0 + tx;
        if (OP == 1) {
            v += bias[c];
            v = (v > 20.f) ? v : log1pf(__expf(v));
            v = fminf(fmaxf(v, 0.001f), 0.1f);
        } else if (OP == 2) {
            v = v / (1.f + __expf(-v));
        }
        dst[((size_t)c * dmul + doff) * R + r] = (TD)v;
    }
}

// ---------------------------------------------------------------- rmsnorm
__global__ __launch_bounds__(256)
void rmsnorm_kernel(const float* __restrict__ x, const float* __restrict__ w,
                    __bf16* __restrict__ out)
{
    const int row = blockIdx.x;
    const int t = threadIdx.x;
    float4 v = ((const float4*)(x + (size_t)row * DDIM))[t];
    float ss = v.x * v.x + v.y * v.y + v.z * v.z + v.w * v.w;
#pragma unroll
    for (int m = 32; m; m >>= 1) ss += __shfl_xor(ss, m);
    __shared__ float red[4];
    if ((t & 63) == 0) red[t >> 6] = ss;
    __syncthreads();
    float scale = rsqrtf((red[0] + red[1] + red[2] + red[3]) * (1.f / DDIM) + 1e-5f);
    float4 wv = ((const float4*)w)[t];
    __bf16* o = out + (size_t)row * DDIM + t * 4;
    o[0] = (__bf16)(v.x * scale * wv.x);
    o[1] = (__bf16)(v.y * scale * wv.y);
    o[2] = (__bf16)(v.z * scale * wv.z);
    o[3] = (__bf16)(v.w * scale * wv.w);
}

// ---------------------------------------------------------------- conv+silu
__global__ __launch_bounds__(256)
void conv_silu_kernel(const __bf16* __restrict__ xp, const float* __restrict__ W,
                      const float* __restrict__ b, __bf16* __restrict__ xc)
{
    int idx = blockIdx.x * 256 + threadIdx.x;     // over T*E
    int t = idx >> 11, e = idx & (EDIM - 1);
    float s = b[e];
#pragma unroll
    for (int k = 0; k < 4; ++k) {                 // SAME pad: taps t-1..t+2
        int tt = t - 1 + k;
        if (tt >= 0 && tt < T_TOK)
            s += (float)xp[(size_t)tt * (2 * EDIM) + e] * W[k * EDIM + e];
    }
    s = s / (1.f + __expf(-s));
    xc[idx] = (__bf16)s;
}

// ---------------------------------------------------------------- glu
__global__ __launch_bounds__(256)
void glu_kernel(const __bf16* __restrict__ gu, __bf16* __restrict__ outm)
{
    int idx = blockIdx.x * 256 + threadIdx.x;     // over T*I
    int t = idx >> 11, i = idx & 2047;
    float g = (float)gu[(size_t)t * 4096 + i];
    float u = (float)gu[(size_t)t * 4096 + 2048 + i];
    outm[idx] = (__bf16)(g / (1.f + __expf(-g)) * u);
}

// ---------------------------------------------------------------- scan
template<int CTRL, int ROWMASK>
__device__ __forceinline__ float dpp_add(float v)
{
    int y = __builtin_amdgcn_update_dpp(0, __builtin_bit_cast(int, v),
                                        CTRL, ROWMASK, 0xf, true);
    return v + __builtin_bit_cast(float, y);
}

// Block = 512 threads = 8 waves, handling ONE chunk ck and 16 channels.
// Wave w: channels eg+2w (lanes 0-31, c=0) and eg+2w+1 (lanes 32-63, c=1).
// Lane holds states n = 2i, 2i+1.
// bc2 layout: bc2[t*128 + 4i] = {B[t,2i], C[t,2i], B[t,2i+1], C[t,2i+1]}.
// All operands staged in LDS: inner loop is pure LDS+VALU (no vmcnt).

// Pass 1: per (e,chunk) local h_end (h0=0) and P = exp2(An' * sum dt).
__global__ __launch_bounds__(512)
void scan1_kernel(const float* __restrict__ dtT, const __bf16* __restrict__ xcT,
                  const float* __restrict__ bc2, const float* __restrict__ A_log,
                  float* __restrict__ hend, float* __restrict__ dAp)
{
    __shared__ float  s_bc[CKLEN * 128];   // 32 KB
    __shared__ float  s_dt[16][CKLEN];     // 4 KB
    __shared__ __bf16 s_x[16][CKLEN];      // 2 KB
    const int tid = threadIdx.x;
    const int lane = tid & 63, w = tid >> 6;
    const int c = lane >> 5, i = lane & 31;
    const int ck = blockIdx.x & (NCHUNK - 1);
    const int eg = (blockIdx.x >> 5) * 16;

    // ---- stage (coalesced, independent loads -> full MLP)
    {
        const float4* sb = (const float4*)(bc2 + (size_t)ck * CKLEN * 128);
        float4* db = (float4*)s_bc;
#pragma unroll
        for (int r = 0; r < 4; ++r) db[r * 512 + tid] = sb[r * 512 + tid];
        if (tid < 256) {
            int ch = tid >> 4, k = tid & 15;
            *((float4*)&s_dt[ch][0] + k) =
                *(const float4*)(dtT + (size_t)(eg + ch) * T_TOK + ck * CKLEN + 4 * k);
        } else if (tid < 384) {
            int q = tid - 256, ch = q >> 3, k = q & 7;
            *((bf16x8*)&s_x[ch][0] + k) =
                *(const bf16x8*)(xcT + (size_t)(eg + ch) * T_TOK + ck * CKLEN + 8 * k);
        }
    }
    __syncthreads();

    const int ch = 2 * w + c;
    float2 al = *(const float2*)(A_log + 2 * i);
    const float L2E = 1.44269504f;
    const float An0 = -__expf(al.x) * L2E;
    const float An1 = -__expf(al.y) * L2E;
    float h0 = 0.f, h1 = 0.f, D = 0.f;

#pragma unroll 2
    for (int t0 = 0; t0 < CKLEN; t0 += 8) {
        float4 da = *(const float4*)&s_dt[ch][t0];
        float4 db = *(const float4*)&s_dt[ch][t0 + 4];
        bf16x8 x8 = *(const bf16x8*)&s_x[ch][t0];
        float dtv[8] = {da.x, da.y, da.z, da.w, db.x, db.y, db.z, db.w};
#pragma unroll
        for (int j = 0; j < 8; ++j) {
            float4 bcv = *(const float4*)&s_bc[(t0 + j) * 128 + 4 * i];
            float u = dtv[j] * (float)x8[j];
            float dA0 = __builtin_amdgcn_exp2f(dtv[j] * An0);
            float dA1 = __builtin_amdgcn_exp2f(dtv[j] * An1);
            h0 = fmaf(dA0, h0, u * bcv.x);
            h1 = fmaf(dA1, h1, u * bcv.z);
            D += dtv[j];
        }
    }
    const int e = eg + ch;
    size_t idx = ((size_t)e * NCHUNK + ck) * 64 + 2 * i;
    *(float2*)(hend + idx) = make_float2(h0, h1);
    *(float2*)(dAp + idx)  = make_float2(__builtin_amdgcn_exp2f(An0 * D),
                                         __builtin_amdgcn_exp2f(An1 * D));
}

// Mid: serial scan over chunk summaries -> h_start per chunk, IN PLACE over hend.
__global__ __launch_bounds__(256)
void scan_mid_kernel(float* __restrict__ hend_h0, const float* __restrict__ dAp)
{
    int gid = blockIdx.x * 256 + threadIdx.x;     // over E*64
    int e = gid >> 6, n = gid & 63;
    float h = 0.f;
#pragma unroll
    for (int ck = 0; ck < NCHUNK; ++ck) {
        size_t idx = ((size_t)e * NCHUNK + ck) * 64 + n;
        float he = hend_h0[idx];
        float P  = dAp[idx];
        hend_h0[idx] = h;                         // h0 for this chunk
        h = P * h + he;
    }
}

// Pass 2: re-run each chunk from its true h_start, emit y (gated by silu(z)).
__global__ __launch_bounds__(512)
void scan2_kernel(const float* __restrict__ dtT, const __bf16* __restrict__ xcT,
                  const __bf16* __restrict__ szT, const float* __restrict__ bc2,
                  const float* __restrict__ A_log, const float* __restrict__ h0s,
                  __bf16* __restrict__ yT)
{
    __shared__ float  s_bc[CKLEN * 128];   // 32 KB
    __shared__ float  s_dt[16][CKLEN];     // 4 KB
    __shared__ __bf16 s_x[16][CKLEN];      // 2 KB
    __shared__ __bf16 s_z[16][CKLEN];      // 2 KB
    const int tid = threadIdx.x;
    const int lane = tid & 63, w = tid >> 6;
    const int c = lane >> 5, i = lane & 31;
    const int ck = blockIdx.x & (NCHUNK - 1);
    const int eg = (blockIdx.x >> 5) * 16;

    // ---- stage
    {
        const float4* sb = (const float4*)(bc2 + (size_t)ck * CKLEN * 128);
        float4* db = (float4*)s_bc;
#pragma unroll
        for (int r = 0; r < 4; ++r) db[r * 512 + tid] = sb[r * 512 + tid];
        if (tid < 256) {
            int ch = tid >> 4, k = tid & 15;
            *((float4*)&s_dt[ch][0] + k) =
                *(const float4*)(dtT + (size_t)(eg + ch) * T_TOK + ck * CKLEN + 4 * k);
        } else if (tid < 384) {
            int q = tid - 256, ch = q >> 3, k = q & 7;
            *((bf16x8*)&s_x[ch][0] + k) =
                *(const bf16x8*)(xcT + (size_t)(eg + ch) * T_TOK + ck * CKLEN + 8 * k);
        } else {
            int q = tid - 384, ch = q >> 3, k = q & 7;
            *((bf16x8*)&s_z[ch][0] + k) =
                *(const bf16x8*)(szT + (size_t)(eg + ch) * T_TOK + ck * CKLEN + 8 * k);
        }
    }
    __syncthreads();

    const int ch = 2 * w + c;
    const int e = eg + ch;
    float2 al = *(const float2*)(A_log + 2 * i);
    const float L2E = 1.44269504f;
    const float An0 = -__expf(al.x) * L2E;
    const float An1 = -__expf(al.y) * L2E;
    __bf16* yrow = yT + (size_t)e * T_TOK + ck * CKLEN;
    float2 hh = *(const float2*)(h0s + ((size_t)e * NCHUNK + ck) * 64 + 2 * i);
    float h0 = hh.x, h1 = hh.y;
    float ysave = 0.f;

#pragma unroll 2
    for (int t0 = 0; t0 < CKLEN; t0 += 8) {
        float4 da = *(const float4*)&s_dt[ch][t0];
        float4 db = *(const float4*)&s_dt[ch][t0 + 4];
        bf16x8 x8 = *(const bf16x8*)&s_x[ch][t0];
        bf16x8 z8 = *(const bf16x8*)&s_z[ch][t0];
        float dtv[8] = {da.x, da.y, da.z, da.w, db.x, db.y, db.z, db.w};
#pragma unroll
        for (int j = 0; j < 8; ++j) {
            float4 bcv = *(const float4*)&s_bc[(t0 + j) * 128 + 4 * i];
            float u = dtv[j] * (float)x8[j];
            float dA0 = __builtin_amdgcn_exp2f(dtv[j] * An0);
            float dA1 = __builtin_amdgcn_exp2f(dtv[j] * An1);
            h0 = fmaf(dA0, h0, u * bcv.x);
            h1 = fmaf(dA1, h1, u * bcv.z);
            float p = fmaf(h1, bcv.w, h0 * bcv.y);   // h0*C0 + h1*C1
            p *= (float)z8[j];                        // gate with silu(z)
            // 32-lane tree per half (5 steps, both channels at once)
            p = dpp_add<0x111, 0xf>(p);   // row_shr:1
            p = dpp_add<0x112, 0xf>(p);   // row_shr:2
            p = dpp_add<0x114, 0xf>(p);   // row_shr:4
            p = dpp_add<0x118, 0xf>(p);   // row_shr:8
            p = dpp_add<0x142, 0xa>(p);   // row_bcast:15 -> rows 1,3
            int pi = __builtin_bit_cast(int, p);
            float totA = __builtin_bit_cast(float, __builtin_amdgcn_readlane(pi, 31));
            float totB = __builtin_bit_cast(float, __builtin_amdgcn_readlane(pi, 63));
            float tot = (c == 0) ? totA : totB;   // pick this lane-half's channel
            int t31 = (t0 + j) & 31;
            ysave = (t31 == i) ? tot : ysave;     // bank per-t result at lane i==t
            if (t31 == 31)
                yrow[(t0 + j) - 31 + i] = (__bf16)ysave;
        }
    }
}

// ---------------------------------------------------------------- GEMM
// C[M,N] = A[M,K] @ Bt[N,K]^T.  M,N mult of 128, K mult of 32.
// EPI 0: f32 store. EPI 1: bf16 store. EPI 2: f32 store of acc + res.
template<int EPI>
__global__ __launch_bounds__(256)
void gemm_kernel(const __bf16* __restrict__ A, const __bf16* __restrict__ Bt,
                 void* __restrict__ Cout, const float* __restrict__ res,
                 int M, int N, int K)
{
    __shared__ bf16x8 sA[8 * 64];   // fragment-shuffled: [fm][lane] 16B each
    __shared__ bf16x8 sB[8 * 64];
    const int t = threadIdx.x;
    const int wave = t >> 6, lane = t & 63;
    const int brow = blockIdx.y * 128, bcol = blockIdx.x * 128;
    const int wr = (wave >> 1) * 64, wc = (wave & 1) * 64;
    f32x4 acc[4][4] = {};

    for (int k0 = 0; k0 < K; k0 += 32) {
        __syncthreads();
#pragma unroll
        for (int p = 0; p < 2; ++p) {
            int idx = (p * 256 + t) * 8;
            int r = idx >> 5;          // tile row 0..127
            int kk = idx & 31;         // 0,8,16,24
            bf16x8 va = *(const bf16x8*)(A + (size_t)(brow + r) * K + k0 + kk);
            bf16x8 vb = *(const bf16x8*)(Bt + (size_t)(bcol + r) * K + k0 + kk);
            int l = (r & 15) + (kk >> 3) * 16;   // dest lane within fragment
            sA[(r >> 4) * 64 + l] = va;
            sB[(r >> 4) * 64 + l] = vb;
        }
        __syncthreads();
        bf16x8 af[4], bg[4];
#pragma unroll
        for (int m = 0; m < 4; ++m) af[m] = sA[((wr >> 4) + m) * 64 + lane];
#pragma unroll
        for (int n = 0; n < 4; ++n) bg[n] = sB[((wc >> 4) + n) * 64 + lane];
#pragma unroll
        for (int m = 0; m < 4; ++m)
#pragma unroll
            for (int n = 0; n < 4; ++n)
                acc[m][n] = __builtin_amdgcn_mfma_f32_16x16x32_bf16(
                    af[m], bg[n], acc[m][n], 0, 0, 0);
    }

    const int c_l = lane & 15, r_l = (lane >> 4) * 4;
#pragma unroll
    for (int m = 0; m < 4; ++m) {
#pragma unroll
        for (int n = 0; n < 4; ++n) {
            int row = brow + wr + m * 16 + r_l;
            int col = bcol + wc + n * 16 + c_l;
#pragma unroll
            for (int i = 0; i < 4; ++i) {
                float v = acc[m][n][i];
                size_t off = (size_t)(row + i) * N + col;
                if (EPI == 0)      ((float*)Cout)[off] = v;
                else if (EPI == 1) ((__bf16*)Cout)[off] = (__bf16)v;
                else               ((float*)Cout)[off] = v + res[off];
            }
        }
    }
}

// ---------------------------------------------------------------- launch
extern "C" void kernel_launch(void* const* d_in, const int* in_sizes, int n_in,
                              void* d_out, int out_size, void* d_ws, size_t ws_size,
                              hipStream_t stream)
{
    (void)in_sizes; (void)n_in; (void)out_size; (void)ws_size;
    const float* x     = (const float*)d_in[0];
    const float* inw   = (const float*)d_in[1];
    const float* ffnw  = (const float*)d_in[2];
    const float* inpW  = (const float*)d_in[3];
    const float* convW = (const float*)d_in[4];
    const float* convB = (const float*)d_in[5];
    const float* dtW   = (const float*)d_in[6];
    const float* dtB   = (const float*)d_in[7];
    const float* BW    = (const float*)d_in[8];
    const float* CW    = (const float*)d_in[9];
    const float* Alog  = (const float*)d_in[10];
    const float* outpW = (const float*)d_in[11];
    const float* gateW = (const float*)d_in[12];
    const float* upW   = (const float*)d_in[13];
    const float* downW = (const float*)d_in[14];
    float* out = (float*)d_out;

    char* p = (char*)d_ws;
    auto alloc = [&](size_t n) { char* q = p; p += (n + 255) & ~(size_t)255; return q; };
    __bf16* wt_inproj = (__bf16*)alloc(4096ull * 1024 * 2);
    __bf16* wt_dt     = (__bf16*)alloc(2048ull * 2048 * 2);
    __bf16* wt_bc     = (__bf16*)alloc(128ull * 2048 * 2);   // interleaved {B,C} rows
    __bf16* wt_outp   = (__bf16*)alloc(1024ull * 2048 * 2);
    __bf16* wt_gu     = (__bf16*)alloc(4096ull * 1024 * 2);
    __bf16* wt_down   = (__bf16*)alloc(1024ull * 2048 * 2);
    __bf16* normed    = (__bf16*)alloc(2048ull * 1024 * 2);  // reused as n2
    __bf16* xp        = (__bf16*)alloc(2048ull * 4096 * 2);  // reused: dAp + gu
    __bf16* xc        = (__bf16*)alloc(2048ull * 2048 * 2);  // reused as y
    float*  dt_pre    = (float*)alloc(2048ull * 2048 * 4);   // reused: hend/h0 + ffnmid
    float*  bc        = (float*)alloc(2048ull * 128 * 4);
    float*  dtT       = (float*)alloc(2048ull * 2048 * 4);
    __bf16* xcT       = (__bf16*)alloc(2048ull * 2048 * 2);
    __bf16* szT       = (__bf16*)alloc(2048ull * 2048 * 2);
    __bf16* yT        = (__bf16*)alloc(2048ull * 2048 * 2);
    float*  x2        = (float*)alloc(2048ull * 1024 * 4);

    dim3 B256(256);
    // weight prep (f32 -> bf16, transposed to [N][K])
    transpose_kernel<0, float, __bf16><<<dim3(128, 32), B256, 0, stream>>>(inpW, wt_inproj, 1024, 4096, 4096, nullptr, 1, 0);
    transpose_kernel<0, float, __bf16><<<dim3(64, 64), B256, 0, stream>>>(dtW, wt_dt, 2048, 2048, 2048, nullptr, 1, 0);
    transpose_kernel<0, float, __bf16><<<dim3(2, 64), B256, 0, stream>>>(BW, wt_bc, 2048, 64, 64, nullptr, 2, 0);
    transpose_kernel<0, float, __bf16><<<dim3(2, 64), B256, 0, stream>>>(CW, wt_bc, 2048, 64, 64, nullptr, 2, 1);
    transpose_kernel<0, float, __bf16><<<dim3(32, 64), B256, 0, stream>>>(outpW, wt_outp, 2048, 1024, 1024, nullptr, 1, 0);
    transpose_kernel<0, float, __bf16><<<dim3(64, 32), B256, 0, stream>>>(gateW, wt_gu, 1024, 2048, 2048, nullptr, 1, 0);
    transpose_kernel<0, float, __bf16><<<dim3(64, 32), B256, 0, stream>>>(upW, wt_gu + 2048ull * 1024, 1024, 2048, 2048, nullptr, 1, 0);
    transpose_kernel<0, float, __bf16><<<dim3(32, 64), B256, 0, stream>>>(downW, wt_down, 2048, 1024, 1024, nullptr, 1, 0);

    // normed = rmsnorm(x, inw)
    rmsnorm_kernel<<<dim3(2048), B256, 0, stream>>>(x, inw, normed);
    // xp = normed @ in_proj  (bf16)
    gemm_kernel<1><<<dim3(32, 16), B256, 0, stream>>>(normed, wt_inproj, xp, nullptr, 2048, 4096, 1024);
    // xc = silu(conv(xp[:, :E]) + b)
    conv_silu_kernel<<<dim3(T_TOK * EDIM / 256), B256, 0, stream>>>(xp, convW, convB, xc);
    // dt_pre = xc @ dt_W
    gemm_kernel<0><<<dim3(16, 16), B256, 0, stream>>>(xc, wt_dt, dt_pre, nullptr, 2048, 2048, 2048);
    // bc = xc @ [B|C interleaved]  (bc[t][4i] = {B2i, C2i, B2i+1, C2i+1})
    gemm_kernel<0><<<dim3(1, 16), B256, 0, stream>>>(xc, wt_bc, bc, nullptr, 2048, 128, 2048);
    // channel-major transposes for the scan
    transpose_kernel<1, float, float><<<dim3(64, 64), B256, 0, stream>>>(dt_pre, dtT, 2048, 2048, 2048, dtB, 1, 0);
    transpose_kernel<0, __bf16, __bf16><<<dim3(64, 64), B256, 0, stream>>>(xc, xcT, 2048, 2048, 2048, nullptr, 1, 0);
    transpose_kernel<2, __bf16, __bf16><<<dim3(64, 64), B256, 0, stream>>>(xp + 2048, szT, 2048, 2048, 4096, nullptr, 1, 0);

    // chunked SSM scan.  dt_pre is free (dtT holds softplus'd dt) -> hend/h0;
    // xp is dead after the szT transpose -> dAp.  h0 is computed in place
    // over hend by scan_mid (read-before-overwrite).
    float* hend = dt_pre;                         // 16 MB (E*32*64 f32)
    float* dAp  = (float*)xp;                     // 16 MB
    scan1_kernel<<<dim3(4096), dim3(512), 0, stream>>>(dtT, xcT, bc, Alog, hend, dAp);
    scan_mid_kernel<<<dim3(512), B256, 0, stream>>>(hend, dAp);
    scan2_kernel<<<dim3(4096), dim3(512), 0, stream>>>(dtT, xcT, szT, bc, Alog, hend, yT);

    // y = yT^T  (t-major, into xc buffer)
    __bf16* y = xc;
    transpose_kernel<0, __bf16, __bf16><<<dim3(64, 64), B256, 0, stream>>>(yT, y, 2048, 2048, 2048, nullptr, 1, 0);
    // x2 = x + y @ out_proj
    gemm_kernel<2><<<dim3(8, 16), B256, 0, stream>>>(y, wt_outp, x2, x, 2048, 1024, 2048);
    // n2 = rmsnorm(x2, ffnw)
    rmsnorm_kernel<<<dim3(2048), B256, 0, stream>>>(x2, ffnw, normed);
    // gu = n2 @ [gate|up]
    __bf16* gu = xp;
    gemm_kernel<1><<<dim3(32, 16), B256, 0, stream>>>(normed, wt_gu, gu, nullptr, 2048, 4096, 1024);
    // ffnmid = silu(gate)*up
    __bf16* ffnmid = (__bf16*)dt_pre;
    glu_kernel<<<dim3(T_TOK * 2048 / 256), B256, 0, stream>>>(gu, ffnmid);
    // out = x2 + ffnmid @ down
    gemm_kernel<2><<<dim3(8, 16), B256, 0, stream>>>(ffnmid, wt_down, out, x2, 2048, 1024, 2048);
}

// Round 9
// 508.685 us; speedup vs baseline: 1.4530x; 1.0679x over previous
//
#include <hip/hip_runtime.h>
#include <hip/hip_bf16.h>

typedef __bf16 bf16x8 __attribute__((ext_vector_type(8)));
typedef float  f32x4  __attribute__((ext_vector_type(4)));

#define T_TOK 2048
#define DDIM  1024
#define EDIM  2048
#define NCHUNK 32
#define CKLEN  64

// ---------------------------------------------------------------- transpose
// dst[(c*dmul + doff)*R + r] = op(src[r*S + c]);  R,C multiples of 32.
// OP 0: plain cast. OP 1: softplus(v + bias[c]) clipped to [1e-3, 0.1].
// OP 2: silu(v).
template<int OP, typename TS, typename TD>
__global__ __launch_bounds__(256)
void transpose_kernel(const TS* __restrict__ src, TD* __restrict__ dst,
                      int R, int C, int S, const float* __restrict__ bias,
                      int dmul, int doff)
{
    __shared__ float tile[32][33];
    const int tc0 = blockIdx.x * 32, tr0 = blockIdx.y * 32;
    const int tx = threadIdx.x & 31, ty = threadIdx.x >> 5;
#pragma unroll
    for (int p = 0; p < 4; ++p) {
        int rl = ty + p * 8;
        tile[rl][tx] = (float)src[(size_t)(tr0 + rl) * S + tc0 + tx];
    }
    __syncthreads();
#pragma unroll
    for (int p = 0; p < 4; ++p) {
        int cl = ty + p * 8;
        float v = tile[tx][cl];
        int c = tc0 + cl, r = tr0 + tx;
        if (OP == 1) {
            v += bias[c];
            v = (v > 20.f) ? v : log1pf(__expf(v));
            v = fminf(fmaxf(v, 0.001f), 0.1f);
        } else if (OP == 2) {
            v = v / (1.f + __expf(-v));
        }
        dst[((size_t)c * dmul + doff) * R + r] = (TD)v;
    }
}

// ---------------------------------------------------------------- rmsnorm
__global__ __launch_bounds__(256)
void rmsnorm_kernel(const float* __restrict__ x, const float* __restrict__ w,
                    __bf16* __restrict__ out)
{
    const int row = blockIdx.x;
    const int t = threadIdx.x;
    float4 v = ((const float4*)(x + (size_t)row * DDIM))[t];
    float ss = v.x * v.x + v.y * v.y + v.z * v.z + v.w * v.w;
#pragma unroll
    for (int m = 32; m; m >>= 1) ss += __shfl_xor(ss, m);
    __shared__ float red[4];
    if ((t & 63) == 0) red[t >> 6] = ss;
    __syncthreads();
    float scale = rsqrtf((red[0] + red[1] + red[2] + red[3]) * (1.f / DDIM) + 1e-5f);
    float4 wv = ((const float4*)w)[t];
    __bf16* o = out + (size_t)row * DDIM + t * 4;
    o[0] = (__bf16)(v.x * scale * wv.x);
    o[1] = (__bf16)(v.y * scale * wv.y);
    o[2] = (__bf16)(v.z * scale * wv.z);
    o[3] = (__bf16)(v.w * scale * wv.w);
}

// ---------------------------------------------------------------- conv+silu
__global__ __launch_bounds__(256)
void conv_silu_kernel(const __bf16* __restrict__ xp, const float* __restrict__ W,
                      const float* __restrict__ b, __bf16* __restrict__ xc)
{
    int idx = blockIdx.x * 256 + threadIdx.x;     // over T*E
    int t = idx >> 11, e = idx & (EDIM - 1);
    float s = b[e];
#pragma unroll
    for (int k = 0; k < 4; ++k) {                 // SAME pad: taps t-1..t+2
        int tt = t - 1 + k;
        if (tt >= 0 && tt < T_TOK)
            s += (float)xp[(size_t)tt * (2 * EDIM) + e] * W[k * EDIM + e];
    }
    s = s / (1.f + __expf(-s));
    xc[idx] = (__bf16)s;
}

// ---------------------------------------------------------------- glu
__global__ __launch_bounds__(256)
void glu_kernel(const __bf16* __restrict__ gu, __bf16* __restrict__ outm)
{
    int idx = blockIdx.x * 256 + threadIdx.x;     // over T*I
    int t = idx >> 11, i = idx & 2047;
    float g = (float)gu[(size_t)t * 4096 + i];
    float u = (float)gu[(size_t)t * 4096 + 2048 + i];
    outm[idx] = (__bf16)(g / (1.f + __expf(-g)) * u);
}

// ---------------------------------------------------------------- scan
template<int CTRL, int ROWMASK>
__device__ __forceinline__ float dpp_add(float v)
{
    int y = __builtin_amdgcn_update_dpp(0, __builtin_bit_cast(int, v),
                                        CTRL, ROWMASK, 0xf, true);
    return v + __builtin_bit_cast(float, y);
}

// Block = 512 threads = 8 waves, handling ONE chunk ck and 16 channels.
// Wave w: channels eg+2w (lanes 0-31, c=0) and eg+2w+1 (lanes 32-63, c=1).
// Lane holds states n = 2i, 2i+1.
// bc2 layout: bc2[t*128 + 4i] = {B[t,2i], C[t,2i], B[t,2i+1], C[t,2i+1]}.
// All operands staged in LDS: inner loop is pure LDS+VALU (no vmcnt).

// Pass 1: per (e,chunk) local h_end (h0=0) and P = exp2(An' * sum dt).
__global__ __launch_bounds__(512)
void scan1_kernel(const float* __restrict__ dtT, const __bf16* __restrict__ xcT,
                  const float* __restrict__ bc2, const float* __restrict__ A_log,
                  float* __restrict__ hend, float* __restrict__ dAp)
{
    __shared__ float  s_bc[CKLEN * 128];   // 32 KB
    __shared__ float  s_dt[16][CKLEN];     // 4 KB
    __shared__ __bf16 s_x[16][CKLEN];      // 2 KB
    const int tid = threadIdx.x;
    const int lane = tid & 63, w = tid >> 6;
    const int c = lane >> 5, i = lane & 31;
    const int ck = blockIdx.x & (NCHUNK - 1);
    const int eg = (blockIdx.x >> 5) * 16;

    // ---- stage (coalesced, independent loads -> full MLP)
    {
        const float4* sb = (const float4*)(bc2 + (size_t)ck * CKLEN * 128);
        float4* db = (float4*)s_bc;
#pragma unroll
        for (int r = 0; r < 4; ++r) db[r * 512 + tid] = sb[r * 512 + tid];
        if (tid < 256) {
            int ch = tid >> 4, k = tid & 15;
            *((float4*)&s_dt[ch][0] + k) =
                *(const float4*)(dtT + (size_t)(eg + ch) * T_TOK + ck * CKLEN + 4 * k);
        } else if (tid < 384) {
            int q = tid - 256, ch = q >> 3, k = q & 7;
            *((bf16x8*)&s_x[ch][0] + k) =
                *(const bf16x8*)(xcT + (size_t)(eg + ch) * T_TOK + ck * CKLEN + 8 * k);
        }
    }
    __syncthreads();

    const int ch = 2 * w + c;
    float2 al = *(const float2*)(A_log + 2 * i);
    const float L2E = 1.44269504f;
    const float An0 = -__expf(al.x) * L2E;
    const float An1 = -__expf(al.y) * L2E;
    float h0 = 0.f, h1 = 0.f, D = 0.f;

#pragma unroll 2
    for (int t0 = 0; t0 < CKLEN; t0 += 8) {
        float4 da = *(const float4*)&s_dt[ch][t0];
        float4 db = *(const float4*)&s_dt[ch][t0 + 4];
        bf16x8 x8 = *(const bf16x8*)&s_x[ch][t0];
        float dtv[8] = {da.x, da.y, da.z, da.w, db.x, db.y, db.z, db.w};
#pragma unroll
        for (int j = 0; j < 8; ++j) {
            float4 bcv = *(const float4*)&s_bc[(t0 + j) * 128 + 4 * i];
            float u = dtv[j] * (float)x8[j];
            float dA0 = __builtin_amdgcn_exp2f(dtv[j] * An0);
            float dA1 = __builtin_amdgcn_exp2f(dtv[j] * An1);
            h0 = fmaf(dA0, h0, u * bcv.x);
            h1 = fmaf(dA1, h1, u * bcv.z);
            D += dtv[j];
        }
    }
    const int e = eg + ch;
    size_t idx = ((size_t)e * NCHUNK + ck) * 64 + 2 * i;
    *(float2*)(hend + idx) = make_float2(h0, h1);
    *(float2*)(dAp + idx)  = make_float2(__builtin_amdgcn_exp2f(An0 * D),
                                         __builtin_amdgcn_exp2f(An1 * D));
}

// Mid: serial scan over chunk summaries -> h_start per chunk, IN PLACE over hend.
__global__ __launch_bounds__(256)
void scan_mid_kernel(float* __restrict__ hend_h0, const float* __restrict__ dAp)
{
    int gid = blockIdx.x * 256 + threadIdx.x;     // over E*64
    int e = gid >> 6, n = gid & 63;
    float h = 0.f;
#pragma unroll
    for (int ck = 0; ck < NCHUNK; ++ck) {
        size_t idx = ((size_t)e * NCHUNK + ck) * 64 + n;
        float he = hend_h0[idx];
        float P  = dAp[idx];
        hend_h0[idx] = h;                         // h0 for this chunk
        h = P * h + he;
    }
}

// Pass 2: re-run each chunk from its true h_start, emit y (gated by silu(z)).
__global__ __launch_bounds__(512)
void scan2_kernel(const float* __restrict__ dtT, const __bf16* __restrict__ xcT,
                  const __bf16* __restrict__ szT, const float* __restrict__ bc2,
                  const float* __restrict__ A_log, const float* __restrict__ h0s,
                  __bf16* __restrict__ yT)
{
    __shared__ float  s_bc[CKLEN * 128];   // 32 KB
    __shared__ float  s_dt[16][CKLEN];     // 4 KB
    __shared__ __bf16 s_x[16][CKLEN];      // 2 KB
    __shared__ __bf16 s_z[16][CKLEN];      // 2 KB
    const int tid = threadIdx.x;
    const int lane = tid & 63, w = tid >> 6;
    const int c = lane >> 5, i = lane & 31;
    const int ck = blockIdx.x & (NCHUNK - 1);
    const int eg = (blockIdx.x >> 5) * 16;

    // ---- stage
    {
        const float4* sb = (const float4*)(bc2 + (size_t)ck * CKLEN * 128);
        float4* db = (float4*)s_bc;
#pragma unroll
        for (int r = 0; r < 4; ++r) db[r * 512 + tid] = sb[r * 512 + tid];
        if (tid < 256) {
            int ch = tid >> 4, k = tid & 15;
            *((float4*)&s_dt[ch][0] + k) =
                *(const float4*)(dtT + (size_t)(eg + ch) * T_TOK + ck * CKLEN + 4 * k);
        } else if (tid < 384) {
            int q = tid - 256, ch = q >> 3, k = q & 7;
            *((bf16x8*)&s_x[ch][0] + k) =
                *(const bf16x8*)(xcT + (size_t)(eg + ch) * T_TOK + ck * CKLEN + 8 * k);
        } else {
            int q = tid - 384, ch = q >> 3, k = q & 7;
            *((bf16x8*)&s_z[ch][0] + k) =
                *(const bf16x8*)(szT + (size_t)(eg + ch) * T_TOK + ck * CKLEN + 8 * k);
        }
    }
    __syncthreads();

    const int ch = 2 * w + c;
    const int e = eg + ch;
    float2 al = *(const float2*)(A_log + 2 * i);
    const float L2E = 1.44269504f;
    const float An0 = -__expf(al.x) * L2E;
    const float An1 = -__expf(al.y) * L2E;
    __bf16* yrow = yT + (size_t)e * T_TOK + ck * CKLEN;
    float2 hh = *(const float2*)(h0s + ((size_t)e * NCHUNK + ck) * 64 + 2 * i);
    float h0 = hh.x, h1 = hh.y;
    float ysave = 0.f;

#pragma unroll 2
    for (int t0 = 0; t0 < CKLEN; t0 += 8) {
        float4 da = *(const float4*)&s_dt[ch][t0];
        float4 db = *(const float4*)&s_dt[ch][t0 + 4];
        bf16x8 x8 = *(const bf16x8*)&s_x[ch][t0];
        bf16x8 z8 = *(const bf16x8*)&s_z[ch][t0];
        float dtv[8] = {da.x, da.y, da.z, da.w, db.x, db.y, db.z, db.w};
#pragma unroll
        for (int j = 0; j < 8; ++j) {
            float4 bcv = *(const float4*)&s_bc[(t0 + j) * 128 + 4 * i];
            float u = dtv[j] * (float)x8[j];
            float dA0 = __builtin_amdgcn_exp2f(dtv[j] * An0);
            float dA1 = __builtin_amdgcn_exp2f(dtv[j] * An1);
            h0 = fmaf(dA0, h0, u * bcv.x);
            h1 = fmaf(dA1, h1, u * bcv.z);
            float p = fmaf(h1, bcv.w, h0 * bcv.y);   // h0*C0 + h1*C1
            p *= (float)z8[j];                        // gate with silu(z)
            // 32-lane tree per half (5 steps, both channels at once)
            p = dpp_add<0x111, 0xf>(p);   // row_shr:1
            p = dpp_add<0x112, 0xf>(p);   // row_shr:2
            p = dpp_add<0x114, 0xf>(p);   // row_shr:4
            p = dpp_add<0x118, 0xf>(p);   // row_shr:8
            p = dpp_add<0x142, 0xa>(p);   // row_bcast:15 -> rows 1,3
            int pi = __builtin_bit_cast(int, p);
            float totA = __builtin_bit_cast(float, __builtin_amdgcn_readlane(pi, 31));
            float totB = __builtin_bit_cast(float, __builtin_amdgcn_readlane(pi, 63));
            float tot = (c == 0) ? totA : totB;   // pick this lane-half's channel
            int t31 = (t0 + j) & 31;
            ysave = (t31 == i) ? tot : ysave;     // bank per-t result at lane i==t
            if (t31 == 31)
                yrow[(t0 + j) - 31 + i] = (__bf16)ysave;
        }
    }
}

// ---------------------------------------------------------------- GEMM
// C[M,N] = A[M,K] @ Bt[N,K]^T.  M,N mult of 128, K mult of 32.
// EPI 0: f32 store. EPI 1: bf16 store. EPI 2: f32 store of acc + res.
// m97-style staging: global_load_lds (16B) into linear LDS [128][32] bf16.
__device__ __forceinline__ void glds16(const __bf16* g, __bf16* l)
{
    __builtin_amdgcn_global_load_lds(
        (const __attribute__((address_space(1))) unsigned*)g,
        (__attribute__((address_space(3))) unsigned*)l, 16, 0, 0);
}

template<int EPI>
__global__ __launch_bounds__(256)
void gemm_kernel(const __bf16* __restrict__ A, const __bf16* __restrict__ Bt,
                 void* __restrict__ Cout, const float* __restrict__ res,
                 int M, int N, int K)
{
    __shared__ __bf16 sAl[128 * 32];   // linear [row][k] tile, 8 KB
    __shared__ __bf16 sBl[128 * 32];
    const int t = threadIdx.x;
    const int wave = t >> 6, lane = t & 63;
    const int brow = blockIdx.y * 128, bcol = blockIdx.x * 128;
    const int wr = (wave >> 1) * 64, wc = (wave & 1) * 64;
    const int w16 = wave * 16;
    f32x4 acc[4][4] = {};

    // lane l of wave w stages LDS bytes [w16*64 + l*16]: row = w16 + (l>>2),
    // k-chunk = (l&3)*8.  Global source arranged to match (wave-uniform LDS base).
    const __bf16* gA = A  + (size_t)(brow + w16 + (lane >> 2)) * K + (lane & 3) * 8;
    const __bf16* gB = Bt + (size_t)(bcol + w16 + (lane >> 2)) * K + (lane & 3) * 8;
    __bf16* lA0 = sAl + w16 * 32;
    __bf16* lA1 = sAl + (w16 + 64) * 32;
    __bf16* lB0 = sBl + w16 * 32;
    __bf16* lB1 = sBl + (w16 + 64) * 32;

    for (int k0 = 0; k0 < K; k0 += 32) {
        __syncthreads();                   // prior reads done: safe to overwrite
        glds16(gA + k0, lA0);
        glds16(gA + (size_t)64 * K + k0, lA1);
        glds16(gB + k0, lB0);
        glds16(gB + (size_t)64 * K + k0, lB1);
        __syncthreads();                   // vmcnt drained: LDS tile ready
        bf16x8 af[4], bg[4];
#pragma unroll
        for (int m = 0; m < 4; ++m)
            af[m] = *(const bf16x8*)&sAl[(wr + m * 16 + (lane & 15)) * 32 + (lane >> 4) * 8];
#pragma unroll
        for (int n = 0; n < 4; ++n)
            bg[n] = *(const bf16x8*)&sBl[(wc + n * 16 + (lane & 15)) * 32 + (lane >> 4) * 8];
#pragma unroll
        for (int m = 0; m < 4; ++m)
#pragma unroll
            for (int n = 0; n < 4; ++n)
                acc[m][n] = __builtin_amdgcn_mfma_f32_16x16x32_bf16(
                    af[m], bg[n], acc[m][n], 0, 0, 0);
    }

    const int c_l = lane & 15, r_l = (lane >> 4) * 4;
#pragma unroll
    for (int m = 0; m < 4; ++m) {
#pragma unroll
        for (int n = 0; n < 4; ++n) {
            int row = brow + wr + m * 16 + r_l;
            int col = bcol + wc + n * 16 + c_l;
#pragma unroll
            for (int i = 0; i < 4; ++i) {
                float v = acc[m][n][i];
                size_t off = (size_t)(row + i) * N + col;
                if (EPI == 0)      ((float*)Cout)[off] = v;
                else if (EPI == 1) ((__bf16*)Cout)[off] = (__bf16)v;
                else               ((float*)Cout)[off] = v + res[off];
            }
        }
    }
}

// ---------------------------------------------------------------- launch
extern "C" void kernel_launch(void* const* d_in, const int* in_sizes, int n_in,
                              void* d_out, int out_size, void* d_ws, size_t ws_size,
                              hipStream_t stream)
{
    (void)in_sizes; (void)n_in; (void)out_size; (void)ws_size;
    const float* x     = (const float*)d_in[0];
    const float* inw   = (const float*)d_in[1];
    const float* ffnw  = (const float*)d_in[2];
    const float* inpW  = (const float*)d_in[3];
    const float* convW = (const float*)d_in[4];
    const float* convB = (const float*)d_in[5];
    const float* dtW   = (const float*)d_in[6];
    const float* dtB   = (const float*)d_in[7];
    const float* BW    = (const float*)d_in[8];
    const float* CW    = (const float*)d_in[9];
    const float* Alog  = (const float*)d_in[10];
    const float* outpW = (const float*)d_in[11];
    const float* gateW = (const float*)d_in[12];
    const float* upW   = (const float*)d_in[13];
    const float* downW = (const float*)d_in[14];
    float* out = (float*)d_out;

    char* p = (char*)d_ws;
    auto alloc = [&](size_t n) { char* q = p; p += (n + 255) & ~(size_t)255; return q; };
    __bf16* wt_inproj = (__bf16*)alloc(4096ull * 1024 * 2);
    __bf16* wt_dt     = (__bf16*)alloc(2048ull * 2048 * 2);
    __bf16* wt_bc     = (__bf16*)alloc(128ull * 2048 * 2);   // interleaved {B,C} rows
    __bf16* wt_outp   = (__bf16*)alloc(1024ull * 2048 * 2);
    __bf16* wt_gu     = (__bf16*)alloc(4096ull * 1024 * 2);
    __bf16* wt_down   = (__bf16*)alloc(1024ull * 2048 * 2);
    __bf16* normed    = (__bf16*)alloc(2048ull * 1024 * 2);  // reused as n2
    __bf16* xp        = (__bf16*)alloc(2048ull * 4096 * 2);  // reused: dAp + gu
    __bf16* xc        = (__bf16*)alloc(2048ull * 2048 * 2);  // reused as y
    float*  dt_pre    = (float*)alloc(2048ull * 2048 * 4);   // reused: hend/h0 + ffnmid
    float*  bc        = (float*)alloc(2048ull * 128 * 4);
    float*  dtT       = (float*)alloc(2048ull * 2048 * 4);
    __bf16* xcT       = (__bf16*)alloc(2048ull * 2048 * 2);
    __bf16* szT       = (__bf16*)alloc(2048ull * 2048 * 2);
    __bf16* yT        = (__bf16*)alloc(2048ull * 2048 * 2);
    float*  x2        = (float*)alloc(2048ull * 1024 * 4);

    dim3 B256(256);
    // weight prep (f32 -> bf16, transposed to [N][K])
    transpose_kernel<0, float, __bf16><<<dim3(128, 32), B256, 0, stream>>>(inpW, wt_inproj, 1024, 4096, 4096, nullptr, 1, 0);
    transpose_kernel<0, float, __bf16><<<dim3(64, 64), B256, 0, stream>>>(dtW, wt_dt, 2048, 2048, 2048, nullptr, 1, 0);
    transpose_kernel<0, float, __bf16><<<dim3(2, 64), B256, 0, stream>>>(BW, wt_bc, 2048, 64, 64, nullptr, 2, 0);
    transpose_kernel<0, float, __bf16><<<dim3(2, 64), B256, 0, stream>>>(CW, wt_bc, 2048, 64, 64, nullptr, 2, 1);
    transpose_kernel<0, float, __bf16><<<dim3(32, 64), B256, 0, stream>>>(outpW, wt_outp, 2048, 1024, 1024, nullptr, 1, 0);
    transpose_kernel<0, float, __bf16><<<dim3(64, 32), B256, 0, stream>>>(gateW, wt_gu, 1024, 2048, 2048, nullptr, 1, 0);
    transpose_kernel<0, float, __bf16><<<dim3(64, 32), B256, 0, stream>>>(upW, wt_gu + 2048ull * 1024, 1024, 2048, 2048, nullptr, 1, 0);
    transpose_kernel<0, float, __bf16><<<dim3(32, 64), B256, 0, stream>>>(downW, wt_down, 2048, 1024, 1024, nullptr, 1, 0);

    // normed = rmsnorm(x, inw)
    rmsnorm_kernel<<<dim3(2048), B256, 0, stream>>>(x, inw, normed);
    // xp = normed @ in_proj  (bf16)
    gemm_kernel<1><<<dim3(32, 16), B256, 0, stream>>>(normed, wt_inproj, xp, nullptr, 2048, 4096, 1024);
    // xc = silu(conv(xp[:, :E]) + b)
    conv_silu_kernel<<<dim3(T_TOK * EDIM / 256), B256, 0, stream>>>(xp, convW, convB, xc);
    // dt_pre = xc @ dt_W
    gemm_kernel<0><<<dim3(16, 16), B256, 0, stream>>>(xc, wt_dt, dt_pre, nullptr, 2048, 2048, 2048);
    // bc = xc @ [B|C interleaved]  (bc[t][4i] = {B2i, C2i, B2i+1, C2i+1})
    gemm_kernel<0><<<dim3(1, 16), B256, 0, stream>>>(xc, wt_bc, bc, nullptr, 2048, 128, 2048);
    // channel-major transposes for the scan
    transpose_kernel<1, float, float><<<dim3(64, 64), B256, 0, stream>>>(dt_pre, dtT, 2048, 2048, 2048, dtB, 1, 0);
    transpose_kernel<0, __bf16, __bf16><<<dim3(64, 64), B256, 0, stream>>>(xc, xcT, 2048, 2048, 2048, nullptr, 1, 0);
    transpose_kernel<2, __bf16, __bf16><<<dim3(64, 64), B256, 0, stream>>>(xp + 2048, szT, 2048, 2048, 4096, nullptr, 1, 0);

    // chunked SSM scan.  dt_pre is free (dtT holds softplus'd dt) -> hend/h0;
    // xp is dead after the szT transpose -> dAp.  h0 is computed in place
    // over hend by scan_mid (read-before-overwrite).
    float* hend = dt_pre;                         // 16 MB (E*32*64 f32)
    float* dAp  = (float*)xp;                     // 16 MB
    scan1_kernel<<<dim3(4096), dim3(512), 0, stream>>>(dtT, xcT, bc, Alog, hend, dAp);
    scan_mid_kernel<<<dim3(512), B256, 0, stream>>>(hend, dAp);
    scan2_kernel<<<dim3(4096), dim3(512), 0, stream>>>(dtT, xcT, szT, bc, Alog, hend, yT);

    // y = yT^T  (t-major, into xc buffer)
    __bf16* y = xc;
    transpose_kernel<0, __bf16, __bf16><<<dim3(64, 64), B256, 0, stream>>>(yT, y, 2048, 2048, 2048, nullptr, 1, 0);
    // x2 = x + y @ out_proj
    gemm_kernel<2><<<dim3(8, 16), B256, 0, stream>>>(y, wt_outp, x2, x, 2048, 1024, 2048);
    // n2 = rmsnorm(x2, ffnw)
    rmsnorm_kernel<<<dim3(2048), B256, 0, stream>>>(x2, ffnw, normed);
    // gu = n2 @ [gate|up]
    __bf16* gu = xp;
    gemm_kernel<1><<<dim3(32, 16), B256, 0, stream>>>(normed, wt_gu, gu, nullptr, 2048, 4096, 1024);
    // ffnmid = silu(gate)*up
    __bf16* ffnmid = (__bf16*)dt_pre;
    glu_kernel<<<dim3(T_TOK * 2048 / 256), B256, 0, stream>>>(gu, ffnmid);
    // out = x2 + ffnmid @ down
    gemm_kernel<2><<<dim3(8, 16), B256, 0, stream>>>(ffnmid, wt_down, out, x2, 2048, 1024, 2048);
}

// Round 10
// 470.127 us; speedup vs baseline: 1.5722x; 1.0820x over previous
//
#include <hip/hip_runtime.h>
#include <hip/hip_bf16.h>

typedef __bf16 bf16x8 __attribute__((ext_vector_type(8)));
typedef __bf16 bf16x4 __attribute__((ext_vector_type(4)));
typedef float  f32x4  __attribute__((ext_vector_type(4)));

#define T_TOK 2048
#define DDIM  1024
#define EDIM  2048
#define NCHUNK 32
#define CKLEN  64

// ---------------------------------------------------------------- transpose
// dst[(c*dmul + doff)*R + r] = src[r*S + c];  R,C multiples of 32.
template<typename TS, typename TD>
__global__ __launch_bounds__(256)
void transpose_kernel(const TS* __restrict__ src, TD* __restrict__ dst,
                      int R, int C, int S, int dmul, int doff)
{
    __shared__ float tile[32][33];
    const int tc0 = blockIdx.x * 32, tr0 = blockIdx.y * 32;
    const int tx = threadIdx.x & 31, ty = threadIdx.x >> 5;
#pragma unroll
    for (int p = 0; p < 4; ++p) {
        int rl = ty + p * 8;
        tile[rl][tx] = (float)src[(size_t)(tr0 + rl) * S + tc0 + tx];
    }
    __syncthreads();
#pragma unroll
    for (int p = 0; p < 4; ++p) {
        int cl = ty + p * 8;
        float v = tile[tx][cl];
        int c = tc0 + cl, r = tr0 + tx;
        dst[((size_t)c * dmul + doff) * R + r] = (TD)v;
    }
}

// ---------------------------------------------------------------- rmsnorm
__global__ __launch_bounds__(256)
void rmsnorm_kernel(const float* __restrict__ x, const float* __restrict__ w,
                    __bf16* __restrict__ out)
{
    const int row = blockIdx.x;
    const int t = threadIdx.x;
    float4 v = ((const float4*)(x + (size_t)row * DDIM))[t];
    float ss = v.x * v.x + v.y * v.y + v.z * v.z + v.w * v.w;
#pragma unroll
    for (int m = 32; m; m >>= 1) ss += __shfl_xor(ss, m);
    __shared__ float red[4];
    if ((t & 63) == 0) red[t >> 6] = ss;
    __syncthreads();
    float scale = rsqrtf((red[0] + red[1] + red[2] + red[3]) * (1.f / DDIM) + 1e-5f);
    float4 wv = ((const float4*)w)[t];
    __bf16* o = out + (size_t)row * DDIM + t * 4;
    o[0] = (__bf16)(v.x * scale * wv.x);
    o[1] = (__bf16)(v.y * scale * wv.y);
    o[2] = (__bf16)(v.z * scale * wv.z);
    o[3] = (__bf16)(v.w * scale * wv.w);
}

// ---------------------------------------------------------------- conv+silu
__global__ __launch_bounds__(256)
void conv_silu_kernel(const __bf16* __restrict__ xz, const float* __restrict__ W,
                      const float* __restrict__ b, __bf16* __restrict__ xc)
{
    int idx = blockIdx.x * 256 + threadIdx.x;     // over T*E
    int t = idx >> 11, e = idx & (EDIM - 1);
    float s = b[e];
#pragma unroll
    for (int k = 0; k < 4; ++k) {                 // SAME pad: taps t-1..t+2
        int tt = t - 1 + k;
        if (tt >= 0 && tt < T_TOK)
            s += (float)xz[(size_t)tt * EDIM + e] * W[k * EDIM + e];
    }
    s = s / (1.f + __expf(-s));
    xc[idx] = (__bf16)s;
}

// ---------------------------------------------------------------- glu
__global__ __launch_bounds__(256)
void glu_kernel(const __bf16* __restrict__ gu, __bf16* __restrict__ outm)
{
    int idx = blockIdx.x * 256 + threadIdx.x;     // over T*I
    int t = idx >> 11, i = idx & 2047;
    float g = (float)gu[(size_t)t * 4096 + i];
    float u = (float)gu[(size_t)t * 4096 + 2048 + i];
    outm[idx] = (__bf16)(g / (1.f + __expf(-g)) * u);
}

// ---------------------------------------------------------------- scan
template<int CTRL, int ROWMASK>
__device__ __forceinline__ float dpp_add(float v)
{
    int y = __builtin_amdgcn_update_dpp(0, __builtin_bit_cast(int, v),
                                        CTRL, ROWMASK, 0xf, true);
    return v + __builtin_bit_cast(float, y);
}

// Block = 512 threads = 8 waves, handling ONE chunk ck and 16 channels.
// Wave w: channels eg+2w (lanes 0-31, c=0) and eg+2w+1 (lanes 32-63, c=1).
// Lane holds states n = 2i, 2i+1.
// bc2 layout: bc2[t*128 + 4i] = {B[t,2i], C[t,2i], B[t,2i+1], C[t,2i+1]}.

// Pass 1: per (e,chunk) local h_end (h0=0) and P = exp2(An' * sum dt).
__global__ __launch_bounds__(512)
void scan1_kernel(const float* __restrict__ dtT, const __bf16* __restrict__ xcT,
                  const float* __restrict__ bc2, const float* __restrict__ A_log,
                  float* __restrict__ hend, float* __restrict__ dAp)
{
    __shared__ float  s_bc[CKLEN * 128];   // 32 KB
    __shared__ float  s_dt[16][CKLEN];     // 4 KB
    __shared__ __bf16 s_x[16][CKLEN];      // 2 KB
    const int tid = threadIdx.x;
    const int lane = tid & 63, w = tid >> 6;
    const int c = lane >> 5, i = lane & 31;
    const int ck = blockIdx.x & (NCHUNK - 1);
    const int eg = (blockIdx.x >> 5) * 16;

    {
        const float4* sb = (const float4*)(bc2 + (size_t)ck * CKLEN * 128);
        float4* db = (float4*)s_bc;
#pragma unroll
        for (int r = 0; r < 4; ++r) db[r * 512 + tid] = sb[r * 512 + tid];
        if (tid < 256) {
            int ch = tid >> 4, k = tid & 15;
            *((float4*)&s_dt[ch][0] + k) =
                *(const float4*)(dtT + (size_t)(eg + ch) * T_TOK + ck * CKLEN + 4 * k);
        } else if (tid < 384) {
            int q = tid - 256, ch = q >> 3, k = q & 7;
            *((bf16x8*)&s_x[ch][0] + k) =
                *(const bf16x8*)(xcT + (size_t)(eg + ch) * T_TOK + ck * CKLEN + 8 * k);
        }
    }
    __syncthreads();

    const int ch = 2 * w + c;
    float2 al = *(const float2*)(A_log + 2 * i);
    const float L2E = 1.44269504f;
    const float An0 = -__expf(al.x) * L2E;
    const float An1 = -__expf(al.y) * L2E;
    float h0 = 0.f, h1 = 0.f, D = 0.f;

#pragma unroll 2
    for (int t0 = 0; t0 < CKLEN; t0 += 8) {
        float4 da = *(const float4*)&s_dt[ch][t0];
        float4 db = *(const float4*)&s_dt[ch][t0 + 4];
        bf16x8 x8 = *(const bf16x8*)&s_x[ch][t0];
        float dtv[8] = {da.x, da.y, da.z, da.w, db.x, db.y, db.z, db.w};
#pragma unroll
        for (int j = 0; j < 8; ++j) {
            float4 bcv = *(const float4*)&s_bc[(t0 + j) * 128 + 4 * i];
            float u = dtv[j] * (float)x8[j];
            float dA0 = __builtin_amdgcn_exp2f(dtv[j] * An0);
            float dA1 = __builtin_amdgcn_exp2f(dtv[j] * An1);
            h0 = fmaf(dA0, h0, u * bcv.x);
            h1 = fmaf(dA1, h1, u * bcv.z);
            D += dtv[j];
        }
    }
    const int e = eg + ch;
    size_t idx = ((size_t)e * NCHUNK + ck) * 64 + 2 * i;
    *(float2*)(hend + idx) = make_float2(h0, h1);
    *(float2*)(dAp + idx)  = make_float2(__builtin_amdgcn_exp2f(An0 * D),
                                         __builtin_amdgcn_exp2f(An1 * D));
}

// Mid: serial scan over chunk summaries -> h_start per chunk, IN PLACE over hend.
__global__ __launch_bounds__(256)
void scan_mid_kernel(float* __restrict__ hend_h0, const float* __restrict__ dAp)
{
    int gid = blockIdx.x * 256 + threadIdx.x;     // over E*64
    int e = gid >> 6, n = gid & 63;
    float h = 0.f;
#pragma unroll
    for (int ck = 0; ck < NCHUNK; ++ck) {
        size_t idx = ((size_t)e * NCHUNK + ck) * 64 + n;
        float he = hend_h0[idx];
        float P  = dAp[idx];
        hend_h0[idx] = h;
        h = P * h + he;
    }
}

// Pass 2: re-run each chunk from its true h_start; emit y T-MAJOR via LDS tile.
__global__ __launch_bounds__(512)
void scan2_kernel(const float* __restrict__ dtT, const __bf16* __restrict__ xcT,
                  const __bf16* __restrict__ szT, const float* __restrict__ bc2,
                  const float* __restrict__ A_log, const float* __restrict__ h0s,
                  __bf16* __restrict__ y)
{
    __shared__ float  s_bc[CKLEN * 128];   // 32 KB
    __shared__ float  s_dt[16][CKLEN];     // 4 KB
    __shared__ __bf16 s_x[16][CKLEN];      // 2 KB
    __shared__ __bf16 s_z[16][CKLEN];      // 2 KB
    __shared__ __bf16 s_y[CKLEN][16];      // 2 KB  (t-major output tile)
    const int tid = threadIdx.x;
    const int lane = tid & 63, w = tid >> 6;
    const int c = lane >> 5, i = lane & 31;
    const int ck = blockIdx.x & (NCHUNK - 1);
    const int eg = (blockIdx.x >> 5) * 16;

    {
        const float4* sb = (const float4*)(bc2 + (size_t)ck * CKLEN * 128);
        float4* db = (float4*)s_bc;
#pragma unroll
        for (int r = 0; r < 4; ++r) db[r * 512 + tid] = sb[r * 512 + tid];
        if (tid < 256) {
            int ch = tid >> 4, k = tid & 15;
            *((float4*)&s_dt[ch][0] + k) =
                *(const float4*)(dtT + (size_t)(eg + ch) * T_TOK + ck * CKLEN + 4 * k);
        } else if (tid < 384) {
            int q = tid - 256, ch = q >> 3, k = q & 7;
            *((bf16x8*)&s_x[ch][0] + k) =
                *(const bf16x8*)(xcT + (size_t)(eg + ch) * T_TOK + ck * CKLEN + 8 * k);
        } else {
            int q = tid - 384, ch = q >> 3, k = q & 7;
            *((bf16x8*)&s_z[ch][0] + k) =
                *(const bf16x8*)(szT + (size_t)(eg + ch) * T_TOK + ck * CKLEN + 8 * k);
        }
    }
    __syncthreads();

    const int ch = 2 * w + c;
    const int e = eg + ch;
    float2 al = *(const float2*)(A_log + 2 * i);
    const float L2E = 1.44269504f;
    const float An0 = -__expf(al.x) * L2E;
    const float An1 = -__expf(al.y) * L2E;
    float2 hh = *(const float2*)(h0s + ((size_t)e * NCHUNK + ck) * 64 + 2 * i);
    float h0 = hh.x, h1 = hh.y;
    float ysave = 0.f;

#pragma unroll 2
    for (int t0 = 0; t0 < CKLEN; t0 += 8) {
        float4 da = *(const float4*)&s_dt[ch][t0];
        float4 db = *(const float4*)&s_dt[ch][t0 + 4];
        bf16x8 x8 = *(const bf16x8*)&s_x[ch][t0];
        bf16x8 z8 = *(const bf16x8*)&s_z[ch][t0];
        float dtv[8] = {da.x, da.y, da.z, da.w, db.x, db.y, db.z, db.w};
#pragma unroll
        for (int j = 0; j < 8; ++j) {
            float4 bcv = *(const float4*)&s_bc[(t0 + j) * 128 + 4 * i];
            float u = dtv[j] * (float)x8[j];
            float dA0 = __builtin_amdgcn_exp2f(dtv[j] * An0);
            float dA1 = __builtin_amdgcn_exp2f(dtv[j] * An1);
            h0 = fmaf(dA0, h0, u * bcv.x);
            h1 = fmaf(dA1, h1, u * bcv.z);
            float p = fmaf(h1, bcv.w, h0 * bcv.y);   // h0*C0 + h1*C1
            p *= (float)z8[j];                        // gate with silu(z)
            p = dpp_add<0x111, 0xf>(p);   // row_shr:1
            p = dpp_add<0x112, 0xf>(p);   // row_shr:2
            p = dpp_add<0x114, 0xf>(p);   // row_shr:4
            p = dpp_add<0x118, 0xf>(p);   // row_shr:8
            p = dpp_add<0x142, 0xa>(p);   // row_bcast:15 -> rows 1,3
            int pi = __builtin_bit_cast(int, p);
            float totA = __builtin_bit_cast(float, __builtin_amdgcn_readlane(pi, 31));
            float totB = __builtin_bit_cast(float, __builtin_amdgcn_readlane(pi, 63));
            float tot = (c == 0) ? totA : totB;
            int t31 = (t0 + j) & 31;
            ysave = (t31 == i) ? tot : ysave;
            if (t31 == 31)
                s_y[(t0 + j) - 31 + i][ch] = (__bf16)ysave;
        }
    }
    __syncthreads();
    // write y[t][e] t-major: 64 t-rows x 16 ch (32B/row)
    {
        int tt = tid >> 3, q = tid & 7;
        unsigned val = *(const unsigned*)&s_y[tt][2 * q];
        *(unsigned*)(y + (size_t)(ck * CKLEN + tt) * EDIM + eg + 2 * q) = val;
    }
}

// ---------------------------------------------------------------- GEMM
// C[M,N] = A[M,K] @ Bt[N,K]^T.  M,N mult of 128, K mult of 32.
// EPI 1: bf16 store (stride N).
// EPI 2: f32 store of acc + res (stride N).
// EPI 3: dt+bc fused: col<2048 -> softplus(acc+res[col]) clipped, TRANSPOSED
//        float4 to Cout[col][row] (stride T_TOK); col>=2048 -> f32 to
//        Cout2[row*128 + col-2048].
// EPI 4: in_proj split: col<2048 -> bf16 to Cout[row][col] (stride EDIM);
//        col>=2048 -> silu(acc), TRANSPOSED bf16x4 to Cout2[col-2048][row].
__device__ __forceinline__ void glds16(const __bf16* g, __bf16* l)
{
    __builtin_amdgcn_global_load_lds(
        (const __attribute__((address_space(1))) unsigned*)g,
        (__attribute__((address_space(3))) unsigned*)l, 16, 0, 0);
}

template<int EPI>
__global__ __launch_bounds__(256)
void gemm_kernel(const __bf16* __restrict__ A, const __bf16* __restrict__ Bt,
                 void* __restrict__ Cout, void* __restrict__ Cout2,
                 const float* __restrict__ res, int M, int N, int K)
{
    __shared__ __bf16 sAl[128 * 32];   // linear [row][k] tile, 8 KB
    __shared__ __bf16 sBl[128 * 32];
    const int t = threadIdx.x;
    const int wave = t >> 6, lane = t & 63;
    const int brow = blockIdx.y * 128, bcol = blockIdx.x * 128;
    const int wr = (wave >> 1) * 64, wc = (wave & 1) * 64;
    const int w16 = wave * 16;
    f32x4 acc[4][4] = {};

    const __bf16* gA = A  + (size_t)(brow + w16 + (lane >> 2)) * K + (lane & 3) * 8;
    const __bf16* gB = Bt + (size_t)(bcol + w16 + (lane >> 2)) * K + (lane & 3) * 8;
    __bf16* lA0 = sAl + w16 * 32;
    __bf16* lA1 = sAl + (w16 + 64) * 32;
    __bf16* lB0 = sBl + w16 * 32;
    __bf16* lB1 = sBl + (w16 + 64) * 32;

    for (int k0 = 0; k0 < K; k0 += 32) {
        __syncthreads();
        glds16(gA + k0, lA0);
        glds16(gA + (size_t)64 * K + k0, lA1);
        glds16(gB + k0, lB0);
        glds16(gB + (size_t)64 * K + k0, lB1);
        __syncthreads();
        bf16x8 af[4], bg[4];
#pragma unroll
        for (int m = 0; m < 4; ++m)
            af[m] = *(const bf16x8*)&sAl[(wr + m * 16 + (lane & 15)) * 32 + (lane >> 4) * 8];
#pragma unroll
        for (int n = 0; n < 4; ++n)
            bg[n] = *(const bf16x8*)&sBl[(wc + n * 16 + (lane & 15)) * 32 + (lane >> 4) * 8];
#pragma unroll
        for (int m = 0; m < 4; ++m)
#pragma unroll
            for (int n = 0; n < 4; ++n)
                acc[m][n] = __builtin_amdgcn_mfma_f32_16x16x32_bf16(
                    af[m], bg[n], acc[m][n], 0, 0, 0);
    }

    const int c_l = lane & 15, r_l = (lane >> 4) * 4;
#pragma unroll
    for (int m = 0; m < 4; ++m) {
#pragma unroll
        for (int n = 0; n < 4; ++n) {
            int row = brow + wr + m * 16 + r_l;
            int col = bcol + wc + n * 16 + c_l;
            if (EPI == 1) {
#pragma unroll
                for (int i = 0; i < 4; ++i)
                    ((__bf16*)Cout)[(size_t)(row + i) * N + col] = (__bf16)acc[m][n][i];
            } else if (EPI == 2) {
#pragma unroll
                for (int i = 0; i < 4; ++i) {
                    size_t off = (size_t)(row + i) * N + col;
                    ((float*)Cout)[off] = acc[m][n][i] + res[off];
                }
            } else if (EPI == 3) {
                if (col < 2048) {
                    float bias = res[col];
                    float4 v;
                    float* vv = (float*)&v;
#pragma unroll
                    for (int i = 0; i < 4; ++i) {
                        float s = acc[m][n][i] + bias;
                        s = (s > 20.f) ? s : log1pf(__expf(s));
                        vv[i] = fminf(fmaxf(s, 0.001f), 0.1f);
                    }
                    *(float4*)((float*)Cout + (size_t)col * T_TOK + row) = v;
                } else {
#pragma unroll
                    for (int i = 0; i < 4; ++i)
                        ((float*)Cout2)[(size_t)(row + i) * 128 + (col - 2048)] = acc[m][n][i];
                }
            } else if (EPI == 4) {
                if (col < 2048) {
#pragma unroll
                    for (int i = 0; i < 4; ++i)
                        ((__bf16*)Cout)[(size_t)(row + i) * EDIM + col] = (__bf16)acc[m][n][i];
                } else {
                    bf16x4 v;
#pragma unroll
                    for (int i = 0; i < 4; ++i) {
                        float s = acc[m][n][i];
                        v[i] = (__bf16)(s / (1.f + __expf(-s)));
                    }
                    *(bf16x4*)((__bf16*)Cout2 + (size_t)(col - 2048) * T_TOK + row) = v;
                }
            }
        }
    }
}

// ---------------------------------------------------------------- launch
extern "C" void kernel_launch(void* const* d_in, const int* in_sizes, int n_in,
                              void* d_out, int out_size, void* d_ws, size_t ws_size,
                              hipStream_t stream)
{
    (void)in_sizes; (void)n_in; (void)out_size; (void)ws_size;
    const float* x     = (const float*)d_in[0];
    const float* inw   = (const float*)d_in[1];
    const float* ffnw  = (const float*)d_in[2];
    const float* inpW  = (const float*)d_in[3];
    const float* convW = (const float*)d_in[4];
    const float* convB = (const float*)d_in[5];
    const float* dtW   = (const float*)d_in[6];
    const float* dtB   = (const float*)d_in[7];
    const float* BW    = (const float*)d_in[8];
    const float* CW    = (const float*)d_in[9];
    const float* Alog  = (const float*)d_in[10];
    const float* outpW = (const float*)d_in[11];
    const float* gateW = (const float*)d_in[12];
    const float* upW   = (const float*)d_in[13];
    const float* downW = (const float*)d_in[14];
    float* out = (float*)d_out;

    char* p = (char*)d_ws;
    auto alloc = [&](size_t n) { char* q = p; p += (n + 255) & ~(size_t)255; return q; };
    __bf16* wt_inproj = (__bf16*)alloc(4096ull * 1024 * 2);
    __bf16* wt_dtbc   = (__bf16*)alloc(2176ull * 2048 * 2);  // rows 0-2047 dt, 2048+ {B,C}
    __bf16* wt_outp   = (__bf16*)alloc(1024ull * 2048 * 2);
    __bf16* wt_gu     = (__bf16*)alloc(4096ull * 1024 * 2);
    __bf16* wt_down   = (__bf16*)alloc(1024ull * 2048 * 2);
    __bf16* normed    = (__bf16*)alloc(2048ull * 1024 * 2);  // reused as n2
    __bf16* xz        = (__bf16*)alloc(2048ull * 2048 * 2);  // x_z half of in_proj
    __bf16* gu_buf    = (__bf16*)alloc(2048ull * 4096 * 2);  // dAp then gu
    __bf16* xc        = (__bf16*)alloc(2048ull * 2048 * 2);  // conv out, reused as y
    float*  scratch16 = (float*)alloc(2048ull * 2048 * 4);   // hend/h0 then ffnmid
    float*  bc        = (float*)alloc(2048ull * 128 * 4);
    float*  dtT       = (float*)alloc(2048ull * 2048 * 4);
    __bf16* xcT       = (__bf16*)alloc(2048ull * 2048 * 2);
    __bf16* szT       = (__bf16*)alloc(2048ull * 2048 * 2);
    float*  x2        = (float*)alloc(2048ull * 1024 * 4);

    dim3 B256(256);
    // weight prep (f32 -> bf16, transposed to [N][K])
    transpose_kernel<float, __bf16><<<dim3(128, 32), B256, 0, stream>>>(inpW, wt_inproj, 1024, 4096, 4096, 1, 0);
    transpose_kernel<float, __bf16><<<dim3(64, 64), B256, 0, stream>>>(dtW, wt_dtbc, 2048, 2048, 2048, 1, 0);
    transpose_kernel<float, __bf16><<<dim3(2, 64), B256, 0, stream>>>(BW, wt_dtbc + 2048ull * 2048, 2048, 64, 64, 2, 0);
    transpose_kernel<float, __bf16><<<dim3(2, 64), B256, 0, stream>>>(CW, wt_dtbc + 2048ull * 2048, 2048, 64, 64, 2, 1);
    transpose_kernel<float, __bf16><<<dim3(32, 64), B256, 0, stream>>>(outpW, wt_outp, 2048, 1024, 1024, 1, 0);
    transpose_kernel<float, __bf16><<<dim3(64, 32), B256, 0, stream>>>(gateW, wt_gu, 1024, 2048, 2048, 1, 0);
    transpose_kernel<float, __bf16><<<dim3(64, 32), B256, 0, stream>>>(upW, wt_gu + 2048ull * 1024, 1024, 2048, 2048, 1, 0);
    transpose_kernel<float, __bf16><<<dim3(32, 64), B256, 0, stream>>>(downW, wt_down, 2048, 1024, 1024, 1, 0);

    // normed = rmsnorm(x, inw)
    rmsnorm_kernel<<<dim3(2048), B256, 0, stream>>>(x, inw, normed);
    // in_proj: xz (t-major bf16) + szT (silu'd z, channel-major)
    gemm_kernel<4><<<dim3(32, 16), B256, 0, stream>>>(normed, wt_inproj, xz, szT, nullptr, 2048, 4096, 1024);
    // xc = silu(conv(xz) + b)
    conv_silu_kernel<<<dim3(T_TOK * EDIM / 256), B256, 0, stream>>>(xz, convW, convB, xc);
    // fused dt+bc: dtT (softplus'd, channel-major f32) + bc (t-major f32)
    gemm_kernel<3><<<dim3(17, 16), B256, 0, stream>>>(xc, wt_dtbc, dtT, bc, dtB, 2048, 2176, 2048);
    // xcT channel-major
    transpose_kernel<__bf16, __bf16><<<dim3(64, 64), B256, 0, stream>>>(xc, xcT, 2048, 2048, 2048, 1, 0);

    // chunked SSM scan
    float* hend = scratch16;                      // 16 MB (E*32*64 f32)
    float* dAp  = (float*)gu_buf;                 // 16 MB
    scan1_kernel<<<dim3(4096), dim3(512), 0, stream>>>(dtT, xcT, bc, Alog, hend, dAp);
    scan_mid_kernel<<<dim3(512), B256, 0, stream>>>(hend, dAp);
    __bf16* y = xc;                               // xc dead after xcT+dt GEMM
    scan2_kernel<<<dim3(4096), dim3(512), 0, stream>>>(dtT, xcT, szT, bc, Alog, hend, y);

    // x2 = x + y @ out_proj
    gemm_kernel<2><<<dim3(8, 16), B256, 0, stream>>>(y, wt_outp, x2, nullptr, x, 2048, 1024, 2048);
    // n2 = rmsnorm(x2, ffnw)
    rmsnorm_kernel<<<dim3(2048), B256, 0, stream>>>(x2, ffnw, normed);
    // gu = n2 @ [gate|up]
    __bf16* gu = gu_buf;
    gemm_kernel<1><<<dim3(32, 16), B256, 0, stream>>>(normed, wt_gu, gu, nullptr, nullptr, 2048, 4096, 1024);
    // ffnmid = silu(gate)*up
    __bf16* ffnmid = (__bf16*)scratch16;
    glu_kernel<<<dim3(T_TOK * 2048 / 256), B256, 0, stream>>>(gu, ffnmid);
    // out = x2 + ffnmid @ down
    gemm_kernel<2><<<dim3(8, 16), B256, 0, stream>>>(ffnmid, wt_down, out, nullptr, x2, 2048, 1024, 2048);
}

// Round 11
// 413.177 us; speedup vs baseline: 1.7889x; 1.1378x over previous
//
#include <hip/hip_runtime.h>
#include <hip/hip_bf16.h>

typedef __bf16 bf16x8 __attribute__((ext_vector_type(8)));
typedef __bf16 bf16x4 __attribute__((ext_vector_type(4)));
typedef float  f32x4  __attribute__((ext_vector_type(4)));

#define T_TOK 2048
#define DDIM  1024
#define EDIM  2048
#define NCHUNK 32
#define CKLEN  64

// ---------------------------------------------------------------- transpose
// dst[(c*dmul + doff)*R + r] = src[r*S + c];  R,C multiples of 32.
template<typename TS, typename TD>
__global__ __launch_bounds__(256)
void transpose_kernel(const TS* __restrict__ src, TD* __restrict__ dst,
                      int R, int C, int S, int dmul, int doff)
{
    __shared__ float tile[32][33];
    const int tc0 = blockIdx.x * 32, tr0 = blockIdx.y * 32;
    const int tx = threadIdx.x & 31, ty = threadIdx.x >> 5;
#pragma unroll
    for (int p = 0; p < 4; ++p) {
        int rl = ty + p * 8;
        tile[rl][tx] = (float)src[(size_t)(tr0 + rl) * S + tc0 + tx];
    }
    __syncthreads();
#pragma unroll
    for (int p = 0; p < 4; ++p) {
        int cl = ty + p * 8;
        float v = tile[tx][cl];
        int c = tc0 + cl, r = tr0 + tx;
        dst[((size_t)c * dmul + doff) * R + r] = (TD)v;
    }
}

// ---------------------------------------------------------------- rmsnorm
__global__ __launch_bounds__(256)
void rmsnorm_kernel(const float* __restrict__ x, const float* __restrict__ w,
                    __bf16* __restrict__ out)
{
    const int row = blockIdx.x;
    const int t = threadIdx.x;
    float4 v = ((const float4*)(x + (size_t)row * DDIM))[t];
    float ss = v.x * v.x + v.y * v.y + v.z * v.z + v.w * v.w;
#pragma unroll
    for (int m = 32; m; m >>= 1) ss += __shfl_xor(ss, m);
    __shared__ float red[4];
    if ((t & 63) == 0) red[t >> 6] = ss;
    __syncthreads();
    float scale = rsqrtf((red[0] + red[1] + red[2] + red[3]) * (1.f / DDIM) + 1e-5f);
    float4 wv = ((const float4*)w)[t];
    __bf16* o = out + (size_t)row * DDIM + t * 4;
    o[0] = (__bf16)(v.x * scale * wv.x);
    o[1] = (__bf16)(v.y * scale * wv.y);
    o[2] = (__bf16)(v.z * scale * wv.z);
    o[3] = (__bf16)(v.w * scale * wv.w);
}

// ---------------------------------------------------------------- conv+silu
__global__ __launch_bounds__(256)
void conv_silu_kernel(const __bf16* __restrict__ xz, const float* __restrict__ W,
                      const float* __restrict__ b, __bf16* __restrict__ xc)
{
    int idx = blockIdx.x * 256 + threadIdx.x;     // over T*E
    int t = idx >> 11, e = idx & (EDIM - 1);
    float s = b[e];
#pragma unroll
    for (int k = 0; k < 4; ++k) {                 // SAME pad: taps t-1..t+2
        int tt = t - 1 + k;
        if (tt >= 0 && tt < T_TOK)
            s += (float)xz[(size_t)tt * EDIM + e] * W[k * EDIM + e];
    }
    s = s / (1.f + __expf(-s));
    xc[idx] = (__bf16)s;
}

// ---------------------------------------------------------------- glu
__global__ __launch_bounds__(256)
void glu_kernel(const __bf16* __restrict__ gu, __bf16* __restrict__ outm)
{
    int idx = blockIdx.x * 256 + threadIdx.x;     // over T*I
    int t = idx >> 11, i = idx & 2047;
    float g = (float)gu[(size_t)t * 4096 + i];
    float u = (float)gu[(size_t)t * 4096 + 2048 + i];
    outm[idx] = (__bf16)(g / (1.f + __expf(-g)) * u);
}

// ---------------------------------------------------------------- scan
template<int CTRL, int ROWMASK>
__device__ __forceinline__ float dpp_add(float v)
{
    int y = __builtin_amdgcn_update_dpp(0, __builtin_bit_cast(int, v),
                                        CTRL, ROWMASK, 0xf, true);
    return v + __builtin_bit_cast(float, y);
}

// bc2 layout: bc2[t*128 + 4i] = {B[t,2i], C[t,2i], B[t,2i+1], C[t,2i+1]}.

// Pass 1 (unchanged layout): block = 8 waves, 16 channels, one chunk.
// Wave w: channels eg+2w (lanes 0-31) / eg+2w+1 (lanes 32-63); 2 states/lane.
__global__ __launch_bounds__(512)
void scan1_kernel(const float* __restrict__ dtT, const __bf16* __restrict__ xcT,
                  const float* __restrict__ bc2, const float* __restrict__ A_log,
                  float* __restrict__ hend, float* __restrict__ dAp)
{
    __shared__ float  s_bc[CKLEN * 128];   // 32 KB
    __shared__ float  s_dt[16][CKLEN];     // 4 KB
    __shared__ __bf16 s_x[16][CKLEN];      // 2 KB
    const int tid = threadIdx.x;
    const int lane = tid & 63, w = tid >> 6;
    const int c = lane >> 5, i = lane & 31;
    const int ck = blockIdx.x & (NCHUNK - 1);
    const int eg = (blockIdx.x >> 5) * 16;

    {
        const float4* sb = (const float4*)(bc2 + (size_t)ck * CKLEN * 128);
        float4* db = (float4*)s_bc;
#pragma unroll
        for (int r = 0; r < 4; ++r) db[r * 512 + tid] = sb[r * 512 + tid];
        if (tid < 256) {
            int ch = tid >> 4, k = tid & 15;
            *((float4*)&s_dt[ch][0] + k) =
                *(const float4*)(dtT + (size_t)(eg + ch) * T_TOK + ck * CKLEN + 4 * k);
        } else if (tid < 384) {
            int q = tid - 256, ch = q >> 3, k = q & 7;
            *((bf16x8*)&s_x[ch][0] + k) =
                *(const bf16x8*)(xcT + (size_t)(eg + ch) * T_TOK + ck * CKLEN + 8 * k);
        }
    }
    __syncthreads();

    const int ch = 2 * w + c;
    float2 al = *(const float2*)(A_log + 2 * i);
    const float L2E = 1.44269504f;
    const float An0 = -__expf(al.x) * L2E;
    const float An1 = -__expf(al.y) * L2E;
    float h0 = 0.f, h1 = 0.f, D = 0.f;

#pragma unroll 2
    for (int t0 = 0; t0 < CKLEN; t0 += 8) {
        float4 da = *(const float4*)&s_dt[ch][t0];
        float4 db = *(const float4*)&s_dt[ch][t0 + 4];
        bf16x8 x8 = *(const bf16x8*)&s_x[ch][t0];
        float dtv[8] = {da.x, da.y, da.z, da.w, db.x, db.y, db.z, db.w};
#pragma unroll
        for (int j = 0; j < 8; ++j) {
            float4 bcv = *(const float4*)&s_bc[(t0 + j) * 128 + 4 * i];
            float u = dtv[j] * (float)x8[j];
            float dA0 = __builtin_amdgcn_exp2f(dtv[j] * An0);
            float dA1 = __builtin_amdgcn_exp2f(dtv[j] * An1);
            h0 = fmaf(dA0, h0, u * bcv.x);
            h1 = fmaf(dA1, h1, u * bcv.z);
            D += dtv[j];
        }
    }
    const int e = eg + ch;
    size_t idx = ((size_t)e * NCHUNK + ck) * 64 + 2 * i;
    *(float2*)(hend + idx) = make_float2(h0, h1);
    *(float2*)(dAp + idx)  = make_float2(__builtin_amdgcn_exp2f(An0 * D),
                                         __builtin_amdgcn_exp2f(An1 * D));
}

// Mid: serial scan over chunk summaries -> h_start per chunk, IN PLACE over hend.
__global__ __launch_bounds__(256)
void scan_mid_kernel(float* __restrict__ hend_h0, const float* __restrict__ dAp)
{
    int gid = blockIdx.x * 256 + threadIdx.x;     // over E*64
    int e = gid >> 6, n = gid & 63;
    float h = 0.f;
#pragma unroll
    for (int ck = 0; ck < NCHUNK; ++ck) {
        size_t idx = ((size_t)e * NCHUNK + ck) * 64 + n;
        float he = hend_h0[idx];
        float P  = dAp[idx];
        hend_h0[idx] = h;
        h = P * h + he;
    }
}

// Pass 2: block = 8 waves, 32 channels, one chunk.
// Wave w: 4 channels (w*4+g, g=lane>>4), 16 lanes/channel, 4 states/lane
// (states 4i..4i+3, i=lane&15).  Reduction = 4-step DPP row_shr tree within
// the native 16-lane row; lane i==15 holds the channel sum (no readlane).
__global__ __launch_bounds__(512)
void scan2_kernel(const float* __restrict__ dtT, const __bf16* __restrict__ xcT,
                  const __bf16* __restrict__ szT, const float* __restrict__ bc2,
                  const float* __restrict__ A_log, const float* __restrict__ h0s,
                  __bf16* __restrict__ y)
{
    __shared__ float  s_bc[CKLEN * 128];   // 32 KB
    __shared__ float  s_dt[32][68];        // 8.5 KB (padded rows)
    __shared__ __bf16 s_x[32][72];         // 4.5 KB (padded rows)
    __shared__ __bf16 s_y[CKLEN][36];      // 4.5 KB (padded, t-major tile)
    const int tid = threadIdx.x;
    const int lane = tid & 63, w = tid >> 6;
    const int g = lane >> 4, i = lane & 15;
    const int ck = blockIdx.x & (NCHUNK - 1);
    const int eg = (blockIdx.x >> 5) * 32;

    // ---- stage
    {
        const float4* sb = (const float4*)(bc2 + (size_t)ck * CKLEN * 128);
        float4* db = (float4*)s_bc;
#pragma unroll
        for (int r = 0; r < 4; ++r) db[r * 512 + tid] = sb[r * 512 + tid];
        { int ch = tid >> 4, k = tid & 15;      // 512 = 32ch x 16
          *(float4*)&s_dt[ch][4 * k] =
              *(const float4*)(dtT + (size_t)(eg + ch) * T_TOK + ck * CKLEN + 4 * k); }
        if (tid < 256) { int ch = tid >> 3, k = tid & 7;   // 256 = 32ch x 8
          *(bf16x8*)&s_x[ch][8 * k] =
              *(const bf16x8*)(xcT + (size_t)(eg + ch) * T_TOK + ck * CKLEN + 8 * k); }
    }
    __syncthreads();

    const int ch = w * 4 + g;
    const int e = eg + ch;
    float4 al4 = *(const float4*)(A_log + 4 * i);
    const float L2E = 1.44269504f;
    const float An0 = -__expf(al4.x) * L2E;
    const float An1 = -__expf(al4.y) * L2E;
    const float An2 = -__expf(al4.z) * L2E;
    const float An3 = -__expf(al4.w) * L2E;
    float4 hh = *(const float4*)(h0s + ((size_t)e * NCHUNK + ck) * 64 + 4 * i);
    float h0 = hh.x, h1 = hh.y, h2 = hh.z, h3 = hh.w;

#pragma unroll 2
    for (int t0 = 0; t0 < CKLEN; t0 += 8) {
        float4 da = *(const float4*)&s_dt[ch][t0];
        float4 db = *(const float4*)&s_dt[ch][t0 + 4];
        bf16x8 x8 = *(const bf16x8*)&s_x[ch][t0];
        float dtv[8] = {da.x, da.y, da.z, da.w, db.x, db.y, db.z, db.w};
#pragma unroll
        for (int j = 0; j < 8; ++j) {
            float4 b0 = *(const float4*)&s_bc[(t0 + j) * 128 + 8 * i];
            float4 b1 = *(const float4*)&s_bc[(t0 + j) * 128 + 8 * i + 4];
            float dt = dtv[j];
            float u = dt * (float)x8[j];
            h0 = fmaf(__builtin_amdgcn_exp2f(dt * An0), h0, u * b0.x);
            h1 = fmaf(__builtin_amdgcn_exp2f(dt * An1), h1, u * b0.z);
            h2 = fmaf(__builtin_amdgcn_exp2f(dt * An2), h2, u * b1.x);
            h3 = fmaf(__builtin_amdgcn_exp2f(dt * An3), h3, u * b1.z);
            float p = h0 * b0.y;
            p = fmaf(h1, b0.w, p);
            p = fmaf(h2, b1.y, p);
            p = fmaf(h3, b1.w, p);
            // 4-step tree within 16-lane row; lane i==15 gets the sum
            p = dpp_add<0x111, 0xf>(p);   // row_shr:1
            p = dpp_add<0x112, 0xf>(p);   // row_shr:2
            p = dpp_add<0x114, 0xf>(p);   // row_shr:4
            p = dpp_add<0x118, 0xf>(p);   // row_shr:8
            if (i == 15) s_y[t0 + j][ch] = (__bf16)p;
        }
    }
    __syncthreads();

    // gate with silu(z) (already applied in szT) and write y t-major
    {
        int tt = tid >> 3, q = tid & 7;          // 64 t-rows x 8 threads
        bf16x4 o;
#pragma unroll
        for (int d = 0; d < 4; ++d) {
            float zv = (float)szT[(size_t)(eg + 4 * q + d) * T_TOK + ck * CKLEN + tt];
            o[d] = (__bf16)((float)s_y[tt][4 * q + d] * zv);
        }
        *(bf16x4*)(y + (size_t)(ck * CKLEN + tt) * EDIM + eg + 4 * q) = o;
    }
}

// ---------------------------------------------------------------- GEMM
// C[M,N] = A[M,K] @ Bt[N,K]^T.  M mult of TM, N mult of 128, K mult of 32.
// EPI 1: bf16 store (stride N).
// EPI 2: f32 store of acc + res (stride N).
// EPI 3: dt+bc fused (see R10 comment).
// EPI 4: in_proj split (see R10 comment).
__device__ __forceinline__ void glds16(const __bf16* g, __bf16* l)
{
    __builtin_amdgcn_global_load_lds(
        (const __attribute__((address_space(1))) unsigned*)g,
        (__attribute__((address_space(3))) unsigned*)l, 16, 0, 0);
}

template<int EPI, int TM>
__global__ __launch_bounds__(256)
void gemm_kernel(const __bf16* __restrict__ A, const __bf16* __restrict__ Bt,
                 void* __restrict__ Cout, void* __restrict__ Cout2,
                 const float* __restrict__ res, int M, int N, int K)
{
    constexpr int MF = TM / 32;          // m-frags per wave
    __shared__ __bf16 sAl[TM * 32];      // linear [row][k] tile
    __shared__ __bf16 sBl[128 * 32];
    const int t = threadIdx.x;
    const int wave = t >> 6, lane = t & 63;
    const int brow = blockIdx.y * TM, bcol = blockIdx.x * 128;
    const int wr = (wave >> 1) * (TM / 2), wc = (wave & 1) * 64;
    const int w16 = wave * 16;
    f32x4 acc[MF][4] = {};

    const __bf16* gA = A  + (size_t)(brow + w16 + (lane >> 2)) * K + (lane & 3) * 8;
    const __bf16* gB = Bt + (size_t)(bcol + w16 + (lane >> 2)) * K + (lane & 3) * 8;
    __bf16* lA0 = sAl + w16 * 32;
    __bf16* lA1 = sAl + (w16 + 64) * 32;
    __bf16* lB0 = sBl + w16 * 32;
    __bf16* lB1 = sBl + (w16 + 64) * 32;

    for (int k0 = 0; k0 < K; k0 += 32) {
        __syncthreads();
        glds16(gA + k0, lA0);
        if constexpr (TM == 128) glds16(gA + (size_t)64 * K + k0, lA1);
        glds16(gB + k0, lB0);
        glds16(gB + (size_t)64 * K + k0, lB1);
        __syncthreads();
        bf16x8 af[MF], bg[4];
#pragma unroll
        for (int m = 0; m < MF; ++m)
            af[m] = *(const bf16x8*)&sAl[(wr + m * 16 + (lane & 15)) * 32 + (lane >> 4) * 8];
#pragma unroll
        for (int n = 0; n < 4; ++n)
            bg[n] = *(const bf16x8*)&sBl[(wc + n * 16 + (lane & 15)) * 32 + (lane >> 4) * 8];
#pragma unroll
        for (int m = 0; m < MF; ++m)
#pragma unroll
            for (int n = 0; n < 4; ++n)
                acc[m][n] = __builtin_amdgcn_mfma_f32_16x16x32_bf16(
                    af[m], bg[n], acc[m][n], 0, 0, 0);
    }

    const int c_l = lane & 15, r_l = (lane >> 4) * 4;
#pragma unroll
    for (int m = 0; m < MF; ++m) {
#pragma unroll
        for (int n = 0; n < 4; ++n) {
            int row = brow + wr + m * 16 + r_l;
            int col = bcol + wc + n * 16 + c_l;
            if (EPI == 1) {
#pragma unroll
                for (int i = 0; i < 4; ++i)
                    ((__bf16*)Cout)[(size_t)(row + i) * N + col] = (__bf16)acc[m][n][i];
            } else if (EPI == 2) {
#pragma unroll
                for (int i = 0; i < 4; ++i) {
                    size_t off = (size_t)(row + i) * N + col;
                    ((float*)Cout)[off] = acc[m][n][i] + res[off];
                }
            } else if (EPI == 3) {
                if (col < 2048) {
                    float bias = res[col];
                    float4 v;
                    float* vv = (float*)&v;
#pragma unroll
                    for (int i = 0; i < 4; ++i) {
                        float s = acc[m][n][i] + bias;
                        s = (s > 20.f) ? s : log1pf(__expf(s));
                        vv[i] = fminf(fmaxf(s, 0.001f), 0.1f);
                    }
                    *(float4*)((float*)Cout + (size_t)col * T_TOK + row) = v;
                } else {
#pragma unroll
                    for (int i = 0; i < 4; ++i)
                        ((float*)Cout2)[(size_t)(row + i) * 128 + (col - 2048)] = acc[m][n][i];
                }
            } else if (EPI == 4) {
                if (col < 2048) {
#pragma unroll
                    for (int i = 0; i < 4; ++i)
                        ((__bf16*)Cout)[(size_t)(row + i) * EDIM + col] = (__bf16)acc[m][n][i];
                } else {
                    bf16x4 v;
#pragma unroll
                    for (int i = 0; i < 4; ++i) {
                        float s = acc[m][n][i];
                        v[i] = (__bf16)(s / (1.f + __expf(-s)));
                    }
                    *(bf16x4*)((__bf16*)Cout2 + (size_t)(col - 2048) * T_TOK + row) = v;
                }
            }
        }
    }
}

// ---------------------------------------------------------------- launch
extern "C" void kernel_launch(void* const* d_in, const int* in_sizes, int n_in,
                              void* d_out, int out_size, void* d_ws, size_t ws_size,
                              hipStream_t stream)
{
    (void)in_sizes; (void)n_in; (void)out_size; (void)ws_size;
    const float* x     = (const float*)d_in[0];
    const float* inw   = (const float*)d_in[1];
    const float* ffnw  = (const float*)d_in[2];
    const float* inpW  = (const float*)d_in[3];
    const float* convW = (const float*)d_in[4];
    const float* convB = (const float*)d_in[5];
    const float* dtW   = (const float*)d_in[6];
    const float* dtB   = (const float*)d_in[7];
    const float* BW    = (const float*)d_in[8];
    const float* CW    = (const float*)d_in[9];
    const float* Alog  = (const float*)d_in[10];
    const float* outpW = (const float*)d_in[11];
    const float* gateW = (const float*)d_in[12];
    const float* upW   = (const float*)d_in[13];
    const float* downW = (const float*)d_in[14];
    float* out = (float*)d_out;

    char* p = (char*)d_ws;
    auto alloc = [&](size_t n) { char* q = p; p += (n + 255) & ~(size_t)255; return q; };
    __bf16* wt_inproj = (__bf16*)alloc(4096ull * 1024 * 2);
    __bf16* wt_dtbc   = (__bf16*)alloc(2176ull * 2048 * 2);  // rows 0-2047 dt, 2048+ {B,C}
    __bf16* wt_outp   = (__bf16*)alloc(1024ull * 2048 * 2);
    __bf16* wt_gu     = (__bf16*)alloc(4096ull * 1024 * 2);
    __bf16* wt_down   = (__bf16*)alloc(1024ull * 2048 * 2);
    __bf16* normed    = (__bf16*)alloc(2048ull * 1024 * 2);  // reused as n2
    __bf16* xz        = (__bf16*)alloc(2048ull * 2048 * 2);  // x_z half of in_proj
    __bf16* gu_buf    = (__bf16*)alloc(2048ull * 4096 * 2);  // dAp then gu
    __bf16* xc        = (__bf16*)alloc(2048ull * 2048 * 2);  // conv out, reused as y
    float*  scratch16 = (float*)alloc(2048ull * 2048 * 4);   // hend/h0 then ffnmid
    float*  bc        = (float*)alloc(2048ull * 128 * 4);
    float*  dtT       = (float*)alloc(2048ull * 2048 * 4);
    __bf16* xcT       = (__bf16*)alloc(2048ull * 2048 * 2);
    __bf16* szT       = (__bf16*)alloc(2048ull * 2048 * 2);
    float*  x2        = (float*)alloc(2048ull * 1024 * 4);

    dim3 B256(256);
    // weight prep (f32 -> bf16, transposed to [N][K])
    transpose_kernel<float, __bf16><<<dim3(128, 32), B256, 0, stream>>>(inpW, wt_inproj, 1024, 4096, 4096, 1, 0);
    transpose_kernel<float, __bf16><<<dim3(64, 64), B256, 0, stream>>>(dtW, wt_dtbc, 2048, 2048, 2048, 1, 0);
    transpose_kernel<float, __bf16><<<dim3(2, 64), B256, 0, stream>>>(BW, wt_dtbc + 2048ull * 2048, 2048, 64, 64, 2, 0);
    transpose_kernel<float, __bf16><<<dim3(2, 64), B256, 0, stream>>>(CW, wt_dtbc + 2048ull * 2048, 2048, 64, 64, 2, 1);
    transpose_kernel<float, __bf16><<<dim3(32, 64), B256, 0, stream>>>(outpW, wt_outp, 2048, 1024, 1024, 1, 0);
    transpose_kernel<float, __bf16><<<dim3(64, 32), B256, 0, stream>>>(gateW, wt_gu, 1024, 2048, 2048, 1, 0);
    transpose_kernel<float, __bf16><<<dim3(64, 32), B256, 0, stream>>>(upW, wt_gu + 2048ull * 1024, 1024, 2048, 2048, 1, 0);
    transpose_kernel<float, __bf16><<<dim3(32, 64), B256, 0, stream>>>(downW, wt_down, 2048, 1024, 1024, 1, 0);

    // normed = rmsnorm(x, inw)
    rmsnorm_kernel<<<dim3(2048), B256, 0, stream>>>(x, inw, normed);
    // in_proj: xz (t-major bf16) + szT (silu'd z, channel-major)
    gemm_kernel<4, 128><<<dim3(32, 16), B256, 0, stream>>>(normed, wt_inproj, xz, szT, nullptr, 2048, 4096, 1024);
    // xc = silu(conv(xz) + b)
    conv_silu_kernel<<<dim3(T_TOK * EDIM / 256), B256, 0, stream>>>(xz, convW, convB, xc);
    // fused dt+bc: dtT (softplus'd, channel-major f32) + bc (t-major f32)
    gemm_kernel<3, 128><<<dim3(17, 16), B256, 0, stream>>>(xc, wt_dtbc, dtT, bc, dtB, 2048, 2176, 2048);
    // xcT channel-major
    transpose_kernel<__bf16, __bf16><<<dim3(64, 64), B256, 0, stream>>>(xc, xcT, 2048, 2048, 2048, 1, 0);

    // chunked SSM scan
    float* hend = scratch16;                      // 16 MB (E*32*64 f32)
    float* dAp  = (float*)gu_buf;                 // 16 MB
    scan1_kernel<<<dim3(4096), dim3(512), 0, stream>>>(dtT, xcT, bc, Alog, hend, dAp);
    scan_mid_kernel<<<dim3(512), B256, 0, stream>>>(hend, dAp);
    __bf16* y = xc;                               // xc dead after xcT+dt GEMM
    scan2_kernel<<<dim3(2048), dim3(512), 0, stream>>>(dtT, xcT, szT, bc, Alog, hend, y);

    // x2 = x + y @ out_proj
    gemm_kernel<2, 64><<<dim3(8, 32), B256, 0, stream>>>(y, wt_outp, x2, nullptr, x, 2048, 1024, 2048);
    // n2 = rmsnorm(x2, ffnw)
    rmsnorm_kernel<<<dim3(2048), B256, 0, stream>>>(x2, ffnw, normed);
    // gu = n2 @ [gate|up]
    __bf16* gu = gu_buf;
    gemm_kernel<1, 128><<<dim3(32, 16), B256, 0, stream>>>(normed, wt_gu, gu, nullptr, nullptr, 2048, 4096, 1024);
    // ffnmid = silu(gate)*up
    __bf16* ffnmid = (__bf16*)scratch16;
    glu_kernel<<<dim3(T_TOK * 2048 / 256), B256, 0, stream>>>(gu, ffnmid);
    // out = x2 + ffnmid @ down
    gemm_kernel<2, 64><<<dim3(8, 32), B256, 0, stream>>>(ffnmid, wt_down, out, nullptr, x2, 2048, 1024, 2048);
}

// Round 12
// 386.591 us; speedup vs baseline: 1.9119x; 1.0688x over previous
//
#include <hip/hip_runtime.h>
#include <hip/hip_bf16.h>

typedef __bf16 bf16x8 __attribute__((ext_vector_type(8)));
typedef __bf16 bf16x4 __attribute__((ext_vector_type(4)));
typedef float  f32x4  __attribute__((ext_vector_type(4)));

#define T_TOK 2048
#define DDIM  1024
#define EDIM  2048
#define NCHUNK 32
#define CKLEN  64

// ---------------------------------------------------------------- transpose
// dst[(c*dmul + doff)*R + r] = src[r*S + c];  R,C multiples of 32.
template<typename TS, typename TD>
__global__ __launch_bounds__(256)
void transpose_kernel(const TS* __restrict__ src, TD* __restrict__ dst,
                      int R, int C, int S, int dmul, int doff)
{
    __shared__ float tile[32][33];
    const int tc0 = blockIdx.x * 32, tr0 = blockIdx.y * 32;
    const int tx = threadIdx.x & 31, ty = threadIdx.x >> 5;
#pragma unroll
    for (int p = 0; p < 4; ++p) {
        int rl = ty + p * 8;
        tile[rl][tx] = (float)src[(size_t)(tr0 + rl) * S + tc0 + tx];
    }
    __syncthreads();
#pragma unroll
    for (int p = 0; p < 4; ++p) {
        int cl = ty + p * 8;
        float v = tile[tx][cl];
        int c = tc0 + cl, r = tr0 + tx;
        dst[((size_t)c * dmul + doff) * R + r] = (TD)v;
    }
}

// ---------------------------------------------------------------- rmsnorm
__global__ __launch_bounds__(256)
void rmsnorm_kernel(const float* __restrict__ x, const float* __restrict__ w,
                    __bf16* __restrict__ out)
{
    const int row = blockIdx.x;
    const int t = threadIdx.x;
    float4 v = ((const float4*)(x + (size_t)row * DDIM))[t];
    float ss = v.x * v.x + v.y * v.y + v.z * v.z + v.w * v.w;
#pragma unroll
    for (int m = 32; m; m >>= 1) ss += __shfl_xor(ss, m);
    __shared__ float red[4];
    if ((t & 63) == 0) red[t >> 6] = ss;
    __syncthreads();
    float scale = rsqrtf((red[0] + red[1] + red[2] + red[3]) * (1.f / DDIM) + 1e-5f);
    float4 wv = ((const float4*)w)[t];
    __bf16* o = out + (size_t)row * DDIM + t * 4;
    o[0] = (__bf16)(v.x * scale * wv.x);
    o[1] = (__bf16)(v.y * scale * wv.y);
    o[2] = (__bf16)(v.z * scale * wv.z);
    o[3] = (__bf16)(v.w * scale * wv.w);
}

// ---------------------------------------------------------------- conv+silu
__global__ __launch_bounds__(256)
void conv_silu_kernel(const __bf16* __restrict__ xz, const float* __restrict__ W,
                      const float* __restrict__ b, __bf16* __restrict__ xc)
{
    int idx = blockIdx.x * 256 + threadIdx.x;     // over T*E
    int t = idx >> 11, e = idx & (EDIM - 1);
    float s = b[e];
#pragma unroll
    for (int k = 0; k < 4; ++k) {                 // SAME pad: taps t-1..t+2
        int tt = t - 1 + k;
        if (tt >= 0 && tt < T_TOK)
            s += (float)xz[(size_t)tt * EDIM + e] * W[k * EDIM + e];
    }
    s = s / (1.f + __expf(-s));
    xc[idx] = (__bf16)s;
}

// ---------------------------------------------------------------- glu
__global__ __launch_bounds__(256)
void glu_kernel(const __bf16* __restrict__ gu, __bf16* __restrict__ outm)
{
    int idx = blockIdx.x * 256 + threadIdx.x;     // over T*I
    int t = idx >> 11, i = idx & 2047;
    float g = (float)gu[(size_t)t * 4096 + i];
    float u = (float)gu[(size_t)t * 4096 + 2048 + i];
    outm[idx] = (__bf16)(g / (1.f + __expf(-g)) * u);
}

// ---------------------------------------------------------------- scan
template<int CTRL, int ROWMASK>
__device__ __forceinline__ float dpp_add(float v)
{
    int y = __builtin_amdgcn_update_dpp(0, __builtin_bit_cast(int, v),
                                        CTRL, ROWMASK, 0xf, true);
    return v + __builtin_bit_cast(float, y);
}

// bc2 layout: bc2[t*128 + 4i] = {B[t,2i], C[t,2i], B[t,2i+1], C[t,2i+1]}.

// Pass 1: block = 8 waves, 16 channels, one chunk.
// Wave w: channels eg+2w (lanes 0-31) / eg+2w+1 (lanes 32-63); 2 states/lane.
__global__ __launch_bounds__(512)
void scan1_kernel(const float* __restrict__ dtT, const __bf16* __restrict__ xcT,
                  const float* __restrict__ bc2, const float* __restrict__ A_log,
                  float* __restrict__ hend, float* __restrict__ dAp)
{
    __shared__ float  s_bc[CKLEN * 128];   // 32 KB
    __shared__ float  s_dt[16][CKLEN];     // 4 KB
    __shared__ __bf16 s_x[16][CKLEN];      // 2 KB
    const int tid = threadIdx.x;
    const int lane = tid & 63, w = tid >> 6;
    const int c = lane >> 5, i = lane & 31;
    const int ck = blockIdx.x & (NCHUNK - 1);
    const int eg = (blockIdx.x >> 5) * 16;

    {
        const float4* sb = (const float4*)(bc2 + (size_t)ck * CKLEN * 128);
        float4* db = (float4*)s_bc;
#pragma unroll
        for (int r = 0; r < 4; ++r) db[r * 512 + tid] = sb[r * 512 + tid];
        if (tid < 256) {
            int ch = tid >> 4, k = tid & 15;
            *((float4*)&s_dt[ch][0] + k) =
                *(const float4*)(dtT + (size_t)(eg + ch) * T_TOK + ck * CKLEN + 4 * k);
        } else if (tid < 384) {
            int q = tid - 256, ch = q >> 3, k = q & 7;
            *((bf16x8*)&s_x[ch][0] + k) =
                *(const bf16x8*)(xcT + (size_t)(eg + ch) * T_TOK + ck * CKLEN + 8 * k);
        }
    }
    __syncthreads();

    const int ch = 2 * w + c;
    float2 al = *(const float2*)(A_log + 2 * i);
    const float L2E = 1.44269504f;
    const float An0 = -__expf(al.x) * L2E;
    const float An1 = -__expf(al.y) * L2E;
    float h0 = 0.f, h1 = 0.f, D = 0.f;

#pragma unroll 2
    for (int t0 = 0; t0 < CKLEN; t0 += 8) {
        float4 da = *(const float4*)&s_dt[ch][t0];
        float4 db = *(const float4*)&s_dt[ch][t0 + 4];
        bf16x8 x8 = *(const bf16x8*)&s_x[ch][t0];
        float dtv[8] = {da.x, da.y, da.z, da.w, db.x, db.y, db.z, db.w};
#pragma unroll
        for (int j = 0; j < 8; ++j) {
            float4 bcv = *(const float4*)&s_bc[(t0 + j) * 128 + 4 * i];
            float u = dtv[j] * (float)x8[j];
            float dA0 = __builtin_amdgcn_exp2f(dtv[j] * An0);
            float dA1 = __builtin_amdgcn_exp2f(dtv[j] * An1);
            h0 = fmaf(dA0, h0, u * bcv.x);
            h1 = fmaf(dA1, h1, u * bcv.z);
            D += dtv[j];
        }
    }
    const int e = eg + ch;
    size_t idx = ((size_t)e * NCHUNK + ck) * 64 + 2 * i;
    *(float2*)(hend + idx) = make_float2(h0, h1);
    *(float2*)(dAp + idx)  = make_float2(__builtin_amdgcn_exp2f(An0 * D),
                                         __builtin_amdgcn_exp2f(An1 * D));
}

// Mid: serial scan over chunk summaries -> h_start per chunk, IN PLACE over hend.
__global__ __launch_bounds__(256)
void scan_mid_kernel(float* __restrict__ hend_h0, const float* __restrict__ dAp)
{
    int gid = blockIdx.x * 256 + threadIdx.x;     // over E*64
    int e = gid >> 6, n = gid & 63;
    float h = 0.f;
#pragma unroll
    for (int ck = 0; ck < NCHUNK; ++ck) {
        size_t idx = ((size_t)e * NCHUNK + ck) * 64 + n;
        float he = hend_h0[idx];
        float P  = dAp[idx];
        hend_h0[idx] = h;
        h = P * h + he;
    }
}

// Pass 2: block = 8 waves, 32 channels, one chunk.
// Wave w: 4 channels (w*4+g, g=lane>>4), 16 lanes/channel, 4 states/lane.
__global__ __launch_bounds__(512)
void scan2_kernel(const float* __restrict__ dtT, const __bf16* __restrict__ xcT,
                  const __bf16* __restrict__ szT, const float* __restrict__ bc2,
                  const float* __restrict__ A_log, const float* __restrict__ h0s,
                  __bf16* __restrict__ y)
{
    __shared__ float  s_bc[CKLEN * 128];   // 32 KB
    __shared__ float  s_dt[32][68];        // 8.5 KB (padded rows)
    __shared__ __bf16 s_x[32][72];         // 4.5 KB (padded rows)
    __shared__ __bf16 s_y[CKLEN][36];      // 4.5 KB (padded, t-major tile)
    const int tid = threadIdx.x;
    const int lane = tid & 63, w = tid >> 6;
    const int g = lane >> 4, i = lane & 15;
    const int ck = blockIdx.x & (NCHUNK - 1);
    const int eg = (blockIdx.x >> 5) * 32;

    {
        const float4* sb = (const float4*)(bc2 + (size_t)ck * CKLEN * 128);
        float4* db = (float4*)s_bc;
#pragma unroll
        for (int r = 0; r < 4; ++r) db[r * 512 + tid] = sb[r * 512 + tid];
        { int ch = tid >> 4, k = tid & 15;      // 512 = 32ch x 16
          *(float4*)&s_dt[ch][4 * k] =
              *(const float4*)(dtT + (size_t)(eg + ch) * T_TOK + ck * CKLEN + 4 * k); }
        if (tid < 256) { int ch = tid >> 3, k = tid & 7;   // 256 = 32ch x 8
          *(bf16x8*)&s_x[ch][8 * k] =
              *(const bf16x8*)(xcT + (size_t)(eg + ch) * T_TOK + ck * CKLEN + 8 * k); }
    }
    __syncthreads();

    const int ch = w * 4 + g;
    const int e = eg + ch;
    float4 al4 = *(const float4*)(A_log + 4 * i);
    const float L2E = 1.44269504f;
    const float An0 = -__expf(al4.x) * L2E;
    const float An1 = -__expf(al4.y) * L2E;
    const float An2 = -__expf(al4.z) * L2E;
    const float An3 = -__expf(al4.w) * L2E;
    float4 hh = *(const float4*)(h0s + ((size_t)e * NCHUNK + ck) * 64 + 4 * i);
    float h0 = hh.x, h1 = hh.y, h2 = hh.z, h3 = hh.w;

#pragma unroll 2
    for (int t0 = 0; t0 < CKLEN; t0 += 8) {
        float4 da = *(const float4*)&s_dt[ch][t0];
        float4 db = *(const float4*)&s_dt[ch][t0 + 4];
        bf16x8 x8 = *(const bf16x8*)&s_x[ch][t0];
        float dtv[8] = {da.x, da.y, da.z, da.w, db.x, db.y, db.z, db.w};
#pragma unroll
        for (int j = 0; j < 8; ++j) {
            float4 b0 = *(const float4*)&s_bc[(t0 + j) * 128 + 8 * i];
            float4 b1 = *(const float4*)&s_bc[(t0 + j) * 128 + 8 * i + 4];
            float dt = dtv[j];
            float u = dt * (float)x8[j];
            h0 = fmaf(__builtin_amdgcn_exp2f(dt * An0), h0, u * b0.x);
            h1 = fmaf(__builtin_amdgcn_exp2f(dt * An1), h1, u * b0.z);
            h2 = fmaf(__builtin_amdgcn_exp2f(dt * An2), h2, u * b1.x);
            h3 = fmaf(__builtin_amdgcn_exp2f(dt * An3), h3, u * b1.z);
            float p = h0 * b0.y;
            p = fmaf(h1, b0.w, p);
            p = fmaf(h2, b1.y, p);
            p = fmaf(h3, b1.w, p);
            p = dpp_add<0x111, 0xf>(p);   // row_shr:1
            p = dpp_add<0x112, 0xf>(p);   // row_shr:2
            p = dpp_add<0x114, 0xf>(p);   // row_shr:4
            p = dpp_add<0x118, 0xf>(p);   // row_shr:8
            if (i == 15) s_y[t0 + j][ch] = (__bf16)p;
        }
    }
    __syncthreads();

    // gate with silu(z) (already applied in szT) and write y t-major
    {
        int tt = tid >> 3, q = tid & 7;          // 64 t-rows x 8 threads
        bf16x4 o;
#pragma unroll
        for (int d = 0; d < 4; ++d) {
            float zv = (float)szT[(size_t)(eg + 4 * q + d) * T_TOK + ck * CKLEN + tt];
            o[d] = (__bf16)((float)s_y[tt][4 * q + d] * zv);
        }
        *(bf16x4*)(y + (size_t)(ck * CKLEN + tt) * EDIM + eg + 4 * q) = o;
    }
}

// ---------------------------------------------------------------- GEMM
// C[M,N] = A[M,K] @ Bt[N,K]^T.  M mult of TM, N mult of 128, K mult of 32.
// 2-phase pipeline: stage tile k+1 via global_load_lds while computing tile k;
// ONE __syncthreads per K-step (drains vmcnt -> staged tile ready).
// EPI 1: bf16 store (stride N).
// EPI 2: f32 store of acc + res (stride N).
// EPI 3: dt+bc fused: col<2048 -> softplus(acc+res[col]) clipped, TRANSPOSED
//        float4 to Cout[col][row]; col>=2048 -> f32 to Cout2[row*128+col-2048].
// EPI 4: in_proj split: col<2048 -> bf16 to Cout[row][col] (stride EDIM);
//        col>=2048 -> silu(acc), TRANSPOSED bf16x4 to Cout2[col-2048][row].
__device__ __forceinline__ void glds16(const __bf16* g, __bf16* l)
{
    __builtin_amdgcn_global_load_lds(
        (const __attribute__((address_space(1))) unsigned*)g,
        (__attribute__((address_space(3))) unsigned*)l, 16, 0, 0);
}

template<int EPI, int TM>
__global__ __launch_bounds__(256)
void gemm_kernel(const __bf16* __restrict__ A, const __bf16* __restrict__ Bt,
                 void* __restrict__ Cout, void* __restrict__ Cout2,
                 const float* __restrict__ res, int M, int N, int K)
{
    constexpr int MF = TM / 32;          // m-frags per wave
    __shared__ __bf16 sAl[2 * TM * 32];  // double-buffered linear tiles
    __shared__ __bf16 sBl[2 * 128 * 32];
    const int t = threadIdx.x;
    const int wave = t >> 6, lane = t & 63;
    const int brow = blockIdx.y * TM, bcol = blockIdx.x * 128;
    const int wr = (wave >> 1) * (TM / 2), wc = (wave & 1) * 64;
    const int w16 = wave * 16;
    f32x4 acc[MF][4] = {};

    const __bf16* gA = A  + (size_t)(brow + w16 + (lane >> 2)) * K + (lane & 3) * 8;
    const __bf16* gB = Bt + (size_t)(bcol + w16 + (lane >> 2)) * K + (lane & 3) * 8;

    auto stage = [&](int buf, int k0) {
        __bf16* ba = sAl + buf * (TM * 32) + w16 * 32;
        __bf16* bb = sBl + buf * (128 * 32) + w16 * 32;
        glds16(gA + k0, ba);
        if constexpr (TM == 128) glds16(gA + (size_t)64 * K + k0, ba + 64 * 32);
        glds16(gB + k0, bb);
        glds16(gB + (size_t)64 * K + k0, bb + 64 * 32);
    };

    stage(0, 0);
    int cur = 0;
    for (int k0 = 0; k0 < K; k0 += 32) {
        __syncthreads();                  // staged tile `cur` landed; buf cur^1 free
        if (k0 + 32 < K) stage(cur ^ 1, k0 + 32);   // prefetch next (overlaps MFMA)
        const __bf16* At = sAl + cur * (TM * 32);
        const __bf16* Btl = sBl + cur * (128 * 32);
        bf16x8 af[MF], bg[4];
#pragma unroll
        for (int m = 0; m < MF; ++m)
            af[m] = *(const bf16x8*)&At[(wr + m * 16 + (lane & 15)) * 32 + (lane >> 4) * 8];
#pragma unroll
        for (int n = 0; n < 4; ++n)
            bg[n] = *(const bf16x8*)&Btl[(wc + n * 16 + (lane & 15)) * 32 + (lane >> 4) * 8];
#pragma unroll
        for (int m = 0; m < MF; ++m)
#pragma unroll
            for (int n = 0; n < 4; ++n)
                acc[m][n] = __builtin_amdgcn_mfma_f32_16x16x32_bf16(
                    af[m], bg[n], acc[m][n], 0, 0, 0);
        cur ^= 1;
    }

    const int c_l = lane & 15, r_l = (lane >> 4) * 4;
#pragma unroll
    for (int m = 0; m < MF; ++m) {
#pragma unroll
        for (int n = 0; n < 4; ++n) {
            int row = brow + wr + m * 16 + r_l;
            int col = bcol + wc + n * 16 + c_l;
            if (EPI == 1) {
#pragma unroll
                for (int i = 0; i < 4; ++i)
                    ((__bf16*)Cout)[(size_t)(row + i) * N + col] = (__bf16)acc[m][n][i];
            } else if (EPI == 2) {
#pragma unroll
                for (int i = 0; i < 4; ++i) {
                    size_t off = (size_t)(row + i) * N + col;
                    ((float*)Cout)[off] = acc[m][n][i] + res[off];
                }
            } else if (EPI == 3) {
                if (col < 2048) {
                    float bias = res[col];
                    float4 v;
                    float* vv = (float*)&v;
#pragma unroll
                    for (int i = 0; i < 4; ++i) {
                        float s = acc[m][n][i] + bias;
                        s = (s > 20.f) ? s : log1pf(__expf(s));
                        vv[i] = fminf(fmaxf(s, 0.001f), 0.1f);
                    }
                    *(float4*)((float*)Cout + (size_t)col * T_TOK + row) = v;
                } else {
#pragma unroll
                    for (int i = 0; i < 4; ++i)
                        ((float*)Cout2)[(size_t)(row + i) * 128 + (col - 2048)] = acc[m][n][i];
                }
            } else if (EPI == 4) {
                if (col < 2048) {
#pragma unroll
                    for (int i = 0; i < 4; ++i)
                        ((__bf16*)Cout)[(size_t)(row + i) * EDIM + col] = (__bf16)acc[m][n][i];
                } else {
                    bf16x4 v;
#pragma unroll
                    for (int i = 0; i < 4; ++i) {
                        float s = acc[m][n][i];
                        v[i] = (__bf16)(s / (1.f + __expf(-s)));
                    }
                    *(bf16x4*)((__bf16*)Cout2 + (size_t)(col - 2048) * T_TOK + row) = v;
                }
            }
        }
    }
}

// ---------------------------------------------------------------- launch
extern "C" void kernel_launch(void* const* d_in, const int* in_sizes, int n_in,
                              void* d_out, int out_size, void* d_ws, size_t ws_size,
                              hipStream_t stream)
{
    (void)in_sizes; (void)n_in; (void)out_size; (void)ws_size;
    const float* x     = (const float*)d_in[0];
    const float* inw   = (const float*)d_in[1];
    const float* ffnw  = (const float*)d_in[2];
    const float* inpW  = (const float*)d_in[3];
    const float* convW = (const float*)d_in[4];
    const float* convB = (const float*)d_in[5];
    const float* dtW   = (const float*)d_in[6];
    const float* dtB   = (const float*)d_in[7];
    const float* BW    = (const float*)d_in[8];
    const float* CW    = (const float*)d_in[9];
    const float* Alog  = (const float*)d_in[10];
    const float* outpW = (const float*)d_in[11];
    const float* gateW = (const float*)d_in[12];
    const float* upW   = (const float*)d_in[13];
    const float* downW = (const float*)d_in[14];
    float* out = (float*)d_out;

    char* p = (char*)d_ws;
    auto alloc = [&](size_t n) { char* q = p; p += (n + 255) & ~(size_t)255; return q; };
    __bf16* wt_inproj = (__bf16*)alloc(4096ull * 1024 * 2);
    __bf16* wt_dtbc   = (__bf16*)alloc(2176ull * 2048 * 2);  // rows 0-2047 dt, 2048+ {B,C}
    __bf16* wt_outp   = (__bf16*)alloc(1024ull * 2048 * 2);
    __bf16* wt_gu     = (__bf16*)alloc(4096ull * 1024 * 2);
    __bf16* wt_down   = (__bf16*)alloc(1024ull * 2048 * 2);
    __bf16* normed    = (__bf16*)alloc(2048ull * 1024 * 2);  // reused as n2
    __bf16* xz        = (__bf16*)alloc(2048ull * 2048 * 2);  // x_z half of in_proj
    __bf16* gu_buf    = (__bf16*)alloc(2048ull * 4096 * 2);  // dAp then gu
    __bf16* xc        = (__bf16*)alloc(2048ull * 2048 * 2);  // conv out, reused as y
    float*  scratch16 = (float*)alloc(2048ull * 2048 * 4);   // hend/h0 then ffnmid
    float*  bc        = (float*)alloc(2048ull * 128 * 4);
    float*  dtT       = (float*)alloc(2048ull * 2048 * 4);
    __bf16* xcT       = (__bf16*)alloc(2048ull * 2048 * 2);
    __bf16* szT       = (__bf16*)alloc(2048ull * 2048 * 2);
    float*  x2        = (float*)alloc(2048ull * 1024 * 4);

    dim3 B256(256);
    // weight prep (f32 -> bf16, transposed to [N][K])
    transpose_kernel<float, __bf16><<<dim3(128, 32), B256, 0, stream>>>(inpW, wt_inproj, 1024, 4096, 4096, 1, 0);
    transpose_kernel<float, __bf16><<<dim3(64, 64), B256, 0, stream>>>(dtW, wt_dtbc, 2048, 2048, 2048, 1, 0);
    transpose_kernel<float, __bf16><<<dim3(2, 64), B256, 0, stream>>>(BW, wt_dtbc + 2048ull * 2048, 2048, 64, 64, 2, 0);
    transpose_kernel<float, __bf16><<<dim3(2, 64), B256, 0, stream>>>(CW, wt_dtbc + 2048ull * 2048, 2048, 64, 64, 2, 1);
    transpose_kernel<float, __bf16><<<dim3(32, 64), B256, 0, stream>>>(outpW, wt_outp, 2048, 1024, 1024, 1, 0);
    transpose_kernel<float, __bf16><<<dim3(64, 32), B256, 0, stream>>>(gateW, wt_gu, 1024, 2048, 2048, 1, 0);
    transpose_kernel<float, __bf16><<<dim3(64, 32), B256, 0, stream>>>(upW, wt_gu + 2048ull * 1024, 1024, 2048, 2048, 1, 0);
    transpose_kernel<float, __bf16><<<dim3(32, 64), B256, 0, stream>>>(downW, wt_down, 2048, 1024, 1024, 1, 0);

    // normed = rmsnorm(x, inw)
    rmsnorm_kernel<<<dim3(2048), B256, 0, stream>>>(x, inw, normed);
    // in_proj: xz (t-major bf16) + szT (silu'd z, channel-major)
    gemm_kernel<4, 128><<<dim3(32, 16), B256, 0, stream>>>(normed, wt_inproj, xz, szT, nullptr, 2048, 4096, 1024);
    // xc = silu(conv(xz) + b)
    conv_silu_kernel<<<dim3(T_TOK * EDIM / 256), B256, 0, stream>>>(xz, convW, convB, xc);
    // fused dt+bc: dtT (softplus'd, channel-major f32) + bc (t-major f32)
    gemm_kernel<3, 64><<<dim3(17, 32), B256, 0, stream>>>(xc, wt_dtbc, dtT, bc, dtB, 2048, 2176, 2048);
    // xcT channel-major
    transpose_kernel<__bf16, __bf16><<<dim3(64, 64), B256, 0, stream>>>(xc, xcT, 2048, 2048, 2048, 1, 0);

    // chunked SSM scan
    float* hend = scratch16;                      // 16 MB (E*32*64 f32)
    float* dAp  = (float*)gu_buf;                 // 16 MB
    scan1_kernel<<<dim3(4096), dim3(512), 0, stream>>>(dtT, xcT, bc, Alog, hend, dAp);
    scan_mid_kernel<<<dim3(512), B256, 0, stream>>>(hend, dAp);
    __bf16* y = xc;                               // xc dead after xcT+dt GEMM
    scan2_kernel<<<dim3(2048), dim3(512), 0, stream>>>(dtT, xcT, szT, bc, Alog, hend, y);

    // x2 = x + y @ out_proj
    gemm_kernel<2, 64><<<dim3(8, 32), B256, 0, stream>>>(y, wt_outp, x2, nullptr, x, 2048, 1024, 2048);
    // n2 = rmsnorm(x2, ffnw)
    rmsnorm_kernel<<<dim3(2048), B256, 0, stream>>>(x2, ffnw, normed);
    // gu = n2 @ [gate|up]
    __bf16* gu = gu_buf;
    gemm_kernel<1, 128><<<dim3(32, 16), B256, 0, stream>>>(normed, wt_gu, gu, nullptr, nullptr, 2048, 4096, 1024);
    // ffnmid = silu(gate)*up
    __bf16* ffnmid = (__bf16*)scratch16;
    glu_kernel<<<dim3(T_TOK * 2048 / 256), B256, 0, stream>>>(gu, ffnmid);
    // out = x2 + ffnmid @ down
    gemm_kernel<2, 64><<<dim3(8, 32), B256, 0, stream>>>(ffnmid, wt_down, out, nullptr, x2, 2048, 1024, 2048);
}

// Round 13
// 357.092 us; speedup vs baseline: 2.0698x; 1.0826x over previous
//
#include <hip/hip_runtime.h>
#include <hip/hip_bf16.h>

typedef __bf16 bf16x8 __attribute__((ext_vector_type(8)));
typedef __bf16 bf16x4 __attribute__((ext_vector_type(4)));
typedef float  f32x4  __attribute__((ext_vector_type(4)));

#define T_TOK 2048
#define DDIM  1024
#define EDIM  2048
#define NCHUNK 32
#define CKLEN  64

// ---------------------------------------------------------------- transpose
// dst[(c*dmul + doff)*R + r] = src[r*S + c];  R,C multiples of 32.
template<typename TS, typename TD>
__global__ __launch_bounds__(256)
void transpose_kernel(const TS* __restrict__ src, TD* __restrict__ dst,
                      int R, int C, int S, int dmul, int doff)
{
    __shared__ float tile[32][33];
    const int tc0 = blockIdx.x * 32, tr0 = blockIdx.y * 32;
    const int tx = threadIdx.x & 31, ty = threadIdx.x >> 5;
#pragma unroll
    for (int p = 0; p < 4; ++p) {
        int rl = ty + p * 8;
        tile[rl][tx] = (float)src[(size_t)(tr0 + rl) * S + tc0 + tx];
    }
    __syncthreads();
#pragma unroll
    for (int p = 0; p < 4; ++p) {
        int cl = ty + p * 8;
        float v = tile[tx][cl];
        int c = tc0 + cl, r = tr0 + tx;
        dst[((size_t)c * dmul + doff) * R + r] = (TD)v;
    }
}

// ---------------------------------------------------------------- rmsnorm
__global__ __launch_bounds__(256)
void rmsnorm_kernel(const float* __restrict__ x, const float* __restrict__ w,
                    __bf16* __restrict__ out)
{
    const int row = blockIdx.x;
    const int t = threadIdx.x;
    float4 v = ((const float4*)(x + (size_t)row * DDIM))[t];
    float ss = v.x * v.x + v.y * v.y + v.z * v.z + v.w * v.w;
#pragma unroll
    for (int m = 32; m; m >>= 1) ss += __shfl_xor(ss, m);
    __shared__ float red[4];
    if ((t & 63) == 0) red[t >> 6] = ss;
    __syncthreads();
    float scale = rsqrtf((red[0] + red[1] + red[2] + red[3]) * (1.f / DDIM) + 1e-5f);
    float4 wv = ((const float4*)w)[t];
    __bf16* o = out + (size_t)row * DDIM + t * 4;
    o[0] = (__bf16)(v.x * scale * wv.x);
    o[1] = (__bf16)(v.y * scale * wv.y);
    o[2] = (__bf16)(v.z * scale * wv.z);
    o[3] = (__bf16)(v.w * scale * wv.w);
}

// ---------------------------------------------------------------- conv+silu
__global__ __launch_bounds__(256)
void conv_silu_kernel(const __bf16* __restrict__ xz, const float* __restrict__ W,
                      const float* __restrict__ b, __bf16* __restrict__ xc)
{
    int idx = blockIdx.x * 256 + threadIdx.x;     // over T*E
    int t = idx >> 11, e = idx & (EDIM - 1);
    float s = b[e];
#pragma unroll
    for (int k = 0; k < 4; ++k) {                 // SAME pad: taps t-1..t+2
        int tt = t - 1 + k;
        if (tt >= 0 && tt < T_TOK)
            s += (float)xz[(size_t)tt * EDIM + e] * W[k * EDIM + e];
    }
    s = s / (1.f + __expf(-s));
    xc[idx] = (__bf16)s;
}

// ---------------------------------------------------------------- glu
__global__ __launch_bounds__(256)
void glu_kernel(const __bf16* __restrict__ gu, __bf16* __restrict__ outm)
{
    int idx = blockIdx.x * 256 + threadIdx.x;     // over T*I
    int t = idx >> 11, i = idx & 2047;
    float g = (float)gu[(size_t)t * 4096 + i];
    float u = (float)gu[(size_t)t * 4096 + 2048 + i];
    outm[idx] = (__bf16)(g / (1.f + __expf(-g)) * u);
}

// ---------------------------------------------------------------- scan
template<int CTRL, int ROWMASK>
__device__ __forceinline__ float dpp_add(float v)
{
    int y = __builtin_amdgcn_update_dpp(0, __builtin_bit_cast(int, v),
                                        CTRL, ROWMASK, 0xf, true);
    return v + __builtin_bit_cast(float, y);
}

// bc layout (plane-split): bc[t*128 + n] = B[t,n], bc[t*128 + 64 + n] = C[t,n].

// Pass 1: block = 8 waves, 16 channels, one chunk; B-plane only staged.
// Wave w: channels eg+2w (lanes 0-31) / eg+2w+1 (lanes 32-63); 2 states/lane.
__global__ __launch_bounds__(512)
void scan1_kernel(const float* __restrict__ dtT, const __bf16* __restrict__ xcT,
                  const float* __restrict__ bc2, const float* __restrict__ A_log,
                  float* __restrict__ hend, float* __restrict__ dAp)
{
    __shared__ float  s_b[CKLEN * 64];     // 16 KB (B-plane)
    __shared__ float  s_dt[16][CKLEN];     // 4 KB
    __shared__ __bf16 s_x[16][CKLEN];      // 2 KB
    const int tid = threadIdx.x;
    const int lane = tid & 63, w = tid >> 6;
    const int c = lane >> 5, i = lane & 31;
    const int ck = blockIdx.x & (NCHUNK - 1);
    const int eg = (blockIdx.x >> 5) * 16;

    {
        // B-plane: 64 t x 64 floats = 1024 float4s, 2 per thread
#pragma unroll
        for (int r = 0; r < 2; ++r) {
            int linear = r * 512 + tid;
            int t = linear >> 4, k = linear & 15;
            *(float4*)&s_b[t * 64 + 4 * k] =
                *(const float4*)(bc2 + (size_t)(ck * CKLEN + t) * 128 + 4 * k);
        }
        if (tid < 256) {
            int ch = tid >> 4, k = tid & 15;
            *((float4*)&s_dt[ch][0] + k) =
                *(const float4*)(dtT + (size_t)(eg + ch) * T_TOK + ck * CKLEN + 4 * k);
        } else if (tid < 384) {
            int q = tid - 256, ch = q >> 3, k = q & 7;
            *((bf16x8*)&s_x[ch][0] + k) =
                *(const bf16x8*)(xcT + (size_t)(eg + ch) * T_TOK + ck * CKLEN + 8 * k);
        }
    }
    __syncthreads();

    const int ch = 2 * w + c;
    float2 al = *(const float2*)(A_log + 2 * i);
    const float L2E = 1.44269504f;
    const float An0 = -__expf(al.x) * L2E;
    const float An1 = -__expf(al.y) * L2E;
    float h0 = 0.f, h1 = 0.f, D = 0.f;

#pragma unroll 2
    for (int t0 = 0; t0 < CKLEN; t0 += 8) {
        float4 da = *(const float4*)&s_dt[ch][t0];
        float4 db = *(const float4*)&s_dt[ch][t0 + 4];
        bf16x8 x8 = *(const bf16x8*)&s_x[ch][t0];
        float dtv[8] = {da.x, da.y, da.z, da.w, db.x, db.y, db.z, db.w};
#pragma unroll
        for (int j = 0; j < 8; ++j) {
            float2 Bv = *(const float2*)&s_b[(t0 + j) * 64 + 2 * i];
            float u = dtv[j] * (float)x8[j];
            float dA0 = __builtin_amdgcn_exp2f(dtv[j] * An0);
            float dA1 = __builtin_amdgcn_exp2f(dtv[j] * An1);
            h0 = fmaf(dA0, h0, u * Bv.x);
            h1 = fmaf(dA1, h1, u * Bv.y);
            D += dtv[j];
        }
    }
    const int e = eg + ch;
    size_t idx = ((size_t)e * NCHUNK + ck) * 64 + 2 * i;
    *(float2*)(hend + idx) = make_float2(h0, h1);
    *(float2*)(dAp + idx)  = make_float2(__builtin_amdgcn_exp2f(An0 * D),
                                         __builtin_amdgcn_exp2f(An1 * D));
}

// Mid: serial scan over chunk summaries -> h_start per chunk, IN PLACE over hend.
__global__ __launch_bounds__(256)
void scan_mid_kernel(float* __restrict__ hend_h0, const float* __restrict__ dAp)
{
    int gid = blockIdx.x * 256 + threadIdx.x;     // over E*64
    int e = gid >> 6, n = gid & 63;
    float h = 0.f;
#pragma unroll
    for (int ck = 0; ck < NCHUNK; ++ck) {
        size_t idx = ((size_t)e * NCHUNK + ck) * 64 + n;
        float he = hend_h0[idx];
        float P  = dAp[idx];
        hend_h0[idx] = h;
        h = P * h + he;
    }
}

// Pass 2: block = 8 waves, 32 channels, one chunk; B/C planes staged separately.
// Wave w: 4 channels (w*4+g, g=lane>>4), 16 lanes/channel, 4 states/lane.
__global__ __launch_bounds__(512)
void scan2_kernel(const float* __restrict__ dtT, const __bf16* __restrict__ xcT,
                  const __bf16* __restrict__ szT, const float* __restrict__ bc2,
                  const float* __restrict__ A_log, const float* __restrict__ h0s,
                  __bf16* __restrict__ y)
{
    __shared__ float  s_bp[CKLEN * 64];    // 16 KB (B-plane)
    __shared__ float  s_cp[CKLEN * 64];    // 16 KB (C-plane)
    __shared__ float  s_dt[32][68];        // 8.5 KB (padded rows)
    __shared__ __bf16 s_x[32][72];         // 4.5 KB (padded rows)
    __shared__ __bf16 s_y[CKLEN][36];      // 4.5 KB (padded, t-major tile)
    const int tid = threadIdx.x;
    const int lane = tid & 63, w = tid >> 6;
    const int g = lane >> 4, i = lane & 15;
    const int ck = blockIdx.x & (NCHUNK - 1);
    const int eg = (blockIdx.x >> 5) * 32;

    {
#pragma unroll
        for (int r = 0; r < 2; ++r) {
            int linear = r * 512 + tid;
            int t = linear >> 4, k = linear & 15;
            const float* src = bc2 + (size_t)(ck * CKLEN + t) * 128 + 4 * k;
            *(float4*)&s_bp[t * 64 + 4 * k] = *(const float4*)src;
            *(float4*)&s_cp[t * 64 + 4 * k] = *(const float4*)(src + 64);
        }
        { int ch = tid >> 4, k = tid & 15;      // 512 = 32ch x 16
          *(float4*)&s_dt[ch][4 * k] =
              *(const float4*)(dtT + (size_t)(eg + ch) * T_TOK + ck * CKLEN + 4 * k); }
        if (tid < 256) { int ch = tid >> 3, k = tid & 7;   // 256 = 32ch x 8
          *(bf16x8*)&s_x[ch][8 * k] =
              *(const bf16x8*)(xcT + (size_t)(eg + ch) * T_TOK + ck * CKLEN + 8 * k); }
    }
    __syncthreads();

    const int ch = w * 4 + g;
    const int e = eg + ch;
    float4 al4 = *(const float4*)(A_log + 4 * i);
    const float L2E = 1.44269504f;
    const float An0 = -__expf(al4.x) * L2E;
    const float An1 = -__expf(al4.y) * L2E;
    const float An2 = -__expf(al4.z) * L2E;
    const float An3 = -__expf(al4.w) * L2E;
    float4 hh = *(const float4*)(h0s + ((size_t)e * NCHUNK + ck) * 64 + 4 * i);
    float h0 = hh.x, h1 = hh.y, h2 = hh.z, h3 = hh.w;

#pragma unroll 2
    for (int t0 = 0; t0 < CKLEN; t0 += 8) {
        float4 da = *(const float4*)&s_dt[ch][t0];
        float4 db = *(const float4*)&s_dt[ch][t0 + 4];
        bf16x8 x8 = *(const bf16x8*)&s_x[ch][t0];
        float dtv[8] = {da.x, da.y, da.z, da.w, db.x, db.y, db.z, db.w};
#pragma unroll
        for (int j = 0; j < 8; ++j) {
            float4 b0 = *(const float4*)&s_bp[(t0 + j) * 64 + 4 * i];
            float4 c0 = *(const float4*)&s_cp[(t0 + j) * 64 + 4 * i];
            float dt = dtv[j];
            float u = dt * (float)x8[j];
            h0 = fmaf(__builtin_amdgcn_exp2f(dt * An0), h0, u * b0.x);
            h1 = fmaf(__builtin_amdgcn_exp2f(dt * An1), h1, u * b0.y);
            h2 = fmaf(__builtin_amdgcn_exp2f(dt * An2), h2, u * b0.z);
            h3 = fmaf(__builtin_amdgcn_exp2f(dt * An3), h3, u * b0.w);
            float p = h0 * c0.x;
            p = fmaf(h1, c0.y, p);
            p = fmaf(h2, c0.z, p);
            p = fmaf(h3, c0.w, p);
            p = dpp_add<0x111, 0xf>(p);   // row_shr:1
            p = dpp_add<0x112, 0xf>(p);   // row_shr:2
            p = dpp_add<0x114, 0xf>(p);   // row_shr:4
            p = dpp_add<0x118, 0xf>(p);   // row_shr:8
            if (i == 15) s_y[t0 + j][ch] = (__bf16)p;
        }
    }
    __syncthreads();

    // gate with silu(z) (already applied in szT) and write y t-major
    {
        int tt = tid >> 3, q = tid & 7;          // 64 t-rows x 8 threads
        bf16x4 o;
#pragma unroll
        for (int d = 0; d < 4; ++d) {
            float zv = (float)szT[(size_t)(eg + 4 * q + d) * T_TOK + ck * CKLEN + tt];
            o[d] = (__bf16)((float)s_y[tt][4 * q + d] * zv);
        }
        *(bf16x4*)(y + (size_t)(ck * CKLEN + tt) * EDIM + eg + 4 * q) = o;
    }
}

// ---------------------------------------------------------------- GEMM
// C[M,N] = A[M,K] @ Bt[N,K]^T.  M mult of TM, N mult of 128, K mult of 32.
// 2-phase pipeline: stage tile k+1 via global_load_lds while computing tile k.
// EPI 1: bf16 store (stride N).
// EPI 2: f32 store of acc + res (stride N).
// EPI 3: dt+bc fused: col<2048 -> softplus(acc+res[col]) clipped, TRANSPOSED
//        float4 to Cout[col][row]; col>=2048 -> f32 to Cout2[row*128+col-2048]
//        (weight rows 2048-2111 = B, 2112-2175 = C -> bc plane layout).
// EPI 4: in_proj split: col<2048 -> bf16 to Cout[row][col] (stride EDIM);
//        col>=2048 -> silu(acc), TRANSPOSED bf16x4 to Cout2[col-2048][row].
__device__ __forceinline__ void glds16(const __bf16* g, __bf16* l)
{
    __builtin_amdgcn_global_load_lds(
        (const __attribute__((address_space(1))) unsigned*)g,
        (__attribute__((address_space(3))) unsigned*)l, 16, 0, 0);
}

template<int EPI, int TM>
__global__ __launch_bounds__(256)
void gemm_kernel(const __bf16* __restrict__ A, const __bf16* __restrict__ Bt,
                 void* __restrict__ Cout, void* __restrict__ Cout2,
                 const float* __restrict__ res, int M, int N, int K)
{
    constexpr int MF = TM / 32;          // m-frags per wave
    __shared__ __bf16 sAl[2 * TM * 32];  // double-buffered linear tiles
    __shared__ __bf16 sBl[2 * 128 * 32];
    const int t = threadIdx.x;
    const int wave = t >> 6, lane = t & 63;
    const int brow = blockIdx.y * TM, bcol = blockIdx.x * 128;
    const int wr = (wave >> 1) * (TM / 2), wc = (wave & 1) * 64;
    const int w16 = wave * 16;
    f32x4 acc[MF][4] = {};

    const __bf16* gA = A  + (size_t)(brow + w16 + (lane >> 2)) * K + (lane & 3) * 8;
    const __bf16* gB = Bt + (size_t)(bcol + w16 + (lane >> 2)) * K + (lane & 3) * 8;

    auto stage = [&](int buf, int k0) {
        __bf16* ba = sAl + buf * (TM * 32) + w16 * 32;
        __bf16* bb = sBl + buf * (128 * 32) + w16 * 32;
        glds16(gA + k0, ba);
        if constexpr (TM == 128) glds16(gA + (size_t)64 * K + k0, ba + 64 * 32);
        glds16(gB + k0, bb);
        glds16(gB + (size_t)64 * K + k0, bb + 64 * 32);
    };

    stage(0, 0);
    int cur = 0;
    for (int k0 = 0; k0 < K; k0 += 32) {
        __syncthreads();                  // staged tile `cur` landed; buf cur^1 free
        if (k0 + 32 < K) stage(cur ^ 1, k0 + 32);   // prefetch next (overlaps MFMA)
        const __bf16* At = sAl + cur * (TM * 32);
        const __bf16* Btl = sBl + cur * (128 * 32);
        bf16x8 af[MF], bg[4];
#pragma unroll
        for (int m = 0; m < MF; ++m)
            af[m] = *(const bf16x8*)&At[(wr + m * 16 + (lane & 15)) * 32 + (lane >> 4) * 8];
#pragma unroll
        for (int n = 0; n < 4; ++n)
            bg[n] = *(const bf16x8*)&Btl[(wc + n * 16 + (lane & 15)) * 32 + (lane >> 4) * 8];
#pragma unroll
        for (int m = 0; m < MF; ++m)
#pragma unroll
            for (int n = 0; n < 4; ++n)
                acc[m][n] = __builtin_amdgcn_mfma_f32_16x16x32_bf16(
                    af[m], bg[n], acc[m][n], 0, 0, 0);
        cur ^= 1;
    }

    const int c_l = lane & 15, r_l = (lane >> 4) * 4;
#pragma unroll
    for (int m = 0; m < MF; ++m) {
#pragma unroll
        for (int n = 0; n < 4; ++n) {
            int row = brow + wr + m * 16 + r_l;
            int col = bcol + wc + n * 16 + c_l;
            if (EPI == 1) {
#pragma unroll
                for (int i = 0; i < 4; ++i)
                    ((__bf16*)Cout)[(size_t)(row + i) * N + col] = (__bf16)acc[m][n][i];
            } else if (EPI == 2) {
#pragma unroll
                for (int i = 0; i < 4; ++i) {
                    size_t off = (size_t)(row + i) * N + col;
                    ((float*)Cout)[off] = acc[m][n][i] + res[off];
                }
            } else if (EPI == 3) {
                if (col < 2048) {
                    float bias = res[col];
                    float4 v;
                    float* vv = (float*)&v;
#pragma unroll
                    for (int i = 0; i < 4; ++i) {
                        float s = acc[m][n][i] + bias;
                        s = (s > 20.f) ? s : log1pf(__expf(s));
                        vv[i] = fminf(fmaxf(s, 0.001f), 0.1f);
                    }
                    *(float4*)((float*)Cout + (size_t)col * T_TOK + row) = v;
                } else {
#pragma unroll
                    for (int i = 0; i < 4; ++i)
                        ((float*)Cout2)[(size_t)(row + i) * 128 + (col - 2048)] = acc[m][n][i];
                }
            } else if (EPI == 4) {
                if (col < 2048) {
#pragma unroll
                    for (int i = 0; i < 4; ++i)
                        ((__bf16*)Cout)[(size_t)(row + i) * EDIM + col] = (__bf16)acc[m][n][i];
                } else {
                    bf16x4 v;
#pragma unroll
                    for (int i = 0; i < 4; ++i) {
                        float s = acc[m][n][i];
                        v[i] = (__bf16)(s / (1.f + __expf(-s)));
                    }
                    *(bf16x4*)((__bf16*)Cout2 + (size_t)(col - 2048) * T_TOK + row) = v;
                }
            }
        }
    }
}

// ---------------------------------------------------------------- launch
extern "C" void kernel_launch(void* const* d_in, const int* in_sizes, int n_in,
                              void* d_out, int out_size, void* d_ws, size_t ws_size,
                              hipStream_t stream)
{
    (void)in_sizes; (void)n_in; (void)out_size; (void)ws_size;
    const float* x     = (const float*)d_in[0];
    const float* inw   = (const float*)d_in[1];
    const float* ffnw  = (const float*)d_in[2];
    const float* inpW  = (const float*)d_in[3];
    const float* convW = (const float*)d_in[4];
    const float* convB = (const float*)d_in[5];
    const float* dtW   = (const float*)d_in[6];
    const float* dtB   = (const float*)d_in[7];
    const float* BW    = (const float*)d_in[8];
    const float* CW    = (const float*)d_in[9];
    const float* Alog  = (const float*)d_in[10];
    const float* outpW = (const float*)d_in[11];
    const float* gateW = (const float*)d_in[12];
    const float* upW   = (const float*)d_in[13];
    const float* downW = (const float*)d_in[14];
    float* out = (float*)d_out;

    char* p = (char*)d_ws;
    auto alloc = [&](size_t n) { char* q = p; p += (n + 255) & ~(size_t)255; return q; };
    __bf16* wt_inproj = (__bf16*)alloc(4096ull * 1024 * 2);
    __bf16* wt_dtbc   = (__bf16*)alloc(2176ull * 2048 * 2);  // rows: 0-2047 dt, 2048-2111 B, 2112-2175 C
    __bf16* wt_outp   = (__bf16*)alloc(1024ull * 2048 * 2);
    __bf16* wt_gu     = (__bf16*)alloc(4096ull * 1024 * 2);
    __bf16* wt_down   = (__bf16*)alloc(1024ull * 2048 * 2);
    __bf16* normed    = (__bf16*)alloc(2048ull * 1024 * 2);  // reused as n2
    __bf16* xz        = (__bf16*)alloc(2048ull * 2048 * 2);  // x_z half of in_proj
    __bf16* gu_buf    = (__bf16*)alloc(2048ull * 4096 * 2);  // dAp then gu
    __bf16* xc        = (__bf16*)alloc(2048ull * 2048 * 2);  // conv out, reused as y
    float*  scratch16 = (float*)alloc(2048ull * 2048 * 4);   // hend/h0 then ffnmid
    float*  bc        = (float*)alloc(2048ull * 128 * 4);
    float*  dtT       = (float*)alloc(2048ull * 2048 * 4);
    __bf16* xcT       = (__bf16*)alloc(2048ull * 2048 * 2);
    __bf16* szT       = (__bf16*)alloc(2048ull * 2048 * 2);
    float*  x2        = (float*)alloc(2048ull * 1024 * 4);

    dim3 B256(256);
    // weight prep (f32 -> bf16, transposed to [N][K]); B/C as separate planes
    transpose_kernel<float, __bf16><<<dim3(128, 32), B256, 0, stream>>>(inpW, wt_inproj, 1024, 4096, 4096, 1, 0);
    transpose_kernel<float, __bf16><<<dim3(64, 64), B256, 0, stream>>>(dtW, wt_dtbc, 2048, 2048, 2048, 1, 0);
    transpose_kernel<float, __bf16><<<dim3(2, 64), B256, 0, stream>>>(BW, wt_dtbc + 2048ull * 2048, 2048, 64, 64, 1, 0);
    transpose_kernel<float, __bf16><<<dim3(2, 64), B256, 0, stream>>>(CW, wt_dtbc + 2112ull * 2048, 2048, 64, 64, 1, 0);
    transpose_kernel<float, __bf16><<<dim3(32, 64), B256, 0, stream>>>(outpW, wt_outp, 2048, 1024, 1024, 1, 0);
    transpose_kernel<float, __bf16><<<dim3(64, 32), B256, 0, stream>>>(gateW, wt_gu, 1024, 2048, 2048, 1, 0);
    transpose_kernel<float, __bf16><<<dim3(64, 32), B256, 0, stream>>>(upW, wt_gu + 2048ull * 1024, 1024, 2048, 2048, 1, 0);
    transpose_kernel<float, __bf16><<<dim3(32, 64), B256, 0, stream>>>(downW, wt_down, 2048, 1024, 1024, 1, 0);

    // normed = rmsnorm(x, inw)
    rmsnorm_kernel<<<dim3(2048), B256, 0, stream>>>(x, inw, normed);
    // in_proj: xz (t-major bf16) + szT (silu'd z, channel-major)
    gemm_kernel<4, 128><<<dim3(32, 16), B256, 0, stream>>>(normed, wt_inproj, xz, szT, nullptr, 2048, 4096, 1024);
    // xc = silu(conv(xz) + b)
    conv_silu_kernel<<<dim3(T_TOK * EDIM / 256), B256, 0, stream>>>(xz, convW, convB, xc);
    // fused dt+bc: dtT (softplus'd, channel-major f32) + bc (t-major f32, planes)
    gemm_kernel<3, 64><<<dim3(17, 32), B256, 0, stream>>>(xc, wt_dtbc, dtT, bc, dtB, 2048, 2176, 2048);
    // xcT channel-major
    transpose_kernel<__bf16, __bf16><<<dim3(64, 64), B256, 0, stream>>>(xc, xcT, 2048, 2048, 2048, 1, 0);

    // chunked SSM scan
    float* hend = scratch16;                      // 16 MB (E*32*64 f32)
    float* dAp  = (float*)gu_buf;                 // 16 MB
    scan1_kernel<<<dim3(4096), dim3(512), 0, stream>>>(dtT, xcT, bc, Alog, hend, dAp);
    scan_mid_kernel<<<dim3(512), B256, 0, stream>>>(hend, dAp);
    __bf16* y = xc;                               // xc dead after xcT+dt GEMM
    scan2_kernel<<<dim3(2048), dim3(512), 0, stream>>>(dtT, xcT, szT, bc, Alog, hend, y);

    // x2 = x + y @ out_proj
    gemm_kernel<2, 64><<<dim3(8, 32), B256, 0, stream>>>(y, wt_outp, x2, nullptr, x, 2048, 1024, 2048);
    // n2 = rmsnorm(x2, ffnw)
    rmsnorm_kernel<<<dim3(2048), B256, 0, stream>>>(x2, ffnw, normed);
    // gu = n2 @ [gate|up]
    __bf16* gu = gu_buf;
    gemm_kernel<1, 128><<<dim3(32, 16), B256, 0, stream>>>(normed, wt_gu, gu, nullptr, nullptr, 2048, 4096, 1024);
    // ffnmid = silu(gate)*up
    __bf16* ffnmid = (__bf16*)scratch16;
    glu_kernel<<<dim3(T_TOK * 2048 / 256), B256, 0, stream>>>(gu, ffnmid);
    // out = x2 + ffnmid @ down
    gemm_kernel<2, 64><<<dim3(8, 32), B256, 0, stream>>>(ffnmid, wt_down, out, nullptr, x2, 2048, 1024, 2048);
}

// Round 14
// 354.812 us; speedup vs baseline: 2.0831x; 1.0064x over previous
//
#include <hip/hip_runtime.h>
#include <hip/hip_bf16.h>

typedef __bf16 bf16x8 __attribute__((ext_vector_type(8)));
typedef __bf16 bf16x4 __attribute__((ext_vector_type(4)));
typedef float  f32x4  __attribute__((ext_vector_type(4)));

#define T_TOK 2048
#define DDIM  1024
#define EDIM  2048
#define NCHUNK 32
#define CKLEN  64

// ---------------------------------------------------------------- transpose
template<typename TS, typename TD>
__global__ __launch_bounds__(256)
void transpose_kernel(const TS* __restrict__ src, TD* __restrict__ dst,
                      int R, int C, int S, int dmul, int doff)
{
    __shared__ float tile[32][33];
    const int tc0 = blockIdx.x * 32, tr0 = blockIdx.y * 32;
    const int tx = threadIdx.x & 31, ty = threadIdx.x >> 5;
#pragma unroll
    for (int p = 0; p < 4; ++p) {
        int rl = ty + p * 8;
        tile[rl][tx] = (float)src[(size_t)(tr0 + rl) * S + tc0 + tx];
    }
    __syncthreads();
#pragma unroll
    for (int p = 0; p < 4; ++p) {
        int cl = ty + p * 8;
        float v = tile[tx][cl];
        int c = tc0 + cl, r = tr0 + tx;
        dst[((size_t)c * dmul + doff) * R + r] = (TD)v;
    }
}

// ---------------------------------------------------------------- rmsnorm
__global__ __launch_bounds__(256)
void rmsnorm_kernel(const float* __restrict__ x, const float* __restrict__ w,
                    __bf16* __restrict__ out)
{
    const int row = blockIdx.x;
    const int t = threadIdx.x;
    float4 v = ((const float4*)(x + (size_t)row * DDIM))[t];
    float ss = v.x * v.x + v.y * v.y + v.z * v.z + v.w * v.w;
#pragma unroll
    for (int m = 32; m; m >>= 1) ss += __shfl_xor(ss, m);
    __shared__ float red[4];
    if ((t & 63) == 0) red[t >> 6] = ss;
    __syncthreads();
    float scale = rsqrtf((red[0] + red[1] + red[2] + red[3]) * (1.f / DDIM) + 1e-5f);
    float4 wv = ((const float4*)w)[t];
    __bf16* o = out + (size_t)row * DDIM + t * 4;
    o[0] = (__bf16)(v.x * scale * wv.x);
    o[1] = (__bf16)(v.y * scale * wv.y);
    o[2] = (__bf16)(v.z * scale * wv.z);
    o[3] = (__bf16)(v.w * scale * wv.w);
}

// ---------------------------------------------------------------- conv+silu
__global__ __launch_bounds__(256)
void conv_silu_kernel(const __bf16* __restrict__ xz, const float* __restrict__ W,
                      const float* __restrict__ b, __bf16* __restrict__ xc)
{
    int idx = blockIdx.x * 256 + threadIdx.x;     // over T*E
    int t = idx >> 11, e = idx & (EDIM - 1);
    float s = b[e];
#pragma unroll
    for (int k = 0; k < 4; ++k) {                 // SAME pad: taps t-1..t+2
        int tt = t - 1 + k;
        if (tt >= 0 && tt < T_TOK)
            s += (float)xz[(size_t)tt * EDIM + e] * W[k * EDIM + e];
    }
    s = s / (1.f + __expf(-s));
    xc[idx] = (__bf16)s;
}

// ---------------------------------------------------------------- glu
__global__ __launch_bounds__(256)
void glu_kernel(const __bf16* __restrict__ gu, __bf16* __restrict__ outm)
{
    int idx = blockIdx.x * 256 + threadIdx.x;     // over T*I
    int t = idx >> 11, i = idx & 2047;
    float g = (float)gu[(size_t)t * 4096 + i];
    float u = (float)gu[(size_t)t * 4096 + 2048 + i];
    outm[idx] = (__bf16)(g / (1.f + __expf(-g)) * u);
}

// ---------------------------------------------------------------- scan
template<int CTRL, int ROWMASK>
__device__ __forceinline__ float dpp_add(float v)
{
    int y = __builtin_amdgcn_update_dpp(0, __builtin_bit_cast(int, v),
                                        CTRL, ROWMASK, 0xf, true);
    return v + __builtin_bit_cast(float, y);
}

// bc layout (plane-split): bc[t*128 + n] = B[t,n], bc[t*128 + 64 + n] = C[t,n].

// Pass 1: block = 8 waves, 16 channels, one chunk; B-plane only staged.
__global__ __launch_bounds__(512)
void scan1_kernel(const float* __restrict__ dtT, const __bf16* __restrict__ xcT,
                  const float* __restrict__ bc2, const float* __restrict__ A_log,
                  float* __restrict__ hend, float* __restrict__ dAp)
{
    __shared__ float  s_b[CKLEN * 64];     // 16 KB (B-plane)
    __shared__ float  s_dt[16][CKLEN];     // 4 KB
    __shared__ __bf16 s_x[16][CKLEN];      // 2 KB
    const int tid = threadIdx.x;
    const int lane = tid & 63, w = tid >> 6;
    const int c = lane >> 5, i = lane & 31;
    const int ck = blockIdx.x & (NCHUNK - 1);
    const int eg = (blockIdx.x >> 5) * 16;

    {
#pragma unroll
        for (int r = 0; r < 2; ++r) {
            int linear = r * 512 + tid;
            int t = linear >> 4, k = linear & 15;
            *(float4*)&s_b[t * 64 + 4 * k] =
                *(const float4*)(bc2 + (size_t)(ck * CKLEN + t) * 128 + 4 * k);
        }
        if (tid < 256) {
            int ch = tid >> 4, k = tid & 15;
            *((float4*)&s_dt[ch][0] + k) =
                *(const float4*)(dtT + (size_t)(eg + ch) * T_TOK + ck * CKLEN + 4 * k);
        } else if (tid < 384) {
            int q = tid - 256, ch = q >> 3, k = q & 7;
            *((bf16x8*)&s_x[ch][0] + k) =
                *(const bf16x8*)(xcT + (size_t)(eg + ch) * T_TOK + ck * CKLEN + 8 * k);
        }
    }
    __syncthreads();

    const int ch = 2 * w + c;
    float2 al = *(const float2*)(A_log + 2 * i);
    const float L2E = 1.44269504f;
    const float An0 = -__expf(al.x) * L2E;
    const float An1 = -__expf(al.y) * L2E;
    float h0 = 0.f, h1 = 0.f, D = 0.f;

#pragma unroll 2
    for (int t0 = 0; t0 < CKLEN; t0 += 8) {
        float4 da = *(const float4*)&s_dt[ch][t0];
        float4 db = *(const float4*)&s_dt[ch][t0 + 4];
        bf16x8 x8 = *(const bf16x8*)&s_x[ch][t0];
        float dtv[8] = {da.x, da.y, da.z, da.w, db.x, db.y, db.z, db.w};
#pragma unroll
        for (int j = 0; j < 8; ++j) {
            float2 Bv = *(const float2*)&s_b[(t0 + j) * 64 + 2 * i];
            float u = dtv[j] * (float)x8[j];
            float dA0 = __builtin_amdgcn_exp2f(dtv[j] * An0);
            float dA1 = __builtin_amdgcn_exp2f(dtv[j] * An1);
            h0 = fmaf(dA0, h0, u * Bv.x);
            h1 = fmaf(dA1, h1, u * Bv.y);
            D += dtv[j];
        }
    }
    const int e = eg + ch;
    size_t idx = ((size_t)e * NCHUNK + ck) * 64 + 2 * i;
    *(float2*)(hend + idx) = make_float2(h0, h1);
    *(float2*)(dAp + idx)  = make_float2(__builtin_amdgcn_exp2f(An0 * D),
                                         __builtin_amdgcn_exp2f(An1 * D));
}

// Mid: serial scan over chunk summaries -> h_start per chunk, IN PLACE over hend.
__global__ __launch_bounds__(256)
void scan_mid_kernel(float* __restrict__ hend_h0, const float* __restrict__ dAp)
{
    int gid = blockIdx.x * 256 + threadIdx.x;     // over E*64
    int e = gid >> 6, n = gid & 63;
    float h = 0.f;
#pragma unroll
    for (int ck = 0; ck < NCHUNK; ++ck) {
        size_t idx = ((size_t)e * NCHUNK + ck) * 64 + n;
        float he = hend_h0[idx];
        float P  = dAp[idx];
        hend_h0[idx] = h;
        h = P * h + he;
    }
}

// Pass 2: block = 8 waves, 32 channels, one chunk; B/C planes staged separately.
__global__ __launch_bounds__(512)
void scan2_kernel(const float* __restrict__ dtT, const __bf16* __restrict__ xcT,
                  const __bf16* __restrict__ szT, const float* __restrict__ bc2,
                  const float* __restrict__ A_log, const float* __restrict__ h0s,
                  __bf16* __restrict__ y)
{
    __shared__ float  s_bp[CKLEN * 64];    // 16 KB (B-plane)
    __shared__ float  s_cp[CKLEN * 64];    // 16 KB (C-plane)
    __shared__ float  s_dt[32][68];        // padded rows
    __shared__ __bf16 s_x[32][72];         // padded rows
    __shared__ __bf16 s_y[CKLEN][36];      // padded, t-major tile
    const int tid = threadIdx.x;
    const int lane = tid & 63, w = tid >> 6;
    const int g = lane >> 4, i = lane & 15;
    const int ck = blockIdx.x & (NCHUNK - 1);
    const int eg = (blockIdx.x >> 5) * 32;

    {
#pragma unroll
        for (int r = 0; r < 2; ++r) {
            int linear = r * 512 + tid;
            int t = linear >> 4, k = linear & 15;
            const float* src = bc2 + (size_t)(ck * CKLEN + t) * 128 + 4 * k;
            *(float4*)&s_bp[t * 64 + 4 * k] = *(const float4*)src;
            *(float4*)&s_cp[t * 64 + 4 * k] = *(const float4*)(src + 64);
        }
        { int ch = tid >> 4, k = tid & 15;
          *(float4*)&s_dt[ch][4 * k] =
              *(const float4*)(dtT + (size_t)(eg + ch) * T_TOK + ck * CKLEN + 4 * k); }
        if (tid < 256) { int ch = tid >> 3, k = tid & 7;
          *(bf16x8*)&s_x[ch][8 * k] =
              *(const bf16x8*)(xcT + (size_t)(eg + ch) * T_TOK + ck * CKLEN + 8 * k); }
    }
    __syncthreads();

    const int ch = w * 4 + g;
    const int e = eg + ch;
    float4 al4 = *(const float4*)(A_log + 4 * i);
    const float L2E = 1.44269504f;
    const float An0 = -__expf(al4.x) * L2E;
    const float An1 = -__expf(al4.y) * L2E;
    const float An2 = -__expf(al4.z) * L2E;
    const float An3 = -__expf(al4.w) * L2E;
    float4 hh = *(const float4*)(h0s + ((size_t)e * NCHUNK + ck) * 64 + 4 * i);
    float h0 = hh.x, h1 = hh.y, h2 = hh.z, h3 = hh.w;

#pragma unroll 2
    for (int t0 = 0; t0 < CKLEN; t0 += 8) {
        float4 da = *(const float4*)&s_dt[ch][t0];
        float4 db = *(const float4*)&s_dt[ch][t0 + 4];
        bf16x8 x8 = *(const bf16x8*)&s_x[ch][t0];
        float dtv[8] = {da.x, da.y, da.z, da.w, db.x, db.y, db.z, db.w};
#pragma unroll
        for (int j = 0; j < 8; ++j) {
            float4 b0 = *(const float4*)&s_bp[(t0 + j) * 64 + 4 * i];
            float4 c0 = *(const float4*)&s_cp[(t0 + j) * 64 + 4 * i];
            float dt = dtv[j];
            float u = dt * (float)x8[j];
            h0 = fmaf(__builtin_amdgcn_exp2f(dt * An0), h0, u * b0.x);
            h1 = fmaf(__builtin_amdgcn_exp2f(dt * An1), h1, u * b0.y);
            h2 = fmaf(__builtin_amdgcn_exp2f(dt * An2), h2, u * b0.z);
            h3 = fmaf(__builtin_amdgcn_exp2f(dt * An3), h3, u * b0.w);
            float p = h0 * c0.x;
            p = fmaf(h1, c0.y, p);
            p = fmaf(h2, c0.z, p);
            p = fmaf(h3, c0.w, p);
            p = dpp_add<0x111, 0xf>(p);
            p = dpp_add<0x112, 0xf>(p);
            p = dpp_add<0x114, 0xf>(p);
            p = dpp_add<0x118, 0xf>(p);
            if (i == 15) s_y[t0 + j][ch] = (__bf16)p;
        }
    }
    __syncthreads();

    {
        int tt = tid >> 3, q = tid & 7;
        bf16x4 o;
#pragma unroll
        for (int d = 0; d < 4; ++d) {
            float zv = (float)szT[(size_t)(eg + 4 * q + d) * T_TOK + ck * CKLEN + tt];
            o[d] = (__bf16)((float)s_y[tt][4 * q + d] * zv);
        }
        *(bf16x4*)(y + (size_t)(ck * CKLEN + tt) * EDIM + eg + 4 * q) = o;
    }
}

// ---------------------------------------------------------------- GEMM common
__device__ __forceinline__ void glds16(const __bf16* g, __bf16* l)
{
    __builtin_amdgcn_global_load_lds(
        (const __attribute__((address_space(1))) unsigned*)g,
        (__attribute__((address_space(3))) unsigned*)l, 16, 0, 0);
}

// Epilogue (shared by both GEMM variants).  See R12 comments for EPI 1..4.
template<int EPI>
__device__ __forceinline__ void gemm_epilogue(
    const f32x4& a, int row, int col, int N,
    void* Cout, void* Cout2, const float* res)
{
    if (EPI == 1) {
#pragma unroll
        for (int i = 0; i < 4; ++i)
            ((__bf16*)Cout)[(size_t)(row + i) * N + col] = (__bf16)a[i];
    } else if (EPI == 2) {
#pragma unroll
        for (int i = 0; i < 4; ++i) {
            size_t off = (size_t)(row + i) * N + col;
            ((float*)Cout)[off] = a[i] + res[off];
        }
    } else if (EPI == 3) {
        if (col < 2048) {
            float bias = res[col];
            float4 v;
            float* vv = (float*)&v;
#pragma unroll
            for (int i = 0; i < 4; ++i) {
                float s = a[i] + bias;
                s = (s > 20.f) ? s : log1pf(__expf(s));
                vv[i] = fminf(fmaxf(s, 0.001f), 0.1f);
            }
            *(float4*)((float*)Cout + (size_t)col * T_TOK + row) = v;
        } else {
#pragma unroll
            for (int i = 0; i < 4; ++i)
                ((float*)Cout2)[(size_t)(row + i) * 128 + (col - 2048)] = a[i];
        }
    } else if (EPI == 4) {
        if (col < 2048) {
#pragma unroll
            for (int i = 0; i < 4; ++i)
                ((__bf16*)Cout)[(size_t)(row + i) * EDIM + col] = (__bf16)a[i];
        } else {
            bf16x4 v;
#pragma unroll
            for (int i = 0; i < 4; ++i) {
                float s = a[i];
                v[i] = (__bf16)(s / (1.f + __expf(-s)));
            }
            *(bf16x4*)((__bf16*)Cout2 + (size_t)(col - 2048) * T_TOK + row) = v;
        }
    }
}

// 4-wave GEMM: TM x 128 tile, BK=32, 2-phase, XOR chunk-swizzled LDS.
// SWZ<1> additionally remaps blocks XCD-contiguously (grid must be mult of 8).
template<int EPI, int TM, int SWZ>
__global__ __launch_bounds__(256)
void gemm_kernel(const __bf16* __restrict__ A, const __bf16* __restrict__ Bt,
                 void* __restrict__ Cout, void* __restrict__ Cout2,
                 const float* __restrict__ res, int M, int N, int K)
{
    constexpr int MF = TM / 32;
    __shared__ __bf16 sAl[2 * TM * 32];
    __shared__ __bf16 sBl[2 * 128 * 32];
    const int t = threadIdx.x;
    const int wave = t >> 6, lane = t & 63;
    int bx = blockIdx.x, by = blockIdx.y;
    if (SWZ) {
        int nwg = gridDim.x * gridDim.y;
        int bid = by * gridDim.x + bx;
        int cpx = nwg >> 3;
        int swz = (bid & 7) * cpx + (bid >> 3);
        bx = swz % gridDim.x;
        by = swz / gridDim.x;
    }
    const int brow = by * TM, bcol = bx * 128;
    const int wr = (wave >> 1) * (TM / 2), wc = (wave & 1) * 64;
    const int w16 = wave * 16;
    f32x4 acc[MF][4] = {};

    // swizzled staging source: lane -> row w16+(lane>>2), chunk (lane&3)^(row&3)
    const int rowl = lane >> 2;
    const int chkl = (lane & 3) ^ (rowl & 3);
    const __bf16* gA = A  + (size_t)(brow + w16 + rowl) * K + chkl * 8;
    const __bf16* gB = Bt + (size_t)(bcol + w16 + rowl) * K + chkl * 8;

    auto stage = [&](int buf, int k0) {
        __bf16* ba = sAl + buf * (TM * 32) + w16 * 32;
        __bf16* bb = sBl + buf * (128 * 32) + w16 * 32;
        glds16(gA + k0, ba);
        if constexpr (TM == 128) glds16(gA + (size_t)64 * K + k0, ba + 64 * 32);
        glds16(gB + k0, bb);
        glds16(gB + (size_t)64 * K + k0, bb + 64 * 32);
    };

    const int rchk = ((lane >> 4) ^ (lane & 3)) * 8;   // swizzled read chunk
    stage(0, 0);
    int cur = 0;
    for (int k0 = 0; k0 < K; k0 += 32) {
        __syncthreads();
        if (k0 + 32 < K) stage(cur ^ 1, k0 + 32);
        const __bf16* At = sAl + cur * (TM * 32);
        const __bf16* Btl = sBl + cur * (128 * 32);
        bf16x8 af[MF], bg[4];
#pragma unroll
        for (int m = 0; m < MF; ++m)
            af[m] = *(const bf16x8*)&At[(wr + m * 16 + (lane & 15)) * 32 + rchk];
#pragma unroll
        for (int n = 0; n < 4; ++n)
            bg[n] = *(const bf16x8*)&Btl[(wc + n * 16 + (lane & 15)) * 32 + rchk];
#pragma unroll
        for (int m = 0; m < MF; ++m)
#pragma unroll
            for (int n = 0; n < 4; ++n)
                acc[m][n] = __builtin_amdgcn_mfma_f32_16x16x32_bf16(
                    af[m], bg[n], acc[m][n], 0, 0, 0);
        cur ^= 1;
    }

    const int c_l = lane & 15, r_l = (lane >> 4) * 4;
#pragma unroll
    for (int m = 0; m < MF; ++m)
#pragma unroll
        for (int n = 0; n < 4; ++n)
            gemm_epilogue<EPI>(acc[m][n], brow + wr + m * 16 + r_l,
                               bcol + wc + n * 16 + c_l, N, Cout, Cout2, res);
}

// 8-wave big GEMM: 256 x 128 tile, BK=64, 2-phase, XOR chunk-swizzled LDS.
// Wave tile 64x64 -> 32 MFMA per wave per K-step (hides staging latency).
template<int EPI>
__global__ __launch_bounds__(512)
void gemm_big(const __bf16* __restrict__ A, const __bf16* __restrict__ Bt,
              void* __restrict__ Cout, void* __restrict__ Cout2,
              const float* __restrict__ res, int M, int N, int K)
{
    __shared__ __bf16 sAl[2 * 256 * 64];   // 64 KB
    __shared__ __bf16 sBl[2 * 128 * 64];   // 32 KB
    const int t = threadIdx.x;
    const int w = t >> 6, lane = t & 63;
    const int brow = blockIdx.y * 256, bcol = blockIdx.x * 128;
    const int wr = (w >> 1) * 64, wc = (w & 1) * 64;
    f32x4 acc[4][4] = {};

    // staging source: lane -> row +(lane>>3), chunk (lane&7)^(lane>>3)
    const int rl8 = lane >> 3;
    const int ck8 = (lane & 7) ^ rl8;
    const __bf16* gA = A  + (size_t)(brow + w * 32 + rl8) * K + ck8 * 8;
    const __bf16* gB = Bt + (size_t)(bcol + w * 16 + rl8) * K + ck8 * 8;

    auto stage = [&](int buf, int k0) {
        __bf16* ba = sAl + buf * (256 * 64) + (w * 32) * 64;
        __bf16* bb = sBl + buf * (128 * 64) + (w * 16) * 64;
#pragma unroll
        for (int q = 0; q < 4; ++q)
            glds16(gA + (size_t)(q * 8) * K + k0, ba + q * 8 * 64);
#pragma unroll
        for (int q = 0; q < 2; ++q)
            glds16(gB + (size_t)(q * 8) * K + k0, bb + q * 8 * 64);
    };

    stage(0, 0);
    int cur = 0;
    for (int k0 = 0; k0 < K; k0 += 64) {
        __syncthreads();
        if (k0 + 64 < K) stage(cur ^ 1, k0 + 64);
        const __bf16* At = sAl + cur * (256 * 64);
        const __bf16* Btl = sBl + cur * (128 * 64);
#pragma unroll
        for (int ks = 0; ks < 2; ++ks) {
            const int rchk = (((ks * 4 + (lane >> 4)) ^ (lane & 7))) * 8;
            bf16x8 af[4], bg[4];
#pragma unroll
            for (int m = 0; m < 4; ++m)
                af[m] = *(const bf16x8*)&At[(wr + m * 16 + (lane & 15)) * 64 + rchk];
#pragma unroll
            for (int n = 0; n < 4; ++n)
                bg[n] = *(const bf16x8*)&Btl[(wc + n * 16 + (lane & 15)) * 64 + rchk];
#pragma unroll
            for (int m = 0; m < 4; ++m)
#pragma unroll
                for (int n = 0; n < 4; ++n)
                    acc[m][n] = __builtin_amdgcn_mfma_f32_16x16x32_bf16(
                        af[m], bg[n], acc[m][n], 0, 0, 0);
        }
        cur ^= 1;
    }

    const int c_l = lane & 15, r_l = (lane >> 4) * 4;
#pragma unroll
    for (int m = 0; m < 4; ++m)
#pragma unroll
        for (int n = 0; n < 4; ++n)
            gemm_epilogue<EPI>(acc[m][n], brow + wr + m * 16 + r_l,
                               bcol + wc + n * 16 + c_l, N, Cout, Cout2, res);
}

// ---------------------------------------------------------------- launch
extern "C" void kernel_launch(void* const* d_in, const int* in_sizes, int n_in,
                              void* d_out, int out_size, void* d_ws, size_t ws_size,
                              hipStream_t stream)
{
    (void)in_sizes; (void)n_in; (void)out_size; (void)ws_size;
    const float* x     = (const float*)d_in[0];
    const float* inw   = (const float*)d_in[1];
    const float* ffnw  = (const float*)d_in[2];
    const float* inpW  = (const float*)d_in[3];
    const float* convW = (const float*)d_in[4];
    const float* convB = (const float*)d_in[5];
    const float* dtW   = (const float*)d_in[6];
    const float* dtB   = (const float*)d_in[7];
    const float* BW    = (const float*)d_in[8];
    const float* CW    = (const float*)d_in[9];
    const float* Alog  = (const float*)d_in[10];
    const float* outpW = (const float*)d_in[11];
    const float* gateW = (const float*)d_in[12];
    const float* upW   = (const float*)d_in[13];
    const float* downW = (const float*)d_in[14];
    float* out = (float*)d_out;

    char* p = (char*)d_ws;
    auto alloc = [&](size_t n) { char* q = p; p += (n + 255) & ~(size_t)255; return q; };
    __bf16* wt_inproj = (__bf16*)alloc(4096ull * 1024 * 2);
    __bf16* wt_dtbc   = (__bf16*)alloc(2176ull * 2048 * 2);  // rows: 0-2047 dt, 2048-2111 B, 2112-2175 C
    __bf16* wt_outp   = (__bf16*)alloc(1024ull * 2048 * 2);
    __bf16* wt_gu     = (__bf16*)alloc(4096ull * 1024 * 2);
    __bf16* wt_down   = (__bf16*)alloc(1024ull * 2048 * 2);
    __bf16* normed    = (__bf16*)alloc(2048ull * 1024 * 2);  // reused as n2
    __bf16* xz        = (__bf16*)alloc(2048ull * 2048 * 2);  // x_z half of in_proj
    __bf16* gu_buf    = (__bf16*)alloc(2048ull * 4096 * 2);  // dAp then gu
    __bf16* xc        = (__bf16*)alloc(2048ull * 2048 * 2);  // conv out, reused as y
    float*  scratch16 = (float*)alloc(2048ull * 2048 * 4);   // hend/h0 then ffnmid
    float*  bc        = (float*)alloc(2048ull * 128 * 4);
    float*  dtT       = (float*)alloc(2048ull * 2048 * 4);
    __bf16* xcT       = (__bf16*)alloc(2048ull * 2048 * 2);
    __bf16* szT       = (__bf16*)alloc(2048ull * 2048 * 2);
    float*  x2        = (float*)alloc(2048ull * 1024 * 4);

    dim3 B256(256);
    // weight prep (f32 -> bf16, transposed to [N][K]); B/C as separate planes
    transpose_kernel<float, __bf16><<<dim3(128, 32), B256, 0, stream>>>(inpW, wt_inproj, 1024, 4096, 4096, 1, 0);
    transpose_kernel<float, __bf16><<<dim3(64, 64), B256, 0, stream>>>(dtW, wt_dtbc, 2048, 2048, 2048, 1, 0);
    transpose_kernel<float, __bf16><<<dim3(2, 64), B256, 0, stream>>>(BW, wt_dtbc + 2048ull * 2048, 2048, 64, 64, 1, 0);
    transpose_kernel<float, __bf16><<<dim3(2, 64), B256, 0, stream>>>(CW, wt_dtbc + 2112ull * 2048, 2048, 64, 64, 1, 0);
    transpose_kernel<float, __bf16><<<dim3(32, 64), B256, 0, stream>>>(outpW, wt_outp, 2048, 1024, 1024, 1, 0);
    transpose_kernel<float, __bf16><<<dim3(64, 32), B256, 0, stream>>>(gateW, wt_gu, 1024, 2048, 2048, 1, 0);
    transpose_kernel<float, __bf16><<<dim3(64, 32), B256, 0, stream>>>(upW, wt_gu + 2048ull * 1024, 1024, 2048, 2048, 1, 0);
    transpose_kernel<float, __bf16><<<dim3(32, 64), B256, 0, stream>>>(downW, wt_down, 2048, 1024, 1024, 1, 0);

    // normed = rmsnorm(x, inw)
    rmsnorm_kernel<<<dim3(2048), B256, 0, stream>>>(x, inw, normed);
    // in_proj: xz (t-major bf16) + szT (silu'd z, channel-major)
    gemm_big<4><<<dim3(32, 8), dim3(512), 0, stream>>>(normed, wt_inproj, xz, szT, nullptr, 2048, 4096, 1024);
    // xc = silu(conv(xz) + b)
    conv_silu_kernel<<<dim3(T_TOK * EDIM / 256), B256, 0, stream>>>(xz, convW, convB, xc);
    // fused dt+bc: dtT (softplus'd, channel-major f32) + bc (t-major f32, planes)
    gemm_kernel<3, 64, 1><<<dim3(17, 32), B256, 0, stream>>>(xc, wt_dtbc, dtT, bc, dtB, 2048, 2176, 2048);
    // xcT channel-major
    transpose_kernel<__bf16, __bf16><<<dim3(64, 64), B256, 0, stream>>>(xc, xcT, 2048, 2048, 2048, 1, 0);

    // chunked SSM scan
    float* hend = scratch16;                      // 16 MB (E*32*64 f32)
    float* dAp  = (float*)gu_buf;                 // 16 MB
    scan1_kernel<<<dim3(4096), dim3(512), 0, stream>>>(dtT, xcT, bc, Alog, hend, dAp);
    scan_mid_kernel<<<dim3(512), B256, 0, stream>>>(hend, dAp);
    __bf16* y = xc;                               // xc dead after xcT+dt GEMM
    scan2_kernel<<<dim3(2048), dim3(512), 0, stream>>>(dtT, xcT, szT, bc, Alog, hend, y);

    // x2 = x + y @ out_proj
    gemm_kernel<2, 64, 0><<<dim3(8, 32), B256, 0, stream>>>(y, wt_outp, x2, nullptr, x, 2048, 1024, 2048);
    // n2 = rmsnorm(x2, ffnw)
    rmsnorm_kernel<<<dim3(2048), B256, 0, stream>>>(x2, ffnw, normed);
    // gu = n2 @ [gate|up]
    __bf16* gu = gu_buf;
    gemm_big<1><<<dim3(32, 8), dim3(512), 0, stream>>>(normed, wt_gu, gu, nullptr, nullptr, 2048, 4096, 1024);
    // ffnmid = silu(gate)*up
    __bf16* ffnmid = (__bf16*)scratch16;
    glu_kernel<<<dim3(T_TOK * 2048 / 256), B256, 0, stream>>>(gu, ffnmid);
    // out = x2 + ffnmid @ down
    gemm_kernel<2, 64, 0><<<dim3(8, 32), B256, 0, stream>>>(ffnmid, wt_down, out, nullptr, x2, 2048, 1024, 2048);
}

// Round 15
// 323.918 us; speedup vs baseline: 2.2818x; 1.0954x over previous
//
#include <hip/hip_runtime.h>
#include <hip/hip_bf16.h>

typedef __bf16 bf16x8 __attribute__((ext_vector_type(8)));
typedef __bf16 bf16x4 __attribute__((ext_vector_type(4)));
typedef float  f32x4  __attribute__((ext_vector_type(4)));

#define T_TOK 2048
#define DDIM  1024
#define EDIM  2048
#define NCHUNK 32
#define CKLEN  64

// ---------------------------------------------------------------- batched weight prep
// One dispatch transposes all 8 weight matrices (f32 -> bf16, [N][K] layout).
struct TJob { const float* src; __bf16* dst; int R, C, S, tilesX, tileOff; };
struct TJobs8 { TJob j[8]; };

__global__ __launch_bounds__(256)
void wprep_kernel(TJobs8 jobs)
{
    int tile = blockIdx.x;
    int ji = 0;
#pragma unroll
    for (int k = 1; k < 8; ++k) if (tile >= jobs.j[k].tileOff) ji = k;
    const TJob jb = jobs.j[ji];
    int rel = tile - jb.tileOff;
    int bx = rel % jb.tilesX, by = rel / jb.tilesX;
    __shared__ float tilebuf[32][33];
    const int tc0 = bx * 32, tr0 = by * 32;
    const int tx = threadIdx.x & 31, ty = threadIdx.x >> 5;
#pragma unroll
    for (int p = 0; p < 4; ++p) {
        int rl = ty + p * 8;
        tilebuf[rl][tx] = jb.src[(size_t)(tr0 + rl) * jb.S + tc0 + tx];
    }
    __syncthreads();
#pragma unroll
    for (int p = 0; p < 4; ++p) {
        int cl = ty + p * 8;
        float v = tilebuf[tx][cl];
        int c = tc0 + cl, r = tr0 + tx;
        jb.dst[(size_t)c * jb.R + r] = (__bf16)v;
    }
}

// ---------------------------------------------------------------- transpose (xcT)
template<typename TS, typename TD>
__global__ __launch_bounds__(256)
void transpose_kernel(const TS* __restrict__ src, TD* __restrict__ dst,
                      int R, int C, int S, int dmul, int doff)
{
    __shared__ float tile[32][33];
    const int tc0 = blockIdx.x * 32, tr0 = blockIdx.y * 32;
    const int tx = threadIdx.x & 31, ty = threadIdx.x >> 5;
#pragma unroll
    for (int p = 0; p < 4; ++p) {
        int rl = ty + p * 8;
        tile[rl][tx] = (float)src[(size_t)(tr0 + rl) * S + tc0 + tx];
    }
    __syncthreads();
#pragma unroll
    for (int p = 0; p < 4; ++p) {
        int cl = ty + p * 8;
        float v = tile[tx][cl];
        int c = tc0 + cl, r = tr0 + tx;
        dst[((size_t)c * dmul + doff) * R + r] = (TD)v;
    }
}

// ---------------------------------------------------------------- rmsnorm
__global__ __launch_bounds__(256)
void rmsnorm_kernel(const float* __restrict__ x, const float* __restrict__ w,
                    __bf16* __restrict__ out)
{
    const int row = blockIdx.x;
    const int t = threadIdx.x;
    float4 v = ((const float4*)(x + (size_t)row * DDIM))[t];
    float ss = v.x * v.x + v.y * v.y + v.z * v.z + v.w * v.w;
#pragma unroll
    for (int m = 32; m; m >>= 1) ss += __shfl_xor(ss, m);
    __shared__ float red[4];
    if ((t & 63) == 0) red[t >> 6] = ss;
    __syncthreads();
    float scale = rsqrtf((red[0] + red[1] + red[2] + red[3]) * (1.f / DDIM) + 1e-5f);
    float4 wv = ((const float4*)w)[t];
    __bf16* o = out + (size_t)row * DDIM + t * 4;
    o[0] = (__bf16)(v.x * scale * wv.x);
    o[1] = (__bf16)(v.y * scale * wv.y);
    o[2] = (__bf16)(v.z * scale * wv.z);
    o[3] = (__bf16)(v.w * scale * wv.w);
}

// ---------------------------------------------------------------- conv+silu
__global__ __launch_bounds__(256)
void conv_silu_kernel(const __bf16* __restrict__ xz, const float* __restrict__ W,
                      const float* __restrict__ b, __bf16* __restrict__ xc)
{
    int idx = blockIdx.x * 256 + threadIdx.x;     // over T*E
    int t = idx >> 11, e = idx & (EDIM - 1);
    float s = b[e];
#pragma unroll
    for (int k = 0; k < 4; ++k) {                 // SAME pad: taps t-1..t+2
        int tt = t - 1 + k;
        if (tt >= 0 && tt < T_TOK)
            s += (float)xz[(size_t)tt * EDIM + e] * W[k * EDIM + e];
    }
    s = s / (1.f + __expf(-s));
    xc[idx] = (__bf16)s;
}

// ---------------------------------------------------------------- glu
__global__ __launch_bounds__(256)
void glu_kernel(const __bf16* __restrict__ gu, __bf16* __restrict__ outm)
{
    int idx = blockIdx.x * 256 + threadIdx.x;     // over T*I
    int t = idx >> 11, i = idx & 2047;
    float g = (float)gu[(size_t)t * 4096 + i];
    float u = (float)gu[(size_t)t * 4096 + 2048 + i];
    outm[idx] = (__bf16)(g / (1.f + __expf(-g)) * u);
}

// ---------------------------------------------------------------- scan
template<int CTRL, int ROWMASK>
__device__ __forceinline__ float dpp_add(float v)
{
    int y = __builtin_amdgcn_update_dpp(0, __builtin_bit_cast(int, v),
                                        CTRL, ROWMASK, 0xf, true);
    return v + __builtin_bit_cast(float, y);
}

// bc layout (plane-split): bc[t*128 + n] = B[t,n], bc[t*128 + 64 + n] = C[t,n].

// Pass 1: block = 8 waves, 16 channels, one chunk; B-plane only staged.
__global__ __launch_bounds__(512)
void scan1_kernel(const float* __restrict__ dtT, const __bf16* __restrict__ xcT,
                  const float* __restrict__ bc2, const float* __restrict__ A_log,
                  float* __restrict__ hend, float* __restrict__ dAp)
{
    __shared__ float  s_b[CKLEN * 64];     // 16 KB (B-plane)
    __shared__ float  s_dt[16][CKLEN];     // 4 KB
    __shared__ __bf16 s_x[16][CKLEN];      // 2 KB
    const int tid = threadIdx.x;
    const int lane = tid & 63, w = tid >> 6;
    const int c = lane >> 5, i = lane & 31;
    const int ck = blockIdx.x & (NCHUNK - 1);
    const int eg = (blockIdx.x >> 5) * 16;

    {
#pragma unroll
        for (int r = 0; r < 2; ++r) {
            int linear = r * 512 + tid;
            int t = linear >> 4, k = linear & 15;
            *(float4*)&s_b[t * 64 + 4 * k] =
                *(const float4*)(bc2 + (size_t)(ck * CKLEN + t) * 128 + 4 * k);
        }
        if (tid < 256) {
            int ch = tid >> 4, k = tid & 15;
            *((float4*)&s_dt[ch][0] + k) =
                *(const float4*)(dtT + (size_t)(eg + ch) * T_TOK + ck * CKLEN + 4 * k);
        } else if (tid < 384) {
            int q = tid - 256, ch = q >> 3, k = q & 7;
            *((bf16x8*)&s_x[ch][0] + k) =
                *(const bf16x8*)(xcT + (size_t)(eg + ch) * T_TOK + ck * CKLEN + 8 * k);
        }
    }
    __syncthreads();

    const int ch = 2 * w + c;
    float2 al = *(const float2*)(A_log + 2 * i);
    const float L2E = 1.44269504f;
    const float An0 = -__expf(al.x) * L2E;
    const float An1 = -__expf(al.y) * L2E;
    float h0 = 0.f, h1 = 0.f, D = 0.f;

#pragma unroll 2
    for (int t0 = 0; t0 < CKLEN; t0 += 8) {
        float4 da = *(const float4*)&s_dt[ch][t0];
        float4 db = *(const float4*)&s_dt[ch][t0 + 4];
        bf16x8 x8 = *(const bf16x8*)&s_x[ch][t0];
        float dtv[8] = {da.x, da.y, da.z, da.w, db.x, db.y, db.z, db.w};
#pragma unroll
        for (int j = 0; j < 8; ++j) {
            float2 Bv = *(const float2*)&s_b[(t0 + j) * 64 + 2 * i];
            float u = dtv[j] * (float)x8[j];
            float dA0 = __builtin_amdgcn_exp2f(dtv[j] * An0);
            float dA1 = __builtin_amdgcn_exp2f(dtv[j] * An1);
            h0 = fmaf(dA0, h0, u * Bv.x);
            h1 = fmaf(dA1, h1, u * Bv.y);
            D += dtv[j];
        }
    }
    const int e = eg + ch;
    size_t idx = ((size_t)e * NCHUNK + ck) * 64 + 2 * i;
    *(float2*)(hend + idx) = make_float2(h0, h1);
    *(float2*)(dAp + idx)  = make_float2(__builtin_amdgcn_exp2f(An0 * D),
                                         __builtin_amdgcn_exp2f(An1 * D));
}

// Mid: serial scan over chunk summaries -> h_start per chunk, IN PLACE over hend.
__global__ __launch_bounds__(256)
void scan_mid_kernel(float* __restrict__ hend_h0, const float* __restrict__ dAp)
{
    int gid = blockIdx.x * 256 + threadIdx.x;     // over E*64
    int e = gid >> 6, n = gid & 63;
    float h = 0.f;
#pragma unroll
    for (int ck = 0; ck < NCHUNK; ++ck) {
        size_t idx = ((size_t)e * NCHUNK + ck) * 64 + n;
        float he = hend_h0[idx];
        float P  = dAp[idx];
        hend_h0[idx] = h;
        h = P * h + he;
    }
}

// Pass 2: block = 8 waves, 32 channels, one chunk; B/C planes staged separately.
__global__ __launch_bounds__(512)
void scan2_kernel(const float* __restrict__ dtT, const __bf16* __restrict__ xcT,
                  const __bf16* __restrict__ szT, const float* __restrict__ bc2,
                  const float* __restrict__ A_log, const float* __restrict__ h0s,
                  __bf16* __restrict__ y)
{
    __shared__ float  s_bp[CKLEN * 64];    // 16 KB (B-plane)
    __shared__ float  s_cp[CKLEN * 64];    // 16 KB (C-plane)
    __shared__ float  s_dt[32][68];        // padded rows
    __shared__ __bf16 s_x[32][72];         // padded rows
    __shared__ __bf16 s_y[CKLEN][36];      // padded, t-major tile
    const int tid = threadIdx.x;
    const int lane = tid & 63, w = tid >> 6;
    const int g = lane >> 4, i = lane & 15;
    const int ck = blockIdx.x & (NCHUNK - 1);
    const int eg = (blockIdx.x >> 5) * 32;

    {
#pragma unroll
        for (int r = 0; r < 2; ++r) {
            int linear = r * 512 + tid;
            int t = linear >> 4, k = linear & 15;
            const float* src = bc2 + (size_t)(ck * CKLEN + t) * 128 + 4 * k;
            *(float4*)&s_bp[t * 64 + 4 * k] = *(const float4*)src;
            *(float4*)&s_cp[t * 64 + 4 * k] = *(const float4*)(src + 64);
        }
        { int ch = tid >> 4, k = tid & 15;
          *(float4*)&s_dt[ch][4 * k] =
              *(const float4*)(dtT + (size_t)(eg + ch) * T_TOK + ck * CKLEN + 4 * k); }
        if (tid < 256) { int ch = tid >> 3, k = tid & 7;
          *(bf16x8*)&s_x[ch][8 * k] =
              *(const bf16x8*)(xcT + (size_t)(eg + ch) * T_TOK + ck * CKLEN + 8 * k); }
    }
    __syncthreads();

    const int ch = w * 4 + g;
    const int e = eg + ch;
    float4 al4 = *(const float4*)(A_log + 4 * i);
    const float L2E = 1.44269504f;
    const float An0 = -__expf(al4.x) * L2E;
    const float An1 = -__expf(al4.y) * L2E;
    const float An2 = -__expf(al4.z) * L2E;
    const float An3 = -__expf(al4.w) * L2E;
    float4 hh = *(const float4*)(h0s + ((size_t)e * NCHUNK + ck) * 64 + 4 * i);
    float h0 = hh.x, h1 = hh.y, h2 = hh.z, h3 = hh.w;

#pragma unroll 2
    for (int t0 = 0; t0 < CKLEN; t0 += 8) {
        float4 da = *(const float4*)&s_dt[ch][t0];
        float4 db = *(const float4*)&s_dt[ch][t0 + 4];
        bf16x8 x8 = *(const bf16x8*)&s_x[ch][t0];
        float dtv[8] = {da.x, da.y, da.z, da.w, db.x, db.y, db.z, db.w};
#pragma unroll
        for (int j = 0; j < 8; ++j) {
            float4 b0 = *(const float4*)&s_bp[(t0 + j) * 64 + 4 * i];
            float4 c0 = *(const float4*)&s_cp[(t0 + j) * 64 + 4 * i];
            float dt = dtv[j];
            float u = dt * (float)x8[j];
            h0 = fmaf(__builtin_amdgcn_exp2f(dt * An0), h0, u * b0.x);
            h1 = fmaf(__builtin_amdgcn_exp2f(dt * An1), h1, u * b0.y);
            h2 = fmaf(__builtin_amdgcn_exp2f(dt * An2), h2, u * b0.z);
            h3 = fmaf(__builtin_amdgcn_exp2f(dt * An3), h3, u * b0.w);
            float p = h0 * c0.x;
            p = fmaf(h1, c0.y, p);
            p = fmaf(h2, c0.z, p);
            p = fmaf(h3, c0.w, p);
            p = dpp_add<0x111, 0xf>(p);
            p = dpp_add<0x112, 0xf>(p);
            p = dpp_add<0x114, 0xf>(p);
            p = dpp_add<0x118, 0xf>(p);
            if (i == 15) s_y[t0 + j][ch] = (__bf16)p;
        }
    }
    __syncthreads();

    {
        int tt = tid >> 3, q = tid & 7;
        bf16x4 o;
#pragma unroll
        for (int d = 0; d < 4; ++d) {
            float zv = (float)szT[(size_t)(eg + 4 * q + d) * T_TOK + ck * CKLEN + tt];
            o[d] = (__bf16)((float)s_y[tt][4 * q + d] * zv);
        }
        *(bf16x4*)(y + (size_t)(ck * CKLEN + tt) * EDIM + eg + 4 * q) = o;
    }
}

// ---------------------------------------------------------------- GEMM common
__device__ __forceinline__ void glds16(const __bf16* g, __bf16* l)
{
    __builtin_amdgcn_global_load_lds(
        (const __attribute__((address_space(1))) unsigned*)g,
        (__attribute__((address_space(3))) unsigned*)l, 16, 0, 0);
}

// Epilogue (shared by both GEMM variants).
template<int EPI>
__device__ __forceinline__ void gemm_epilogue(
    const f32x4& a, int row, int col, int N,
    void* Cout, void* Cout2, const float* res)
{
    if (EPI == 1) {
#pragma unroll
        for (int i = 0; i < 4; ++i)
            ((__bf16*)Cout)[(size_t)(row + i) * N + col] = (__bf16)a[i];
    } else if (EPI == 2) {
#pragma unroll
        for (int i = 0; i < 4; ++i) {
            size_t off = (size_t)(row + i) * N + col;
            ((float*)Cout)[off] = a[i] + res[off];
        }
    } else if (EPI == 3) {
        if (col < 2048) {
            float bias = res[col];
            float4 v;
            float* vv = (float*)&v;
#pragma unroll
            for (int i = 0; i < 4; ++i) {
                float s = a[i] + bias;
                s = (s > 20.f) ? s : log1pf(__expf(s));
                vv[i] = fminf(fmaxf(s, 0.001f), 0.1f);
            }
            *(float4*)((float*)Cout + (size_t)col * T_TOK + row) = v;
        } else {
#pragma unroll
            for (int i = 0; i < 4; ++i)
                ((float*)Cout2)[(size_t)(row + i) * 128 + (col - 2048)] = a[i];
        }
    } else if (EPI == 4) {
        if (col < 2048) {
#pragma unroll
            for (int i = 0; i < 4; ++i)
                ((__bf16*)Cout)[(size_t)(row + i) * EDIM + col] = (__bf16)a[i];
        } else {
            bf16x4 v;
#pragma unroll
            for (int i = 0; i < 4; ++i) {
                float s = a[i];
                v[i] = (__bf16)(s / (1.f + __expf(-s)));
            }
            *(bf16x4*)((__bf16*)Cout2 + (size_t)(col - 2048) * T_TOK + row) = v;
        }
    }
}

// 4-wave GEMM: 64 x 128 tile, BK=64, 2-phase, 8-chunk XOR-swizzled LDS.
// LDS[row][c] = global[row][c ^ (row&7)] (chunks of 8 bf16 = 16B); read slot
// g^(lane&7) covers all 8 16B-slots per 8 lanes (minimal bank aliasing).
// SWZ<1>: XCD-contiguous block remap (grid total must be mult of 8).
template<int EPI, int SWZ>
__global__ __launch_bounds__(256)
void gemm_kernel(const __bf16* __restrict__ A, const __bf16* __restrict__ Bt,
                 void* __restrict__ Cout, void* __restrict__ Cout2,
                 const float* __restrict__ res, int M, int N, int K)
{
    __shared__ __bf16 sAl[2 * 64 * 64];    // 16 KB
    __shared__ __bf16 sBl[2 * 128 * 64];   // 32 KB
    const int t = threadIdx.x;
    const int wave = t >> 6, lane = t & 63;
    int bx = blockIdx.x, by = blockIdx.y;
    if (SWZ) {
        int nwg = gridDim.x * gridDim.y;
        int bid = by * gridDim.x + bx;
        int cpx = nwg >> 3;
        int swz = (bid & 7) * cpx + (bid >> 3);
        bx = swz % gridDim.x;
        by = swz / gridDim.x;
    }
    const int brow = by * 64, bcol = bx * 128;
    const int wr = (wave >> 1) * 32, wc = (wave & 1) * 64;
    f32x4 acc[2][4] = {};

    // staging source: lane -> row +(lane>>3), chunk (lane&7)^(lane>>3)
    const int rl8 = lane >> 3;
    const int ck8 = (lane & 7) ^ rl8;
    const __bf16* gA = A  + (size_t)(brow + wave * 16 + rl8) * K + ck8 * 8;
    const __bf16* gB = Bt + (size_t)(bcol + wave * 32 + rl8) * K + ck8 * 8;

    auto stage = [&](int buf, int k0) {
        __bf16* ba = sAl + buf * (64 * 64) + (wave * 16) * 64;
        __bf16* bb = sBl + buf * (128 * 64) + (wave * 32) * 64;
#pragma unroll
        for (int q = 0; q < 2; ++q)
            glds16(gA + (size_t)(q * 8) * K + k0, ba + q * 8 * 64);
#pragma unroll
        for (int q = 0; q < 4; ++q)
            glds16(gB + (size_t)(q * 8) * K + k0, bb + q * 8 * 64);
    };

    stage(0, 0);
    int cur = 0;
    for (int k0 = 0; k0 < K; k0 += 64) {
        __syncthreads();                  // staged tile landed; other buf free
        if (k0 + 64 < K) stage(cur ^ 1, k0 + 64);
        const __bf16* At = sAl + cur * (64 * 64);
        const __bf16* Btl = sBl + cur * (128 * 64);
#pragma unroll
        for (int ks = 0; ks < 2; ++ks) {
            const int rc = (((ks * 4 + (lane >> 4)) ^ (lane & 7))) * 8;
            bf16x8 af[2], bg[4];
#pragma unroll
            for (int m = 0; m < 2; ++m)
                af[m] = *(const bf16x8*)&At[(wr + m * 16 + (lane & 15)) * 64 + rc];
#pragma unroll
            for (int n = 0; n < 4; ++n)
                bg[n] = *(const bf16x8*)&Btl[(wc + n * 16 + (lane & 15)) * 64 + rc];
#pragma unroll
            for (int m = 0; m < 2; ++m)
#pragma unroll
                for (int n = 0; n < 4; ++n)
                    acc[m][n] = __builtin_amdgcn_mfma_f32_16x16x32_bf16(
                        af[m], bg[n], acc[m][n], 0, 0, 0);
        }
        cur ^= 1;
    }

    const int c_l = lane & 15, r_l = (lane >> 4) * 4;
#pragma unroll
    for (int m = 0; m < 2; ++m)
#pragma unroll
        for (int n = 0; n < 4; ++n)
            gemm_epilogue<EPI>(acc[m][n], brow + wr + m * 16 + r_l,
                               bcol + wc + n * 16 + c_l, N, Cout, Cout2, res);
}

// 8-wave big GEMM: 256 x 128 tile, BK=64, 2-phase, XOR chunk-swizzled LDS.
template<int EPI>
__global__ __launch_bounds__(512)
void gemm_big(const __bf16* __restrict__ A, const __bf16* __restrict__ Bt,
              void* __restrict__ Cout, void* __restrict__ Cout2,
              const float* __restrict__ res, int M, int N, int K)
{
    __shared__ __bf16 sAl[2 * 256 * 64];   // 64 KB
    __shared__ __bf16 sBl[2 * 128 * 64];   // 32 KB
    const int t = threadIdx.x;
    const int w = t >> 6, lane = t & 63;
    const int brow = blockIdx.y * 256, bcol = blockIdx.x * 128;
    const int wr = (w >> 1) * 64, wc = (w & 1) * 64;
    f32x4 acc[4][4] = {};

    const int rl8 = lane >> 3;
    const int ck8 = (lane & 7) ^ rl8;
    const __bf16* gA = A  + (size_t)(brow + w * 32 + rl8) * K + ck8 * 8;
    const __bf16* gB = Bt + (size_t)(bcol + w * 16 + rl8) * K + ck8 * 8;

    auto stage = [&](int buf, int k0) {
        __bf16* ba = sAl + buf * (256 * 64) + (w * 32) * 64;
        __bf16* bb = sBl + buf * (128 * 64) + (w * 16) * 64;
#pragma unroll
        for (int q = 0; q < 4; ++q)
            glds16(gA + (size_t)(q * 8) * K + k0, ba + q * 8 * 64);
#pragma unroll
        for (int q = 0; q < 2; ++q)
            glds16(gB + (size_t)(q * 8) * K + k0, bb + q * 8 * 64);
    };

    stage(0, 0);
    int cur = 0;
    for (int k0 = 0; k0 < K; k0 += 64) {
        __syncthreads();
        if (k0 + 64 < K) stage(cur ^ 1, k0 + 64);
        const __bf16* At = sAl + cur * (256 * 64);
        const __bf16* Btl = sBl + cur * (128 * 64);
#pragma unroll
        for (int ks = 0; ks < 2; ++ks) {
            const int rchk = (((ks * 4 + (lane >> 4)) ^ (lane & 7))) * 8;
            bf16x8 af[4], bg[4];
#pragma unroll
            for (int m = 0; m < 4; ++m)
                af[m] = *(const bf16x8*)&At[(wr + m * 16 + (lane & 15)) * 64 + rchk];
#pragma unroll
            for (int n = 0; n < 4; ++n)
                bg[n] = *(const bf16x8*)&Btl[(wc + n * 16 + (lane & 15)) * 64 + rchk];
#pragma unroll
            for (int m = 0; m < 4; ++m)
#pragma unroll
                for (int n = 0; n < 4; ++n)
                    acc[m][n] = __builtin_amdgcn_mfma_f32_16x16x32_bf16(
                        af[m], bg[n], acc[m][n], 0, 0, 0);
        }
        cur ^= 1;
    }

    const int c_l = lane & 15, r_l = (lane >> 4) * 4;
#pragma unroll
    for (int m = 0; m < 4; ++m)
#pragma unroll
        for (int n = 0; n < 4; ++n)
            gemm_epilogue<EPI>(acc[m][n], brow + wr + m * 16 + r_l,
                               bcol + wc + n * 16 + c_l, N, Cout, Cout2, res);
}

// ---------------------------------------------------------------- launch
extern "C" void kernel_launch(void* const* d_in, const int* in_sizes, int n_in,
                              void* d_out, int out_size, void* d_ws, size_t ws_size,
                              hipStream_t stream)
{
    (void)in_sizes; (void)n_in; (void)out_size; (void)ws_size;
    const float* x     = (const float*)d_in[0];
    const float* inw   = (const float*)d_in[1];
    const float* ffnw  = (const float*)d_in[2];
    const float* inpW  = (const float*)d_in[3];
    const float* convW = (const float*)d_in[4];
    const float* convB = (const float*)d_in[5];
    const float* dtW   = (const float*)d_in[6];
    const float* dtB   = (const float*)d_in[7];
    const float* BW    = (const float*)d_in[8];
    const float* CW    = (const float*)d_in[9];
    const float* Alog  = (const float*)d_in[10];
    const float* outpW = (const float*)d_in[11];
    const float* gateW = (const float*)d_in[12];
    const float* upW   = (const float*)d_in[13];
    const float* downW = (const float*)d_in[14];
    float* out = (float*)d_out;

    char* p = (char*)d_ws;
    auto alloc = [&](size_t n) { char* q = p; p += (n + 255) & ~(size_t)255; return q; };
    __bf16* wt_inproj = (__bf16*)alloc(4096ull * 1024 * 2);
    __bf16* wt_dtbc   = (__bf16*)alloc(2176ull * 2048 * 2);  // rows: 0-2047 dt, 2048-2111 B, 2112-2175 C
    __bf16* wt_outp   = (__bf16*)alloc(1024ull * 2048 * 2);
    __bf16* wt_gu     = (__bf16*)alloc(4096ull * 1024 * 2);
    __bf16* wt_down   = (__bf16*)alloc(1024ull * 2048 * 2);
    __bf16* normed    = (__bf16*)alloc(2048ull * 1024 * 2);  // reused as n2
    __bf16* xz        = (__bf16*)alloc(2048ull * 2048 * 2);  // x_z half of in_proj
    __bf16* gu_buf    = (__bf16*)alloc(2048ull * 4096 * 2);  // dAp then gu
    __bf16* xc        = (__bf16*)alloc(2048ull * 2048 * 2);  // conv out, reused as y
    float*  scratch16 = (float*)alloc(2048ull * 2048 * 4);   // hend/h0 then ffnmid
    float*  bc        = (float*)alloc(2048ull * 128 * 4);
    float*  dtT       = (float*)alloc(2048ull * 2048 * 4);
    __bf16* xcT       = (__bf16*)alloc(2048ull * 2048 * 2);
    __bf16* szT       = (__bf16*)alloc(2048ull * 2048 * 2);
    float*  x2        = (float*)alloc(2048ull * 1024 * 4);

    dim3 B256(256);
    // batched weight prep (f32 -> bf16, transposed to [N][K]); one dispatch
    {
        TJobs8 tj;
        int off = 0, ji = 0;
        auto addjob = [&](const float* s, __bf16* d, int R, int C, int S) {
            tj.j[ji++] = TJob{s, d, R, C, S, C / 32, off};
            off += (C / 32) * (R / 32);
        };
        addjob(inpW,  wt_inproj, 1024, 4096, 4096);
        addjob(dtW,   wt_dtbc,   2048, 2048, 2048);
        addjob(BW,    wt_dtbc + 2048ull * 2048, 2048, 64, 64);
        addjob(CW,    wt_dtbc + 2112ull * 2048, 2048, 64, 64);
        addjob(outpW, wt_outp,   2048, 1024, 1024);
        addjob(gateW, wt_gu,     1024, 2048, 2048);
        addjob(upW,   wt_gu + 2048ull * 1024, 1024, 2048, 2048);
        addjob(downW, wt_down,   2048, 1024, 1024);
        wprep_kernel<<<dim3(off), B256, 0, stream>>>(tj);
    }

    // normed = rmsnorm(x, inw)
    rmsnorm_kernel<<<dim3(2048), B256, 0, stream>>>(x, inw, normed);
    // in_proj: xz (t-major bf16) + szT (silu'd z, channel-major)
    gemm_big<4><<<dim3(32, 8), dim3(512), 0, stream>>>(normed, wt_inproj, xz, szT, nullptr, 2048, 4096, 1024);
    // xc = silu(conv(xz) + b)
    conv_silu_kernel<<<dim3(T_TOK * EDIM / 256), B256, 0, stream>>>(xz, convW, convB, xc);
    // fused dt+bc: dtT (softplus'd, channel-major f32) + bc (t-major f32, planes)
    gemm_kernel<3, 1><<<dim3(17, 32), B256, 0, stream>>>(xc, wt_dtbc, dtT, bc, dtB, 2048, 2176, 2048);
    // xcT channel-major
    transpose_kernel<__bf16, __bf16><<<dim3(64, 64), B256, 0, stream>>>(xc, xcT, 2048, 2048, 2048, 1, 0);

    // chunked SSM scan
    float* hend = scratch16;                      // 16 MB (E*32*64 f32)
    float* dAp  = (float*)gu_buf;                 // 16 MB
    scan1_kernel<<<dim3(4096), dim3(512), 0, stream>>>(dtT, xcT, bc, Alog, hend, dAp);
    scan_mid_kernel<<<dim3(512), B256, 0, stream>>>(hend, dAp);
    __bf16* y = xc;                               // xc dead after xcT+dt GEMM
    scan2_kernel<<<dim3(2048), dim3(512), 0, stream>>>(dtT, xcT, szT, bc, Alog, hend, y);

    // x2 = x + y @ out_proj
    gemm_kernel<2, 0><<<dim3(8, 32), B256, 0, stream>>>(y, wt_outp, x2, nullptr, x, 2048, 1024, 2048);
    // n2 = rmsnorm(x2, ffnw)
    rmsnorm_kernel<<<dim3(2048), B256, 0, stream>>>(x2, ffnw, normed);
    // gu = n2 @ [gate|up]
    __bf16* gu = gu_buf;
    gemm_big<1><<<dim3(32, 8), dim3(512), 0, stream>>>(normed, wt_gu, gu, nullptr, nullptr, 2048, 4096, 1024);
    // ffnmid = silu(gate)*up
    __bf16* ffnmid = (__bf16*)scratch16;
    glu_kernel<<<dim3(T_TOK * 2048 / 256), B256, 0, stream>>>(gu, ffnmid);
    // out = x2 + ffnmid @ down
    gemm_kernel<2, 0><<<dim3(8, 32), B256, 0, stream>>>(ffnmid, wt_down, out, nullptr, x2, 2048, 1024, 2048);
}

// Round 16
// 304.008 us; speedup vs baseline: 2.4312x; 1.0655x over previous
//
#include <hip/hip_runtime.h>
#include <hip/hip_bf16.h>

typedef __bf16 bf16x8 __attribute__((ext_vector_type(8)));
typedef __bf16 bf16x4 __attribute__((ext_vector_type(4)));
typedef float  f32x4  __attribute__((ext_vector_type(4)));

#define T_TOK 2048
#define DDIM  1024
#define EDIM  2048
#define NCHUNK 32
#define CKLEN  64

// ---------------------------------------------------------------- batched weight prep
// One dispatch transposes all weight matrices (f32 -> bf16, [N][K] layout).
// mode 0: dst row = src col c.  mode 1: row = 32*(c>>4)+(c&15) (gate interleave).
// mode 2: row = 32*(c>>4)+16+(c&15) (up interleave).
struct TJob { const float* src; __bf16* dst; int R, C, S, tilesX, tileOff, mode; };
struct TJobs8 { TJob j[8]; };

__global__ __launch_bounds__(256)
void wprep_kernel(TJobs8 jobs)
{
    int tile = blockIdx.x;
    int ji = 0;
#pragma unroll
    for (int k = 1; k < 8; ++k) if (tile >= jobs.j[k].tileOff) ji = k;
    const TJob jb = jobs.j[ji];
    int rel = tile - jb.tileOff;
    int bx = rel % jb.tilesX, by = rel / jb.tilesX;
    __shared__ float tilebuf[32][33];
    const int tc0 = bx * 32, tr0 = by * 32;
    const int tx = threadIdx.x & 31, ty = threadIdx.x >> 5;
#pragma unroll
    for (int p = 0; p < 4; ++p) {
        int rl = ty + p * 8;
        tilebuf[rl][tx] = jb.src[(size_t)(tr0 + rl) * jb.S + tc0 + tx];
    }
    __syncthreads();
#pragma unroll
    for (int p = 0; p < 4; ++p) {
        int cl = ty + p * 8;
        float v = tilebuf[tx][cl];
        int c = tc0 + cl, r = tr0 + tx;
        int dr = (jb.mode == 0) ? c
               : ((c >> 4) * 32 + (c & 15) + ((jb.mode == 2) ? 16 : 0));
        jb.dst[(size_t)dr * jb.R + r] = (__bf16)v;
    }
}

// ---------------------------------------------------------------- rmsnorm
__global__ __launch_bounds__(256)
void rmsnorm_kernel(const float* __restrict__ x, const float* __restrict__ w,
                    __bf16* __restrict__ out)
{
    const int row = blockIdx.x;
    const int t = threadIdx.x;
    float4 v = ((const float4*)(x + (size_t)row * DDIM))[t];
    float ss = v.x * v.x + v.y * v.y + v.z * v.z + v.w * v.w;
#pragma unroll
    for (int m = 32; m; m >>= 1) ss += __shfl_xor(ss, m);
    __shared__ float red[4];
    if ((t & 63) == 0) red[t >> 6] = ss;
    __syncthreads();
    float scale = rsqrtf((red[0] + red[1] + red[2] + red[3]) * (1.f / DDIM) + 1e-5f);
    float4 wv = ((const float4*)w)[t];
    __bf16* o = out + (size_t)row * DDIM + t * 4;
    o[0] = (__bf16)(v.x * scale * wv.x);
    o[1] = (__bf16)(v.y * scale * wv.y);
    o[2] = (__bf16)(v.z * scale * wv.z);
    o[3] = (__bf16)(v.w * scale * wv.w);
}

// ---------------------------------------------------------------- conv+silu (+xcT)
// Tile [32 t][64 e]: writes xc (t-major) AND xcT (channel-major) in one pass.
__global__ __launch_bounds__(256)
void conv_silu_xt_kernel(const __bf16* __restrict__ xz, const float* __restrict__ W,
                         const float* __restrict__ b, __bf16* __restrict__ xc,
                         __bf16* __restrict__ xcT)
{
    __shared__ __bf16 s_t[32][72];      // 144 B rows (16B-aligned)
    const int tid = threadIdx.x;
    const int e0 = blockIdx.x * 64, t0 = blockIdx.y * 32;
    const int tl = tid >> 3, e8 = (tid & 7) * 8;
    const int t = t0 + tl;
    float acc[8];
    {
        float4 b0 = *(const float4*)(b + e0 + e8);
        float4 b1 = *(const float4*)(b + e0 + e8 + 4);
        acc[0] = b0.x; acc[1] = b0.y; acc[2] = b0.z; acc[3] = b0.w;
        acc[4] = b1.x; acc[5] = b1.y; acc[6] = b1.z; acc[7] = b1.w;
    }
#pragma unroll
    for (int k = 0; k < 4; ++k) {       // SAME pad: taps t-1..t+2
        int tt = t - 1 + k;
        if (tt >= 0 && tt < T_TOK) {
            bf16x8 v = *(const bf16x8*)(xz + (size_t)tt * EDIM + e0 + e8);
            float4 w0 = *(const float4*)(W + k * EDIM + e0 + e8);
            float4 w1 = *(const float4*)(W + k * EDIM + e0 + e8 + 4);
            acc[0] += (float)v[0] * w0.x; acc[1] += (float)v[1] * w0.y;
            acc[2] += (float)v[2] * w0.z; acc[3] += (float)v[3] * w0.w;
            acc[4] += (float)v[4] * w1.x; acc[5] += (float)v[5] * w1.y;
            acc[6] += (float)v[6] * w1.z; acc[7] += (float)v[7] * w1.w;
        }
    }
    bf16x8 o;
#pragma unroll
    for (int j = 0; j < 8; ++j) {
        float s = acc[j];
        o[j] = (__bf16)(s / (1.f + __expf(-s)));
    }
    *(bf16x8*)(xc + (size_t)t * EDIM + e0 + e8) = o;
    *(bf16x8*)&s_t[tl][e8] = o;
    __syncthreads();
    // transposed write: thread -> (e_local, 8 t-contiguous)
    {
        int el = tid >> 2, t8 = (tid & 3) * 8;
        bf16x8 o2;
#pragma unroll
        for (int j = 0; j < 8; ++j) o2[j] = s_t[t8 + j][el];
        *(bf16x8*)(xcT + (size_t)(e0 + el) * T_TOK + t0 + t8) = o2;
    }
}

// ---------------------------------------------------------------- scan
template<int CTRL, int ROWMASK>
__device__ __forceinline__ float dpp_add(float v)
{
    int y = __builtin_amdgcn_update_dpp(0, __builtin_bit_cast(int, v),
                                        CTRL, ROWMASK, 0xf, true);
    return v + __builtin_bit_cast(float, y);
}

// bc layout (plane-split): bc[t*128 + n] = B[t,n], bc[t*128 + 64 + n] = C[t,n].

// Pass 1: block = 8 waves, 16 channels, one chunk; B-plane only staged.
__global__ __launch_bounds__(512)
void scan1_kernel(const float* __restrict__ dtT, const __bf16* __restrict__ xcT,
                  const float* __restrict__ bc2, const float* __restrict__ A_log,
                  float* __restrict__ hend, float* __restrict__ dAp)
{
    __shared__ float  s_b[CKLEN * 64];     // 16 KB (B-plane)
    __shared__ float  s_dt[16][CKLEN];     // 4 KB
    __shared__ __bf16 s_x[16][CKLEN];      // 2 KB
    const int tid = threadIdx.x;
    const int lane = tid & 63, w = tid >> 6;
    const int c = lane >> 5, i = lane & 31;
    const int ck = blockIdx.x & (NCHUNK - 1);
    const int eg = (blockIdx.x >> 5) * 16;

    {
#pragma unroll
        for (int r = 0; r < 2; ++r) {
            int linear = r * 512 + tid;
            int t = linear >> 4, k = linear & 15;
            *(float4*)&s_b[t * 64 + 4 * k] =
                *(const float4*)(bc2 + (size_t)(ck * CKLEN + t) * 128 + 4 * k);
        }
        if (tid < 256) {
            int ch = tid >> 4, k = tid & 15;
            *((float4*)&s_dt[ch][0] + k) =
                *(const float4*)(dtT + (size_t)(eg + ch) * T_TOK + ck * CKLEN + 4 * k);
        } else if (tid < 384) {
            int q = tid - 256, ch = q >> 3, k = q & 7;
            *((bf16x8*)&s_x[ch][0] + k) =
                *(const bf16x8*)(xcT + (size_t)(eg + ch) * T_TOK + ck * CKLEN + 8 * k);
        }
    }
    __syncthreads();

    const int ch = 2 * w + c;
    float2 al = *(const float2*)(A_log + 2 * i);
    const float L2E = 1.44269504f;
    const float An0 = -__expf(al.x) * L2E;
    const float An1 = -__expf(al.y) * L2E;
    float h0 = 0.f, h1 = 0.f, D = 0.f;

#pragma unroll 2
    for (int t0 = 0; t0 < CKLEN; t0 += 8) {
        float4 da = *(const float4*)&s_dt[ch][t0];
        float4 db = *(const float4*)&s_dt[ch][t0 + 4];
        bf16x8 x8 = *(const bf16x8*)&s_x[ch][t0];
        float dtv[8] = {da.x, da.y, da.z, da.w, db.x, db.y, db.z, db.w};
#pragma unroll
        for (int j = 0; j < 8; ++j) {
            float2 Bv = *(const float2*)&s_b[(t0 + j) * 64 + 2 * i];
            float u = dtv[j] * (float)x8[j];
            float dA0 = __builtin_amdgcn_exp2f(dtv[j] * An0);
            float dA1 = __builtin_amdgcn_exp2f(dtv[j] * An1);
            h0 = fmaf(dA0, h0, u * Bv.x);
            h1 = fmaf(dA1, h1, u * Bv.y);
            D += dtv[j];
        }
    }
    const int e = eg + ch;
    size_t idx = ((size_t)e * NCHUNK + ck) * 64 + 2 * i;
    *(float2*)(hend + idx) = make_float2(h0, h1);
    *(float2*)(dAp + idx)  = make_float2(__builtin_amdgcn_exp2f(An0 * D),
                                         __builtin_amdgcn_exp2f(An1 * D));
}

// Mid: serial scan over chunk summaries -> h_start per chunk, IN PLACE over hend.
__global__ __launch_bounds__(256)
void scan_mid_kernel(float* __restrict__ hend_h0, const float* __restrict__ dAp)
{
    int gid = blockIdx.x * 256 + threadIdx.x;     // over E*64
    int e = gid >> 6, n = gid & 63;
    float h = 0.f;
#pragma unroll
    for (int ck = 0; ck < NCHUNK; ++ck) {
        size_t idx = ((size_t)e * NCHUNK + ck) * 64 + n;
        float he = hend_h0[idx];
        float P  = dAp[idx];
        hend_h0[idx] = h;
        h = P * h + he;
    }
}

// Pass 2: block = 8 waves, 32 channels, one chunk; B/C planes staged separately.
__global__ __launch_bounds__(512)
void scan2_kernel(const float* __restrict__ dtT, const __bf16* __restrict__ xcT,
                  const __bf16* __restrict__ szT, const float* __restrict__ bc2,
                  const float* __restrict__ A_log, const float* __restrict__ h0s,
                  __bf16* __restrict__ y)
{
    __shared__ float  s_bp[CKLEN * 64];    // 16 KB (B-plane)
    __shared__ float  s_cp[CKLEN * 64];    // 16 KB (C-plane)
    __shared__ float  s_dt[32][68];        // padded rows
    __shared__ __bf16 s_x[32][72];         // padded rows
    __shared__ __bf16 s_y[CKLEN][36];      // padded, t-major tile
    const int tid = threadIdx.x;
    const int lane = tid & 63, w = tid >> 6;
    const int g = lane >> 4, i = lane & 15;
    const int ck = blockIdx.x & (NCHUNK - 1);
    const int eg = (blockIdx.x >> 5) * 32;

    {
#pragma unroll
        for (int r = 0; r < 2; ++r) {
            int linear = r * 512 + tid;
            int t = linear >> 4, k = linear & 15;
            const float* src = bc2 + (size_t)(ck * CKLEN + t) * 128 + 4 * k;
            *(float4*)&s_bp[t * 64 + 4 * k] = *(const float4*)src;
            *(float4*)&s_cp[t * 64 + 4 * k] = *(const float4*)(src + 64);
        }
        { int ch = tid >> 4, k = tid & 15;
          *(float4*)&s_dt[ch][4 * k] =
              *(const float4*)(dtT + (size_t)(eg + ch) * T_TOK + ck * CKLEN + 4 * k); }
        if (tid < 256) { int ch = tid >> 3, k = tid & 7;
          *(bf16x8*)&s_x[ch][8 * k] =
              *(const bf16x8*)(xcT + (size_t)(eg + ch) * T_TOK + ck * CKLEN + 8 * k); }
    }
    __syncthreads();

    const int ch = w * 4 + g;
    const int e = eg + ch;
    float4 al4 = *(const float4*)(A_log + 4 * i);
    const float L2E = 1.44269504f;
    const float An0 = -__expf(al4.x) * L2E;
    const float An1 = -__expf(al4.y) * L2E;
    const float An2 = -__expf(al4.z) * L2E;
    const float An3 = -__expf(al4.w) * L2E;
    float4 hh = *(const float4*)(h0s + ((size_t)e * NCHUNK + ck) * 64 + 4 * i);
    float h0 = hh.x, h1 = hh.y, h2 = hh.z, h3 = hh.w;

#pragma unroll 2
    for (int t0 = 0; t0 < CKLEN; t0 += 8) {
        float4 da = *(const float4*)&s_dt[ch][t0];
        float4 db = *(const float4*)&s_dt[ch][t0 + 4];
        bf16x8 x8 = *(const bf16x8*)&s_x[ch][t0];
        float dtv[8] = {da.x, da.y, da.z, da.w, db.x, db.y, db.z, db.w};
#pragma unroll
        for (int j = 0; j < 8; ++j) {
            float4 b0 = *(const float4*)&s_bp[(t0 + j) * 64 + 4 * i];
            float4 c0 = *(const float4*)&s_cp[(t0 + j) * 64 + 4 * i];
            float dt = dtv[j];
            float u = dt * (float)x8[j];
            h0 = fmaf(__builtin_amdgcn_exp2f(dt * An0), h0, u * b0.x);
            h1 = fmaf(__builtin_amdgcn_exp2f(dt * An1), h1, u * b0.y);
            h2 = fmaf(__builtin_amdgcn_exp2f(dt * An2), h2, u * b0.z);
            h3 = fmaf(__builtin_amdgcn_exp2f(dt * An3), h3, u * b0.w);
            float p = h0 * c0.x;
            p = fmaf(h1, c0.y, p);
            p = fmaf(h2, c0.z, p);
            p = fmaf(h3, c0.w, p);
            p = dpp_add<0x111, 0xf>(p);
            p = dpp_add<0x112, 0xf>(p);
            p = dpp_add<0x114, 0xf>(p);
            p = dpp_add<0x118, 0xf>(p);
            if (i == 15) s_y[t0 + j][ch] = (__bf16)p;
        }
    }
    __syncthreads();

    {
        int tt = tid >> 3, q = tid & 7;
        bf16x4 o;
#pragma unroll
        for (int d = 0; d < 4; ++d) {
            float zv = (float)szT[(size_t)(eg + 4 * q + d) * T_TOK + ck * CKLEN + tt];
            o[d] = (__bf16)((float)s_y[tt][4 * q + d] * zv);
        }
        *(bf16x4*)(y + (size_t)(ck * CKLEN + tt) * EDIM + eg + 4 * q) = o;
    }
}

// ---------------------------------------------------------------- GEMM common
__device__ __forceinline__ void glds16(const __bf16* g, __bf16* l)
{
    __builtin_amdgcn_global_load_lds(
        (const __attribute__((address_space(1))) unsigned*)g,
        (__attribute__((address_space(3))) unsigned*)l, 16, 0, 0);
}

template<int EPI>
__device__ __forceinline__ void gemm_epilogue(
    const f32x4& a, int row, int col, int N,
    void* Cout, void* Cout2, const float* res)
{
    if (EPI == 1) {
#pragma unroll
        for (int i = 0; i < 4; ++i)
            ((__bf16*)Cout)[(size_t)(row + i) * N + col] = (__bf16)a[i];
    } else if (EPI == 2) {
#pragma unroll
        for (int i = 0; i < 4; ++i) {
            size_t off = (size_t)(row + i) * N + col;
            ((float*)Cout)[off] = a[i] + res[off];
        }
    } else if (EPI == 3) {
        if (col < 2048) {
            float bias = res[col];
            float4 v;
            float* vv = (float*)&v;
#pragma unroll
            for (int i = 0; i < 4; ++i) {
                float s = a[i] + bias;
                s = (s > 20.f) ? s : log1pf(__expf(s));
                vv[i] = fminf(fmaxf(s, 0.001f), 0.1f);
            }
            *(float4*)((float*)Cout + (size_t)col * T_TOK + row) = v;
        } else {
#pragma unroll
            for (int i = 0; i < 4; ++i)
                ((float*)Cout2)[(size_t)(row + i) * 128 + (col - 2048)] = a[i];
        }
    } else if (EPI == 4) {
        if (col < 2048) {
#pragma unroll
            for (int i = 0; i < 4; ++i)
                ((__bf16*)Cout)[(size_t)(row + i) * EDIM + col] = (__bf16)a[i];
        } else {
            bf16x4 v;
#pragma unroll
            for (int i = 0; i < 4; ++i) {
                float s = a[i];
                v[i] = (__bf16)(s / (1.f + __expf(-s)));
            }
            *(bf16x4*)((__bf16*)Cout2 + (size_t)(col - 2048) * T_TOK + row) = v;
        }
    }
}

// 4-wave GEMM: 64 x 128 tile, BK=64, 2-phase, 8-chunk XOR-swizzled LDS.
template<int EPI, int SWZ>
__global__ __launch_bounds__(256)
void gemm_kernel(const __bf16* __restrict__ A, const __bf16* __restrict__ Bt,
                 void* __restrict__ Cout, void* __restrict__ Cout2,
                 const float* __restrict__ res, int M, int N, int K)
{
    __shared__ __bf16 sAl[2 * 64 * 64];    // 16 KB
    __shared__ __bf16 sBl[2 * 128 * 64];   // 32 KB
    const int t = threadIdx.x;
    const int wave = t >> 6, lane = t & 63;
    int bx = blockIdx.x, by = blockIdx.y;
    if (SWZ) {
        int nwg = gridDim.x * gridDim.y;
        int bid = by * gridDim.x + bx;
        int cpx = nwg >> 3;
        int swz = (bid & 7) * cpx + (bid >> 3);
        bx = swz % gridDim.x;
        by = swz / gridDim.x;
    }
    const int brow = by * 64, bcol = bx * 128;
    const int wr = (wave >> 1) * 32, wc = (wave & 1) * 64;
    f32x4 acc[2][4] = {};

    const int rl8 = lane >> 3;
    const int ck8 = (lane & 7) ^ rl8;
    const __bf16* gA = A  + (size_t)(brow + wave * 16 + rl8) * K + ck8 * 8;
    const __bf16* gB = Bt + (size_t)(bcol + wave * 32 + rl8) * K + ck8 * 8;

    auto stage = [&](int buf, int k0) {
        __bf16* ba = sAl + buf * (64 * 64) + (wave * 16) * 64;
        __bf16* bb = sBl + buf * (128 * 64) + (wave * 32) * 64;
#pragma unroll
        for (int q = 0; q < 2; ++q)
            glds16(gA + (size_t)(q * 8) * K + k0, ba + q * 8 * 64);
#pragma unroll
        for (int q = 0; q < 4; ++q)
            glds16(gB + (size_t)(q * 8) * K + k0, bb + q * 8 * 64);
    };

    stage(0, 0);
    int cur = 0;
    for (int k0 = 0; k0 < K; k0 += 64) {
        __syncthreads();
        if (k0 + 64 < K) stage(cur ^ 1, k0 + 64);
        const __bf16* At = sAl + cur * (64 * 64);
        const __bf16* Btl = sBl + cur * (128 * 64);
#pragma unroll
        for (int ks = 0; ks < 2; ++ks) {
            const int rc = (((ks * 4 + (lane >> 4)) ^ (lane & 7))) * 8;
            bf16x8 af[2], bg[4];
#pragma unroll
            for (int m = 0; m < 2; ++m)
                af[m] = *(const bf16x8*)&At[(wr + m * 16 + (lane & 15)) * 64 + rc];
#pragma unroll
            for (int n = 0; n < 4; ++n)
                bg[n] = *(const bf16x8*)&Btl[(wc + n * 16 + (lane & 15)) * 64 + rc];
#pragma unroll
            for (int m = 0; m < 2; ++m)
#pragma unroll
                for (int n = 0; n < 4; ++n)
                    acc[m][n] = __builtin_amdgcn_mfma_f32_16x16x32_bf16(
                        af[m], bg[n], acc[m][n], 0, 0, 0);
        }
        cur ^= 1;
    }

    const int c_l = lane & 15, r_l = (lane >> 4) * 4;
#pragma unroll
    for (int m = 0; m < 2; ++m)
#pragma unroll
        for (int n = 0; n < 4; ++n)
            gemm_epilogue<EPI>(acc[m][n], brow + wr + m * 16 + r_l,
                               bcol + wc + n * 16 + c_l, N, Cout, Cout2, res);
}

// 8-wave big GEMM: 256 x 128 tile, BK=64, 2-phase, XOR chunk-swizzled LDS.
// EPI 5: fused GLU (16-col interleaved gate/up weights): frag n (even) = gate,
//        n+1 = up for the same ffn cols; writes silu(g)*u bf16 to Cout[row][fcol]
//        with fcol = 16*((bcol+wc+n*16)>>5)+c_l, row stride 2048.
template<int EPI>
__global__ __launch_bounds__(512)
void gemm_big(const __bf16* __restrict__ A, const __bf16* __restrict__ Bt,
              void* __restrict__ Cout, void* __restrict__ Cout2,
              const float* __restrict__ res, int M, int N, int K)
{
    __shared__ __bf16 sAl[2 * 256 * 64];   // 64 KB
    __shared__ __bf16 sBl[2 * 128 * 64];   // 32 KB
    const int t = threadIdx.x;
    const int w = t >> 6, lane = t & 63;
    const int brow = blockIdx.y * 256, bcol = blockIdx.x * 128;
    const int wr = (w >> 1) * 64, wc = (w & 1) * 64;
    f32x4 acc[4][4] = {};

    const int rl8 = lane >> 3;
    const int ck8 = (lane & 7) ^ rl8;
    const __bf16* gA = A  + (size_t)(brow + w * 32 + rl8) * K + ck8 * 8;
    const __bf16* gB = Bt + (size_t)(bcol + w * 16 + rl8) * K + ck8 * 8;

    auto stage = [&](int buf, int k0) {
        __bf16* ba = sAl + buf * (256 * 64) + (w * 32) * 64;
        __bf16* bb = sBl + buf * (128 * 64) + (w * 16) * 64;
#pragma unroll
        for (int q = 0; q < 4; ++q)
            glds16(gA + (size_t)(q * 8) * K + k0, ba + q * 8 * 64);
#pragma unroll
        for (int q = 0; q < 2; ++q)
            glds16(gB + (size_t)(q * 8) * K + k0, bb + q * 8 * 64);
    };

    stage(0, 0);
    int cur = 0;
    for (int k0 = 0; k0 < K; k0 += 64) {
        __syncthreads();
        if (k0 + 64 < K) stage(cur ^ 1, k0 + 64);
        const __bf16* At = sAl + cur * (256 * 64);
        const __bf16* Btl = sBl + cur * (128 * 64);
#pragma unroll
        for (int ks = 0; ks < 2; ++ks) {
            const int rchk = (((ks * 4 + (lane >> 4)) ^ (lane & 7))) * 8;
            bf16x8 af[4], bg[4];
#pragma unroll
            for (int m = 0; m < 4; ++m)
                af[m] = *(const bf16x8*)&At[(wr + m * 16 + (lane & 15)) * 64 + rchk];
#pragma unroll
            for (int n = 0; n < 4; ++n)
                bg[n] = *(const bf16x8*)&Btl[(wc + n * 16 + (lane & 15)) * 64 + rchk];
#pragma unroll
            for (int m = 0; m < 4; ++m)
#pragma unroll
                for (int n = 0; n < 4; ++n)
                    acc[m][n] = __builtin_amdgcn_mfma_f32_16x16x32_bf16(
                        af[m], bg[n], acc[m][n], 0, 0, 0);
        }
        cur ^= 1;
    }

    const int c_l = lane & 15, r_l = (lane >> 4) * 4;
    if constexpr (EPI == 5) {
#pragma unroll
        for (int m = 0; m < 4; ++m) {
#pragma unroll
            for (int n = 0; n < 4; n += 2) {
                int row = brow + wr + m * 16 + r_l;
                int fcol = (((bcol + wc + n * 16) >> 5) << 4) + c_l;
#pragma unroll
                for (int i = 0; i < 4; ++i) {
                    float gg = acc[m][n][i];
                    float uu = acc[m][n + 1][i];
                    ((__bf16*)Cout)[(size_t)(row + i) * 2048 + fcol] =
                        (__bf16)(gg / (1.f + __expf(-gg)) * uu);
                }
            }
        }
    } else {
#pragma unroll
        for (int m = 0; m < 4; ++m)
#pragma unroll
            for (int n = 0; n < 4; ++n)
                gemm_epilogue<EPI>(acc[m][n], brow + wr + m * 16 + r_l,
                                   bcol + wc + n * 16 + c_l, N, Cout, Cout2, res);
    }
}

// ---------------------------------------------------------------- launch
extern "C" void kernel_launch(void* const* d_in, const int* in_sizes, int n_in,
                              void* d_out, int out_size, void* d_ws, size_t ws_size,
                              hipStream_t stream)
{
    (void)in_sizes; (void)n_in; (void)out_size; (void)ws_size;
    const float* x     = (const float*)d_in[0];
    const float* inw   = (const float*)d_in[1];
    const float* ffnw  = (const float*)d_in[2];
    const float* inpW  = (const float*)d_in[3];
    const float* convW = (const float*)d_in[4];
    const float* convB = (const float*)d_in[5];
    const float* dtW   = (const float*)d_in[6];
    const float* dtB   = (const float*)d_in[7];
    const float* BW    = (const float*)d_in[8];
    const float* CW    = (const float*)d_in[9];
    const float* Alog  = (const float*)d_in[10];
    const float* outpW = (const float*)d_in[11];
    const float* gateW = (const float*)d_in[12];
    const float* upW   = (const float*)d_in[13];
    const float* downW = (const float*)d_in[14];
    float* out = (float*)d_out;

    char* p = (char*)d_ws;
    auto alloc = [&](size_t n) { char* q = p; p += (n + 255) & ~(size_t)255; return q; };
    __bf16* wt_inproj = (__bf16*)alloc(4096ull * 1024 * 2);
    __bf16* wt_dtbc   = (__bf16*)alloc(2176ull * 2048 * 2);  // rows: 0-2047 dt, 2048-2111 B, 2112-2175 C
    __bf16* wt_outp   = (__bf16*)alloc(1024ull * 2048 * 2);
    __bf16* wt_gu     = (__bf16*)alloc(4096ull * 1024 * 2);  // 16-col interleaved gate/up
    __bf16* wt_down   = (__bf16*)alloc(1024ull * 2048 * 2);
    __bf16* normed    = (__bf16*)alloc(2048ull * 1024 * 2);  // reused as n2
    __bf16* xz        = (__bf16*)alloc(2048ull * 2048 * 2);  // x_z half of in_proj
    __bf16* gu_buf    = (__bf16*)alloc(2048ull * 4096 * 2);  // dAp scratch
    __bf16* xc        = (__bf16*)alloc(2048ull * 2048 * 2);  // conv out, reused as y
    float*  scratch16 = (float*)alloc(2048ull * 2048 * 4);   // hend/h0 then ffnmid
    float*  bc        = (float*)alloc(2048ull * 128 * 4);
    float*  dtT       = (float*)alloc(2048ull * 2048 * 4);
    __bf16* xcT       = (__bf16*)alloc(2048ull * 2048 * 2);
    __bf16* szT       = (__bf16*)alloc(2048ull * 2048 * 2);
    float*  x2        = (float*)alloc(2048ull * 1024 * 4);

    dim3 B256(256);
    // batched weight prep (one dispatch); gate/up interleaved at 16-col granularity
    {
        TJobs8 tj;
        int off = 0, ji = 0;
        auto addjob = [&](const float* s, __bf16* d, int R, int C, int S, int mode) {
            tj.j[ji++] = TJob{s, d, R, C, S, C / 32, off, mode};
            off += (C / 32) * (R / 32);
        };
        addjob(inpW,  wt_inproj, 1024, 4096, 4096, 0);
        addjob(dtW,   wt_dtbc,   2048, 2048, 2048, 0);
        addjob(BW,    wt_dtbc + 2048ull * 2048, 2048, 64, 64, 0);
        addjob(CW,    wt_dtbc + 2112ull * 2048, 2048, 64, 64, 0);
        addjob(outpW, wt_outp,   2048, 1024, 1024, 0);
        addjob(gateW, wt_gu,     1024, 2048, 2048, 1);
        addjob(upW,   wt_gu,     1024, 2048, 2048, 2);
        addjob(downW, wt_down,   2048, 1024, 1024, 0);
        wprep_kernel<<<dim3(off), B256, 0, stream>>>(tj);
    }

    // normed = rmsnorm(x, inw)
    rmsnorm_kernel<<<dim3(2048), B256, 0, stream>>>(x, inw, normed);
    // in_proj: xz (t-major bf16) + szT (silu'd z, channel-major)
    gemm_big<4><<<dim3(32, 8), dim3(512), 0, stream>>>(normed, wt_inproj, xz, szT, nullptr, 2048, 4096, 1024);
    // xc = silu(conv(xz) + b), also writes xcT (channel-major) in one pass
    conv_silu_xt_kernel<<<dim3(32, 64), B256, 0, stream>>>(xz, convW, convB, xc, xcT);
    // fused dt+bc: dtT (softplus'd, channel-major f32) + bc (t-major f32, planes)
    gemm_kernel<3, 1><<<dim3(17, 32), B256, 0, stream>>>(xc, wt_dtbc, dtT, bc, dtB, 2048, 2176, 2048);

    // chunked SSM scan
    float* hend = scratch16;                      // 16 MB (E*32*64 f32)
    float* dAp  = (float*)gu_buf;                 // 16 MB
    scan1_kernel<<<dim3(4096), dim3(512), 0, stream>>>(dtT, xcT, bc, Alog, hend, dAp);
    scan_mid_kernel<<<dim3(512), B256, 0, stream>>>(hend, dAp);
    __bf16* y = xc;                               // xc dead after dt GEMM
    scan2_kernel<<<dim3(2048), dim3(512), 0, stream>>>(dtT, xcT, szT, bc, Alog, hend, y);

    // x2 = x + y @ out_proj
    gemm_kernel<2, 0><<<dim3(8, 32), B256, 0, stream>>>(y, wt_outp, x2, nullptr, x, 2048, 1024, 2048);
    // n2 = rmsnorm(x2, ffnw)
    rmsnorm_kernel<<<dim3(2048), B256, 0, stream>>>(x2, ffnw, normed);
    // ffnmid = silu(n2@gate) * (n2@up)  -- fused GLU epilogue
    __bf16* ffnmid = (__bf16*)scratch16;
    gemm_big<5><<<dim3(32, 8), dim3(512), 0, stream>>>(normed, wt_gu, ffnmid, nullptr, nullptr, 2048, 4096, 1024);
    // out = x2 + ffnmid @ down
    gemm_kernel<2, 0><<<dim3(8, 32), B256, 0, stream>>>(ffnmid, wt_down, out, nullptr, x2, 2048, 1024, 2048);
}

// Round 17
// 298.228 us; speedup vs baseline: 2.4784x; 1.0194x over previous
//
#include <hip/hip_runtime.h>
#include <hip/hip_bf16.h>

typedef __bf16 bf16x8 __attribute__((ext_vector_type(8)));
typedef __bf16 bf16x4 __attribute__((ext_vector_type(4)));
typedef float  f32x4  __attribute__((ext_vector_type(4)));
typedef float  f32x2  __attribute__((ext_vector_type(2)));

#define T_TOK 2048
#define DDIM  1024
#define EDIM  2048
#define NCHUNK 32
#define CKLEN  64

__device__ __forceinline__ f32x2 vfma2(f32x2 a, f32x2 b, f32x2 c)
{
#if __has_builtin(__builtin_elementwise_fma)
    return __builtin_elementwise_fma(a, b, c);
#else
    return (f32x2){fmaf(a.x, b.x, c.x), fmaf(a.y, b.y, c.y)};
#endif
}

// ---------------------------------------------------------------- batched weight prep
// One dispatch transposes all weight matrices (f32 -> bf16, [N][K] layout).
// mode 0: dst row = src col c.  mode 1: row = 32*(c>>4)+(c&15) (gate interleave).
// mode 2: row = 32*(c>>4)+16+(c&15) (up interleave).
struct TJob { const float* src; __bf16* dst; int R, C, S, tilesX, tileOff, mode; };
struct TJobs8 { TJob j[8]; };

__global__ __launch_bounds__(256)
void wprep_kernel(TJobs8 jobs)
{
    int tile = blockIdx.x;
    int ji = 0;
#pragma unroll
    for (int k = 1; k < 8; ++k) if (tile >= jobs.j[k].tileOff) ji = k;
    const TJob jb = jobs.j[ji];
    int rel = tile - jb.tileOff;
    int bx = rel % jb.tilesX, by = rel / jb.tilesX;
    __shared__ float tilebuf[32][33];
    const int tc0 = bx * 32, tr0 = by * 32;
    const int tx = threadIdx.x & 31, ty = threadIdx.x >> 5;
#pragma unroll
    for (int p = 0; p < 4; ++p) {
        int rl = ty + p * 8;
        tilebuf[rl][tx] = jb.src[(size_t)(tr0 + rl) * jb.S + tc0 + tx];
    }
    __syncthreads();
#pragma unroll
    for (int p = 0; p < 4; ++p) {
        int cl = ty + p * 8;
        float v = tilebuf[tx][cl];
        int c = tc0 + cl, r = tr0 + tx;
        int dr = (jb.mode == 0) ? c
               : ((c >> 4) * 32 + (c & 15) + ((jb.mode == 2) ? 16 : 0));
        jb.dst[(size_t)dr * jb.R + r] = (__bf16)v;
    }
}

// ---------------------------------------------------------------- rmsnorm
__global__ __launch_bounds__(256)
void rmsnorm_kernel(const float* __restrict__ x, const float* __restrict__ w,
                    __bf16* __restrict__ out)
{
    const int row = blockIdx.x;
    const int t = threadIdx.x;
    float4 v = ((const float4*)(x + (size_t)row * DDIM))[t];
    float ss = v.x * v.x + v.y * v.y + v.z * v.z + v.w * v.w;
#pragma unroll
    for (int m = 32; m; m >>= 1) ss += __shfl_xor(ss, m);
    __shared__ float red[4];
    if ((t & 63) == 0) red[t >> 6] = ss;
    __syncthreads();
    float scale = rsqrtf((red[0] + red[1] + red[2] + red[3]) * (1.f / DDIM) + 1e-5f);
    float4 wv = ((const float4*)w)[t];
    __bf16* o = out + (size_t)row * DDIM + t * 4;
    o[0] = (__bf16)(v.x * scale * wv.x);
    o[1] = (__bf16)(v.y * scale * wv.y);
    o[2] = (__bf16)(v.z * scale * wv.z);
    o[3] = (__bf16)(v.w * scale * wv.w);
}

// ---------------------------------------------------------------- conv+silu (+xcT)
__global__ __launch_bounds__(256)
void conv_silu_xt_kernel(const __bf16* __restrict__ xz, const float* __restrict__ W,
                         const float* __restrict__ b, __bf16* __restrict__ xc,
                         __bf16* __restrict__ xcT)
{
    __shared__ __bf16 s_t[32][72];
    const int tid = threadIdx.x;
    const int e0 = blockIdx.x * 64, t0 = blockIdx.y * 32;
    const int tl = tid >> 3, e8 = (tid & 7) * 8;
    const int t = t0 + tl;
    float acc[8];
    {
        float4 b0 = *(const float4*)(b + e0 + e8);
        float4 b1 = *(const float4*)(b + e0 + e8 + 4);
        acc[0] = b0.x; acc[1] = b0.y; acc[2] = b0.z; acc[3] = b0.w;
        acc[4] = b1.x; acc[5] = b1.y; acc[6] = b1.z; acc[7] = b1.w;
    }
#pragma unroll
    for (int k = 0; k < 4; ++k) {
        int tt = t - 1 + k;
        if (tt >= 0 && tt < T_TOK) {
            bf16x8 v = *(const bf16x8*)(xz + (size_t)tt * EDIM + e0 + e8);
            float4 w0 = *(const float4*)(W + k * EDIM + e0 + e8);
            float4 w1 = *(const float4*)(W + k * EDIM + e0 + e8 + 4);
            acc[0] += (float)v[0] * w0.x; acc[1] += (float)v[1] * w0.y;
            acc[2] += (float)v[2] * w0.z; acc[3] += (float)v[3] * w0.w;
            acc[4] += (float)v[4] * w1.x; acc[5] += (float)v[5] * w1.y;
            acc[6] += (float)v[6] * w1.z; acc[7] += (float)v[7] * w1.w;
        }
    }
    bf16x8 o;
#pragma unroll
    for (int j = 0; j < 8; ++j) {
        float s = acc[j];
        o[j] = (__bf16)(s / (1.f + __expf(-s)));
    }
    *(bf16x8*)(xc + (size_t)t * EDIM + e0 + e8) = o;
    *(bf16x8*)&s_t[tl][e8] = o;
    __syncthreads();
    {
        int el = tid >> 2, t8 = (tid & 3) * 8;
        bf16x8 o2;
#pragma unroll
        for (int j = 0; j < 8; ++j) o2[j] = s_t[t8 + j][el];
        *(bf16x8*)(xcT + (size_t)(e0 + el) * T_TOK + t0 + t8) = o2;
    }
}

// ---------------------------------------------------------------- scan
template<int CTRL, int ROWMASK>
__device__ __forceinline__ float dpp_add(float v)
{
    int y = __builtin_amdgcn_update_dpp(0, __builtin_bit_cast(int, v),
                                        CTRL, ROWMASK, 0xf, true);
    return v + __builtin_bit_cast(float, y);
}

// bc layout (plane-split): bc[t*128 + n] = B[t,n], bc[t*128 + 64 + n] = C[t,n].

// Pass 1: block = 8 waves, 32 channels, one chunk; B-plane only staged.
// Wave w: 4 channels (w*4+g, g=lane>>4), 16 lanes/channel, 4 states/lane.
__global__ __launch_bounds__(512)
void scan1_kernel(const float* __restrict__ dtT, const __bf16* __restrict__ xcT,
                  const float* __restrict__ bc2, const float* __restrict__ A_log,
                  float* __restrict__ hend, float* __restrict__ dAp)
{
    __shared__ float  s_b[CKLEN * 64];     // 16 KB (B-plane)
    __shared__ float  s_dt[32][68];        // padded rows
    __shared__ __bf16 s_x[32][72];         // padded rows
    const int tid = threadIdx.x;
    const int lane = tid & 63, w = tid >> 6;
    const int g = lane >> 4, i = lane & 15;
    const int ck = blockIdx.x & (NCHUNK - 1);
    const int eg = (blockIdx.x >> 5) * 32;

    {
#pragma unroll
        for (int r = 0; r < 2; ++r) {
            int linear = r * 512 + tid;
            int t = linear >> 4, k = linear & 15;
            *(float4*)&s_b[t * 64 + 4 * k] =
                *(const float4*)(bc2 + (size_t)(ck * CKLEN + t) * 128 + 4 * k);
        }
        { int ch = tid >> 4, k = tid & 15;
          *(float4*)&s_dt[ch][4 * k] =
              *(const float4*)(dtT + (size_t)(eg + ch) * T_TOK + ck * CKLEN + 4 * k); }
        if (tid < 256) { int ch = tid >> 3, k = tid & 7;
          *(bf16x8*)&s_x[ch][8 * k] =
              *(const bf16x8*)(xcT + (size_t)(eg + ch) * T_TOK + ck * CKLEN + 8 * k); }
    }
    __syncthreads();

    const int ch = w * 4 + g;
    const int e = eg + ch;
    float4 al4 = *(const float4*)(A_log + 4 * i);
    const float L2E = 1.44269504f;
    const float An0 = -__expf(al4.x) * L2E;
    const float An1 = -__expf(al4.y) * L2E;
    const float An2 = -__expf(al4.z) * L2E;
    const float An3 = -__expf(al4.w) * L2E;
    f32x2 h01 = {0.f, 0.f}, h23 = {0.f, 0.f};
    float D = 0.f;

#pragma unroll 2
    for (int t0 = 0; t0 < CKLEN; t0 += 8) {
        float4 da = *(const float4*)&s_dt[ch][t0];
        float4 db = *(const float4*)&s_dt[ch][t0 + 4];
        bf16x8 x8 = *(const bf16x8*)&s_x[ch][t0];
        float dtv[8] = {da.x, da.y, da.z, da.w, db.x, db.y, db.z, db.w};
#pragma unroll
        for (int j = 0; j < 8; ++j) {
            float4 b0 = *(const float4*)&s_b[(t0 + j) * 64 + 4 * i];
            float dt = dtv[j];
            float u = dt * (float)x8[j];
            f32x2 dA01 = {__builtin_amdgcn_exp2f(dt * An0),
                          __builtin_amdgcn_exp2f(dt * An1)};
            f32x2 dA23 = {__builtin_amdgcn_exp2f(dt * An2),
                          __builtin_amdgcn_exp2f(dt * An3)};
            f32x2 uu = {u, u};
            h01 = vfma2(dA01, h01, uu * (f32x2){b0.x, b0.y});
            h23 = vfma2(dA23, h23, uu * (f32x2){b0.z, b0.w});
            D += dt;
        }
    }
    size_t idx = ((size_t)e * NCHUNK + ck) * 64 + 4 * i;
    *(float4*)(hend + idx) = make_float4(h01.x, h01.y, h23.x, h23.y);
    *(float4*)(dAp + idx)  = make_float4(__builtin_amdgcn_exp2f(An0 * D),
                                         __builtin_amdgcn_exp2f(An1 * D),
                                         __builtin_amdgcn_exp2f(An2 * D),
                                         __builtin_amdgcn_exp2f(An3 * D));
}

// Mid: serial scan over chunk summaries -> h_start per chunk, IN PLACE over hend.
__global__ __launch_bounds__(256)
void scan_mid_kernel(float* __restrict__ hend_h0, const float* __restrict__ dAp)
{
    int gid = blockIdx.x * 256 + threadIdx.x;     // over E*64
    int e = gid >> 6, n = gid & 63;
    float h = 0.f;
#pragma unroll
    for (int ck = 0; ck < NCHUNK; ++ck) {
        size_t idx = ((size_t)e * NCHUNK + ck) * 64 + n;
        float he = hend_h0[idx];
        float P  = dAp[idx];
        hend_h0[idx] = h;
        h = P * h + he;
    }
}

// Pass 2: block = 8 waves, 32 channels, one chunk; B/C planes staged separately.
__global__ __launch_bounds__(512)
void scan2_kernel(const float* __restrict__ dtT, const __bf16* __restrict__ xcT,
                  const __bf16* __restrict__ szT, const float* __restrict__ bc2,
                  const float* __restrict__ A_log, const float* __restrict__ h0s,
                  __bf16* __restrict__ y)
{
    __shared__ float  s_bp[CKLEN * 64];    // 16 KB (B-plane)
    __shared__ float  s_cp[CKLEN * 64];    // 16 KB (C-plane)
    __shared__ float  s_dt[32][68];        // padded rows
    __shared__ __bf16 s_x[32][72];         // padded rows
    __shared__ __bf16 s_y[CKLEN][36];      // padded, t-major tile
    const int tid = threadIdx.x;
    const int lane = tid & 63, w = tid >> 6;
    const int g = lane >> 4, i = lane & 15;
    const int ck = blockIdx.x & (NCHUNK - 1);
    const int eg = (blockIdx.x >> 5) * 32;

    {
#pragma unroll
        for (int r = 0; r < 2; ++r) {
            int linear = r * 512 + tid;
            int t = linear >> 4, k = linear & 15;
            const float* src = bc2 + (size_t)(ck * CKLEN + t) * 128 + 4 * k;
            *(float4*)&s_bp[t * 64 + 4 * k] = *(const float4*)src;
            *(float4*)&s_cp[t * 64 + 4 * k] = *(const float4*)(src + 64);
        }
        { int ch = tid >> 4, k = tid & 15;
          *(float4*)&s_dt[ch][4 * k] =
              *(const float4*)(dtT + (size_t)(eg + ch) * T_TOK + ck * CKLEN + 4 * k); }
        if (tid < 256) { int ch = tid >> 3, k = tid & 7;
          *(bf16x8*)&s_x[ch][8 * k] =
              *(const bf16x8*)(xcT + (size_t)(eg + ch) * T_TOK + ck * CKLEN + 8 * k); }
    }
    __syncthreads();

    const int ch = w * 4 + g;
    const int e = eg + ch;
    float4 al4 = *(const float4*)(A_log + 4 * i);
    const float L2E = 1.44269504f;
    const float An0 = -__expf(al4.x) * L2E;
    const float An1 = -__expf(al4.y) * L2E;
    const float An2 = -__expf(al4.z) * L2E;
    const float An3 = -__expf(al4.w) * L2E;
    float4 hh = *(const float4*)(h0s + ((size_t)e * NCHUNK + ck) * 64 + 4 * i);
    f32x2 h01 = {hh.x, hh.y}, h23 = {hh.z, hh.w};

#pragma unroll 2
    for (int t0 = 0; t0 < CKLEN; t0 += 8) {
        float4 da = *(const float4*)&s_dt[ch][t0];
        float4 db = *(const float4*)&s_dt[ch][t0 + 4];
        bf16x8 x8 = *(const bf16x8*)&s_x[ch][t0];
        float dtv[8] = {da.x, da.y, da.z, da.w, db.x, db.y, db.z, db.w};
#pragma unroll
        for (int j = 0; j < 8; ++j) {
            float4 b0 = *(const float4*)&s_bp[(t0 + j) * 64 + 4 * i];
            float4 c0 = *(const float4*)&s_cp[(t0 + j) * 64 + 4 * i];
            float dt = dtv[j];
            float u = dt * (float)x8[j];
            f32x2 dA01 = {__builtin_amdgcn_exp2f(dt * An0),
                          __builtin_amdgcn_exp2f(dt * An1)};
            f32x2 dA23 = {__builtin_amdgcn_exp2f(dt * An2),
                          __builtin_amdgcn_exp2f(dt * An3)};
            f32x2 uu = {u, u};
            h01 = vfma2(dA01, h01, uu * (f32x2){b0.x, b0.y});
            h23 = vfma2(dA23, h23, uu * (f32x2){b0.z, b0.w});
            f32x2 pp = h01 * (f32x2){c0.x, c0.y};
            pp = vfma2(h23, (f32x2){c0.z, c0.w}, pp);
            float p = pp.x + pp.y;
            p = dpp_add<0x111, 0xf>(p);
            p = dpp_add<0x112, 0xf>(p);
            p = dpp_add<0x114, 0xf>(p);
            p = dpp_add<0x118, 0xf>(p);
            if (i == 15) s_y[t0 + j][ch] = (__bf16)p;
        }
    }
    __syncthreads();

    {
        int tt = tid >> 3, q = tid & 7;
        bf16x4 o;
#pragma unroll
        for (int d = 0; d < 4; ++d) {
            float zv = (float)szT[(size_t)(eg + 4 * q + d) * T_TOK + ck * CKLEN + tt];
            o[d] = (__bf16)((float)s_y[tt][4 * q + d] * zv);
        }
        *(bf16x4*)(y + (size_t)(ck * CKLEN + tt) * EDIM + eg + 4 * q) = o;
    }
}

// ---------------------------------------------------------------- GEMM common
__device__ __forceinline__ void glds16(const __bf16* g, __bf16* l)
{
    __builtin_amdgcn_global_load_lds(
        (const __attribute__((address_space(1))) unsigned*)g,
        (__attribute__((address_space(3))) unsigned*)l, 16, 0, 0);
}

template<int EPI>
__device__ __forceinline__ void gemm_epilogue(
    const f32x4& a, int row, int col, int N,
    void* Cout, void* Cout2, const float* res)
{
    if (EPI == 1) {
#pragma unroll
        for (int i = 0; i < 4; ++i)
            ((__bf16*)Cout)[(size_t)(row + i) * N + col] = (__bf16)a[i];
    } else if (EPI == 2) {
#pragma unroll
        for (int i = 0; i < 4; ++i) {
            size_t off = (size_t)(row + i) * N + col;
            ((float*)Cout)[off] = a[i] + res[off];
        }
    } else if (EPI == 3) {
        if (col < 2048) {
            float bias = res[col];
            float4 v;
            float* vv = (float*)&v;
#pragma unroll
            for (int i = 0; i < 4; ++i) {
                float s = a[i] + bias;
                s = (s > 20.f) ? s : log1pf(__expf(s));
                vv[i] = fminf(fmaxf(s, 0.001f), 0.1f);
            }
            *(float4*)((float*)Cout + (size_t)col * T_TOK + row) = v;
        } else {
#pragma unroll
            for (int i = 0; i < 4; ++i)
                ((float*)Cout2)[(size_t)(row + i) * 128 + (col - 2048)] = a[i];
        }
    } else if (EPI == 4) {
        if (col < 2048) {
#pragma unroll
            for (int i = 0; i < 4; ++i)
                ((__bf16*)Cout)[(size_t)(row + i) * EDIM + col] = (__bf16)a[i];
        } else {
            bf16x4 v;
#pragma unroll
            for (int i = 0; i < 4; ++i) {
                float s = a[i];
                v[i] = (__bf16)(s / (1.f + __expf(-s)));
            }
            *(bf16x4*)((__bf16*)Cout2 + (size_t)(col - 2048) * T_TOK + row) = v;
        }
    }
}

// 4-wave GEMM: 64 x 128 tile, BK=64, 2-phase, 8-chunk XOR-swizzled LDS.
template<int EPI, int SWZ>
__global__ __launch_bounds__(256)
void gemm_kernel(const __bf16* __restrict__ A, const __bf16* __restrict__ Bt,
                 void* __restrict__ Cout, void* __restrict__ Cout2,
                 const float* __restrict__ res, int M, int N, int K)
{
    __shared__ __bf16 sAl[2 * 64 * 64];    // 16 KB
    __shared__ __bf16 sBl[2 * 128 * 64];   // 32 KB
    const int t = threadIdx.x;
    const int wave = t >> 6, lane = t & 63;
    int bx = blockIdx.x, by = blockIdx.y;
    if (SWZ) {
        int nwg = gridDim.x * gridDim.y;
        int bid = by * gridDim.x + bx;
        int cpx = nwg >> 3;
        int swz = (bid & 7) * cpx + (bid >> 3);
        bx = swz % gridDim.x;
        by = swz / gridDim.x;
    }
    const int brow = by * 64, bcol = bx * 128;
    const int wr = (wave >> 1) * 32, wc = (wave & 1) * 64;
    f32x4 acc[2][4] = {};

    const int rl8 = lane >> 3;
    const int ck8 = (lane & 7) ^ rl8;
    const __bf16* gA = A  + (size_t)(brow + wave * 16 + rl8) * K + ck8 * 8;
    const __bf16* gB = Bt + (size_t)(bcol + wave * 32 + rl8) * K + ck8 * 8;

    auto stage = [&](int buf, int k0) {
        __bf16* ba = sAl + buf * (64 * 64) + (wave * 16) * 64;
        __bf16* bb = sBl + buf * (128 * 64) + (wave * 32) * 64;
#pragma unroll
        for (int q = 0; q < 2; ++q)
            glds16(gA + (size_t)(q * 8) * K + k0, ba + q * 8 * 64);
#pragma unroll
        for (int q = 0; q < 4; ++q)
            glds16(gB + (size_t)(q * 8) * K + k0, bb + q * 8 * 64);
    };

    stage(0, 0);
    int cur = 0;
    for (int k0 = 0; k0 < K; k0 += 64) {
        __syncthreads();
        if (k0 + 64 < K) stage(cur ^ 1, k0 + 64);
        const __bf16* At = sAl + cur * (64 * 64);
        const __bf16* Btl = sBl + cur * (128 * 64);
#pragma unroll
        for (int ks = 0; ks < 2; ++ks) {
            const int rc = (((ks * 4 + (lane >> 4)) ^ (lane & 7))) * 8;
            bf16x8 af[2], bg[4];
#pragma unroll
            for (int m = 0; m < 2; ++m)
                af[m] = *(const bf16x8*)&At[(wr + m * 16 + (lane & 15)) * 64 + rc];
#pragma unroll
            for (int n = 0; n < 4; ++n)
                bg[n] = *(const bf16x8*)&Btl[(wc + n * 16 + (lane & 15)) * 64 + rc];
#pragma unroll
            for (int m = 0; m < 2; ++m)
#pragma unroll
                for (int n = 0; n < 4; ++n)
                    acc[m][n] = __builtin_amdgcn_mfma_f32_16x16x32_bf16(
                        af[m], bg[n], acc[m][n], 0, 0, 0);
        }
        cur ^= 1;
    }

    const int c_l = lane & 15, r_l = (lane >> 4) * 4;
#pragma unroll
    for (int m = 0; m < 2; ++m)
#pragma unroll
        for (int n = 0; n < 4; ++n)
            gemm_epilogue<EPI>(acc[m][n], brow + wr + m * 16 + r_l,
                               bcol + wc + n * 16 + c_l, N, Cout, Cout2, res);
}

// 8-wave big GEMM: 256 x 128 tile, BK=64, 2-phase, XOR chunk-swizzled LDS.
// EPI 5: fused GLU (16-col interleaved gate/up weights).
template<int EPI>
__global__ __launch_bounds__(512)
void gemm_big(const __bf16* __restrict__ A, const __bf16* __restrict__ Bt,
              void* __restrict__ Cout, void* __restrict__ Cout2,
              const float* __restrict__ res, int M, int N, int K)
{
    __shared__ __bf16 sAl[2 * 256 * 64];   // 64 KB
    __shared__ __bf16 sBl[2 * 128 * 64];   // 32 KB
    const int t = threadIdx.x;
    const int w = t >> 6, lane = t & 63;
    const int brow = blockIdx.y * 256, bcol = blockIdx.x * 128;
    const int wr = (w >> 1) * 64, wc = (w & 1) * 64;
    f32x4 acc[4][4] = {};

    const int rl8 = lane >> 3;
    const int ck8 = (lane & 7) ^ rl8;
    const __bf16* gA = A  + (size_t)(brow + w * 32 + rl8) * K + ck8 * 8;
    const __bf16* gB = Bt + (size_t)(bcol + w * 16 + rl8) * K + ck8 * 8;

    auto stage = [&](int buf, int k0) {
        __bf16* ba = sAl + buf * (256 * 64) + (w * 32) * 64;
        __bf16* bb = sBl + buf * (128 * 64) + (w * 16) * 64;
#pragma unroll
        for (int q = 0; q < 4; ++q)
            glds16(gA + (size_t)(q * 8) * K + k0, ba + q * 8 * 64);
#pragma unroll
        for (int q = 0; q < 2; ++q)
            glds16(gB + (size_t)(q * 8) * K + k0, bb + q * 8 * 64);
    };

    stage(0, 0);
    int cur = 0;
    for (int k0 = 0; k0 < K; k0 += 64) {
        __syncthreads();
        if (k0 + 64 < K) stage(cur ^ 1, k0 + 64);
        const __bf16* At = sAl + cur * (256 * 64);
        const __bf16* Btl = sBl + cur * (128 * 64);
#pragma unroll
        for (int ks = 0; ks < 2; ++ks) {
            const int rchk = (((ks * 4 + (lane >> 4)) ^ (lane & 7))) * 8;
            bf16x8 af[4], bg[4];
#pragma unroll
            for (int m = 0; m < 4; ++m)
                af[m] = *(const bf16x8*)&At[(wr + m * 16 + (lane & 15)) * 64 + rchk];
#pragma unroll
            for (int n = 0; n < 4; ++n)
                bg[n] = *(const bf16x8*)&Btl[(wc + n * 16 + (lane & 15)) * 64 + rchk];
#pragma unroll
            for (int m = 0; m < 4; ++m)
#pragma unroll
                for (int n = 0; n < 4; ++n)
                    acc[m][n] = __builtin_amdgcn_mfma_f32_16x16x32_bf16(
                        af[m], bg[n], acc[m][n], 0, 0, 0);
        }
        cur ^= 1;
    }

    const int c_l = lane & 15, r_l = (lane >> 4) * 4;
    if constexpr (EPI == 5) {
#pragma unroll
        for (int m = 0; m < 4; ++m) {
#pragma unroll
            for (int n = 0; n < 4; n += 2) {
                int row = brow + wr + m * 16 + r_l;
                int fcol = (((bcol + wc + n * 16) >> 5) << 4) + c_l;
#pragma unroll
                for (int i = 0; i < 4; ++i) {
                    float gg = acc[m][n][i];
                    float uu = acc[m][n + 1][i];
                    ((__bf16*)Cout)[(size_t)(row + i) * 2048 + fcol] =
                        (__bf16)(gg / (1.f + __expf(-gg)) * uu);
                }
            }
        }
    } else {
#pragma unroll
        for (int m = 0; m < 4; ++m)
#pragma unroll
            for (int n = 0; n < 4; ++n)
                gemm_epilogue<EPI>(acc[m][n], brow + wr + m * 16 + r_l,
                                   bcol + wc + n * 16 + c_l, N, Cout, Cout2, res);
    }
}

// ---------------------------------------------------------------- launch
extern "C" void kernel_launch(void* const* d_in, const int* in_sizes, int n_in,
                              void* d_out, int out_size, void* d_ws, size_t ws_size,
                              hipStream_t stream)
{
    (void)in_sizes; (void)n_in; (void)out_size; (void)ws_size;
    const float* x     = (const float*)d_in[0];
    const float* inw   = (const float*)d_in[1];
    const float* ffnw  = (const float*)d_in[2];
    const float* inpW  = (const float*)d_in[3];
    const float* convW = (const float*)d_in[4];
    const float* convB = (const float*)d_in[5];
    const float* dtW   = (const float*)d_in[6];
    const float* dtB   = (const float*)d_in[7];
    const float* BW    = (const float*)d_in[8];
    const float* CW    = (const float*)d_in[9];
    const float* Alog  = (const float*)d_in[10];
    const float* outpW = (const float*)d_in[11];
    const float* gateW = (const float*)d_in[12];
    const float* upW   = (const float*)d_in[13];
    const float* downW = (const float*)d_in[14];
    float* out = (float*)d_out;

    char* p = (char*)d_ws;
    auto alloc = [&](size_t n) { char* q = p; p += (n + 255) & ~(size_t)255; return q; };
    __bf16* wt_inproj = (__bf16*)alloc(4096ull * 1024 * 2);
    __bf16* wt_dtbc   = (__bf16*)alloc(2176ull * 2048 * 2);  // rows: 0-2047 dt, 2048-2111 B, 2112-2175 C
    __bf16* wt_outp   = (__bf16*)alloc(1024ull * 2048 * 2);
    __bf16* wt_gu     = (__bf16*)alloc(4096ull * 1024 * 2);  // 16-col interleaved gate/up
    __bf16* wt_down   = (__bf16*)alloc(1024ull * 2048 * 2);
    __bf16* normed    = (__bf16*)alloc(2048ull * 1024 * 2);  // reused as n2
    __bf16* xz        = (__bf16*)alloc(2048ull * 2048 * 2);  // x_z half of in_proj
    __bf16* gu_buf    = (__bf16*)alloc(2048ull * 4096 * 2);  // dAp scratch
    __bf16* xc        = (__bf16*)alloc(2048ull * 2048 * 2);  // conv out, reused as y
    float*  scratch16 = (float*)alloc(2048ull * 2048 * 4);   // hend/h0 then ffnmid
    float*  bc        = (float*)alloc(2048ull * 128 * 4);
    float*  dtT       = (float*)alloc(2048ull * 2048 * 4);
    __bf16* xcT       = (__bf16*)alloc(2048ull * 2048 * 2);
    __bf16* szT       = (__bf16*)alloc(2048ull * 2048 * 2);
    float*  x2        = (float*)alloc(2048ull * 1024 * 4);

    dim3 B256(256);
    // batched weight prep (one dispatch); gate/up interleaved at 16-col granularity
    {
        TJobs8 tj;
        int off = 0, ji = 0;
        auto addjob = [&](const float* s, __bf16* d, int R, int C, int S, int mode) {
            tj.j[ji++] = TJob{s, d, R, C, S, C / 32, off, mode};
            off += (C / 32) * (R / 32);
        };
        addjob(inpW,  wt_inproj, 1024, 4096, 4096, 0);
        addjob(dtW,   wt_dtbc,   2048, 2048, 2048, 0);
        addjob(BW,    wt_dtbc + 2048ull * 2048, 2048, 64, 64, 0);
        addjob(CW,    wt_dtbc + 2112ull * 2048, 2048, 64, 64, 0);
        addjob(outpW, wt_outp,   2048, 1024, 1024, 0);
        addjob(gateW, wt_gu,     1024, 2048, 2048, 1);
        addjob(upW,   wt_gu,     1024, 2048, 2048, 2);
        addjob(downW, wt_down,   2048, 1024, 1024, 0);
        wprep_kernel<<<dim3(off), B256, 0, stream>>>(tj);
    }

    // normed = rmsnorm(x, inw)
    rmsnorm_kernel<<<dim3(2048), B256, 0, stream>>>(x, inw, normed);
    // in_proj: xz (t-major bf16) + szT (silu'd z, channel-major)
    gemm_big<4><<<dim3(32, 8), dim3(512), 0, stream>>>(normed, wt_inproj, xz, szT, nullptr, 2048, 4096, 1024);
    // xc = silu(conv(xz) + b), also writes xcT (channel-major) in one pass
    conv_silu_xt_kernel<<<dim3(32, 64), B256, 0, stream>>>(xz, convW, convB, xc, xcT);
    // fused dt+bc: dtT (softplus'd, channel-major f32) + bc (t-major f32, planes)
    gemm_kernel<3, 1><<<dim3(17, 32), B256, 0, stream>>>(xc, wt_dtbc, dtT, bc, dtB, 2048, 2176, 2048);

    // chunked SSM scan
    float* hend = scratch16;                      // 16 MB (E*32*64 f32)
    float* dAp  = (float*)gu_buf;                 // 16 MB
    scan1_kernel<<<dim3(2048), dim3(512), 0, stream>>>(dtT, xcT, bc, Alog, hend, dAp);
    scan_mid_kernel<<<dim3(512), B256, 0, stream>>>(hend, dAp);
    __bf16* y = xc;                               // xc dead after dt GEMM
    scan2_kernel<<<dim3(2048), dim3(512), 0, stream>>>(dtT, xcT, szT, bc, Alog, hend, y);

    // x2 = x + y @ out_proj
    gemm_kernel<2, 0><<<dim3(8, 32), B256, 0, stream>>>(y, wt_outp, x2, nullptr, x, 2048, 1024, 2048);
    // n2 = rmsnorm(x2, ffnw)
    rmsnorm_kernel<<<dim3(2048), B256, 0, stream>>>(x2, ffnw, normed);
    // ffnmid = silu(n2@gate) * (n2@up)  -- fused GLU epilogue
    __bf16* ffnmid = (__bf16*)scratch16;
    gemm_big<5><<<dim3(32, 8), dim3(512), 0, stream>>>(normed, wt_gu, ffnmid, nullptr, nullptr, 2048, 4096, 1024);
    // out = x2 + ffnmid @ down
    gemm_kernel<2, 0><<<dim3(8, 32), B256, 0, stream>>>(ffnmid, wt_down, out, nullptr, x2, 2048, 1024, 2048);
}

// Round 18
// 289.824 us; speedup vs baseline: 2.5502x; 1.0290x over previous
//
#include <hip/hip_runtime.h>
#include <hip/hip_bf16.h>

typedef __bf16 bf16x8 __attribute__((ext_vector_type(8)));
typedef __bf16 bf16x4 __attribute__((ext_vector_type(4)));
typedef float  f32x4  __attribute__((ext_vector_type(4)));
typedef float  f32x2  __attribute__((ext_vector_type(2)));

#define T_TOK 2048
#define DDIM  1024
#define EDIM  2048
#define NCHUNK 32
#define CKLEN  64

__device__ __forceinline__ f32x2 vfma2(f32x2 a, f32x2 b, f32x2 c)
{
#if __has_builtin(__builtin_elementwise_fma)
    return __builtin_elementwise_fma(a, b, c);
#else
    return (f32x2){fmaf(a.x, b.x, c.x), fmaf(a.y, b.y, c.y)};
#endif
}

// exp(w) for w in [-0.15, 0]: degree-3 Taylor, rel err <= 4e-6.
__device__ __forceinline__ f32x2 exps2(f32x2 w)
{
    const f32x2 C6  = {0.166666667f, 0.166666667f};
    const f32x2 CH  = {0.5f, 0.5f};
    const f32x2 ONE = {1.f, 1.f};
    return vfma2(w, vfma2(w, vfma2(w, C6, CH), ONE), ONE);
}

// ---------------------------------------------------------------- batched weight prep
// One dispatch transposes all weight matrices (f32 -> bf16, [N][K] layout).
// mode 0: dst row = src col c.  mode 1: row = 32*(c>>4)+(c&15) (gate interleave).
// mode 2: row = 32*(c>>4)+16+(c&15) (up interleave).
struct TJob { const float* src; __bf16* dst; int R, C, S, tilesX, tileOff, mode; };
struct TJobs8 { TJob j[8]; };

__global__ __launch_bounds__(256)
void wprep_kernel(TJobs8 jobs)
{
    int tile = blockIdx.x;
    int ji = 0;
#pragma unroll
    for (int k = 1; k < 8; ++k) if (tile >= jobs.j[k].tileOff) ji = k;
    const TJob jb = jobs.j[ji];
    int rel = tile - jb.tileOff;
    int bx = rel % jb.tilesX, by = rel / jb.tilesX;
    __shared__ float tilebuf[32][33];
    const int tc0 = bx * 32, tr0 = by * 32;
    const int tx = threadIdx.x & 31, ty = threadIdx.x >> 5;
#pragma unroll
    for (int p = 0; p < 4; ++p) {
        int rl = ty + p * 8;
        tilebuf[rl][tx] = jb.src[(size_t)(tr0 + rl) * jb.S + tc0 + tx];
    }
    __syncthreads();
#pragma unroll
    for (int p = 0; p < 4; ++p) {
        int cl = ty + p * 8;
        float v = tilebuf[tx][cl];
        int c = tc0 + cl, r = tr0 + tx;
        int dr = (jb.mode == 0) ? c
               : ((c >> 4) * 32 + (c & 15) + ((jb.mode == 2) ? 16 : 0));
        jb.dst[(size_t)dr * jb.R + r] = (__bf16)v;
    }
}

// ---------------------------------------------------------------- rmsnorm
__global__ __launch_bounds__(256)
void rmsnorm_kernel(const float* __restrict__ x, const float* __restrict__ w,
                    __bf16* __restrict__ out)
{
    const int row = blockIdx.x;
    const int t = threadIdx.x;
    float4 v = ((const float4*)(x + (size_t)row * DDIM))[t];
    float ss = v.x * v.x + v.y * v.y + v.z * v.z + v.w * v.w;
#pragma unroll
    for (int m = 32; m; m >>= 1) ss += __shfl_xor(ss, m);
    __shared__ float red[4];
    if ((t & 63) == 0) red[t >> 6] = ss;
    __syncthreads();
    float scale = rsqrtf((red[0] + red[1] + red[2] + red[3]) * (1.f / DDIM) + 1e-5f);
    float4 wv = ((const float4*)w)[t];
    __bf16* o = out + (size_t)row * DDIM + t * 4;
    o[0] = (__bf16)(v.x * scale * wv.x);
    o[1] = (__bf16)(v.y * scale * wv.y);
    o[2] = (__bf16)(v.z * scale * wv.z);
    o[3] = (__bf16)(v.w * scale * wv.w);
}

// ---------------------------------------------------------------- conv+silu (+xcT)
__global__ __launch_bounds__(256)
void conv_silu_xt_kernel(const __bf16* __restrict__ xz, const float* __restrict__ W,
                         const float* __restrict__ b, __bf16* __restrict__ xc,
                         __bf16* __restrict__ xcT)
{
    __shared__ __bf16 s_t[32][72];
    const int tid = threadIdx.x;
    const int e0 = blockIdx.x * 64, t0 = blockIdx.y * 32;
    const int tl = tid >> 3, e8 = (tid & 7) * 8;
    const int t = t0 + tl;
    float acc[8];
    {
        float4 b0 = *(const float4*)(b + e0 + e8);
        float4 b1 = *(const float4*)(b + e0 + e8 + 4);
        acc[0] = b0.x; acc[1] = b0.y; acc[2] = b0.z; acc[3] = b0.w;
        acc[4] = b1.x; acc[5] = b1.y; acc[6] = b1.z; acc[7] = b1.w;
    }
#pragma unroll
    for (int k = 0; k < 4; ++k) {
        int tt = t - 1 + k;
        if (tt >= 0 && tt < T_TOK) {
            bf16x8 v = *(const bf16x8*)(xz + (size_t)tt * EDIM + e0 + e8);
            float4 w0 = *(const float4*)(W + k * EDIM + e0 + e8);
            float4 w1 = *(const float4*)(W + k * EDIM + e0 + e8 + 4);
            acc[0] += (float)v[0] * w0.x; acc[1] += (float)v[1] * w0.y;
            acc[2] += (float)v[2] * w0.z; acc[3] += (float)v[3] * w0.w;
            acc[4] += (float)v[4] * w1.x; acc[5] += (float)v[5] * w1.y;
            acc[6] += (float)v[6] * w1.z; acc[7] += (float)v[7] * w1.w;
        }
    }
    bf16x8 o;
#pragma unroll
    for (int j = 0; j < 8; ++j) {
        float s = acc[j];
        o[j] = (__bf16)(s / (1.f + __expf(-s)));
    }
    *(bf16x8*)(xc + (size_t)t * EDIM + e0 + e8) = o;
    *(bf16x8*)&s_t[tl][e8] = o;
    __syncthreads();
    {
        int el = tid >> 2, t8 = (tid & 3) * 8;
        bf16x8 o2;
#pragma unroll
        for (int j = 0; j < 8; ++j) o2[j] = s_t[t8 + j][el];
        *(bf16x8*)(xcT + (size_t)(e0 + el) * T_TOK + t0 + t8) = o2;
    }
}

// ---------------------------------------------------------------- scan
template<int CTRL, int ROWMASK>
__device__ __forceinline__ float dpp_add(float v)
{
    int y = __builtin_amdgcn_update_dpp(0, __builtin_bit_cast(int, v),
                                        CTRL, ROWMASK, 0xf, true);
    return v + __builtin_bit_cast(float, y);
}

// bc layout (plane-split): bc[t*128 + n] = B[t,n], bc[t*128 + 64 + n] = C[t,n].

// Pass 1: block = 8 waves, 32 channels, one chunk; B-plane only staged.
// Wave w: 4 channels (w*4+g, g=lane>>4), 16 lanes/channel, 4 states/lane.
// dA = exp(dt*A) via degree-3 poly (dt*A in [-0.1,0)); chunk product via exp2.
__global__ __launch_bounds__(512)
void scan1_kernel(const float* __restrict__ dtT, const __bf16* __restrict__ xcT,
                  const float* __restrict__ bc2, const float* __restrict__ A_log,
                  float* __restrict__ hend, float* __restrict__ dAp)
{
    __shared__ float  s_b[CKLEN * 64];     // 16 KB (B-plane)
    __shared__ float  s_dt[32][68];        // padded rows
    __shared__ __bf16 s_x[32][72];         // padded rows
    const int tid = threadIdx.x;
    const int lane = tid & 63, w = tid >> 6;
    const int g = lane >> 4, i = lane & 15;
    const int ck = blockIdx.x & (NCHUNK - 1);
    const int eg = (blockIdx.x >> 5) * 32;

    {
#pragma unroll
        for (int r = 0; r < 2; ++r) {
            int linear = r * 512 + tid;
            int t = linear >> 4, k = linear & 15;
            *(float4*)&s_b[t * 64 + 4 * k] =
                *(const float4*)(bc2 + (size_t)(ck * CKLEN + t) * 128 + 4 * k);
        }
        { int ch = tid >> 4, k = tid & 15;
          *(float4*)&s_dt[ch][4 * k] =
              *(const float4*)(dtT + (size_t)(eg + ch) * T_TOK + ck * CKLEN + 4 * k); }
        if (tid < 256) { int ch = tid >> 3, k = tid & 7;
          *(bf16x8*)&s_x[ch][8 * k] =
              *(const bf16x8*)(xcT + (size_t)(eg + ch) * T_TOK + ck * CKLEN + 8 * k); }
    }
    __syncthreads();

    const int ch = w * 4 + g;
    const int e = eg + ch;
    float4 al4 = *(const float4*)(A_log + 4 * i);
    const f32x2 A01 = {-__expf(al4.x), -__expf(al4.y)};
    const f32x2 A23 = {-__expf(al4.z), -__expf(al4.w)};
    f32x2 h01 = {0.f, 0.f}, h23 = {0.f, 0.f};
    float D = 0.f;

#pragma unroll 2
    for (int t0 = 0; t0 < CKLEN; t0 += 8) {
        float4 da = *(const float4*)&s_dt[ch][t0];
        float4 db = *(const float4*)&s_dt[ch][t0 + 4];
        bf16x8 x8 = *(const bf16x8*)&s_x[ch][t0];
        float dtv[8] = {da.x, da.y, da.z, da.w, db.x, db.y, db.z, db.w};
#pragma unroll
        for (int j = 0; j < 8; ++j) {
            float4 b0 = *(const float4*)&s_b[(t0 + j) * 64 + 4 * i];
            float dt = dtv[j];
            float u = dt * (float)x8[j];
            f32x2 dt2 = {dt, dt};
            f32x2 dA01 = exps2(dt2 * A01);
            f32x2 dA23 = exps2(dt2 * A23);
            f32x2 uu = {u, u};
            h01 = vfma2(dA01, h01, uu * (f32x2){b0.x, b0.y});
            h23 = vfma2(dA23, h23, uu * (f32x2){b0.z, b0.w});
            D += dt;
        }
    }
    const float L2E = 1.44269504f;
    size_t idx = ((size_t)e * NCHUNK + ck) * 64 + 4 * i;
    *(float4*)(hend + idx) = make_float4(h01.x, h01.y, h23.x, h23.y);
    *(float4*)(dAp + idx)  = make_float4(__builtin_amdgcn_exp2f(A01.x * L2E * D),
                                         __builtin_amdgcn_exp2f(A01.y * L2E * D),
                                         __builtin_amdgcn_exp2f(A23.x * L2E * D),
                                         __builtin_amdgcn_exp2f(A23.y * L2E * D));
}

// Mid: serial scan over chunk summaries -> h_start per chunk, IN PLACE over hend.
__global__ __launch_bounds__(256)
void scan_mid_kernel(float* __restrict__ hend_h0, const float* __restrict__ dAp)
{
    int gid = blockIdx.x * 256 + threadIdx.x;     // over E*64
    int e = gid >> 6, n = gid & 63;
    float h = 0.f;
#pragma unroll
    for (int ck = 0; ck < NCHUNK; ++ck) {
        size_t idx = ((size_t)e * NCHUNK + ck) * 64 + n;
        float he = hend_h0[idx];
        float P  = dAp[idx];
        hend_h0[idx] = h;
        h = P * h + he;
    }
}

// Pass 2: block = 8 waves, 32 channels, one chunk; B/C planes staged separately.
__global__ __launch_bounds__(512)
void scan2_kernel(const float* __restrict__ dtT, const __bf16* __restrict__ xcT,
                  const __bf16* __restrict__ szT, const float* __restrict__ bc2,
                  const float* __restrict__ A_log, const float* __restrict__ h0s,
                  __bf16* __restrict__ y)
{
    __shared__ float  s_bp[CKLEN * 64];    // 16 KB (B-plane)
    __shared__ float  s_cp[CKLEN * 64];    // 16 KB (C-plane)
    __shared__ float  s_dt[32][68];        // padded rows
    __shared__ __bf16 s_x[32][72];         // padded rows
    __shared__ __bf16 s_y[CKLEN][36];      // padded, t-major tile
    const int tid = threadIdx.x;
    const int lane = tid & 63, w = tid >> 6;
    const int g = lane >> 4, i = lane & 15;
    const int ck = blockIdx.x & (NCHUNK - 1);
    const int eg = (blockIdx.x >> 5) * 32;

    {
#pragma unroll
        for (int r = 0; r < 2; ++r) {
            int linear = r * 512 + tid;
            int t = linear >> 4, k = linear & 15;
            const float* src = bc2 + (size_t)(ck * CKLEN + t) * 128 + 4 * k;
            *(float4*)&s_bp[t * 64 + 4 * k] = *(const float4*)src;
            *(float4*)&s_cp[t * 64 + 4 * k] = *(const float4*)(src + 64);
        }
        { int ch = tid >> 4, k = tid & 15;
          *(float4*)&s_dt[ch][4 * k] =
              *(const float4*)(dtT + (size_t)(eg + ch) * T_TOK + ck * CKLEN + 4 * k); }
        if (tid < 256) { int ch = tid >> 3, k = tid & 7;
          *(bf16x8*)&s_x[ch][8 * k] =
              *(const bf16x8*)(xcT + (size_t)(eg + ch) * T_TOK + ck * CKLEN + 8 * k); }
    }
    __syncthreads();

    const int ch = w * 4 + g;
    const int e = eg + ch;
    float4 al4 = *(const float4*)(A_log + 4 * i);
    const f32x2 A01 = {-__expf(al4.x), -__expf(al4.y)};
    const f32x2 A23 = {-__expf(al4.z), -__expf(al4.w)};
    float4 hh = *(const float4*)(h0s + ((size_t)e * NCHUNK + ck) * 64 + 4 * i);
    f32x2 h01 = {hh.x, hh.y}, h23 = {hh.z, hh.w};

#pragma unroll 2
    for (int t0 = 0; t0 < CKLEN; t0 += 8) {
        float4 da = *(const float4*)&s_dt[ch][t0];
        float4 db = *(const float4*)&s_dt[ch][t0 + 4];
        bf16x8 x8 = *(const bf16x8*)&s_x[ch][t0];
        float dtv[8] = {da.x, da.y, da.z, da.w, db.x, db.y, db.z, db.w};
#pragma unroll
        for (int j = 0; j < 8; ++j) {
            float4 b0 = *(const float4*)&s_bp[(t0 + j) * 64 + 4 * i];
            float4 c0 = *(const float4*)&s_cp[(t0 + j) * 64 + 4 * i];
            float dt = dtv[j];
            float u = dt * (float)x8[j];
            f32x2 dt2 = {dt, dt};
            f32x2 dA01 = exps2(dt2 * A01);
            f32x2 dA23 = exps2(dt2 * A23);
            f32x2 uu = {u, u};
            h01 = vfma2(dA01, h01, uu * (f32x2){b0.x, b0.y});
            h23 = vfma2(dA23, h23, uu * (f32x2){b0.z, b0.w});
            f32x2 pp = h01 * (f32x2){c0.x, c0.y};
            pp = vfma2(h23, (f32x2){c0.z, c0.w}, pp);
            float p = pp.x + pp.y;
            p = dpp_add<0x111, 0xf>(p);
            p = dpp_add<0x112, 0xf>(p);
            p = dpp_add<0x114, 0xf>(p);
            p = dpp_add<0x118, 0xf>(p);
            if (i == 15) s_y[t0 + j][ch] = (__bf16)p;
        }
    }
    __syncthreads();

    {
        int tt = tid >> 3, q = tid & 7;
        bf16x4 o;
#pragma unroll
        for (int d = 0; d < 4; ++d) {
            float zv = (float)szT[(size_t)(eg + 4 * q + d) * T_TOK + ck * CKLEN + tt];
            o[d] = (__bf16)((float)s_y[tt][4 * q + d] * zv);
        }
        *(bf16x4*)(y + (size_t)(ck * CKLEN + tt) * EDIM + eg + 4 * q) = o;
    }
}

// ---------------------------------------------------------------- GEMM common
__device__ __forceinline__ void glds16(const __bf16* g, __bf16* l)
{
    __builtin_amdgcn_global_load_lds(
        (const __attribute__((address_space(1))) unsigned*)g,
        (__attribute__((address_space(3))) unsigned*)l, 16, 0, 0);
}

template<int EPI>
__device__ __forceinline__ void gemm_epilogue(
    const f32x4& a, int row, int col, int N,
    void* Cout, void* Cout2, const float* res)
{
    if (EPI == 1) {
#pragma unroll
        for (int i = 0; i < 4; ++i)
            ((__bf16*)Cout)[(size_t)(row + i) * N + col] = (__bf16)a[i];
    } else if (EPI == 2) {
#pragma unroll
        for (int i = 0; i < 4; ++i) {
            size_t off = (size_t)(row + i) * N + col;
            ((float*)Cout)[off] = a[i] + res[off];
        }
    } else if (EPI == 3) {
        if (col < 2048) {
            float bias = res[col];
            float4 v;
            float* vv = (float*)&v;
#pragma unroll
            for (int i = 0; i < 4; ++i) {
                float s = a[i] + bias;
                s = (s > 20.f) ? s : log1pf(__expf(s));
                vv[i] = fminf(fmaxf(s, 0.001f), 0.1f);
            }
            *(float4*)((float*)Cout + (size_t)col * T_TOK + row) = v;
        } else {
#pragma unroll
            for (int i = 0; i < 4; ++i)
                ((float*)Cout2)[(size_t)(row + i) * 128 + (col - 2048)] = a[i];
        }
    } else if (EPI == 4) {
        if (col < 2048) {
#pragma unroll
            for (int i = 0; i < 4; ++i)
                ((__bf16*)Cout)[(size_t)(row + i) * EDIM + col] = (__bf16)a[i];
        } else {
            bf16x4 v;
#pragma unroll
            for (int i = 0; i < 4; ++i) {
                float s = a[i];
                v[i] = (__bf16)(s / (1.f + __expf(-s)));
            }
            *(bf16x4*)((__bf16*)Cout2 + (size_t)(col - 2048) * T_TOK + row) = v;
        }
    }
}

// 4-wave GEMM: 64 x 128 tile, BK=64, 2-phase, 8-chunk XOR-swizzled LDS.
template<int EPI, int SWZ>
__global__ __launch_bounds__(256)
void gemm_kernel(const __bf16* __restrict__ A, const __bf16* __restrict__ Bt,
                 void* __restrict__ Cout, void* __restrict__ Cout2,
                 const float* __restrict__ res, int M, int N, int K)
{
    __shared__ __bf16 sAl[2 * 64 * 64];    // 16 KB
    __shared__ __bf16 sBl[2 * 128 * 64];   // 32 KB
    const int t = threadIdx.x;
    const int wave = t >> 6, lane = t & 63;
    int bx = blockIdx.x, by = blockIdx.y;
    if (SWZ) {
        int nwg = gridDim.x * gridDim.y;
        int bid = by * gridDim.x + bx;
        int cpx = nwg >> 3;
        int swz = (bid & 7) * cpx + (bid >> 3);
        bx = swz % gridDim.x;
        by = swz / gridDim.x;
    }
    const int brow = by * 64, bcol = bx * 128;
    const int wr = (wave >> 1) * 32, wc = (wave & 1) * 64;
    f32x4 acc[2][4] = {};

    const int rl8 = lane >> 3;
    const int ck8 = (lane & 7) ^ rl8;
    const __bf16* gA = A  + (size_t)(brow + wave * 16 + rl8) * K + ck8 * 8;
    const __bf16* gB = Bt + (size_t)(bcol + wave * 32 + rl8) * K + ck8 * 8;

    auto stage = [&](int buf, int k0) {
        __bf16* ba = sAl + buf * (64 * 64) + (wave * 16) * 64;
        __bf16* bb = sBl + buf * (128 * 64) + (wave * 32) * 64;
#pragma unroll
        for (int q = 0; q < 2; ++q)
            glds16(gA + (size_t)(q * 8) * K + k0, ba + q * 8 * 64);
#pragma unroll
        for (int q = 0; q < 4; ++q)
            glds16(gB + (size_t)(q * 8) * K + k0, bb + q * 8 * 64);
    };

    stage(0, 0);
    int cur = 0;
    for (int k0 = 0; k0 < K; k0 += 64) {
        __syncthreads();
        if (k0 + 64 < K) stage(cur ^ 1, k0 + 64);
        const __bf16* At = sAl + cur * (64 * 64);
        const __bf16* Btl = sBl + cur * (128 * 64);
#pragma unroll
        for (int ks = 0; ks < 2; ++ks) {
            const int rc = (((ks * 4 + (lane >> 4)) ^ (lane & 7))) * 8;
            bf16x8 af[2], bg[4];
#pragma unroll
            for (int m = 0; m < 2; ++m)
                af[m] = *(const bf16x8*)&At[(wr + m * 16 + (lane & 15)) * 64 + rc];
#pragma unroll
            for (int n = 0; n < 4; ++n)
                bg[n] = *(const bf16x8*)&Btl[(wc + n * 16 + (lane & 15)) * 64 + rc];
#pragma unroll
            for (int m = 0; m < 2; ++m)
#pragma unroll
                for (int n = 0; n < 4; ++n)
                    acc[m][n] = __builtin_amdgcn_mfma_f32_16x16x32_bf16(
                        af[m], bg[n], acc[m][n], 0, 0, 0);
        }
        cur ^= 1;
    }

    const int c_l = lane & 15, r_l = (lane >> 4) * 4;
#pragma unroll
    for (int m = 0; m < 2; ++m)
#pragma unroll
        for (int n = 0; n < 4; ++n)
            gemm_epilogue<EPI>(acc[m][n], brow + wr + m * 16 + r_l,
                               bcol + wc + n * 16 + c_l, N, Cout, Cout2, res);
}

// 8-wave big GEMM: 256 x 128 tile, BK=64, 2-phase, XOR chunk-swizzled LDS.
// EPI 5: fused GLU (16-col interleaved gate/up weights).
template<int EPI>
__global__ __launch_bounds__(512)
void gemm_big(const __bf16* __restrict__ A, const __bf16* __restrict__ Bt,
              void* __restrict__ Cout, void* __restrict__ Cout2,
              const float* __restrict__ res, int M, int N, int K)
{
    __shared__ __bf16 sAl[2 * 256 * 64];   // 64 KB
    __shared__ __bf16 sBl[2 * 128 * 64];   // 32 KB
    const int t = threadIdx.x;
    const int w = t >> 6, lane = t & 63;
    const int brow = blockIdx.y * 256, bcol = blockIdx.x * 128;
    const int wr = (w >> 1) * 64, wc = (w & 1) * 64;
    f32x4 acc[4][4] = {};

    const int rl8 = lane >> 3;
    const int ck8 = (lane & 7) ^ rl8;
    const __bf16* gA = A  + (size_t)(brow + w * 32 + rl8) * K + ck8 * 8;
    const __bf16* gB = Bt + (size_t)(bcol + w * 16 + rl8) * K + ck8 * 8;

    auto stage = [&](int buf, int k0) {
        __bf16* ba = sAl + buf * (256 * 64) + (w * 32) * 64;
        __bf16* bb = sBl + buf * (128 * 64) + (w * 16) * 64;
#pragma unroll
        for (int q = 0; q < 4; ++q)
            glds16(gA + (size_t)(q * 8) * K + k0, ba + q * 8 * 64);
#pragma unroll
        for (int q = 0; q < 2; ++q)
            glds16(gB + (size_t)(q * 8) * K + k0, bb + q * 8 * 64);
    };

    stage(0, 0);
    int cur = 0;
    for (int k0 = 0; k0 < K; k0 += 64) {
        __syncthreads();
        if (k0 + 64 < K) stage(cur ^ 1, k0 + 64);
        const __bf16* At = sAl + cur * (256 * 64);
        const __bf16* Btl = sBl + cur * (128 * 64);
#pragma unroll
        for (int ks = 0; ks < 2; ++ks) {
            const int rchk = (((ks * 4 + (lane >> 4)) ^ (lane & 7))) * 8;
            bf16x8 af[4], bg[4];
#pragma unroll
            for (int m = 0; m < 4; ++m)
                af[m] = *(const bf16x8*)&At[(wr + m * 16 + (lane & 15)) * 64 + rchk];
#pragma unroll
            for (int n = 0; n < 4; ++n)
                bg[n] = *(const bf16x8*)&Btl[(wc + n * 16 + (lane & 15)) * 64 + rchk];
#pragma unroll
            for (int m = 0; m < 4; ++m)
#pragma unroll
                for (int n = 0; n < 4; ++n)
                    acc[m][n] = __builtin_amdgcn_mfma_f32_16x16x32_bf16(
                        af[m], bg[n], acc[m][n], 0, 0, 0);
        }
        cur ^= 1;
    }

    const int c_l = lane & 15, r_l = (lane >> 4) * 4;
    if constexpr (EPI == 5) {
#pragma unroll
        for (int m = 0; m < 4; ++m) {
#pragma unroll
            for (int n = 0; n < 4; n += 2) {
                int row = brow + wr + m * 16 + r_l;
                int fcol = (((bcol + wc + n * 16) >> 5) << 4) + c_l;
#pragma unroll
                for (int i = 0; i < 4; ++i) {
                    float gg = acc[m][n][i];
                    float uu = acc[m][n + 1][i];
                    ((__bf16*)Cout)[(size_t)(row + i) * 2048 + fcol] =
                        (__bf16)(gg / (1.f + __expf(-gg)) * uu);
                }
            }
        }
    } else {
#pragma unroll
        for (int m = 0; m < 4; ++m)
#pragma unroll
            for (int n = 0; n < 4; ++n)
                gemm_epilogue<EPI>(acc[m][n], brow + wr + m * 16 + r_l,
                                   bcol + wc + n * 16 + c_l, N, Cout, Cout2, res);
    }
}

// ---------------------------------------------------------------- launch
extern "C" void kernel_launch(void* const* d_in, const int* in_sizes, int n_in,
                              void* d_out, int out_size, void* d_ws, size_t ws_size,
                              hipStream_t stream)
{
    (void)in_sizes; (void)n_in; (void)out_size; (void)ws_size;
    const float* x     = (const float*)d_in[0];
    const float* inw   = (const float*)d_in[1];
    const float* ffnw  = (const float*)d_in[2];
    const float* inpW  = (const float*)d_in[3];
    const float* convW = (const float*)d_in[4];
    const float* convB = (const float*)d_in[5];
    const float* dtW   = (const float*)d_in[6];
    const float* dtB   = (const float*)d_in[7];
    const float* BW    = (const float*)d_in[8];
    const float* CW    = (const float*)d_in[9];
    const float* Alog  = (const float*)d_in[10];
    const float* outpW = (const float*)d_in[11];
    const float* gateW = (const float*)d_in[12];
    const float* upW   = (const float*)d_in[13];
    const float* downW = (const float*)d_in[14];
    float* out = (float*)d_out;

    char* p = (char*)d_ws;
    auto alloc = [&](size_t n) { char* q = p; p += (n + 255) & ~(size_t)255; return q; };
    __bf16* wt_inproj = (__bf16*)alloc(4096ull * 1024 * 2);
    __bf16* wt_dtbc   = (__bf16*)alloc(2176ull * 2048 * 2);  // rows: 0-2047 dt, 2048-2111 B, 2112-2175 C
    __bf16* wt_outp   = (__bf16*)alloc(1024ull * 2048 * 2);
    __bf16* wt_gu     = (__bf16*)alloc(4096ull * 1024 * 2);  // 16-col interleaved gate/up
    __bf16* wt_down   = (__bf16*)alloc(1024ull * 2048 * 2);
    __bf16* normed    = (__bf16*)alloc(2048ull * 1024 * 2);  // reused as n2
    __bf16* xz        = (__bf16*)alloc(2048ull * 2048 * 2);  // x_z half of in_proj
    __bf16* gu_buf    = (__bf16*)alloc(2048ull * 4096 * 2);  // dAp scratch
    __bf16* xc        = (__bf16*)alloc(2048ull * 2048 * 2);  // conv out, reused as y
    float*  scratch16 = (float*)alloc(2048ull * 2048 * 4);   // hend/h0 then ffnmid
    float*  bc        = (float*)alloc(2048ull * 128 * 4);
    float*  dtT       = (float*)alloc(2048ull * 2048 * 4);
    __bf16* xcT       = (__bf16*)alloc(2048ull * 2048 * 2);
    __bf16* szT       = (__bf16*)alloc(2048ull * 2048 * 2);
    float*  x2        = (float*)alloc(2048ull * 1024 * 4);

    dim3 B256(256);
    // batched weight prep (one dispatch); gate/up interleaved at 16-col granularity
    {
        TJobs8 tj;
        int off = 0, ji = 0;
        auto addjob = [&](const float* s, __bf16* d, int R, int C, int S, int mode) {
            tj.j[ji++] = TJob{s, d, R, C, S, C / 32, off, mode};
            off += (C / 32) * (R / 32);
        };
        addjob(inpW,  wt_inproj, 1024, 4096, 4096, 0);
        addjob(dtW,   wt_dtbc,   2048, 2048, 2048, 0);
        addjob(BW,    wt_dtbc + 2048ull * 2048, 2048, 64, 64, 0);
        addjob(CW,    wt_dtbc + 2112ull * 2048, 2048, 64, 64, 0);
        addjob(outpW, wt_outp,   2048, 1024, 1024, 0);
        addjob(gateW, wt_gu,     1024, 2048, 2048, 1);
        addjob(upW,   wt_gu,     1024, 2048, 2048, 2);
        addjob(downW, wt_down,   2048, 1024, 1024, 0);
        wprep_kernel<<<dim3(off), B256, 0, stream>>>(tj);
    }

    // normed = rmsnorm(x, inw)
    rmsnorm_kernel<<<dim3(2048), B256, 0, stream>>>(x, inw, normed);
    // in_proj: xz (t-major bf16) + szT (silu'd z, channel-major)
    gemm_big<4><<<dim3(32, 8), dim3(512), 0, stream>>>(normed, wt_inproj, xz, szT, nullptr, 2048, 4096, 1024);
    // xc = silu(conv(xz) + b), also writes xcT (channel-major) in one pass
    conv_silu_xt_kernel<<<dim3(32, 64), B256, 0, stream>>>(xz, convW, convB, xc, xcT);
    // fused dt+bc: dtT (softplus'd, channel-major f32) + bc (t-major f32, planes)
    gemm_kernel<3, 1><<<dim3(17, 32), B256, 0, stream>>>(xc, wt_dtbc, dtT, bc, dtB, 2048, 2176, 2048);

    // chunked SSM scan
    float* hend = scratch16;                      // 16 MB (E*32*64 f32)
    float* dAp  = (float*)gu_buf;                 // 16 MB
    scan1_kernel<<<dim3(2048), dim3(512), 0, stream>>>(dtT, xcT, bc, Alog, hend, dAp);
    scan_mid_kernel<<<dim3(512), B256, 0, stream>>>(hend, dAp);
    __bf16* y = xc;                               // xc dead after dt GEMM
    scan2_kernel<<<dim3(2048), dim3(512), 0, stream>>>(dtT, xcT, szT, bc, Alog, hend, y);

    // x2 = x + y @ out_proj
    gemm_kernel<2, 0><<<dim3(8, 32), B256, 0, stream>>>(y, wt_outp, x2, nullptr, x, 2048, 1024, 2048);
    // n2 = rmsnorm(x2, ffnw)
    rmsnorm_kernel<<<dim3(2048), B256, 0, stream>>>(x2, ffnw, normed);
    // ffnmid = silu(n2@gate) * (n2@up)  -- fused GLU epilogue
    __bf16* ffnmid = (__bf16*)scratch16;
    gemm_big<5><<<dim3(32, 8), dim3(512), 0, stream>>>(normed, wt_gu, ffnmid, nullptr, nullptr, 2048, 4096, 1024);
    // out = x2 + ffnmid @ down
    gemm_kernel<2, 0><<<dim3(8, 32), B256, 0, stream>>>(ffnmid, wt_down, out, nullptr, x2, 2048, 1024, 2048);
}

// Round 20
// 288.267 us; speedup vs baseline: 2.5640x; 1.0054x over previous
//
#include <hip/hip_runtime.h>
#include <hip/hip_bf16.h>

typedef __bf16 bf16x8 __attribute__((ext_vector_type(8)));
typedef __bf16 bf16x4 __attribute__((ext_vector_type(4)));
typedef float  f32x4  __attribute__((ext_vector_type(4)));
typedef float  f32x2  __attribute__((ext_vector_type(2)));

#define T_TOK 2048
#define DDIM  1024
#define EDIM  2048
#define NCHUNK 32
#define CKLEN  64

__device__ __forceinline__ f32x2 vfma2(f32x2 a, f32x2 b, f32x2 c)
{
#if __has_builtin(__builtin_elementwise_fma)
    return __builtin_elementwise_fma(a, b, c);
#else
    return (f32x2){fmaf(a.x, b.x, c.x), fmaf(a.y, b.y, c.y)};
#endif
}

// exp(w) for w in [-0.15, 0]: degree-3 Taylor, rel err <= 4e-6.
__device__ __forceinline__ f32x2 exps2(f32x2 w)
{
    const f32x2 C6  = {0.166666667f, 0.166666667f};
    const f32x2 CH  = {0.5f, 0.5f};
    const f32x2 ONE = {1.f, 1.f};
    return vfma2(w, vfma2(w, vfma2(w, C6, CH), ONE), ONE);
}

// Fused DPP 16-lane tree sum (lane 15 of each row gets the row total).
// HAZARD-GUARDED: VALU-write -> DPP-read needs 2 wait states (s_nop 1) on
// CDNA; the compiler can't see inside asm, so the nops are explicit.
__device__ __forceinline__ float dpp_sum16(float p)
{
    asm volatile(
        "s_nop 1\n\t"
        "v_add_f32 %0, %0, %0 row_shr:1 bound_ctrl:0\n\t"
        "s_nop 1\n\t"
        "v_add_f32 %0, %0, %0 row_shr:2 bound_ctrl:0\n\t"
        "s_nop 1\n\t"
        "v_add_f32 %0, %0, %0 row_shr:4 bound_ctrl:0\n\t"
        "s_nop 1\n\t"
        "v_add_f32 %0, %0, %0 row_shr:8 bound_ctrl:0"
        : "+v"(p));
    return p;
}

// ---------------------------------------------------------------- batched weight prep
// One dispatch transposes all weight matrices (f32 -> bf16, [N][K] layout).
// mode 0: dst row = src col c.  mode 1: row = 32*(c>>4)+(c&15) (gate interleave).
// mode 2: row = 32*(c>>4)+16+(c&15) (up interleave).
struct TJob { const float* src; __bf16* dst; int R, C, S, tilesX, tileOff, mode; };
struct TJobs8 { TJob j[8]; };

__global__ __launch_bounds__(256)
void wprep_kernel(TJobs8 jobs)
{
    int tile = blockIdx.x;
    int ji = 0;
#pragma unroll
    for (int k = 1; k < 8; ++k) if (tile >= jobs.j[k].tileOff) ji = k;
    const TJob jb = jobs.j[ji];
    int rel = tile - jb.tileOff;
    int bx = rel % jb.tilesX, by = rel / jb.tilesX;
    __shared__ float tilebuf[32][33];
    const int tc0 = bx * 32, tr0 = by * 32;
    const int tx = threadIdx.x & 31, ty = threadIdx.x >> 5;
#pragma unroll
    for (int p = 0; p < 4; ++p) {
        int rl = ty + p * 8;
        tilebuf[rl][tx] = jb.src[(size_t)(tr0 + rl) * jb.S + tc0 + tx];
    }
    __syncthreads();
#pragma unroll
    for (int p = 0; p < 4; ++p) {
        int cl = ty + p * 8;
        float v = tilebuf[tx][cl];
        int c = tc0 + cl, r = tr0 + tx;
        int dr = (jb.mode == 0) ? c
               : ((c >> 4) * 32 + (c & 15) + ((jb.mode == 2) ? 16 : 0));
        jb.dst[(size_t)dr * jb.R + r] = (__bf16)v;
    }
}

// ---------------------------------------------------------------- rmsnorm
__global__ __launch_bounds__(256)
void rmsnorm_kernel(const float* __restrict__ x, const float* __restrict__ w,
                    __bf16* __restrict__ out)
{
    const int row = blockIdx.x;
    const int t = threadIdx.x;
    float4 v = ((const float4*)(x + (size_t)row * DDIM))[t];
    float ss = v.x * v.x + v.y * v.y + v.z * v.z + v.w * v.w;
#pragma unroll
    for (int m = 32; m; m >>= 1) ss += __shfl_xor(ss, m);
    __shared__ float red[4];
    if ((t & 63) == 0) red[t >> 6] = ss;
    __syncthreads();
    float scale = rsqrtf((red[0] + red[1] + red[2] + red[3]) * (1.f / DDIM) + 1e-5f);
    float4 wv = ((const float4*)w)[t];
    __bf16* o = out + (size_t)row * DDIM + t * 4;
    o[0] = (__bf16)(v.x * scale * wv.x);
    o[1] = (__bf16)(v.y * scale * wv.y);
    o[2] = (__bf16)(v.z * scale * wv.z);
    o[3] = (__bf16)(v.w * scale * wv.w);
}

// ---------------------------------------------------------------- conv+silu (+xcT)
__global__ __launch_bounds__(256)
void conv_silu_xt_kernel(const __bf16* __restrict__ xz, const float* __restrict__ W,
                         const float* __restrict__ b, __bf16* __restrict__ xc,
                         __bf16* __restrict__ xcT)
{
    __shared__ __bf16 s_t[32][72];
    const int tid = threadIdx.x;
    const int e0 = blockIdx.x * 64, t0 = blockIdx.y * 32;
    const int tl = tid >> 3, e8 = (tid & 7) * 8;
    const int t = t0 + tl;
    float acc[8];
    {
        float4 b0 = *(const float4*)(b + e0 + e8);
        float4 b1 = *(const float4*)(b + e0 + e8 + 4);
        acc[0] = b0.x; acc[1] = b0.y; acc[2] = b0.z; acc[3] = b0.w;
        acc[4] = b1.x; acc[5] = b1.y; acc[6] = b1.z; acc[7] = b1.w;
    }
#pragma unroll
    for (int k = 0; k < 4; ++k) {
        int tt = t - 1 + k;
        if (tt >= 0 && tt < T_TOK) {
            bf16x8 v = *(const bf16x8*)(xz + (size_t)tt * EDIM + e0 + e8);
            float4 w0 = *(const float4*)(W + k * EDIM + e0 + e8);
            float4 w1 = *(const float4*)(W + k * EDIM + e0 + e8 + 4);
            acc[0] += (float)v[0] * w0.x; acc[1] += (float)v[1] * w0.y;
            acc[2] += (float)v[2] * w0.z; acc[3] += (float)v[3] * w0.w;
            acc[4] += (float)v[4] * w1.x; acc[5] += (float)v[5] * w1.y;
            acc[6] += (float)v[6] * w1.z; acc[7] += (float)v[7] * w1.w;
        }
    }
    bf16x8 o;
#pragma unroll
    for (int j = 0; j < 8; ++j) {
        float s = acc[j];
        o[j] = (__bf16)(s / (1.f + __expf(-s)));
    }
    *(bf16x8*)(xc + (size_t)t * EDIM + e0 + e8) = o;
    *(bf16x8*)&s_t[tl][e8] = o;
    __syncthreads();
    {
        int el = tid >> 2, t8 = (tid & 3) * 8;
        bf16x8 o2;
#pragma unroll
        for (int j = 0; j < 8; ++j) o2[j] = s_t[t8 + j][el];
        *(bf16x8*)(xcT + (size_t)(e0 + el) * T_TOK + t0 + t8) = o2;
    }
}

// ---------------------------------------------------------------- scan
// bc layout (plane-split): bc[t*128 + n] = B[t,n], bc[t*128 + 64 + n] = C[t,n].

// Pass 1: block = 8 waves, 32 channels, one chunk; B-plane only staged.
// Wave w: 4 channels (w*4+g, g=lane>>4), 16 lanes/channel, 4 states/lane.
// dA = exp(dt*A) via degree-3 poly (dt*A in [-0.1,0)); chunk product via exp2.
__global__ __launch_bounds__(512)
void scan1_kernel(const float* __restrict__ dtT, const __bf16* __restrict__ xcT,
                  const float* __restrict__ bc2, const float* __restrict__ A_log,
                  float* __restrict__ hend, float* __restrict__ dAp)
{
    __shared__ float  s_b[CKLEN * 64];     // 16 KB (B-plane)
    __shared__ float  s_dt[32][68];        // padded rows
    __shared__ __bf16 s_x[32][72];         // padded rows
    const int tid = threadIdx.x;
    const int lane = tid & 63, w = tid >> 6;
    const int g = lane >> 4, i = lane & 15;
    const int ck = blockIdx.x & (NCHUNK - 1);
    const int eg = (blockIdx.x >> 5) * 32;

    {
#pragma unroll
        for (int r = 0; r < 2; ++r) {
            int linear = r * 512 + tid;
            int t = linear >> 4, k = linear & 15;
            *(float4*)&s_b[t * 64 + 4 * k] =
                *(const float4*)(bc2 + (size_t)(ck * CKLEN + t) * 128 + 4 * k);
        }
        { int ch = tid >> 4, k = tid & 15;
          *(float4*)&s_dt[ch][4 * k] =
              *(const float4*)(dtT + (size_t)(eg + ch) * T_TOK + ck * CKLEN + 4 * k); }
        if (tid < 256) { int ch = tid >> 3, k = tid & 7;
          *(bf16x8*)&s_x[ch][8 * k] =
              *(const bf16x8*)(xcT + (size_t)(eg + ch) * T_TOK + ck * CKLEN + 8 * k); }
    }
    __syncthreads();

    const int ch = w * 4 + g;
    const int e = eg + ch;
    float4 al4 = *(const float4*)(A_log + 4 * i);
    const f32x2 A01 = {-__expf(al4.x), -__expf(al4.y)};
    const f32x2 A23 = {-__expf(al4.z), -__expf(al4.w)};
    f32x2 h01 = {0.f, 0.f}, h23 = {0.f, 0.f};
    float D = 0.f;

#pragma unroll 2
    for (int t0 = 0; t0 < CKLEN; t0 += 8) {
        float4 da = *(const float4*)&s_dt[ch][t0];
        float4 db = *(const float4*)&s_dt[ch][t0 + 4];
        bf16x8 x8 = *(const bf16x8*)&s_x[ch][t0];
        float dtv[8] = {da.x, da.y, da.z, da.w, db.x, db.y, db.z, db.w};
#pragma unroll
        for (int j = 0; j < 8; ++j) {
            float4 b0 = *(const float4*)&s_b[(t0 + j) * 64 + 4 * i];
            float dt = dtv[j];
            float u = dt * (float)x8[j];
            f32x2 dt2 = {dt, dt};
            f32x2 dA01 = exps2(dt2 * A01);
            f32x2 dA23 = exps2(dt2 * A23);
            f32x2 uu = {u, u};
            h01 = vfma2(dA01, h01, uu * (f32x2){b0.x, b0.y});
            h23 = vfma2(dA23, h23, uu * (f32x2){b0.z, b0.w});
            D += dt;
        }
    }
    const float L2E = 1.44269504f;
    size_t idx = ((size_t)e * NCHUNK + ck) * 64 + 4 * i;
    *(float4*)(hend + idx) = make_float4(h01.x, h01.y, h23.x, h23.y);
    *(float4*)(dAp + idx)  = make_float4(__builtin_amdgcn_exp2f(A01.x * L2E * D),
                                         __builtin_amdgcn_exp2f(A01.y * L2E * D),
                                         __builtin_amdgcn_exp2f(A23.x * L2E * D),
                                         __builtin_amdgcn_exp2f(A23.y * L2E * D));
}

// Mid: serial scan over chunk summaries -> h_start per chunk, IN PLACE over hend.
__global__ __launch_bounds__(256)
void scan_mid_kernel(float* __restrict__ hend_h0, const float* __restrict__ dAp)
{
    int gid = blockIdx.x * 256 + threadIdx.x;     // over E*64
    int e = gid >> 6, n = gid & 63;
    float h = 0.f;
#pragma unroll
    for (int ck = 0; ck < NCHUNK; ++ck) {
        size_t idx = ((size_t)e * NCHUNK + ck) * 64 + n;
        float he = hend_h0[idx];
        float P  = dAp[idx];
        hend_h0[idx] = h;
        h = P * h + he;
    }
}

// Pass 2: block = 8 waves, 32 channels, one chunk; B/C planes staged separately.
__global__ __launch_bounds__(512)
void scan2_kernel(const float* __restrict__ dtT, const __bf16* __restrict__ xcT,
                  const __bf16* __restrict__ szT, const float* __restrict__ bc2,
                  const float* __restrict__ A_log, const float* __restrict__ h0s,
                  __bf16* __restrict__ y)
{
    __shared__ float  s_bp[CKLEN * 64];    // 16 KB (B-plane)
    __shared__ float  s_cp[CKLEN * 64];    // 16 KB (C-plane)
    __shared__ float  s_dt[32][68];        // padded rows
    __shared__ __bf16 s_x[32][72];         // padded rows
    __shared__ __bf16 s_y[CKLEN][36];      // padded, t-major tile
    const int tid = threadIdx.x;
    const int lane = tid & 63, w = tid >> 6;
    const int g = lane >> 4, i = lane & 15;
    const int ck = blockIdx.x & (NCHUNK - 1);
    const int eg = (blockIdx.x >> 5) * 32;

    {
#pragma unroll
        for (int r = 0; r < 2; ++r) {
            int linear = r * 512 + tid;
            int t = linear >> 4, k = linear & 15;
            const float* src = bc2 + (size_t)(ck * CKLEN + t) * 128 + 4 * k;
            *(float4*)&s_bp[t * 64 + 4 * k] = *(const float4*)src;
            *(float4*)&s_cp[t * 64 + 4 * k] = *(const float4*)(src + 64);
        }
        { int ch = tid >> 4, k = tid & 15;
          *(float4*)&s_dt[ch][4 * k] =
              *(const float4*)(dtT + (size_t)(eg + ch) * T_TOK + ck * CKLEN + 4 * k); }
        if (tid < 256) { int ch = tid >> 3, k = tid & 7;
          *(bf16x8*)&s_x[ch][8 * k] =
              *(const bf16x8*)(xcT + (size_t)(eg + ch) * T_TOK + ck * CKLEN + 8 * k); }
    }
    __syncthreads();

    const int ch = w * 4 + g;
    const int e = eg + ch;
    float4 al4 = *(const float4*)(A_log + 4 * i);
    const f32x2 A01 = {-__expf(al4.x), -__expf(al4.y)};
    const f32x2 A23 = {-__expf(al4.z), -__expf(al4.w)};
    float4 hh = *(const float4*)(h0s + ((size_t)e * NCHUNK + ck) * 64 + 4 * i);
    f32x2 h01 = {hh.x, hh.y}, h23 = {hh.z, hh.w};

#pragma unroll 2
    for (int t0 = 0; t0 < CKLEN; t0 += 8) {
        float4 da = *(const float4*)&s_dt[ch][t0];
        float4 db = *(const float4*)&s_dt[ch][t0 + 4];
        bf16x8 x8 = *(const bf16x8*)&s_x[ch][t0];
        float dtv[8] = {da.x, da.y, da.z, da.w, db.x, db.y, db.z, db.w};
#pragma unroll
        for (int j = 0; j < 8; ++j) {
            float4 b0 = *(const float4*)&s_bp[(t0 + j) * 64 + 4 * i];
            float4 c0 = *(const float4*)&s_cp[(t0 + j) * 64 + 4 * i];
            float dt = dtv[j];
            float u = dt * (float)x8[j];
            f32x2 dt2 = {dt, dt};
            f32x2 dA01 = exps2(dt2 * A01);
            f32x2 dA23 = exps2(dt2 * A23);
            f32x2 uu = {u, u};
            h01 = vfma2(dA01, h01, uu * (f32x2){b0.x, b0.y});
            h23 = vfma2(dA23, h23, uu * (f32x2){b0.z, b0.w});
            f32x2 pp = h01 * (f32x2){c0.x, c0.y};
            pp = vfma2(h23, (f32x2){c0.z, c0.w}, pp);
            float p = pp.x + pp.y;
            p = dpp_sum16(p);
            if (i == 15) s_y[t0 + j][ch] = (__bf16)p;
        }
    }
    __syncthreads();

    {
        int tt = tid >> 3, q = tid & 7;
        bf16x4 o;
#pragma unroll
        for (int d = 0; d < 4; ++d) {
            float zv = (float)szT[(size_t)(eg + 4 * q + d) * T_TOK + ck * CKLEN + tt];
            o[d] = (__bf16)((float)s_y[tt][4 * q + d] * zv);
        }
        *(bf16x4*)(y + (size_t)(ck * CKLEN + tt) * EDIM + eg + 4 * q) = o;
    }
}

// ---------------------------------------------------------------- GEMM common
__device__ __forceinline__ void glds16(const __bf16* g, __bf16* l)
{
    __builtin_amdgcn_global_load_lds(
        (const __attribute__((address_space(1))) unsigned*)g,
        (__attribute__((address_space(3))) unsigned*)l, 16, 0, 0);
}

template<int EPI>
__device__ __forceinline__ void gemm_epilogue(
    const f32x4& a, int row, int col, int N,
    void* Cout, void* Cout2, const float* res)
{
    if (EPI == 1) {
#pragma unroll
        for (int i = 0; i < 4; ++i)
            ((__bf16*)Cout)[(size_t)(row + i) * N + col] = (__bf16)a[i];
    } else if (EPI == 2) {
#pragma unroll
        for (int i = 0; i < 4; ++i) {
            size_t off = (size_t)(row + i) * N + col;
            ((float*)Cout)[off] = a[i] + res[off];
        }
    } else if (EPI == 3) {
        if (col < 2048) {
            float bias = res[col];
            float4 v;
            float* vv = (float*)&v;
#pragma unroll
            for (int i = 0; i < 4; ++i) {
                float s = a[i] + bias;
                s = (s > 20.f) ? s : log1pf(__expf(s));
                vv[i] = fminf(fmaxf(s, 0.001f), 0.1f);
            }
            *(float4*)((float*)Cout + (size_t)col * T_TOK + row) = v;
        } else {
#pragma unroll
            for (int i = 0; i < 4; ++i)
                ((float*)Cout2)[(size_t)(row + i) * 128 + (col - 2048)] = a[i];
        }
    } else if (EPI == 4) {
        if (col < 2048) {
#pragma unroll
            for (int i = 0; i < 4; ++i)
                ((__bf16*)Cout)[(size_t)(row + i) * EDIM + col] = (__bf16)a[i];
        } else {
            bf16x4 v;
#pragma unroll
            for (int i = 0; i < 4; ++i) {
                float s = a[i];
                v[i] = (__bf16)(s / (1.f + __expf(-s)));
            }
            *(bf16x4*)((__bf16*)Cout2 + (size_t)(col - 2048) * T_TOK + row) = v;
        }
    }
}

// 4-wave GEMM: 64 x 128 tile, BK=64, 2-phase, 8-chunk XOR-swizzled LDS.
template<int EPI, int SWZ>
__global__ __launch_bounds__(256)
void gemm_kernel(const __bf16* __restrict__ A, const __bf16* __restrict__ Bt,
                 void* __restrict__ Cout, void* __restrict__ Cout2,
                 const float* __restrict__ res, int M, int N, int K)
{
    __shared__ __bf16 sAl[2 * 64 * 64];    // 16 KB
    __shared__ __bf16 sBl[2 * 128 * 64];   // 32 KB
    const int t = threadIdx.x;
    const int wave = t >> 6, lane = t & 63;
    int bx = blockIdx.x, by = blockIdx.y;
    if (SWZ) {
        int nwg = gridDim.x * gridDim.y;
        int bid = by * gridDim.x + bx;
        int cpx = nwg >> 3;
        int swz = (bid & 7) * cpx + (bid >> 3);
        bx = swz % gridDim.x;
        by = swz / gridDim.x;
    }
    const int brow = by * 64, bcol = bx * 128;
    const int wr = (wave >> 1) * 32, wc = (wave & 1) * 64;
    f32x4 acc[2][4] = {};

    const int rl8 = lane >> 3;
    const int ck8 = (lane & 7) ^ rl8;
    const __bf16* gA = A  + (size_t)(brow + wave * 16 + rl8) * K + ck8 * 8;
    const __bf16* gB = Bt + (size_t)(bcol + wave * 32 + rl8) * K + ck8 * 8;

    auto stage = [&](int buf, int k0) {
        __bf16* ba = sAl + buf * (64 * 64) + (wave * 16) * 64;
        __bf16* bb = sBl + buf * (128 * 64) + (wave * 32) * 64;
#pragma unroll
        for (int q = 0; q < 2; ++q)
            glds16(gA + (size_t)(q * 8) * K + k0, ba + q * 8 * 64);
#pragma unroll
        for (int q = 0; q < 4; ++q)
            glds16(gB + (size_t)(q * 8) * K + k0, bb + q * 8 * 64);
    };

    stage(0, 0);
    int cur = 0;
    for (int k0 = 0; k0 < K; k0 += 64) {
        __syncthreads();
        if (k0 + 64 < K) stage(cur ^ 1, k0 + 64);
        const __bf16* At = sAl + cur * (64 * 64);
        const __bf16* Btl = sBl + cur * (128 * 64);
#pragma unroll
        for (int ks = 0; ks < 2; ++ks) {
            const int rc = (((ks * 4 + (lane >> 4)) ^ (lane & 7))) * 8;
            bf16x8 af[2], bg[4];
#pragma unroll
            for (int m = 0; m < 2; ++m)
                af[m] = *(const bf16x8*)&At[(wr + m * 16 + (lane & 15)) * 64 + rc];
#pragma unroll
            for (int n = 0; n < 4; ++n)
                bg[n] = *(const bf16x8*)&Btl[(wc + n * 16 + (lane & 15)) * 64 + rc];
#pragma unroll
            for (int m = 0; m < 2; ++m)
#pragma unroll
                for (int n = 0; n < 4; ++n)
                    acc[m][n] = __builtin_amdgcn_mfma_f32_16x16x32_bf16(
                        af[m], bg[n], acc[m][n], 0, 0, 0);
        }
        cur ^= 1;
    }

    const int c_l = lane & 15, r_l = (lane >> 4) * 4;
#pragma unroll
    for (int m = 0; m < 2; ++m)
#pragma unroll
        for (int n = 0; n < 4; ++n)
            gemm_epilogue<EPI>(acc[m][n], brow + wr + m * 16 + r_l,
                               bcol + wc + n * 16 + c_l, N, Cout, Cout2, res);
}

// 8-wave big GEMM: 256 x 128 tile, BK=64, 2-phase, XOR chunk-swizzled LDS.
// EPI 5: fused GLU (16-col interleaved gate/up weights).
template<int EPI>
__global__ __launch_bounds__(512)
void gemm_big(const __bf16* __restrict__ A, const __bf16* __restrict__ Bt,
              void* __restrict__ Cout, void* __restrict__ Cout2,
              const float* __restrict__ res, int M, int N, int K)
{
    __shared__ __bf16 sAl[2 * 256 * 64];   // 64 KB
    __shared__ __bf16 sBl[2 * 128 * 64];   // 32 KB
    const int t = threadIdx.x;
    const int w = t >> 6, lane = t & 63;
    const int brow = blockIdx.y * 256, bcol = blockIdx.x * 128;
    const int wr = (w >> 1) * 64, wc = (w & 1) * 64;
    f32x4 acc[4][4] = {};

    const int rl8 = lane >> 3;
    const int ck8 = (lane & 7) ^ rl8;
    const __bf16* gA = A  + (size_t)(brow + w * 32 + rl8) * K + ck8 * 8;
    const __bf16* gB = Bt + (size_t)(bcol + w * 16 + rl8) * K + ck8 * 8;

    auto stage = [&](int buf, int k0) {
        __bf16* ba = sAl + buf * (256 * 64) + (w * 32) * 64;
        __bf16* bb = sBl + buf * (128 * 64) + (w * 16) * 64;
#pragma unroll
        for (int q = 0; q < 4; ++q)
            glds16(gA + (size_t)(q * 8) * K + k0, ba + q * 8 * 64);
#pragma unroll
        for (int q = 0; q < 2; ++q)
            glds16(gB + (size_t)(q * 8) * K + k0, bb + q * 8 * 64);
    };

    stage(0, 0);
    int cur = 0;
    for (int k0 = 0; k0 < K; k0 += 64) {
        __syncthreads();
        if (k0 + 64 < K) stage(cur ^ 1, k0 + 64);
        const __bf16* At = sAl + cur * (256 * 64);
        const __bf16* Btl = sBl + cur * (128 * 64);
#pragma unroll
        for (int ks = 0; ks < 2; ++ks) {
            const int rchk = (((ks * 4 + (lane >> 4)) ^ (lane & 7))) * 8;
            bf16x8 af[4], bg[4];
#pragma unroll
            for (int m = 0; m < 4; ++m)
                af[m] = *(const bf16x8*)&At[(wr + m * 16 + (lane & 15)) * 64 + rchk];
#pragma unroll
            for (int n = 0; n < 4; ++n)
                bg[n] = *(const bf16x8*)&Btl[(wc + n * 16 + (lane & 15)) * 64 + rchk];
#pragma unroll
            for (int m = 0; m < 4; ++m)
#pragma unroll
                for (int n = 0; n < 4; ++n)
                    acc[m][n] = __builtin_amdgcn_mfma_f32_16x16x32_bf16(
                        af[m], bg[n], acc[m][n], 0, 0, 0);
        }
        cur ^= 1;
    }

    const int c_l = lane & 15, r_l = (lane >> 4) * 4;
    if constexpr (EPI == 5) {
#pragma unroll
        for (int m = 0; m < 4; ++m) {
#pragma unroll
            for (int n = 0; n < 4; n += 2) {
                int row = brow + wr + m * 16 + r_l;
                int fcol = (((bcol + wc + n * 16) >> 5) << 4) + c_l;
#pragma unroll
                for (int i = 0; i < 4; ++i) {
                    float gg = acc[m][n][i];
                    float uu = acc[m][n + 1][i];
                    ((__bf16*)Cout)[(size_t)(row + i) * 2048 + fcol] =
                        (__bf16)(gg / (1.f + __expf(-gg)) * uu);
                }
            }
        }
    } else {
#pragma unroll
        for (int m = 0; m < 4; ++m)
#pragma unroll
            for (int n = 0; n < 4; ++n)
                gemm_epilogue<EPI>(acc[m][n], brow + wr + m * 16 + r_l,
                                   bcol + wc + n * 16 + c_l, N, Cout, Cout2, res);
    }
}

// ---------------------------------------------------------------- launch
extern "C" void kernel_launch(void* const* d_in, const int* in_sizes, int n_in,
                              void* d_out, int out_size, void* d_ws, size_t ws_size,
                              hipStream_t stream)
{
    (void)in_sizes; (void)n_in; (void)out_size; (void)ws_size;
    const float* x     = (const float*)d_in[0];
    const float* inw   = (const float*)d_in[1];
    const float* ffnw  = (const float*)d_in[2];
    const float* inpW  = (const float*)d_in[3];
    const float* convW = (const float*)d_in[4];
    const float* convB = (const float*)d_in[5];
    const float* dtW   = (const float*)d_in[6];
    const float* dtB   = (const float*)d_in[7];
    const float* BW    = (const float*)d_in[8];
    const float* CW    = (const float*)d_in[9];
    const float* Alog  = (const float*)d_in[10];
    const float* outpW = (const float*)d_in[11];
    const float* gateW = (const float*)d_in[12];
    const float* upW   = (const float*)d_in[13];
    const float* downW = (const float*)d_in[14];
    float* out = (float*)d_out;

    char* p = (char*)d_ws;
    auto alloc = [&](size_t n) { char* q = p; p += (n + 255) & ~(size_t)255; return q; };
    __bf16* wt_inproj = (__bf16*)alloc(4096ull * 1024 * 2);
    __bf16* wt_dtbc   = (__bf16*)alloc(2176ull * 2048 * 2);  // rows: 0-2047 dt, 2048-2111 B, 2112-2175 C
    __bf16* wt_outp   = (__bf16*)alloc(1024ull * 2048 * 2);
    __bf16* wt_gu     = (__bf16*)alloc(4096ull * 1024 * 2);  // 16-col interleaved gate/up
    __bf16* wt_down   = (__bf16*)alloc(1024ull * 2048 * 2);
    __bf16* normed    = (__bf16*)alloc(2048ull * 1024 * 2);  // reused as n2
    __bf16* xz        = (__bf16*)alloc(2048ull * 2048 * 2);  // x_z half of in_proj
    __bf16* gu_buf    = (__bf16*)alloc(2048ull * 4096 * 2);  // dAp scratch
    __bf16* xc        = (__bf16*)alloc(2048ull * 2048 * 2);  // conv out, reused as y
    float*  scratch16 = (float*)alloc(2048ull * 2048 * 4);   // hend/h0 then ffnmid
    float*  bc        = (float*)alloc(2048ull * 128 * 4);
    float*  dtT       = (float*)alloc(2048ull * 2048 * 4);
    __bf16* xcT       = (__bf16*)alloc(2048ull * 2048 * 2);
    __bf16* szT       = (__bf16*)alloc(2048ull * 2048 * 2);
    float*  x2        = (float*)alloc(2048ull * 1024 * 4);

    dim3 B256(256);
    // batched weight prep (one dispatch); gate/up interleaved at 16-col granularity
    {
        TJobs8 tj;
        int off = 0, ji = 0;
        auto addjob = [&](const float* s, __bf16* d, int R, int C, int S, int mode) {
            tj.j[ji++] = TJob{s, d, R, C, S, C / 32, off, mode};
            off += (C / 32) * (R / 32);
        };
        addjob(inpW,  wt_inproj, 1024, 4096, 4096, 0);
        addjob(dtW,   wt_dtbc,   2048, 2048, 2048, 0);
        addjob(BW,    wt_dtbc + 2048ull * 2048, 2048, 64, 64, 0);
        addjob(CW,    wt_dtbc + 2112ull * 2048, 2048, 64, 64, 0);
        addjob(outpW, wt_outp,   2048, 1024, 1024, 0);
        addjob(gateW, wt_gu,     1024, 2048, 2048, 1);
        addjob(upW,   wt_gu,     1024, 2048, 2048, 2);
        addjob(downW, wt_down,   2048, 1024, 1024, 0);
        wprep_kernel<<<dim3(off), B256, 0, stream>>>(tj);
    }

    // normed = rmsnorm(x, inw)
    rmsnorm_kernel<<<dim3(2048), B256, 0, stream>>>(x, inw, normed);
    // in_proj: xz (t-major bf16) + szT (silu'd z, channel-major)
    gemm_big<4><<<dim3(32, 8), dim3(512), 0, stream>>>(normed, wt_inproj, xz, szT, nullptr, 2048, 4096, 1024);
    // xc = silu(conv(xz) + b), also writes xcT (channel-major) in one pass
    conv_silu_xt_kernel<<<dim3(32, 64), B256, 0, stream>>>(xz, convW, convB, xc, xcT);
    // fused dt+bc: dtT (softplus'd, channel-major f32) + bc (t-major f32, planes)
    gemm_kernel<3, 1><<<dim3(17, 32), B256, 0, stream>>>(xc, wt_dtbc, dtT, bc, dtB, 2048, 2176, 2048);

    // chunked SSM scan
    float* hend = scratch16;                      // 16 MB (E*32*64 f32)
    float* dAp  = (float*)gu_buf;                 // 16 MB
    scan1_kernel<<<dim3(2048), dim3(512), 0, stream>>>(dtT, xcT, bc, Alog, hend, dAp);
    scan_mid_kernel<<<dim3(512), B256, 0, stream>>>(hend, dAp);
    __bf16* y = xc;                               // xc dead after dt GEMM
    scan2_kernel<<<dim3(2048), dim3(512), 0, stream>>>(dtT, xcT, szT, bc, Alog, hend, y);

    // x2 = x + y @ out_proj
    gemm_kernel<2, 0><<<dim3(8, 32), B256, 0, stream>>>(y, wt_outp, x2, nullptr, x, 2048, 1024, 2048);
    // n2 = rmsnorm(x2, ffnw)
    rmsnorm_kernel<<<dim3(2048), B256, 0, stream>>>(x2, ffnw, normed);
    // ffnmid = silu(n2@gate) * (n2@up)  -- fused GLU epilogue
    __bf16* ffnmid = (__bf16*)scratch16;
    gemm_big<5><<<dim3(32, 8), dim3(512), 0, stream>>>(normed, wt_gu, ffnmid, nullptr, nullptr, 2048, 4096, 1024);
    // out = x2 + ffnmid @ down
    gemm_kernel<2, 0><<<dim3(8, 32), B256, 0, stream>>>(ffnmid, wt_down, out, nullptr, x2, 2048, 1024, 2048);
}

// Round 21
// 282.979 us; speedup vs baseline: 2.6119x; 1.0187x over previous
//
#include <hip/hip_runtime.h>
#include <hip/hip_bf16.h>

typedef __bf16 bf16x8 __attribute__((ext_vector_type(8)));
typedef __bf16 bf16x4 __attribute__((ext_vector_type(4)));
typedef float  f32x4  __attribute__((ext_vector_type(4)));
typedef float  f32x2  __attribute__((ext_vector_type(2)));

#define T_TOK 2048
#define DDIM  1024
#define EDIM  2048
#define NCHUNK 32
#define CKLEN  64

__device__ __forceinline__ f32x2 vfma2(f32x2 a, f32x2 b, f32x2 c)
{
#if __has_builtin(__builtin_elementwise_fma)
    return __builtin_elementwise_fma(a, b, c);
#else
    return (f32x2){fmaf(a.x, b.x, c.x), fmaf(a.y, b.y, c.y)};
#endif
}

// exp(w) for w in [-0.15, 0]: degree-3 Taylor, rel err <= 4e-6.
__device__ __forceinline__ f32x2 exps2(f32x2 w)
{
    const f32x2 C6  = {0.166666667f, 0.166666667f};
    const f32x2 CH  = {0.5f, 0.5f};
    const f32x2 ONE = {1.f, 1.f};
    return vfma2(w, vfma2(w, vfma2(w, C6, CH), ONE), ONE);
}

// Fused DPP 16-lane tree sum (lane 15 of each row gets the row total).
// HAZARD-GUARDED: VALU-write -> DPP-read needs 2 wait states (s_nop 1) on
// CDNA; the compiler can't see inside asm, so the nops are explicit.
__device__ __forceinline__ float dpp_sum16(float p)
{
    asm volatile(
        "s_nop 1\n\t"
        "v_add_f32 %0, %0, %0 row_shr:1 bound_ctrl:0\n\t"
        "s_nop 1\n\t"
        "v_add_f32 %0, %0, %0 row_shr:2 bound_ctrl:0\n\t"
        "s_nop 1\n\t"
        "v_add_f32 %0, %0, %0 row_shr:4 bound_ctrl:0\n\t"
        "s_nop 1\n\t"
        "v_add_f32 %0, %0, %0 row_shr:8 bound_ctrl:0"
        : "+v"(p));
    return p;
}

// ---------------------------------------------------------------- batched weight prep
// One dispatch transposes all weight matrices (f32 -> bf16, [N][K] layout).
// mode 0: dst row = src col c.  mode 1: row = 32*(c>>4)+(c&15) (gate interleave).
// mode 2: row = 32*(c>>4)+16+(c&15) (up interleave).
struct TJob { const float* src; __bf16* dst; int R, C, S, tilesX, tileOff, mode; };
struct TJobs8 { TJob j[8]; };

__global__ __launch_bounds__(256)
void wprep_kernel(TJobs8 jobs)
{
    int tile = blockIdx.x;
    int ji = 0;
#pragma unroll
    for (int k = 1; k < 8; ++k) if (tile >= jobs.j[k].tileOff) ji = k;
    const TJob jb = jobs.j[ji];
    int rel = tile - jb.tileOff;
    int bx = rel % jb.tilesX, by = rel / jb.tilesX;
    __shared__ float tilebuf[32][33];
    const int tc0 = bx * 32, tr0 = by * 32;
    const int tx = threadIdx.x & 31, ty = threadIdx.x >> 5;
#pragma unroll
    for (int p = 0; p < 4; ++p) {
        int rl = ty + p * 8;
        tilebuf[rl][tx] = jb.src[(size_t)(tr0 + rl) * jb.S + tc0 + tx];
    }
    __syncthreads();
#pragma unroll
    for (int p = 0; p < 4; ++p) {
        int cl = ty + p * 8;
        float v = tilebuf[tx][cl];
        int c = tc0 + cl, r = tr0 + tx;
        int dr = (jb.mode == 0) ? c
               : ((c >> 4) * 32 + (c & 15) + ((jb.mode == 2) ? 16 : 0));
        jb.dst[(size_t)dr * jb.R + r] = (__bf16)v;
    }
}

// ---------------------------------------------------------------- rmsnorm
__global__ __launch_bounds__(256)
void rmsnorm_kernel(const float* __restrict__ x, const float* __restrict__ w,
                    __bf16* __restrict__ out)
{
    const int row = blockIdx.x;
    const int t = threadIdx.x;
    float4 v = ((const float4*)(x + (size_t)row * DDIM))[t];
    float ss = v.x * v.x + v.y * v.y + v.z * v.z + v.w * v.w;
#pragma unroll
    for (int m = 32; m; m >>= 1) ss += __shfl_xor(ss, m);
    __shared__ float red[4];
    if ((t & 63) == 0) red[t >> 6] = ss;
    __syncthreads();
    float scale = rsqrtf((red[0] + red[1] + red[2] + red[3]) * (1.f / DDIM) + 1e-5f);
    float4 wv = ((const float4*)w)[t];
    __bf16* o = out + (size_t)row * DDIM + t * 4;
    o[0] = (__bf16)(v.x * scale * wv.x);
    o[1] = (__bf16)(v.y * scale * wv.y);
    o[2] = (__bf16)(v.z * scale * wv.z);
    o[3] = (__bf16)(v.w * scale * wv.w);
}

// ---------------------------------------------------------------- conv+silu (+xcT)
__global__ __launch_bounds__(256)
void conv_silu_xt_kernel(const __bf16* __restrict__ xz, const float* __restrict__ W,
                         const float* __restrict__ b, __bf16* __restrict__ xc,
                         __bf16* __restrict__ xcT)
{
    __shared__ __bf16 s_t[32][72];
    const int tid = threadIdx.x;
    const int e0 = blockIdx.x * 64, t0 = blockIdx.y * 32;
    const int tl = tid >> 3, e8 = (tid & 7) * 8;
    const int t = t0 + tl;
    float acc[8];
    {
        float4 b0 = *(const float4*)(b + e0 + e8);
        float4 b1 = *(const float4*)(b + e0 + e8 + 4);
        acc[0] = b0.x; acc[1] = b0.y; acc[2] = b0.z; acc[3] = b0.w;
        acc[4] = b1.x; acc[5] = b1.y; acc[6] = b1.z; acc[7] = b1.w;
    }
#pragma unroll
    for (int k = 0; k < 4; ++k) {
        int tt = t - 1 + k;
        if (tt >= 0 && tt < T_TOK) {
            bf16x8 v = *(const bf16x8*)(xz + (size_t)tt * EDIM + e0 + e8);
            float4 w0 = *(const float4*)(W + k * EDIM + e0 + e8);
            float4 w1 = *(const float4*)(W + k * EDIM + e0 + e8 + 4);
            acc[0] += (float)v[0] * w0.x; acc[1] += (float)v[1] * w0.y;
            acc[2] += (float)v[2] * w0.z; acc[3] += (float)v[3] * w0.w;
            acc[4] += (float)v[4] * w1.x; acc[5] += (float)v[5] * w1.y;
            acc[6] += (float)v[6] * w1.z; acc[7] += (float)v[7] * w1.w;
        }
    }
    bf16x8 o;
#pragma unroll
    for (int j = 0; j < 8; ++j) {
        float s = acc[j];
        o[j] = (__bf16)(s / (1.f + __expf(-s)));
    }
    *(bf16x8*)(xc + (size_t)t * EDIM + e0 + e8) = o;
    *(bf16x8*)&s_t[tl][e8] = o;
    __syncthreads();
    {
        int el = tid >> 2, t8 = (tid & 3) * 8;
        bf16x8 o2;
#pragma unroll
        for (int j = 0; j < 8; ++j) o2[j] = s_t[t8 + j][el];
        *(bf16x8*)(xcT + (size_t)(e0 + el) * T_TOK + t0 + t8) = o2;
    }
}

// ---------------------------------------------------------------- scan
// bc layout (plane-split): bc[t*128 + n] = B[t,n], bc[t*128 + 64 + n] = C[t,n].

// Pass 1: block = 8 waves, 32 channels, one chunk; B-plane only staged.
// Wave w: 4 channels (w*4+g, g=lane>>4), 16 lanes/channel, 4 states/lane.
// dA = exp(dt*A) via degree-3 poly (dt*A in [-0.1,0)); chunk product via exp2.
__global__ __launch_bounds__(512)
void scan1_kernel(const float* __restrict__ dtT, const __bf16* __restrict__ xcT,
                  const float* __restrict__ bc2, const float* __restrict__ A_log,
                  float* __restrict__ hend, float* __restrict__ dAp)
{
    __shared__ float  s_b[CKLEN * 64];     // 16 KB (B-plane)
    __shared__ float  s_dt[32][68];        // padded rows
    __shared__ __bf16 s_x[32][72];         // padded rows
    const int tid = threadIdx.x;
    const int lane = tid & 63, w = tid >> 6;
    const int g = lane >> 4, i = lane & 15;
    const int ck = blockIdx.x & (NCHUNK - 1);
    const int eg = (blockIdx.x >> 5) * 32;

    {
#pragma unroll
        for (int r = 0; r < 2; ++r) {
            int linear = r * 512 + tid;
            int t = linear >> 4, k = linear & 15;
            *(float4*)&s_b[t * 64 + 4 * k] =
                *(const float4*)(bc2 + (size_t)(ck * CKLEN + t) * 128 + 4 * k);
        }
        { int ch = tid >> 4, k = tid & 15;
          *(float4*)&s_dt[ch][4 * k] =
              *(const float4*)(dtT + (size_t)(eg + ch) * T_TOK + ck * CKLEN + 4 * k); }
        if (tid < 256) { int ch = tid >> 3, k = tid & 7;
          *(bf16x8*)&s_x[ch][8 * k] =
              *(const bf16x8*)(xcT + (size_t)(eg + ch) * T_TOK + ck * CKLEN + 8 * k); }
    }
    __syncthreads();

    const int ch = w * 4 + g;
    const int e = eg + ch;
    float4 al4 = *(const float4*)(A_log + 4 * i);
    const f32x2 A01 = {-__expf(al4.x), -__expf(al4.y)};
    const f32x2 A23 = {-__expf(al4.z), -__expf(al4.w)};
    f32x2 h01 = {0.f, 0.f}, h23 = {0.f, 0.f};
    float D = 0.f;

#pragma unroll 2
    for (int t0 = 0; t0 < CKLEN; t0 += 8) {
        float4 da = *(const float4*)&s_dt[ch][t0];
        float4 db = *(const float4*)&s_dt[ch][t0 + 4];
        bf16x8 x8 = *(const bf16x8*)&s_x[ch][t0];
        float dtv[8] = {da.x, da.y, da.z, da.w, db.x, db.y, db.z, db.w};
#pragma unroll
        for (int j = 0; j < 8; ++j) {
            float4 b0 = *(const float4*)&s_b[(t0 + j) * 64 + 4 * i];
            float dt = dtv[j];
            float u = dt * (float)x8[j];
            f32x2 dt2 = {dt, dt};
            f32x2 dA01 = exps2(dt2 * A01);
            f32x2 dA23 = exps2(dt2 * A23);
            f32x2 uu = {u, u};
            h01 = vfma2(dA01, h01, uu * (f32x2){b0.x, b0.y});
            h23 = vfma2(dA23, h23, uu * (f32x2){b0.z, b0.w});
            D += dt;
        }
    }
    const float L2E = 1.44269504f;
    size_t idx = ((size_t)e * NCHUNK + ck) * 64 + 4 * i;
    *(float4*)(hend + idx) = make_float4(h01.x, h01.y, h23.x, h23.y);
    *(float4*)(dAp + idx)  = make_float4(__builtin_amdgcn_exp2f(A01.x * L2E * D),
                                         __builtin_amdgcn_exp2f(A01.y * L2E * D),
                                         __builtin_amdgcn_exp2f(A23.x * L2E * D),
                                         __builtin_amdgcn_exp2f(A23.y * L2E * D));
}

// Mid: serial scan over chunk summaries -> h_start per chunk, IN PLACE over hend.
__global__ __launch_bounds__(256)
void scan_mid_kernel(float* __restrict__ hend_h0, const float* __restrict__ dAp)
{
    int gid = blockIdx.x * 256 + threadIdx.x;     // over E*64
    int e = gid >> 6, n = gid & 63;
    float h = 0.f;
#pragma unroll
    for (int ck = 0; ck < NCHUNK; ++ck) {
        size_t idx = ((size_t)e * NCHUNK + ck) * 64 + n;
        float he = hend_h0[idx];
        float P  = dAp[idx];
        hend_h0[idx] = h;
        h = P * h + he;
    }
}

// Pass 2: block = 8 waves, 32 channels, one chunk; B/C planes staged separately.
__global__ __launch_bounds__(512)
void scan2_kernel(const float* __restrict__ dtT, const __bf16* __restrict__ xcT,
                  const __bf16* __restrict__ szT, const float* __restrict__ bc2,
                  const float* __restrict__ A_log, const float* __restrict__ h0s,
                  __bf16* __restrict__ y)
{
    __shared__ float  s_bp[CKLEN * 64];    // 16 KB (B-plane)
    __shared__ float  s_cp[CKLEN * 64];    // 16 KB (C-plane)
    __shared__ float  s_dt[32][68];        // padded rows
    __shared__ __bf16 s_x[32][72];         // padded rows
    __shared__ __bf16 s_y[CKLEN][36];      // padded, t-major tile
    const int tid = threadIdx.x;
    const int lane = tid & 63, w = tid >> 6;
    const int g = lane >> 4, i = lane & 15;
    const int ck = blockIdx.x & (NCHUNK - 1);
    const int eg = (blockIdx.x >> 5) * 32;

    {
#pragma unroll
        for (int r = 0; r < 2; ++r) {
            int linear = r * 512 + tid;
            int t = linear >> 4, k = linear & 15;
            const float* src = bc2 + (size_t)(ck * CKLEN + t) * 128 + 4 * k;
            *(float4*)&s_bp[t * 64 + 4 * k] = *(const float4*)src;
            *(float4*)&s_cp[t * 64 + 4 * k] = *(const float4*)(src + 64);
        }
        { int ch = tid >> 4, k = tid & 15;
          *(float4*)&s_dt[ch][4 * k] =
              *(const float4*)(dtT + (size_t)(eg + ch) * T_TOK + ck * CKLEN + 4 * k); }
        if (tid < 256) { int ch = tid >> 3, k = tid & 7;
          *(bf16x8*)&s_x[ch][8 * k] =
              *(const bf16x8*)(xcT + (size_t)(eg + ch) * T_TOK + ck * CKLEN + 8 * k); }
    }
    __syncthreads();

    const int ch = w * 4 + g;
    const int e = eg + ch;
    float4 al4 = *(const float4*)(A_log + 4 * i);
    const f32x2 A01 = {-__expf(al4.x), -__expf(al4.y)};
    const f32x2 A23 = {-__expf(al4.z), -__expf(al4.w)};
    float4 hh = *(const float4*)(h0s + ((size_t)e * NCHUNK + ck) * 64 + 4 * i);
    f32x2 h01 = {hh.x, hh.y}, h23 = {hh.z, hh.w};

#pragma unroll 2
    for (int t0 = 0; t0 < CKLEN; t0 += 8) {
        float4 da = *(const float4*)&s_dt[ch][t0];
        float4 db = *(const float4*)&s_dt[ch][t0 + 4];
        bf16x8 x8 = *(const bf16x8*)&s_x[ch][t0];
        float dtv[8] = {da.x, da.y, da.z, da.w, db.x, db.y, db.z, db.w};
#pragma unroll
        for (int j = 0; j < 8; ++j) {
            float4 b0 = *(const float4*)&s_bp[(t0 + j) * 64 + 4 * i];
            float4 c0 = *(const float4*)&s_cp[(t0 + j) * 64 + 4 * i];
            float dt = dtv[j];
            float u = dt * (float)x8[j];
            f32x2 dt2 = {dt, dt};
            f32x2 dA01 = exps2(dt2 * A01);
            f32x2 dA23 = exps2(dt2 * A23);
            f32x2 uu = {u, u};
            h01 = vfma2(dA01, h01, uu * (f32x2){b0.x, b0.y});
            h23 = vfma2(dA23, h23, uu * (f32x2){b0.z, b0.w});
            f32x2 pp = h01 * (f32x2){c0.x, c0.y};
            pp = vfma2(h23, (f32x2){c0.z, c0.w}, pp);
            float p = pp.x + pp.y;
            p = dpp_sum16(p);
            if (i == 15) s_y[t0 + j][ch] = (__bf16)p;
        }
    }
    __syncthreads();

    {
        int tt = tid >> 3, q = tid & 7;
        bf16x4 o;
#pragma unroll
        for (int d = 0; d < 4; ++d) {
            float zv = (float)szT[(size_t)(eg + 4 * q + d) * T_TOK + ck * CKLEN + tt];
            o[d] = (__bf16)((float)s_y[tt][4 * q + d] * zv);
        }
        *(bf16x4*)(y + (size_t)(ck * CKLEN + tt) * EDIM + eg + 4 * q) = o;
    }
}

// ---------------------------------------------------------------- GEMM common
__device__ __forceinline__ void glds16(const __bf16* g, __bf16* l)
{
    __builtin_amdgcn_global_load_lds(
        (const __attribute__((address_space(1))) unsigned*)g,
        (__attribute__((address_space(3))) unsigned*)l, 16, 0, 0);
}

template<int EPI>
__device__ __forceinline__ void gemm_epilogue(
    const f32x4& a, int row, int col, int N,
    void* Cout, void* Cout2, const float* res)
{
    if (EPI == 1) {
#pragma unroll
        for (int i = 0; i < 4; ++i)
            ((__bf16*)Cout)[(size_t)(row + i) * N + col] = (__bf16)a[i];
    } else if (EPI == 2) {
#pragma unroll
        for (int i = 0; i < 4; ++i) {
            size_t off = (size_t)(row + i) * N + col;
            ((float*)Cout)[off] = a[i] + res[off];
        }
    } else if (EPI == 3) {
        if (col < 2048) {
            float bias = res[col];
            float4 v;
            float* vv = (float*)&v;
#pragma unroll
            for (int i = 0; i < 4; ++i) {
                float s = a[i] + bias;
                s = (s > 20.f) ? s : log1pf(__expf(s));
                vv[i] = fminf(fmaxf(s, 0.001f), 0.1f);
            }
            *(float4*)((float*)Cout + (size_t)col * T_TOK + row) = v;
        } else {
#pragma unroll
            for (int i = 0; i < 4; ++i)
                ((float*)Cout2)[(size_t)(row + i) * 128 + (col - 2048)] = a[i];
        }
    } else if (EPI == 4) {
        if (col < 2048) {
#pragma unroll
            for (int i = 0; i < 4; ++i)
                ((__bf16*)Cout)[(size_t)(row + i) * EDIM + col] = (__bf16)a[i];
        } else {
            bf16x4 v;
#pragma unroll
            for (int i = 0; i < 4; ++i) {
                float s = a[i];
                v[i] = (__bf16)(s / (1.f + __expf(-s)));
            }
            *(bf16x4*)((__bf16*)Cout2 + (size_t)(col - 2048) * T_TOK + row) = v;
        }
    }
}

// 4-wave GEMM: 64 x 64 tile, BK=64, 2-phase, 8-chunk XOR-swizzled LDS.
// 32 KB LDS -> 5 blocks/CU (20 waves) to cross-hide the barrier vmcnt drain.
// SWZ<1>: XCD-contiguous block remap (grid total must be mult of 8).
template<int EPI, int SWZ>
__global__ __launch_bounds__(256)
void gemm_kernel(const __bf16* __restrict__ A, const __bf16* __restrict__ Bt,
                 void* __restrict__ Cout, void* __restrict__ Cout2,
                 const float* __restrict__ res, int M, int N, int K)
{
    __shared__ __bf16 sAl[2 * 64 * 64];    // 16 KB
    __shared__ __bf16 sBl[2 * 64 * 64];    // 16 KB
    const int t = threadIdx.x;
    const int wave = t >> 6, lane = t & 63;
    int bx = blockIdx.x, by = blockIdx.y;
    if (SWZ) {
        int nwg = gridDim.x * gridDim.y;
        int bid = by * gridDim.x + bx;
        int cpx = nwg >> 3;
        int swz = (bid & 7) * cpx + (bid >> 3);
        bx = swz % gridDim.x;
        by = swz / gridDim.x;
    }
    const int brow = by * 64, bcol = bx * 64;
    const int wr = (wave >> 1) * 32, wc = (wave & 1) * 32;
    f32x4 acc[2][2] = {};

    // staging source: lane -> row +(lane>>3), chunk (lane&7)^(lane>>3)
    const int rl8 = lane >> 3;
    const int ck8 = (lane & 7) ^ rl8;
    const __bf16* gA = A  + (size_t)(brow + wave * 16 + rl8) * K + ck8 * 8;
    const __bf16* gB = Bt + (size_t)(bcol + wave * 16 + rl8) * K + ck8 * 8;

    auto stage = [&](int buf, int k0) {
        __bf16* ba = sAl + buf * (64 * 64) + (wave * 16) * 64;
        __bf16* bb = sBl + buf * (64 * 64) + (wave * 16) * 64;
#pragma unroll
        for (int q = 0; q < 2; ++q)
            glds16(gA + (size_t)(q * 8) * K + k0, ba + q * 8 * 64);
#pragma unroll
        for (int q = 0; q < 2; ++q)
            glds16(gB + (size_t)(q * 8) * K + k0, bb + q * 8 * 64);
    };

    stage(0, 0);
    int cur = 0;
    for (int k0 = 0; k0 < K; k0 += 64) {
        __syncthreads();                  // staged tile landed; other buf free
        if (k0 + 64 < K) stage(cur ^ 1, k0 + 64);
        const __bf16* At = sAl + cur * (64 * 64);
        const __bf16* Btl = sBl + cur * (64 * 64);
#pragma unroll
        for (int ks = 0; ks < 2; ++ks) {
            const int rc = (((ks * 4 + (lane >> 4)) ^ (lane & 7))) * 8;
            bf16x8 af[2], bg[2];
#pragma unroll
            for (int m = 0; m < 2; ++m)
                af[m] = *(const bf16x8*)&At[(wr + m * 16 + (lane & 15)) * 64 + rc];
#pragma unroll
            for (int n = 0; n < 2; ++n)
                bg[n] = *(const bf16x8*)&Btl[(wc + n * 16 + (lane & 15)) * 64 + rc];
#pragma unroll
            for (int m = 0; m < 2; ++m)
#pragma unroll
                for (int n = 0; n < 2; ++n)
                    acc[m][n] = __builtin_amdgcn_mfma_f32_16x16x32_bf16(
                        af[m], bg[n], acc[m][n], 0, 0, 0);
        }
        cur ^= 1;
    }

    const int c_l = lane & 15, r_l = (lane >> 4) * 4;
#pragma unroll
    for (int m = 0; m < 2; ++m)
#pragma unroll
        for (int n = 0; n < 2; ++n)
            gemm_epilogue<EPI>(acc[m][n], brow + wr + m * 16 + r_l,
                               bcol + wc + n * 16 + c_l, N, Cout, Cout2, res);
}

// 8-wave big GEMM: 256 x 128 tile, BK=64, 2-phase, XOR chunk-swizzled LDS.
// EPI 5: fused GLU (16-col interleaved gate/up weights).
template<int EPI>
__global__ __launch_bounds__(512)
void gemm_big(const __bf16* __restrict__ A, const __bf16* __restrict__ Bt,
              void* __restrict__ Cout, void* __restrict__ Cout2,
              const float* __restrict__ res, int M, int N, int K)
{
    __shared__ __bf16 sAl[2 * 256 * 64];   // 64 KB
    __shared__ __bf16 sBl[2 * 128 * 64];   // 32 KB
    const int t = threadIdx.x;
    const int w = t >> 6, lane = t & 63;
    const int brow = blockIdx.y * 256, bcol = blockIdx.x * 128;
    const int wr = (w >> 1) * 64, wc = (w & 1) * 64;
    f32x4 acc[4][4] = {};

    const int rl8 = lane >> 3;
    const int ck8 = (lane & 7) ^ rl8;
    const __bf16* gA = A  + (size_t)(brow + w * 32 + rl8) * K + ck8 * 8;
    const __bf16* gB = Bt + (size_t)(bcol + w * 16 + rl8) * K + ck8 * 8;

    auto stage = [&](int buf, int k0) {
        __bf16* ba = sAl + buf * (256 * 64) + (w * 32) * 64;
        __bf16* bb = sBl + buf * (128 * 64) + (w * 16) * 64;
#pragma unroll
        for (int q = 0; q < 4; ++q)
            glds16(gA + (size_t)(q * 8) * K + k0, ba + q * 8 * 64);
#pragma unroll
        for (int q = 0; q < 2; ++q)
            glds16(gB + (size_t)(q * 8) * K + k0, bb + q * 8 * 64);
    };

    stage(0, 0);
    int cur = 0;
    for (int k0 = 0; k0 < K; k0 += 64) {
        __syncthreads();
        if (k0 + 64 < K) stage(cur ^ 1, k0 + 64);
        const __bf16* At = sAl + cur * (256 * 64);
        const __bf16* Btl = sBl + cur * (128 * 64);
#pragma unroll
        for (int ks = 0; ks < 2; ++ks) {
            const int rchk = (((ks * 4 + (lane >> 4)) ^ (lane & 7))) * 8;
            bf16x8 af[4], bg[4];
#pragma unroll
            for (int m = 0; m < 4; ++m)
                af[m] = *(const bf16x8*)&At[(wr + m * 16 + (lane & 15)) * 64 + rchk];
#pragma unroll
            for (int n = 0; n < 4; ++n)
                bg[n] = *(const bf16x8*)&Btl[(wc + n * 16 + (lane & 15)) * 64 + rchk];
#pragma unroll
            for (int m = 0; m < 4; ++m)
#pragma unroll
                for (int n = 0; n < 4; ++n)
                    acc[m][n] = __builtin_amdgcn_mfma_f32_16x16x32_bf16(
                        af[m], bg[n], acc[m][n], 0, 0, 0);
        }
        cur ^= 1;
    }

    const int c_l = lane & 15, r_l = (lane >> 4) * 4;
    if constexpr (EPI == 5) {
#pragma unroll
        for (int m = 0; m < 4; ++m) {
#pragma unroll
            for (int n = 0; n < 4; n += 2) {
                int row = brow + wr + m * 16 + r_l;
                int fcol = (((bcol + wc + n * 16) >> 5) << 4) + c_l;
#pragma unroll
                for (int i = 0; i < 4; ++i) {
                    float gg = acc[m][n][i];
                    float uu = acc[m][n + 1][i];
                    ((__bf16*)Cout)[(size_t)(row + i) * 2048 + fcol] =
                        (__bf16)(gg / (1.f + __expf(-gg)) * uu);
                }
            }
        }
    } else {
#pragma unroll
        for (int m = 0; m < 4; ++m)
#pragma unroll
            for (int n = 0; n < 4; ++n)
                gemm_epilogue<EPI>(acc[m][n], brow + wr + m * 16 + r_l,
                                   bcol + wc + n * 16 + c_l, N, Cout, Cout2, res);
    }
}

// ---------------------------------------------------------------- launch
extern "C" void kernel_launch(void* const* d_in, const int* in_sizes, int n_in,
                              void* d_out, int out_size, void* d_ws, size_t ws_size,
                              hipStream_t stream)
{
    (void)in_sizes; (void)n_in; (void)out_size; (void)ws_size;
    const float* x     = (const float*)d_in[0];
    const float* inw   = (const float*)d_in[1];
    const float* ffnw  = (const float*)d_in[2];
    const float* inpW  = (const float*)d_in[3];
    const float* convW = (const float*)d_in[4];
    const float* convB = (const float*)d_in[5];
    const float* dtW   = (const float*)d_in[6];
    const float* dtB   = (const float*)d_in[7];
    const float* BW    = (const float*)d_in[8];
    const float* CW    = (const float*)d_in[9];
    const float* Alog  = (const float*)d_in[10];
    const float* outpW = (const float*)d_in[11];
    const float* gateW = (const float*)d_in[12];
    const float* upW   = (const float*)d_in[13];
    const float* downW = (const float*)d_in[14];
    float* out = (float*)d_out;

    char* p = (char*)d_ws;
    auto alloc = [&](size_t n) { char* q = p; p += (n + 255) & ~(size_t)255; return q; };
    __bf16* wt_inproj = (__bf16*)alloc(4096ull * 1024 * 2);
    __bf16* wt_dtbc   = (__bf16*)alloc(2176ull * 2048 * 2);  // rows: 0-2047 dt, 2048-2111 B, 2112-2175 C
    __bf16* wt_outp   = (__bf16*)alloc(1024ull * 2048 * 2);
    __bf16* wt_gu     = (__bf16*)alloc(4096ull * 1024 * 2);  // 16-col interleaved gate/up
    __bf16* wt_down   = (__bf16*)alloc(1024ull * 2048 * 2);
    __bf16* normed    = (__bf16*)alloc(2048ull * 1024 * 2);  // reused as n2
    __bf16* xz        = (__bf16*)alloc(2048ull * 2048 * 2);  // x_z half of in_proj
    __bf16* gu_buf    = (__bf16*)alloc(2048ull * 4096 * 2);  // dAp scratch
    __bf16* xc        = (__bf16*)alloc(2048ull * 2048 * 2);  // conv out, reused as y
    float*  scratch16 = (float*)alloc(2048ull * 2048 * 4);   // hend/h0 then ffnmid
    float*  bc        = (float*)alloc(2048ull * 128 * 4);
    float*  dtT       = (float*)alloc(2048ull * 2048 * 4);
    __bf16* xcT       = (__bf16*)alloc(2048ull * 2048 * 2);
    __bf16* szT       = (__bf16*)alloc(2048ull * 2048 * 2);
    float*  x2        = (float*)alloc(2048ull * 1024 * 4);

    dim3 B256(256);
    // batched weight prep (one dispatch); gate/up interleaved at 16-col granularity
    {
        TJobs8 tj;
        int off = 0, ji = 0;
        auto addjob = [&](const float* s, __bf16* d, int R, int C, int S, int mode) {
            tj.j[ji++] = TJob{s, d, R, C, S, C / 32, off, mode};
            off += (C / 32) * (R / 32);
        };
        addjob(inpW,  wt_inproj, 1024, 4096, 4096, 0);
        addjob(dtW,   wt_dtbc,   2048, 2048, 2048, 0);
        addjob(BW,    wt_dtbc + 2048ull * 2048, 2048, 64, 64, 0);
        addjob(CW,    wt_dtbc + 2112ull * 2048, 2048, 64, 64, 0);
        addjob(outpW, wt_outp,   2048, 1024, 1024, 0);
        addjob(gateW, wt_gu,     1024, 2048, 2048, 1);
        addjob(upW,   wt_gu,     1024, 2048, 2048, 2);
        addjob(downW, wt_down,   2048, 1024, 1024, 0);
        wprep_kernel<<<dim3(off), B256, 0, stream>>>(tj);
    }

    // normed = rmsnorm(x, inw)
    rmsnorm_kernel<<<dim3(2048), B256, 0, stream>>>(x, inw, normed);
    // in_proj: xz (t-major bf16) + szT (silu'd z, channel-major)
    gemm_big<4><<<dim3(32, 8), dim3(512), 0, stream>>>(normed, wt_inproj, xz, szT, nullptr, 2048, 4096, 1024);
    // xc = silu(conv(xz) + b), also writes xcT (channel-major) in one pass
    conv_silu_xt_kernel<<<dim3(32, 64), B256, 0, stream>>>(xz, convW, convB, xc, xcT);
    // fused dt+bc: dtT (softplus'd, channel-major f32) + bc (t-major f32, planes)
    gemm_kernel<3, 1><<<dim3(34, 32), B256, 0, stream>>>(xc, wt_dtbc, dtT, bc, dtB, 2048, 2176, 2048);

    // chunked SSM scan
    float* hend = scratch16;                      // 16 MB (E*32*64 f32)
    float* dAp  = (float*)gu_buf;                 // 16 MB
    scan1_kernel<<<dim3(2048), dim3(512), 0, stream>>>(dtT, xcT, bc, Alog, hend, dAp);
    scan_mid_kernel<<<dim3(512), B256, 0, stream>>>(hend, dAp);
    __bf16* y = xc;                               // xc dead after dt GEMM
    scan2_kernel<<<dim3(2048), dim3(512), 0, stream>>>(dtT, xcT, szT, bc, Alog, hend, y);

    // x2 = x + y @ out_proj
    gemm_kernel<2, 0><<<dim3(16, 32), B256, 0, stream>>>(y, wt_outp, x2, nullptr, x, 2048, 1024, 2048);
    // n2 = rmsnorm(x2, ffnw)
    rmsnorm_kernel<<<dim3(2048), B256, 0, stream>>>(x2, ffnw, normed);
    // ffnmid = silu(n2@gate) * (n2@up)  -- fused GLU epilogue
    __bf16* ffnmid = (__bf16*)scratch16;
    gemm_big<5><<<dim3(32, 8), dim3(512), 0, stream>>>(normed, wt_gu, ffnmid, nullptr, nullptr, 2048, 4096, 1024);
    // out = x2 + ffnmid @ down
    gemm_kernel<2, 0><<<dim3(16, 32), B256, 0, stream>>>(ffnmid, wt_down, out, nullptr, x2, 2048, 1024, 2048);
}

// Round 22
// 274.107 us; speedup vs baseline: 2.6965x; 1.0324x over previous
//
#include <hip/hip_runtime.h>
#include <hip/hip_bf16.h>

typedef __bf16 bf16x8 __attribute__((ext_vector_type(8)));
typedef __bf16 bf16x4 __attribute__((ext_vector_type(4)));
typedef float  f32x4  __attribute__((ext_vector_type(4)));
typedef float  f32x2  __attribute__((ext_vector_type(2)));

#define T_TOK 2048
#define DDIM  1024
#define EDIM  2048
#define NCHUNK 32
#define CKLEN  64

__device__ __forceinline__ f32x2 vfma2(f32x2 a, f32x2 b, f32x2 c)
{
#if __has_builtin(__builtin_elementwise_fma)
    return __builtin_elementwise_fma(a, b, c);
#else
    return (f32x2){fmaf(a.x, b.x, c.x), fmaf(a.y, b.y, c.y)};
#endif
}

// exp(w) for w in [-0.15, 0]: degree-3 Taylor, rel err <= 4e-6.
__device__ __forceinline__ f32x2 exps2(f32x2 w)
{
    const f32x2 C6  = {0.166666667f, 0.166666667f};
    const f32x2 CH  = {0.5f, 0.5f};
    const f32x2 ONE = {1.f, 1.f};
    return vfma2(w, vfma2(w, vfma2(w, C6, CH), ONE), ONE);
}

// Fused DPP 16-lane tree sum (lane 15 of each row gets the row total).
// HAZARD-GUARDED: VALU-write -> DPP-read needs 2 wait states (s_nop 1) on
// CDNA; the compiler can't see inside asm, so the nops are explicit.
__device__ __forceinline__ float dpp_sum16(float p)
{
    asm volatile(
        "s_nop 1\n\t"
        "v_add_f32 %0, %0, %0 row_shr:1 bound_ctrl:0\n\t"
        "s_nop 1\n\t"
        "v_add_f32 %0, %0, %0 row_shr:2 bound_ctrl:0\n\t"
        "s_nop 1\n\t"
        "v_add_f32 %0, %0, %0 row_shr:4 bound_ctrl:0\n\t"
        "s_nop 1\n\t"
        "v_add_f32 %0, %0, %0 row_shr:8 bound_ctrl:0"
        : "+v"(p));
    return p;
}

// ---------------------------------------------------------------- batched weight prep
// One dispatch transposes all weight matrices (f32 -> bf16, [N][K] layout).
// mode 0: dst row = src col c.  mode 1: row = 32*(c>>4)+(c&15) (gate interleave).
// mode 2: row = 32*(c>>4)+16+(c&15) (up interleave).
struct TJob { const float* src; __bf16* dst; int R, C, S, tilesX, tileOff, mode; };
struct TJobs8 { TJob j[8]; };

__global__ __launch_bounds__(256)
void wprep_kernel(TJobs8 jobs)
{
    int tile = blockIdx.x;
    int ji = 0;
#pragma unroll
    for (int k = 1; k < 8; ++k) if (tile >= jobs.j[k].tileOff) ji = k;
    const TJob jb = jobs.j[ji];
    int rel = tile - jb.tileOff;
    int bx = rel % jb.tilesX, by = rel / jb.tilesX;
    __shared__ float tilebuf[32][33];
    const int tc0 = bx * 32, tr0 = by * 32;
    const int tx = threadIdx.x & 31, ty = threadIdx.x >> 5;
#pragma unroll
    for (int p = 0; p < 4; ++p) {
        int rl = ty + p * 8;
        tilebuf[rl][tx] = jb.src[(size_t)(tr0 + rl) * jb.S + tc0 + tx];
    }
    __syncthreads();
#pragma unroll
    for (int p = 0; p < 4; ++p) {
        int cl = ty + p * 8;
        float v = tilebuf[tx][cl];
        int c = tc0 + cl, r = tr0 + tx;
        int dr = (jb.mode == 0) ? c
               : ((c >> 4) * 32 + (c & 15) + ((jb.mode == 2) ? 16 : 0));
        jb.dst[(size_t)dr * jb.R + r] = (__bf16)v;
    }
}

// ---------------------------------------------------------------- rmsnorm
__global__ __launch_bounds__(256)
void rmsnorm_kernel(const float* __restrict__ x, const float* __restrict__ w,
                    __bf16* __restrict__ out)
{
    const int row = blockIdx.x;
    const int t = threadIdx.x;
    float4 v = ((const float4*)(x + (size_t)row * DDIM))[t];
    float ss = v.x * v.x + v.y * v.y + v.z * v.z + v.w * v.w;
#pragma unroll
    for (int m = 32; m; m >>= 1) ss += __shfl_xor(ss, m);
    __shared__ float red[4];
    if ((t & 63) == 0) red[t >> 6] = ss;
    __syncthreads();
    float scale = rsqrtf((red[0] + red[1] + red[2] + red[3]) * (1.f / DDIM) + 1e-5f);
    float4 wv = ((const float4*)w)[t];
    __bf16* o = out + (size_t)row * DDIM + t * 4;
    o[0] = (__bf16)(v.x * scale * wv.x);
    o[1] = (__bf16)(v.y * scale * wv.y);
    o[2] = (__bf16)(v.z * scale * wv.z);
    o[3] = (__bf16)(v.w * scale * wv.w);
}

// ---------------------------------------------------------------- conv+silu (+xcT)
__global__ __launch_bounds__(256)
void conv_silu_xt_kernel(const __bf16* __restrict__ xz, const float* __restrict__ W,
                         const float* __restrict__ b, __bf16* __restrict__ xc,
                         __bf16* __restrict__ xcT)
{
    __shared__ __bf16 s_t[32][72];
    const int tid = threadIdx.x;
    const int e0 = blockIdx.x * 64, t0 = blockIdx.y * 32;
    const int tl = tid >> 3, e8 = (tid & 7) * 8;
    const int t = t0 + tl;
    float acc[8];
    {
        float4 b0 = *(const float4*)(b + e0 + e8);
        float4 b1 = *(const float4*)(b + e0 + e8 + 4);
        acc[0] = b0.x; acc[1] = b0.y; acc[2] = b0.z; acc[3] = b0.w;
        acc[4] = b1.x; acc[5] = b1.y; acc[6] = b1.z; acc[7] = b1.w;
    }
#pragma unroll
    for (int k = 0; k < 4; ++k) {
        int tt = t - 1 + k;
        if (tt >= 0 && tt < T_TOK) {
            bf16x8 v = *(const bf16x8*)(xz + (size_t)tt * EDIM + e0 + e8);
            float4 w0 = *(const float4*)(W + k * EDIM + e0 + e8);
            float4 w1 = *(const float4*)(W + k * EDIM + e0 + e8 + 4);
            acc[0] += (float)v[0] * w0.x; acc[1] += (float)v[1] * w0.y;
            acc[2] += (float)v[2] * w0.z; acc[3] += (float)v[3] * w0.w;
            acc[4] += (float)v[4] * w1.x; acc[5] += (float)v[5] * w1.y;
            acc[6] += (float)v[6] * w1.z; acc[7] += (float)v[7] * w1.w;
        }
    }
    bf16x8 o;
#pragma unroll
    for (int j = 0; j < 8; ++j) {
        float s = acc[j];
        o[j] = (__bf16)(s / (1.f + __expf(-s)));
    }
    *(bf16x8*)(xc + (size_t)t * EDIM + e0 + e8) = o;
    *(bf16x8*)&s_t[tl][e8] = o;
    __syncthreads();
    {
        int el = tid >> 2, t8 = (tid & 3) * 8;
        bf16x8 o2;
#pragma unroll
        for (int j = 0; j < 8; ++j) o2[j] = s_t[t8 + j][el];
        *(bf16x8*)(xcT + (size_t)(e0 + el) * T_TOK + t0 + t8) = o2;
    }
}

// ---------------------------------------------------------------- scan
// bc layout (plane-split): bc[t*128 + n] = B[t,n], bc[t*128 + 64 + n] = C[t,n].

// Pass 1: block = 8 waves, 32 channels, one chunk; B-plane only staged.
// Wave w: 4 channels (w*4+g, g=lane>>4), 16 lanes/channel, 4 states/lane.
// dA = exp(dt*A) via degree-3 poly (dt*A in [-0.1,0)); chunk product via exp2.
__global__ __launch_bounds__(512)
void scan1_kernel(const float* __restrict__ dtT, const __bf16* __restrict__ xcT,
                  const float* __restrict__ bc2, const float* __restrict__ A_log,
                  float* __restrict__ hend, float* __restrict__ dAp)
{
    __shared__ float  s_b[CKLEN * 64];     // 16 KB (B-plane)
    __shared__ float  s_dt[32][68];        // padded rows
    __shared__ __bf16 s_x[32][72];         // padded rows
    const int tid = threadIdx.x;
    const int lane = tid & 63, w = tid >> 6;
    const int g = lane >> 4, i = lane & 15;
    const int ck = blockIdx.x & (NCHUNK - 1);
    const int eg = (blockIdx.x >> 5) * 32;

    {
#pragma unroll
        for (int r = 0; r < 2; ++r) {
            int linear = r * 512 + tid;
            int t = linear >> 4, k = linear & 15;
            *(float4*)&s_b[t * 64 + 4 * k] =
                *(const float4*)(bc2 + (size_t)(ck * CKLEN + t) * 128 + 4 * k);
        }
        { int ch = tid >> 4, k = tid & 15;
          *(float4*)&s_dt[ch][4 * k] =
              *(const float4*)(dtT + (size_t)(eg + ch) * T_TOK + ck * CKLEN + 4 * k); }
        if (tid < 256) { int ch = tid >> 3, k = tid & 7;
          *(bf16x8*)&s_x[ch][8 * k] =
              *(const bf16x8*)(xcT + (size_t)(eg + ch) * T_TOK + ck * CKLEN + 8 * k); }
    }
    __syncthreads();

    const int ch = w * 4 + g;
    const int e = eg + ch;
    float4 al4 = *(const float4*)(A_log + 4 * i);
    const f32x2 A01 = {-__expf(al4.x), -__expf(al4.y)};
    const f32x2 A23 = {-__expf(al4.z), -__expf(al4.w)};
    f32x2 h01 = {0.f, 0.f}, h23 = {0.f, 0.f};
    float D = 0.f;

#pragma unroll 2
    for (int t0 = 0; t0 < CKLEN; t0 += 8) {
        float4 da = *(const float4*)&s_dt[ch][t0];
        float4 db = *(const float4*)&s_dt[ch][t0 + 4];
        bf16x8 x8 = *(const bf16x8*)&s_x[ch][t0];
        float dtv[8] = {da.x, da.y, da.z, da.w, db.x, db.y, db.z, db.w};
#pragma unroll
        for (int j = 0; j < 8; ++j) {
            float4 b0 = *(const float4*)&s_b[(t0 + j) * 64 + 4 * i];
            float dt = dtv[j];
            float u = dt * (float)x8[j];
            f32x2 dt2 = {dt, dt};
            f32x2 dA01 = exps2(dt2 * A01);
            f32x2 dA23 = exps2(dt2 * A23);
            f32x2 uu = {u, u};
            h01 = vfma2(dA01, h01, uu * (f32x2){b0.x, b0.y});
            h23 = vfma2(dA23, h23, uu * (f32x2){b0.z, b0.w});
            D += dt;
        }
    }
    const float L2E = 1.44269504f;
    size_t idx = ((size_t)e * NCHUNK + ck) * 64 + 4 * i;
    *(float4*)(hend + idx) = make_float4(h01.x, h01.y, h23.x, h23.y);
    *(float4*)(dAp + idx)  = make_float4(__builtin_amdgcn_exp2f(A01.x * L2E * D),
                                         __builtin_amdgcn_exp2f(A01.y * L2E * D),
                                         __builtin_amdgcn_exp2f(A23.x * L2E * D),
                                         __builtin_amdgcn_exp2f(A23.y * L2E * D));
}

// Mid: serial scan over chunk summaries -> h_start per chunk, IN PLACE over hend.
__global__ __launch_bounds__(256)
void scan_mid_kernel(float* __restrict__ hend_h0, const float* __restrict__ dAp)
{
    int gid = blockIdx.x * 256 + threadIdx.x;     // over E*64
    int e = gid >> 6, n = gid & 63;
    float h = 0.f;
#pragma unroll
    for (int ck = 0; ck < NCHUNK; ++ck) {
        size_t idx = ((size_t)e * NCHUNK + ck) * 64 + n;
        float he = hend_h0[idx];
        float P  = dAp[idx];
        hend_h0[idx] = h;
        h = P * h + he;
    }
}

// Pass 2: block = 8 waves, 32 channels, one chunk; B/C planes staged separately.
__global__ __launch_bounds__(512)
void scan2_kernel(const float* __restrict__ dtT, const __bf16* __restrict__ xcT,
                  const __bf16* __restrict__ szT, const float* __restrict__ bc2,
                  const float* __restrict__ A_log, const float* __restrict__ h0s,
                  __bf16* __restrict__ y)
{
    __shared__ float  s_bp[CKLEN * 64];    // 16 KB (B-plane)
    __shared__ float  s_cp[CKLEN * 64];    // 16 KB (C-plane)
    __shared__ float  s_dt[32][68];        // padded rows
    __shared__ __bf16 s_x[32][72];         // padded rows
    __shared__ __bf16 s_y[CKLEN][36];      // padded, t-major tile
    const int tid = threadIdx.x;
    const int lane = tid & 63, w = tid >> 6;
    const int g = lane >> 4, i = lane & 15;
    const int ck = blockIdx.x & (NCHUNK - 1);
    const int eg = (blockIdx.x >> 5) * 32;

    {
#pragma unroll
        for (int r = 0; r < 2; ++r) {
            int linear = r * 512 + tid;
            int t = linear >> 4, k = linear & 15;
            const float* src = bc2 + (size_t)(ck * CKLEN + t) * 128 + 4 * k;
            *(float4*)&s_bp[t * 64 + 4 * k] = *(const float4*)src;
            *(float4*)&s_cp[t * 64 + 4 * k] = *(const float4*)(src + 64);
        }
        { int ch = tid >> 4, k = tid & 15;
          *(float4*)&s_dt[ch][4 * k] =
              *(const float4*)(dtT + (size_t)(eg + ch) * T_TOK + ck * CKLEN + 4 * k); }
        if (tid < 256) { int ch = tid >> 3, k = tid & 7;
          *(bf16x8*)&s_x[ch][8 * k] =
              *(const bf16x8*)(xcT + (size_t)(eg + ch) * T_TOK + ck * CKLEN + 8 * k); }
    }
    __syncthreads();

    const int ch = w * 4 + g;
    const int e = eg + ch;
    float4 al4 = *(const float4*)(A_log + 4 * i);
    const f32x2 A01 = {-__expf(al4.x), -__expf(al4.y)};
    const f32x2 A23 = {-__expf(al4.z), -__expf(al4.w)};
    float4 hh = *(const float4*)(h0s + ((size_t)e * NCHUNK + ck) * 64 + 4 * i);
    f32x2 h01 = {hh.x, hh.y}, h23 = {hh.z, hh.w};

#pragma unroll 2
    for (int t0 = 0; t0 < CKLEN; t0 += 8) {
        float4 da = *(const float4*)&s_dt[ch][t0];
        float4 db = *(const float4*)&s_dt[ch][t0 + 4];
        bf16x8 x8 = *(const bf16x8*)&s_x[ch][t0];
        float dtv[8] = {da.x, da.y, da.z, da.w, db.x, db.y, db.z, db.w};
#pragma unroll
        for (int j = 0; j < 8; ++j) {
            float4 b0 = *(const float4*)&s_bp[(t0 + j) * 64 + 4 * i];
            float4 c0 = *(const float4*)&s_cp[(t0 + j) * 64 + 4 * i];
            float dt = dtv[j];
            float u = dt * (float)x8[j];
            f32x2 dt2 = {dt, dt};
            f32x2 dA01 = exps2(dt2 * A01);
            f32x2 dA23 = exps2(dt2 * A23);
            f32x2 uu = {u, u};
            h01 = vfma2(dA01, h01, uu * (f32x2){b0.x, b0.y});
            h23 = vfma2(dA23, h23, uu * (f32x2){b0.z, b0.w});
            f32x2 pp = h01 * (f32x2){c0.x, c0.y};
            pp = vfma2(h23, (f32x2){c0.z, c0.w}, pp);
            float p = pp.x + pp.y;
            p = dpp_sum16(p);
            if (i == 15) s_y[t0 + j][ch] = (__bf16)p;
        }
    }
    __syncthreads();

    {
        int tt = tid >> 3, q = tid & 7;
        bf16x4 o;
#pragma unroll
        for (int d = 0; d < 4; ++d) {
            float zv = (float)szT[(size_t)(eg + 4 * q + d) * T_TOK + ck * CKLEN + tt];
            o[d] = (__bf16)((float)s_y[tt][4 * q + d] * zv);
        }
        *(bf16x4*)(y + (size_t)(ck * CKLEN + tt) * EDIM + eg + 4 * q) = o;
    }
}

// ---------------------------------------------------------------- GEMM common
__device__ __forceinline__ void glds16(const __bf16* g, __bf16* l)
{
    __builtin_amdgcn_global_load_lds(
        (const __attribute__((address_space(1))) unsigned*)g,
        (__attribute__((address_space(3))) unsigned*)l, 16, 0, 0);
}

template<int EPI>
__device__ __forceinline__ void gemm_epilogue(
    const f32x4& a, int row, int col, int N,
    void* Cout, void* Cout2, const float* res)
{
    if (EPI == 1) {
#pragma unroll
        for (int i = 0; i < 4; ++i)
            ((__bf16*)Cout)[(size_t)(row + i) * N + col] = (__bf16)a[i];
    } else if (EPI == 2) {
#pragma unroll
        for (int i = 0; i < 4; ++i) {
            size_t off = (size_t)(row + i) * N + col;
            ((float*)Cout)[off] = a[i] + res[off];
        }
    } else if (EPI == 3) {
        if (col < 2048) {
            float bias = res[col];
            float4 v;
            float* vv = (float*)&v;
#pragma unroll
            for (int i = 0; i < 4; ++i) {
                float s = a[i] + bias;
                s = (s > 20.f) ? s : log1pf(__expf(s));
                vv[i] = fminf(fmaxf(s, 0.001f), 0.1f);
            }
            *(float4*)((float*)Cout + (size_t)col * T_TOK + row) = v;
        } else {
#pragma unroll
            for (int i = 0; i < 4; ++i)
                ((float*)Cout2)[(size_t)(row + i) * 128 + (col - 2048)] = a[i];
        }
    } else if (EPI == 4) {
        if (col < 2048) {
#pragma unroll
            for (int i = 0; i < 4; ++i)
                ((__bf16*)Cout)[(size_t)(row + i) * EDIM + col] = (__bf16)a[i];
        } else {
            bf16x4 v;
#pragma unroll
            for (int i = 0; i < 4; ++i) {
                float s = a[i];
                v[i] = (__bf16)(s / (1.f + __expf(-s)));
            }
            *(bf16x4*)((__bf16*)Cout2 + (size_t)(col - 2048) * T_TOK + row) = v;
        }
    }
}

// 4-wave GEMM: 64 x TN tile (TN = 64 or 128), BK=64, 2-phase,
// 8-chunk XOR-swizzled LDS.  TN=64: 32 KB LDS -> 5 blocks/CU (occupancy for
// small-N shapes).  TN=128: 48 KB LDS, 16 MFMA/wave/K-step (density for
// large-grid shapes).  SWZ<1>: XCD-contiguous block remap (grid mult of 8).
template<int EPI, int TN, int SWZ>
__global__ __launch_bounds__(256)
void gemm_kernel(const __bf16* __restrict__ A, const __bf16* __restrict__ Bt,
                 void* __restrict__ Cout, void* __restrict__ Cout2,
                 const float* __restrict__ res, int M, int N, int K)
{
    constexpr int NF = TN / 32;            // n-frags per wave
    constexpr int BQ = TN / 32;            // B glds16 per wave per stage
    __shared__ __bf16 sAl[2 * 64 * 64];    // 16 KB
    __shared__ __bf16 sBl[2 * TN * 64];    // 16 or 32 KB
    const int t = threadIdx.x;
    const int wave = t >> 6, lane = t & 63;
    int bx = blockIdx.x, by = blockIdx.y;
    if (SWZ) {
        int nwg = gridDim.x * gridDim.y;
        int bid = by * gridDim.x + bx;
        int cpx = nwg >> 3;
        int swz = (bid & 7) * cpx + (bid >> 3);
        bx = swz % gridDim.x;
        by = swz / gridDim.x;
    }
    const int brow = by * 64, bcol = bx * TN;
    const int wr = (wave >> 1) * 32, wc = (wave & 1) * (TN / 2);
    f32x4 acc[2][NF] = {};

    // staging source: lane -> row +(lane>>3), chunk (lane&7)^(lane>>3)
    const int rl8 = lane >> 3;
    const int ck8 = (lane & 7) ^ rl8;
    const __bf16* gA = A  + (size_t)(brow + wave * 16 + rl8) * K + ck8 * 8;
    const __bf16* gB = Bt + (size_t)(bcol + wave * (TN / 4) + rl8) * K + ck8 * 8;

    auto stage = [&](int buf, int k0) {
        __bf16* ba = sAl + buf * (64 * 64) + (wave * 16) * 64;
        __bf16* bb = sBl + buf * (TN * 64) + (wave * (TN / 4)) * 64;
#pragma unroll
        for (int q = 0; q < 2; ++q)
            glds16(gA + (size_t)(q * 8) * K + k0, ba + q * 8 * 64);
#pragma unroll
        for (int q = 0; q < BQ; ++q)
            glds16(gB + (size_t)(q * 8) * K + k0, bb + q * 8 * 64);
    };

    stage(0, 0);
    int cur = 0;
    for (int k0 = 0; k0 < K; k0 += 64) {
        __syncthreads();                  // staged tile landed; other buf free
        if (k0 + 64 < K) stage(cur ^ 1, k0 + 64);
        const __bf16* At = sAl + cur * (64 * 64);
        const __bf16* Btl = sBl + cur * (TN * 64);
#pragma unroll
        for (int ks = 0; ks < 2; ++ks) {
            const int rc = (((ks * 4 + (lane >> 4)) ^ (lane & 7))) * 8;
            bf16x8 af[2], bg[NF];
#pragma unroll
            for (int m = 0; m < 2; ++m)
                af[m] = *(const bf16x8*)&At[(wr + m * 16 + (lane & 15)) * 64 + rc];
#pragma unroll
            for (int n = 0; n < NF; ++n)
                bg[n] = *(const bf16x8*)&Btl[(wc + n * 16 + (lane & 15)) * 64 + rc];
#pragma unroll
            for (int m = 0; m < 2; ++m)
#pragma unroll
                for (int n = 0; n < NF; ++n)
                    acc[m][n] = __builtin_amdgcn_mfma_f32_16x16x32_bf16(
                        af[m], bg[n], acc[m][n], 0, 0, 0);
        }
        cur ^= 1;
    }

    const int c_l = lane & 15, r_l = (lane >> 4) * 4;
#pragma unroll
    for (int m = 0; m < 2; ++m)
#pragma unroll
        for (int n = 0; n < NF; ++n)
            gemm_epilogue<EPI>(acc[m][n], brow + wr + m * 16 + r_l,
                               bcol + wc + n * 16 + c_l, N, Cout, Cout2, res);
}

// 8-wave big GEMM: 256 x 128 tile, BK=64, 2-phase, XOR chunk-swizzled LDS.
// EPI 5: fused GLU (16-col interleaved gate/up weights).
template<int EPI>
__global__ __launch_bounds__(512)
void gemm_big(const __bf16* __restrict__ A, const __bf16* __restrict__ Bt,
              void* __restrict__ Cout, void* __restrict__ Cout2,
              const float* __restrict__ res, int M, int N, int K)
{
    __shared__ __bf16 sAl[2 * 256 * 64];   // 64 KB
    __shared__ __bf16 sBl[2 * 128 * 64];   // 32 KB
    const int t = threadIdx.x;
    const int w = t >> 6, lane = t & 63;
    const int brow = blockIdx.y * 256, bcol = blockIdx.x * 128;
    const int wr = (w >> 1) * 64, wc = (w & 1) * 64;
    f32x4 acc[4][4] = {};

    const int rl8 = lane >> 3;
    const int ck8 = (lane & 7) ^ rl8;
    const __bf16* gA = A  + (size_t)(brow + w * 32 + rl8) * K + ck8 * 8;
    const __bf16* gB = Bt + (size_t)(bcol + w * 16 + rl8) * K + ck8 * 8;

    auto stage = [&](int buf, int k0) {
        __bf16* ba = sAl + buf * (256 * 64) + (w * 32) * 64;
        __bf16* bb = sBl + buf * (128 * 64) + (w * 16) * 64;
#pragma unroll
        for (int q = 0; q < 4; ++q)
            glds16(gA + (size_t)(q * 8) * K + k0, ba + q * 8 * 64);
#pragma unroll
        for (int q = 0; q < 2; ++q)
            glds16(gB + (size_t)(q * 8) * K + k0, bb + q * 8 * 64);
    };

    stage(0, 0);
    int cur = 0;
    for (int k0 = 0; k0 < K; k0 += 64) {
        __syncthreads();
        if (k0 + 64 < K) stage(cur ^ 1, k0 + 64);
        const __bf16* At = sAl + cur * (256 * 64);
        const __bf16* Btl = sBl + cur * (128 * 64);
#pragma unroll
        for (int ks = 0; ks < 2; ++ks) {
            const int rchk = (((ks * 4 + (lane >> 4)) ^ (lane & 7))) * 8;
            bf16x8 af[4], bg[4];
#pragma unroll
            for (int m = 0; m < 4; ++m)
                af[m] = *(const bf16x8*)&At[(wr + m * 16 + (lane & 15)) * 64 + rchk];
#pragma unroll
            for (int n = 0; n < 4; ++n)
                bg[n] = *(const bf16x8*)&Btl[(wc + n * 16 + (lane & 15)) * 64 + rchk];
#pragma unroll
            for (int m = 0; m < 4; ++m)
#pragma unroll
                for (int n = 0; n < 4; ++n)
                    acc[m][n] = __builtin_amdgcn_mfma_f32_16x16x32_bf16(
                        af[m], bg[n], acc[m][n], 0, 0, 0);
        }
        cur ^= 1;
    }

    const int c_l = lane & 15, r_l = (lane >> 4) * 4;
    if constexpr (EPI == 5) {
#pragma unroll
        for (int m = 0; m < 4; ++m) {
#pragma unroll
            for (int n = 0; n < 4; n += 2) {
                int row = brow + wr + m * 16 + r_l;
                int fcol = (((bcol + wc + n * 16) >> 5) << 4) + c_l;
#pragma unroll
                for (int i = 0; i < 4; ++i) {
                    float gg = acc[m][n][i];
                    float uu = acc[m][n + 1][i];
                    ((__bf16*)Cout)[(size_t)(row + i) * 2048 + fcol] =
                        (__bf16)(gg / (1.f + __expf(-gg)) * uu);
                }
            }
        }
    } else {
#pragma unroll
        for (int m = 0; m < 4; ++m)
#pragma unroll
            for (int n = 0; n < 4; ++n)
                gemm_epilogue<EPI>(acc[m][n], brow + wr + m * 16 + r_l,
                                   bcol + wc + n * 16 + c_l, N, Cout, Cout2, res);
    }
}

// ---------------------------------------------------------------- launch
extern "C" void kernel_launch(void* const* d_in, const int* in_sizes, int n_in,
                              void* d_out, int out_size, void* d_ws, size_t ws_size,
                              hipStream_t stream)
{
    (void)in_sizes; (void)n_in; (void)out_size; (void)ws_size;
    const float* x     = (const float*)d_in[0];
    const float* inw   = (const float*)d_in[1];
    const float* ffnw  = (const float*)d_in[2];
    const float* inpW  = (const float*)d_in[3];
    const float* convW = (const float*)d_in[4];
    const float* convB = (const float*)d_in[5];
    const float* dtW   = (const float*)d_in[6];
    const float* dtB   = (const float*)d_in[7];
    const float* BW    = (const float*)d_in[8];
    const float* CW    = (const float*)d_in[9];
    const float* Alog  = (const float*)d_in[10];
    const float* outpW = (const float*)d_in[11];
    const float* gateW = (const float*)d_in[12];
    const float* upW   = (const float*)d_in[13];
    const float* downW = (const float*)d_in[14];
    float* out = (float*)d_out;

    char* p = (char*)d_ws;
    auto alloc = [&](size_t n) { char* q = p; p += (n + 255) & ~(size_t)255; return q; };
    __bf16* wt_inproj = (__bf16*)alloc(4096ull * 1024 * 2);
    __bf16* wt_dtbc   = (__bf16*)alloc(2176ull * 2048 * 2);  // rows: 0-2047 dt, 2048-2111 B, 2112-2175 C
    __bf16* wt_outp   = (__bf16*)alloc(1024ull * 2048 * 2);
    __bf16* wt_gu     = (__bf16*)alloc(4096ull * 1024 * 2);  // 16-col interleaved gate/up
    __bf16* wt_down   = (__bf16*)alloc(1024ull * 2048 * 2);
    __bf16* normed    = (__bf16*)alloc(2048ull * 1024 * 2);  // reused as n2
    __bf16* xz        = (__bf16*)alloc(2048ull * 2048 * 2);  // x_z half of in_proj
    __bf16* gu_buf    = (__bf16*)alloc(2048ull * 4096 * 2);  // dAp scratch
    __bf16* xc        = (__bf16*)alloc(2048ull * 2048 * 2);  // conv out, reused as y
    float*  scratch16 = (float*)alloc(2048ull * 2048 * 4);   // hend/h0 then ffnmid
    float*  bc        = (float*)alloc(2048ull * 128 * 4);
    float*  dtT       = (float*)alloc(2048ull * 2048 * 4);
    __bf16* xcT       = (__bf16*)alloc(2048ull * 2048 * 2);
    __bf16* szT       = (__bf16*)alloc(2048ull * 2048 * 2);
    float*  x2        = (float*)alloc(2048ull * 1024 * 4);

    dim3 B256(256);
    // batched weight prep (one dispatch); gate/up interleaved at 16-col granularity
    {
        TJobs8 tj;
        int off = 0, ji = 0;
        auto addjob = [&](const float* s, __bf16* d, int R, int C, int S, int mode) {
            tj.j[ji++] = TJob{s, d, R, C, S, C / 32, off, mode};
            off += (C / 32) * (R / 32);
        };
        addjob(inpW,  wt_inproj, 1024, 4096, 4096, 0);
        addjob(dtW,   wt_dtbc,   2048, 2048, 2048, 0);
        addjob(BW,    wt_dtbc + 2048ull * 2048, 2048, 64, 64, 0);
        addjob(CW,    wt_dtbc + 2112ull * 2048, 2048, 64, 64, 0);
        addjob(outpW, wt_outp,   2048, 1024, 1024, 0);
        addjob(gateW, wt_gu,     1024, 2048, 2048, 1);
        addjob(upW,   wt_gu,     1024, 2048, 2048, 2);
        addjob(downW, wt_down,   2048, 1024, 1024, 0);
        wprep_kernel<<<dim3(off), B256, 0, stream>>>(tj);
    }

    // normed = rmsnorm(x, inw)
    rmsnorm_kernel<<<dim3(2048), B256, 0, stream>>>(x, inw, normed);
    // in_proj: xz (t-major bf16) + szT (silu'd z, channel-major)
    gemm_big<4><<<dim3(32, 8), dim3(512), 0, stream>>>(normed, wt_inproj, xz, szT, nullptr, 2048, 4096, 1024);
    // xc = silu(conv(xz) + b), also writes xcT (channel-major) in one pass
    conv_silu_xt_kernel<<<dim3(32, 64), B256, 0, stream>>>(xz, convW, convB, xc, xcT);
    // fused dt+bc: dtT (softplus'd, channel-major f32) + bc (t-major f32, planes)
    gemm_kernel<3, 128, 1><<<dim3(17, 32), B256, 0, stream>>>(xc, wt_dtbc, dtT, bc, dtB, 2048, 2176, 2048);

    // chunked SSM scan
    float* hend = scratch16;                      // 16 MB (E*32*64 f32)
    float* dAp  = (float*)gu_buf;                 // 16 MB
    scan1_kernel<<<dim3(2048), dim3(512), 0, stream>>>(dtT, xcT, bc, Alog, hend, dAp);
    scan_mid_kernel<<<dim3(512), B256, 0, stream>>>(hend, dAp);
    __bf16* y = xc;                               // xc dead after dt GEMM
    scan2_kernel<<<dim3(2048), dim3(512), 0, stream>>>(dtT, xcT, szT, bc, Alog, hend, y);

    // x2 = x + y @ out_proj
    gemm_kernel<2, 64, 1><<<dim3(16, 32), B256, 0, stream>>>(y, wt_outp, x2, nullptr, x, 2048, 1024, 2048);
    // n2 = rmsnorm(x2, ffnw)
    rmsnorm_kernel<<<dim3(2048), B256, 0, stream>>>(x2, ffnw, normed);
    // ffnmid = silu(n2@gate) * (n2@up)  -- fused GLU epilogue
    __bf16* ffnmid = (__bf16*)scratch16;
    gemm_big<5><<<dim3(32, 8), dim3(512), 0, stream>>>(normed, wt_gu, ffnmid, nullptr, nullptr, 2048, 4096, 1024);
    // out = x2 + ffnmid @ down
    gemm_kernel<2, 64, 1><<<dim3(16, 32), B256, 0, stream>>>(ffnmid, wt_down, out, nullptr, x2, 2048, 1024, 2048);
}